// Round 1
// baseline (7797.276 us; speedup 1.0000x reference)
//
#include <hip/hip_runtime.h>
#include <hip/hip_bf16.h>

// ============================================================================
// VQ-VAE forward, fp32 everywhere (round 1: correctness + baseline profile).
//
// Pipeline (all NCHW, all fp32):
//   conv0 3->64   64x64 -> 32x32  relu      (stride2 pad1 k4)
//   conv1 64->64  32x32 -> 16x16  relu
//   conv2 64->128 16x16 -> 8x8    relu
//   conv3 128->256 8x8  -> 4x4    (no relu)
//   fc0 4096->1024 relu ; fc1 1024->1024 relu ; fc2 1024->1536
//   VQ: z[:, :1024] as (4096,64) rows vs codebook (512,64); argmin (first-min
//       tie-break); e = [codebook[idx], z[:,1024:]]; loss = 1.25*mean(min d^2)
//   g0 1536->512 relu ; g1 512->1024 relu ; g2 1024->4096
//   t0 256->128 4x4->8x8 relu ... t3 64->3 32x32->64x64 (no relu)  (convT s2 p1 k4)
//
// Workspace layout (float offsets), peak 20,975,616 floats = 83.9 MB:
//   H0=0(16.78M) H1=16.78M(4.19M) H2=0 H3=16.78M F0=0 F1=16.78M Z=0 E=16.78M
//   G0=0 G1=16.78M G2=0 T0=16.78M T1=0 T2=4,194,304(16.78M) RL=20,971,520(4096)
// Every producer/consumer pair is disjoint; every buffer fully written before
// it is read (harness poison-safe). No atomics -> deterministic.
// ============================================================================

#define TPB 256

// ---------------- strided conv (stride 2, pad 1, k=4), 2x2 outputs/thread ---
__global__ __launch_bounds__(TPB) void conv_s2_kernel(
    const float* __restrict__ in, const float* __restrict__ w,
    const float* __restrict__ bias, float* __restrict__ out,
    int Bn, int Ci, int Co, int Hi, int Wi, int relu)
{
  const int Ho = Hi >> 1, Wo = Wi >> 1;
  const int Hc = Ho >> 1, Wc = Wo >> 1;
  const int co = blockIdx.y;
  const int cell = blockIdx.x * TPB + threadIdx.x;
  const int ncell = Bn * Hc * Wc;
  if (cell >= ncell) return;
  const int cx = cell % Wc;
  int t = cell / Wc;
  const int cy = t % Hc;
  const int b = t / Hc;
  const int HW = Hi * Wi;
  const float* ip = in + (size_t)b * Ci * HW;
  const float* wp = w + (size_t)co * Ci * 16;
  const int ybase = cy * 4 - 1;
  const int xbase = cx * 4 - 1;

  int ro[6], cofs[6];
  float mr[6], mcol[6], m[6][6];
#pragma unroll
  for (int r = 0; r < 6; ++r) {
    int gy = ybase + r;
    int gyc = min(max(gy, 0), Hi - 1);
    ro[r] = gyc * Wi;
    mr[r] = (gy >= 0 && gy < Hi) ? 1.f : 0.f;
  }
#pragma unroll
  for (int c = 0; c < 6; ++c) {
    int gx = xbase + c;
    int gxc = min(max(gx, 0), Wi - 1);
    cofs[c] = gxc;
    mcol[c] = (gx >= 0 && gx < Wi) ? 1.f : 0.f;
  }
#pragma unroll
  for (int r = 0; r < 6; ++r)
#pragma unroll
    for (int c = 0; c < 6; ++c) m[r][c] = mr[r] * mcol[c];

  float a00 = 0.f, a01 = 0.f, a10 = 0.f, a11 = 0.f;
  for (int ci = 0; ci < Ci; ++ci) {
    const float* iq = ip + ci * HW;
    const float* wq = wp + ci * 16;   // uniform across wave -> scalar loads
    float iv[6][6];
#pragma unroll
    for (int r = 0; r < 6; ++r)
#pragma unroll
      for (int c = 0; c < 6; ++c)
        iv[r][c] = iq[ro[r] + cofs[c]] * m[r][c];
#pragma unroll
    for (int kh = 0; kh < 4; ++kh)
#pragma unroll
      for (int kw = 0; kw < 4; ++kw) {
        float wv = wq[kh * 4 + kw];
        a00 = fmaf(iv[kh][kw],         wv, a00);
        a01 = fmaf(iv[kh][kw + 2],     wv, a01);
        a10 = fmaf(iv[kh + 2][kw],     wv, a10);
        a11 = fmaf(iv[kh + 2][kw + 2], wv, a11);
      }
  }
  const float bv = bias[co];
  a00 += bv; a01 += bv; a10 += bv; a11 += bv;
  if (relu) {
    a00 = fmaxf(a00, 0.f); a01 = fmaxf(a01, 0.f);
    a10 = fmaxf(a10, 0.f); a11 = fmaxf(a11, 0.f);
  }
  const int y0 = cy * 2, x0 = cx * 2;
  float* op = out + (((size_t)b * Co + co) * Ho + y0) * Wo + x0;
  *reinterpret_cast<float2*>(op)      = make_float2(a00, a01);
  *reinterpret_cast<float2*>(op + Wo) = make_float2(a10, a11);
}

// ------------- transposed conv (stride 2, pad 1, k=4), 2x2 outputs/thread ---
// out(2Y+py, 2X+px) taps: py=0: kh=1->iy=Y, kh=3->iy=Y-1 ; py=1: kh=0->Y+1, kh=2->Y
__global__ __launch_bounds__(TPB) void convt_kernel(
    const float* __restrict__ in, const float* __restrict__ w,
    const float* __restrict__ bias, float* __restrict__ out,
    int Bn, int Ci, int Co, int Hi, int Wi, int relu)
{
  const int Ho = Hi * 2, Wo = Wi * 2;
  const int o = blockIdx.y;
  const int cell = blockIdx.x * TPB + threadIdx.x;
  const int ncell = Bn * Hi * Wi;
  if (cell >= ncell) return;
  const int X = cell % Wi;
  int t = cell / Wi;
  const int Y = t % Hi;
  const int b = t / Hi;
  const int HW = Hi * Wi;
  const float* ip = in + (size_t)b * Ci * HW;
  const float* wq0 = w + (size_t)o * 16;   // w[ci][o][kh][kw], stride Co*16 per ci
  const int wstride = Co * 16;

  int ro[3], cofs[3];
  float m[3][3];
#pragma unroll
  for (int j = 0; j < 3; ++j) {
    int gy = Y - 1 + j;
    int gyc = min(max(gy, 0), Hi - 1);
    ro[j] = gyc * Wi;
    float my = (gy >= 0 && gy < Hi) ? 1.f : 0.f;
    int gx = X - 1 + j;
    int gxc = min(max(gx, 0), Wi - 1);
    cofs[j] = gxc;
    m[j][0] = my;   // temp: store row mask; col mask folded below
  }
  {
    float mc[3];
#pragma unroll
    for (int j = 0; j < 3; ++j) {
      int gx = X - 1 + j;
      mc[j] = (gx >= 0 && gx < Wi) ? 1.f : 0.f;
    }
    float mrow[3] = { m[0][0], m[1][0], m[2][0] };
#pragma unroll
    for (int j = 0; j < 3; ++j)
#pragma unroll
      for (int k = 0; k < 3; ++k) m[j][k] = mrow[j] * mc[k];
  }

  float a00 = 0.f, a01 = 0.f, a10 = 0.f, a11 = 0.f;
  for (int ci = 0; ci < Ci; ++ci) {
    const float* iq = ip + ci * HW;
    const float* wq = wq0 + (size_t)ci * wstride;  // uniform -> scalar loads
    float iv[3][3];
#pragma unroll
    for (int j = 0; j < 3; ++j)
#pragma unroll
      for (int k = 0; k < 3; ++k)
        iv[j][k] = iq[ro[j] + cofs[k]] * m[j][k];
    // iv[j][k] = in(Y-1+j, X-1+k)
    a00 = fmaf(iv[1][1], wq[5],  a00);   // w(1,1)
    a00 = fmaf(iv[1][0], wq[7],  a00);   // w(1,3)
    a00 = fmaf(iv[0][1], wq[13], a00);   // w(3,1)
    a00 = fmaf(iv[0][0], wq[15], a00);   // w(3,3)
    a01 = fmaf(iv[1][2], wq[4],  a01);   // w(1,0)
    a01 = fmaf(iv[1][1], wq[6],  a01);   // w(1,2)
    a01 = fmaf(iv[0][2], wq[12], a01);   // w(3,0)
    a01 = fmaf(iv[0][1], wq[14], a01);   // w(3,2)
    a10 = fmaf(iv[2][1], wq[1],  a10);   // w(0,1)
    a10 = fmaf(iv[2][0], wq[3],  a10);   // w(0,3)
    a10 = fmaf(iv[1][1], wq[9],  a10);   // w(2,1)
    a10 = fmaf(iv[1][0], wq[11], a10);   // w(2,3)
    a11 = fmaf(iv[2][2], wq[0],  a11);   // w(0,0)
    a11 = fmaf(iv[2][1], wq[2],  a11);   // w(0,2)
    a11 = fmaf(iv[1][2], wq[8],  a11);   // w(2,0)
    a11 = fmaf(iv[1][1], wq[10], a11);   // w(2,2)
  }
  const float bv = bias[o];
  a00 += bv; a01 += bv; a10 += bv; a11 += bv;
  if (relu) {
    a00 = fmaxf(a00, 0.f); a01 = fmaxf(a01, 0.f);
    a10 = fmaxf(a10, 0.f); a11 = fmaxf(a11, 0.f);
  }
  float* op = out + (((size_t)b * Co + o) * Ho + 2 * Y) * Wo + 2 * X;
  *reinterpret_cast<float2*>(op)      = make_float2(a00, a01);
  *reinterpret_cast<float2*>(op + Wo) = make_float2(a10, a11);
}

// ---------------- GEMM: C[M,N] = A[M,K] @ W[K,N] + bias, optional relu ------
// 32x64 tile, BK=32, 256 threads, 2x4 outputs/thread.
__global__ __launch_bounds__(TPB) void gemm_kernel(
    const float* __restrict__ A, const float* __restrict__ W,
    const float* __restrict__ bias, float* __restrict__ C,
    int M, int K, int N, int relu)
{
  __shared__ float As[32][33];   // [k][m], padded
  __shared__ float Ws[32][64];   // [k][n]
  const int tid = threadIdx.x;
  const int m0 = blockIdx.x * 32;
  const int n0 = blockIdx.y * 64;
  const int tr = tid >> 4;       // 0..15
  const int tc = tid & 15;       // 0..15
  float acc[2][4] = {{0.f, 0.f, 0.f, 0.f}, {0.f, 0.f, 0.f, 0.f}};

  for (int kt = 0; kt < K; kt += 32) {
#pragma unroll
    for (int i = 0; i < 4; ++i) {
      int lin = i * TPB + tid;
      int mm = lin >> 5, kk = lin & 31;
      As[kk][mm] = A[(size_t)(m0 + mm) * K + kt + kk];
    }
#pragma unroll
    for (int i = 0; i < 8; ++i) {
      int lin = i * TPB + tid;
      int kk = lin >> 6, nn = lin & 63;
      Ws[kk][nn] = W[(size_t)(kt + kk) * N + n0 + nn];
    }
    __syncthreads();
#pragma unroll
    for (int k = 0; k < 32; ++k) {
      float a0 = As[k][tr];
      float a1 = As[k][tr + 16];
      const float4 wv = *reinterpret_cast<const float4*>(&Ws[k][tc << 2]);
      acc[0][0] = fmaf(a0, wv.x, acc[0][0]);
      acc[0][1] = fmaf(a0, wv.y, acc[0][1]);
      acc[0][2] = fmaf(a0, wv.z, acc[0][2]);
      acc[0][3] = fmaf(a0, wv.w, acc[0][3]);
      acc[1][0] = fmaf(a1, wv.x, acc[1][0]);
      acc[1][1] = fmaf(a1, wv.y, acc[1][1]);
      acc[1][2] = fmaf(a1, wv.z, acc[1][2]);
      acc[1][3] = fmaf(a1, wv.w, acc[1][3]);
    }
    __syncthreads();
  }
#pragma unroll
  for (int i = 0; i < 2; ++i) {
    int mrow = m0 + tr + i * 16;
    float* cp = C + (size_t)mrow * N + n0 + (tc << 2);
#pragma unroll
    for (int j = 0; j < 4; ++j) {
      float v = acc[i][j] + bias[n0 + (tc << 2) + j];
      if (relu) v = fmaxf(v, 0.f);
      cp[j] = v;
    }
  }
}

// ---------------- VQ: one block per 64-dim row --------------------------------
__global__ __launch_bounds__(TPB) void vq_kernel(
    const float* __restrict__ z, const float* __restrict__ cb,
    float* __restrict__ e, float* __restrict__ rowloss)
{
  const int row = blockIdx.x;          // 0..4095  (b*16 + s)
  const int b = row >> 4, s = row & 15;
  __shared__ float zr[64];
  __shared__ float bval[TPB];
  __shared__ int   bidx[TPB];
  const int tid = threadIdx.x;
  if (tid < 64) zr[tid] = z[(size_t)b * 1536 + s * 64 + tid];
  __syncthreads();

  float best = 3.4e38f;
  int bi = 0;
#pragma unroll
  for (int rep = 0; rep < 2; ++rep) {
    int j = tid + rep * TPB;           // ascending -> first-min tie-break
    const float4* c4 = reinterpret_cast<const float4*>(cb + (size_t)j * 64);
    float d = 0.f;
#pragma unroll
    for (int k = 0; k < 16; ++k) {
      float4 cv = c4[k];
      float t0 = zr[4 * k + 0] - cv.x;
      float t1 = zr[4 * k + 1] - cv.y;
      float t2 = zr[4 * k + 2] - cv.z;
      float t3 = zr[4 * k + 3] - cv.w;
      d = fmaf(t0, t0, d); d = fmaf(t1, t1, d);
      d = fmaf(t2, t2, d); d = fmaf(t3, t3, d);
    }
    if (d < best) { best = d; bi = j; }
  }
  bval[tid] = best; bidx[tid] = bi;
  __syncthreads();
  for (int sft = 128; sft > 0; sft >>= 1) {
    if (tid < sft) {
      float v2 = bval[tid + sft]; int i2 = bidx[tid + sft];
      if (v2 < bval[tid] || (v2 == bval[tid] && i2 < bidx[tid])) {
        bval[tid] = v2; bidx[tid] = i2;
      }
    }
    __syncthreads();
  }
  const int bj = bidx[0];
  if (tid < 64)
    e[(size_t)b * 1536 + s * 64 + tid] = cb[(size_t)bj * 64 + tid];
  if (tid == 0) rowloss[row] = bval[0];
}

__global__ __launch_bounds__(TPB) void zs_copy_kernel(
    const float* __restrict__ z, float* __restrict__ e)
{
  int i = blockIdx.x * TPB + threadIdx.x;   // 0..131071
  int b = i >> 9, k = i & 511;
  e[(size_t)b * 1536 + 1024 + k] = z[(size_t)b * 1536 + 1024 + k];
}

__global__ __launch_bounds__(TPB) void loss_reduce_kernel(
    const float* __restrict__ rl, float* __restrict__ out)
{
  __shared__ float sm[TPB];
  float s = 0.f;
  for (int i = threadIdx.x; i < 4096; i += TPB) s += rl[i];
  sm[threadIdx.x] = s;
  __syncthreads();
  for (int sft = 128; sft > 0; sft >>= 1) {
    if (threadIdx.x < sft) sm[threadIdx.x] += sm[threadIdx.x + sft];
    __syncthreads();
  }
  if (threadIdx.x == 0) out[0] = sm[0] * (1.25f / 262144.f);
}

// ============================================================================
extern "C" void kernel_launch(void* const* d_in, const int* in_sizes, int n_in,
                              void* d_out, int out_size, void* d_ws, size_t ws_size,
                              hipStream_t stream)
{
  const float* x    = (const float*)d_in[0];
  const float* ew0  = (const float*)d_in[1];
  const float* eb0  = (const float*)d_in[2];
  const float* ew1  = (const float*)d_in[3];
  const float* eb1  = (const float*)d_in[4];
  const float* ew2  = (const float*)d_in[5];
  const float* eb2  = (const float*)d_in[6];
  const float* ew3  = (const float*)d_in[7];
  const float* eb3  = (const float*)d_in[8];
  const float* fw0  = (const float*)d_in[9];
  const float* fb0  = (const float*)d_in[10];
  const float* fw1  = (const float*)d_in[11];
  const float* fb1  = (const float*)d_in[12];
  const float* fw2  = (const float*)d_in[13];
  const float* fb2  = (const float*)d_in[14];
  const float* cb   = (const float*)d_in[15];
  const float* gw0  = (const float*)d_in[16];
  const float* gb0  = (const float*)d_in[17];
  const float* gw1  = (const float*)d_in[18];
  const float* gb1  = (const float*)d_in[19];
  const float* gw2  = (const float*)d_in[20];
  const float* gb2  = (const float*)d_in[21];
  const float* tw0  = (const float*)d_in[22];
  const float* tb0  = (const float*)d_in[23];
  const float* tw1  = (const float*)d_in[24];
  const float* tb1  = (const float*)d_in[25];
  const float* tw2  = (const float*)d_in[26];
  const float* tb2  = (const float*)d_in[27];
  const float* tw3  = (const float*)d_in[28];
  const float* tb3  = (const float*)d_in[29];

  float* out = (float*)d_out;
  float* ws  = (float*)d_ws;

  // workspace plan (float offsets) -- see header comment
  float* H0 = ws + 0;
  float* H1 = ws + 16777216;
  float* H2 = ws + 0;
  float* H3 = ws + 16777216;
  float* F0 = ws + 0;
  float* F1 = ws + 16777216;
  float* Z  = ws + 0;
  float* E  = ws + 16777216;
  float* G0 = ws + 0;
  float* G1 = ws + 16777216;
  float* G2 = ws + 0;
  float* T0 = ws + 16777216;
  float* T1 = ws + 0;
  float* T2 = ws + 4194304;
  float* RL = ws + 20971520;

  const int B = 256;

  // ---- encoder convs ----
  // grid.x = B*(Ho/2)*(Wo/2)/256, grid.y = Co
  conv_s2_kernel<<<dim3(256, 64), TPB, 0, stream>>>(x,  ew0, eb0, H0, B, 3,   64,  64, 64, 1);
  conv_s2_kernel<<<dim3(64, 64),  TPB, 0, stream>>>(H0, ew1, eb1, H1, B, 64,  64,  32, 32, 1);
  conv_s2_kernel<<<dim3(16, 128), TPB, 0, stream>>>(H1, ew2, eb2, H2, B, 64,  128, 16, 16, 1);
  conv_s2_kernel<<<dim3(4, 256),  TPB, 0, stream>>>(H2, ew3, eb3, H3, B, 128, 256, 8,  8,  0);

  // ---- encoder FC ----
  gemm_kernel<<<dim3(8, 16), TPB, 0, stream>>>(H3, fw0, fb0, F0, 256, 4096, 1024, 1);
  gemm_kernel<<<dim3(8, 16), TPB, 0, stream>>>(F0, fw1, fb1, F1, 256, 1024, 1024, 1);
  gemm_kernel<<<dim3(8, 24), TPB, 0, stream>>>(F1, fw2, fb2, Z,  256, 1024, 1536, 0);

  // ---- VQ ----
  vq_kernel<<<dim3(4096), TPB, 0, stream>>>(Z, cb, E, RL);
  zs_copy_kernel<<<dim3(512), TPB, 0, stream>>>(Z, E);
  loss_reduce_kernel<<<dim3(1), TPB, 0, stream>>>(RL, out + (size_t)out_size - 1);

  // ---- decoder FC ----
  gemm_kernel<<<dim3(8, 8),  TPB, 0, stream>>>(E,  gw0, gb0, G0, 256, 1536, 512,  1);
  gemm_kernel<<<dim3(8, 16), TPB, 0, stream>>>(G0, gw1, gb1, G1, 256, 512,  1024, 1);
  gemm_kernel<<<dim3(8, 64), TPB, 0, stream>>>(G1, gw2, gb2, G2, 256, 1024, 4096, 0);

  // ---- decoder transposed convs ----
  // grid.x = B*Hi*Wi/256, grid.y = Co
  convt_kernel<<<dim3(16, 128), TPB, 0, stream>>>(G2, tw0, tb0, T0, B, 256, 128, 4,  4,  1);
  convt_kernel<<<dim3(64, 64),  TPB, 0, stream>>>(T0, tw1, tb1, T1, B, 128, 64,  8,  8,  1);
  convt_kernel<<<dim3(256, 64), TPB, 0, stream>>>(T1, tw2, tb2, T2, B, 64,  64,  16, 16, 1);
  convt_kernel<<<dim3(1024, 3), TPB, 0, stream>>>(T2, tw3, tb3, out, B, 64, 3,   32, 32, 0);
}

// Round 2
// 2314.282 us; speedup vs baseline: 3.3692x; 3.3692x over previous
//
#include <hip/hip_runtime.h>
#include <hip/hip_bf16.h>

// ============================================================================
// VQ-VAE forward, fp32 (round 2: LDS-staged implicit-GEMM convs).
// Workspace plan unchanged (peak 83.9 MB, all buffers fully written before
// read, no atomics, deterministic, graph-safe).
// ============================================================================

#define TPB 256

// ---------------- implicit-GEMM strided conv (s2, k4, p1) -------------------
// M = B*Ho*Wo cells, N = Co, K = Ci*16 (zero-padded to mult of 64).
// Tile 32 cells x 64 co, 256 threads, 2x4 acc/thread. Square images only.
__global__ __launch_bounds__(TPB) void conv_ig_kernel(
    const float* __restrict__ in, const float* __restrict__ w,
    const float* __restrict__ bias, float* __restrict__ out,
    int Ci, int Co, int Hi, int lwo, int relu)
{
  const int Wi = Hi, Wo = Hi >> 1, Ho = Wo;
  const int K = Ci << 4;
  const int Kp = (K + 63) & ~63;
  __shared__ __align__(16) float As[64][33];   // [k][cell]
  __shared__ __align__(16) float Ws[64][68];   // [k][co], pad 68 keeps f4 align
  const int tid = threadIdx.x;
  const int m0 = blockIdx.x << 5;
  const int n0 = blockIdx.y << 6;
  const int tr = tid >> 4;        // co quad index 0..15
  const int tc = tid & 15;        // cell index 0..15 (lane-adjacent => coalesced)
  float acc[2][4] = {{0.f,0.f,0.f,0.f},{0.f,0.f,0.f,0.f}};

  for (int kt = 0; kt < Kp; kt += 64) {
    // ---- im2col A-stage: 64k x 32cells, 8 elems/thread
#pragma unroll
    for (int i = 0; i < 8; ++i) {
      int lin = (i << 8) + tid;
      int cell = m0 + (lin & 31);
      int kk = lin >> 5;
      int k = kt + kk;
      int x = cell & (Wo - 1);
      int y = (cell >> lwo) & (Wo - 1);
      int b = cell >> (lwo + lwo);
      int ci = k >> 4;
      int kh = (k >> 2) & 3, kw = k & 3;
      int gy = 2 * y - 1 + kh, gx = 2 * x - 1 + kw;
      bool ok = (k < K) && (gy >= 0) && (gy < Hi) && (gx >= 0) && (gx < Wi);
      float v = 0.f;
      if (ok) v = in[(((size_t)b * Ci + ci) * Hi + gy) * Wi + gx];
      As[kk][lin & 31] = v;
    }
    // ---- W-stage: k-minor (coalesced 64-float runs), 16 elems/thread
#pragma unroll
    for (int i = 0; i < 16; ++i) {
      int lin = (i << 8) + tid;
      int n = lin >> 6, kk = lin & 63;
      int k = kt + kk;
      float v = 0.f;
      if (k < K) v = w[(size_t)(n0 + n) * K + k];
      Ws[kk][n] = v;
    }
    __syncthreads();
#pragma unroll
    for (int k = 0; k < 64; ++k) {
      float a0 = As[k][tc];
      float a1 = As[k][tc + 16];
      const float4 wv = *reinterpret_cast<const float4*>(&Ws[k][tr << 2]);
      acc[0][0] = fmaf(a0, wv.x, acc[0][0]);
      acc[0][1] = fmaf(a0, wv.y, acc[0][1]);
      acc[0][2] = fmaf(a0, wv.z, acc[0][2]);
      acc[0][3] = fmaf(a0, wv.w, acc[0][3]);
      acc[1][0] = fmaf(a1, wv.x, acc[1][0]);
      acc[1][1] = fmaf(a1, wv.y, acc[1][1]);
      acc[1][2] = fmaf(a1, wv.z, acc[1][2]);
      acc[1][3] = fmaf(a1, wv.w, acc[1][3]);
    }
    __syncthreads();
  }
  const int HW = Ho * Wo;
#pragma unroll
  for (int i = 0; i < 2; ++i) {
    int cell = m0 + tc + (i << 4);
    int x = cell & (Wo - 1);
    int y = (cell >> lwo) & (Wo - 1);
    int b = cell >> (lwo + lwo);
#pragma unroll
    for (int j = 0; j < 4; ++j) {
      int co = n0 + (tr << 2) + j;
      float v = acc[i][j] + bias[co];
      if (relu) v = fmaxf(v, 0.f);
      out[((size_t)b * Co + co) * HW + y * Wo + x] = v;
    }
  }
}

// ---------------- implicit-GEMM transposed conv (s2, k4, p1) ----------------
// Per output-parity (py,px): out(b,co,2Y+py,2X+px) = sum_{ci,ay,ax}
//   in(b,ci,Y+py-ay,X+px-ax) * w[ci][co][(1-py)*4+(1-px) + ay*8 + ax*2]
// M = B*Hi*Wi cells, N = Co, K = Ci*4 (always mult of 64 here). grid.z=parity.
__global__ __launch_bounds__(TPB) void convt_ig_kernel(
    const float* __restrict__ in, const float* __restrict__ w,
    const float* __restrict__ bias, float* __restrict__ out,
    int Ci, int Co, int Hi, int lwi, int relu)
{
  const int Wi = Hi;
  const int K = Ci << 2;
  const int py = blockIdx.z >> 1, px = blockIdx.z & 1;
  __shared__ __align__(16) float As[64][33];
  __shared__ __align__(16) float Ws[64][68];
  const int tid = threadIdx.x;
  const int m0 = blockIdx.x << 5;
  const int n0 = blockIdx.y << 6;
  const int tr = tid >> 4;
  const int tc = tid & 15;
  float acc[2][4] = {{0.f,0.f,0.f,0.f},{0.f,0.f,0.f,0.f}};

  for (int kt = 0; kt < K; kt += 64) {
#pragma unroll
    for (int i = 0; i < 8; ++i) {
      int lin = (i << 8) + tid;
      int cell = m0 + (lin & 31);
      int kk = lin >> 5;
      int k = kt + kk;
      int X = cell & (Wi - 1);
      int Y = (cell >> lwi) & (Wi - 1);
      int b = cell >> (lwi + lwi);
      int ci = k >> 2;
      int ay = (k >> 1) & 1, ax = k & 1;
      int gy = Y + py - ay, gx = X + px - ax;
      bool ok = (gy >= 0) && (gy < Hi) && (gx >= 0) && (gx < Wi);
      float v = 0.f;
      if (ok) v = in[(((size_t)b * Ci + ci) * Hi + gy) * Wi + gx];
      As[kk][lin & 31] = v;
    }
#pragma unroll
    for (int i = 0; i < 16; ++i) {
      int lin = (i << 8) + tid;
      int n = lin >> 6, kk = lin & 63;
      int k = kt + kk;
      int ci = k >> 2;
      int ay = (k >> 1) & 1, ax = k & 1;
      int widx = ((1 - py) << 2) + (1 - px) + (ay << 3) + (ax << 1);
      Ws[kk][n] = w[(((size_t)ci * Co + n0 + n) << 4) + widx];
    }
    __syncthreads();
#pragma unroll
    for (int k = 0; k < 64; ++k) {
      float a0 = As[k][tc];
      float a1 = As[k][tc + 16];
      const float4 wv = *reinterpret_cast<const float4*>(&Ws[k][tr << 2]);
      acc[0][0] = fmaf(a0, wv.x, acc[0][0]);
      acc[0][1] = fmaf(a0, wv.y, acc[0][1]);
      acc[0][2] = fmaf(a0, wv.z, acc[0][2]);
      acc[0][3] = fmaf(a0, wv.w, acc[0][3]);
      acc[1][0] = fmaf(a1, wv.x, acc[1][0]);
      acc[1][1] = fmaf(a1, wv.y, acc[1][1]);
      acc[1][2] = fmaf(a1, wv.z, acc[1][2]);
      acc[1][3] = fmaf(a1, wv.w, acc[1][3]);
    }
    __syncthreads();
  }
  const int Ho = Hi << 1, WoT = Wi << 1;
#pragma unroll
  for (int i = 0; i < 2; ++i) {
    int cell = m0 + tc + (i << 4);
    int X = cell & (Wi - 1);
    int Y = (cell >> lwi) & (Wi - 1);
    int b = cell >> (lwi + lwi);
#pragma unroll
    for (int j = 0; j < 4; ++j) {
      int co = n0 + (tr << 2) + j;
      float v = acc[i][j] + bias[co];
      if (relu) v = fmaxf(v, 0.f);
      out[(((size_t)b * Co + co) * Ho + 2 * Y + py) * WoT + 2 * X + px] = v;
    }
  }
}

// ---------------- dedicated t3: convT 64->3, 32x32 -> 64x64 -----------------
// One block per image. All weights (64*3*16=3072 f) in LDS; input staged in
// ci-chunks of 8 with +1-style padded rows (stride 33). Each thread: 4 cells
// (one x-quad of one row) x 3 co x 2x2 outputs = 48 acc.
__global__ __launch_bounds__(TPB) void convt3_kernel(
    const float* __restrict__ in, const float* __restrict__ w,
    const float* __restrict__ bias, float* __restrict__ out)
{
  __shared__ float wl[3072];
  __shared__ float il[8][33 * 32];   // [ci][y*33+x]
  const int b = blockIdx.x;
  const int tid = threadIdx.x;
  for (int i = tid; i < 3072; i += TPB) wl[i] = w[i];
  const int Y = tid >> 3;
  const int X0 = (tid & 7) << 2;
  float acc[3][2][8];
#pragma unroll
  for (int o = 0; o < 3; ++o)
#pragma unroll
    for (int p = 0; p < 2; ++p)
#pragma unroll
      for (int q = 0; q < 8; ++q) acc[o][p][q] = 0.f;

  const float* ib = in + (size_t)b * 64 * 1024;
  for (int c0 = 0; c0 < 64; c0 += 8) {
    __syncthreads();
    for (int i = tid; i < 8192; i += TPB) {
      int cc = i >> 10, y = (i >> 5) & 31, x = i & 31;
      il[cc][y * 33 + x] = ib[(size_t)c0 * 1024 + i];
    }
    __syncthreads();
    for (int cc = 0; cc < 8; ++cc) {
      float iv[3][6];
#pragma unroll
      for (int j = 0; j < 3; ++j) {
        int gy = Y - 1 + j;
        int gyc = min(max(gy, 0), 31);
        float my = (gy >= 0 && gy < 32) ? 1.f : 0.f;
#pragma unroll
        for (int k = 0; k < 6; ++k) {
          int gx = X0 - 1 + k;
          int gxc = min(max(gx, 0), 31);
          float mx = (gx >= 0 && gx < 32) ? 1.f : 0.f;
          iv[j][k] = il[cc][gyc * 33 + gxc] * (my * mx);
        }
      }
      const float* wq = &wl[(c0 + cc) * 48];
#pragma unroll
      for (int o = 0; o < 3; ++o) {
        const float* wo = wq + o * 16;
#pragma unroll
        for (int c = 0; c < 4; ++c) {
          acc[o][0][2*c]   = fmaf(iv[1][c+1], wo[5],  acc[o][0][2*c]);
          acc[o][0][2*c]   = fmaf(iv[1][c],   wo[7],  acc[o][0][2*c]);
          acc[o][0][2*c]   = fmaf(iv[0][c+1], wo[13], acc[o][0][2*c]);
          acc[o][0][2*c]   = fmaf(iv[0][c],   wo[15], acc[o][0][2*c]);
          acc[o][0][2*c+1] = fmaf(iv[1][c+2], wo[4],  acc[o][0][2*c+1]);
          acc[o][0][2*c+1] = fmaf(iv[1][c+1], wo[6],  acc[o][0][2*c+1]);
          acc[o][0][2*c+1] = fmaf(iv[0][c+2], wo[12], acc[o][0][2*c+1]);
          acc[o][0][2*c+1] = fmaf(iv[0][c+1], wo[14], acc[o][0][2*c+1]);
          acc[o][1][2*c]   = fmaf(iv[2][c+1], wo[1],  acc[o][1][2*c]);
          acc[o][1][2*c]   = fmaf(iv[2][c],   wo[3],  acc[o][1][2*c]);
          acc[o][1][2*c]   = fmaf(iv[1][c+1], wo[9],  acc[o][1][2*c]);
          acc[o][1][2*c]   = fmaf(iv[1][c],   wo[11], acc[o][1][2*c]);
          acc[o][1][2*c+1] = fmaf(iv[2][c+2], wo[0],  acc[o][1][2*c+1]);
          acc[o][1][2*c+1] = fmaf(iv[2][c+1], wo[2],  acc[o][1][2*c+1]);
          acc[o][1][2*c+1] = fmaf(iv[1][c+2], wo[8],  acc[o][1][2*c+1]);
          acc[o][1][2*c+1] = fmaf(iv[1][c+1], wo[10], acc[o][1][2*c+1]);
        }
      }
    }
  }
#pragma unroll
  for (int o = 0; o < 3; ++o) {
    float bv = bias[o];
#pragma unroll
    for (int p = 0; p < 2; ++p) {
      float* op = out + (((size_t)b * 3 + o) * 64 + 2 * Y + p) * 64 + 2 * X0;
      float4 v0 = make_float4(acc[o][p][0] + bv, acc[o][p][1] + bv,
                              acc[o][p][2] + bv, acc[o][p][3] + bv);
      float4 v1 = make_float4(acc[o][p][4] + bv, acc[o][p][5] + bv,
                              acc[o][p][6] + bv, acc[o][p][7] + bv);
      *reinterpret_cast<float4*>(op)     = v0;
      *reinterpret_cast<float4*>(op + 4) = v1;
    }
  }
}

// ---------------- GEMM: C[M,N] = A[M,K] @ W[K,N] + bias, optional relu ------
__global__ __launch_bounds__(TPB) void gemm_kernel(
    const float* __restrict__ A, const float* __restrict__ W,
    const float* __restrict__ bias, float* __restrict__ C,
    int M, int K, int N, int relu)
{
  __shared__ float As[32][33];
  __shared__ float Ws[32][64];
  const int tid = threadIdx.x;
  const int m0 = blockIdx.x * 32;
  const int n0 = blockIdx.y * 64;
  const int tr = tid >> 4;
  const int tc = tid & 15;
  float acc[2][4] = {{0.f, 0.f, 0.f, 0.f}, {0.f, 0.f, 0.f, 0.f}};

  for (int kt = 0; kt < K; kt += 32) {
#pragma unroll
    for (int i = 0; i < 4; ++i) {
      int lin = i * TPB + tid;
      int mm = lin >> 5, kk = lin & 31;
      As[kk][mm] = A[(size_t)(m0 + mm) * K + kt + kk];
    }
#pragma unroll
    for (int i = 0; i < 8; ++i) {
      int lin = i * TPB + tid;
      int kk = lin >> 6, nn = lin & 63;
      Ws[kk][nn] = W[(size_t)(kt + kk) * N + n0 + nn];
    }
    __syncthreads();
#pragma unroll
    for (int k = 0; k < 32; ++k) {
      float a0 = As[k][tr];
      float a1 = As[k][tr + 16];
      const float4 wv = *reinterpret_cast<const float4*>(&Ws[k][tc << 2]);
      acc[0][0] = fmaf(a0, wv.x, acc[0][0]);
      acc[0][1] = fmaf(a0, wv.y, acc[0][1]);
      acc[0][2] = fmaf(a0, wv.z, acc[0][2]);
      acc[0][3] = fmaf(a0, wv.w, acc[0][3]);
      acc[1][0] = fmaf(a1, wv.x, acc[1][0]);
      acc[1][1] = fmaf(a1, wv.y, acc[1][1]);
      acc[1][2] = fmaf(a1, wv.z, acc[1][2]);
      acc[1][3] = fmaf(a1, wv.w, acc[1][3]);
    }
    __syncthreads();
  }
#pragma unroll
  for (int i = 0; i < 2; ++i) {
    int mrow = m0 + tr + i * 16;
    float* cp = C + (size_t)mrow * N + n0 + (tc << 2);
#pragma unroll
    for (int j = 0; j < 4; ++j) {
      float v = acc[i][j] + bias[n0 + (tc << 2) + j];
      if (relu) v = fmaxf(v, 0.f);
      cp[j] = v;
    }
  }
}

// ---------------- VQ: one block per 64-dim row ------------------------------
__global__ __launch_bounds__(TPB) void vq_kernel(
    const float* __restrict__ z, const float* __restrict__ cb,
    float* __restrict__ e, float* __restrict__ rowloss)
{
  const int row = blockIdx.x;
  const int b = row >> 4, s = row & 15;
  __shared__ float zr[64];
  __shared__ float bval[TPB];
  __shared__ int   bidx[TPB];
  const int tid = threadIdx.x;
  if (tid < 64) zr[tid] = z[(size_t)b * 1536 + s * 64 + tid];
  __syncthreads();

  float best = 3.4e38f;
  int bi = 0;
#pragma unroll
  for (int rep = 0; rep < 2; ++rep) {
    int j = tid + rep * TPB;
    const float4* c4 = reinterpret_cast<const float4*>(cb + (size_t)j * 64);
    float d = 0.f;
#pragma unroll
    for (int k = 0; k < 16; ++k) {
      float4 cv = c4[k];
      float t0 = zr[4 * k + 0] - cv.x;
      float t1 = zr[4 * k + 1] - cv.y;
      float t2 = zr[4 * k + 2] - cv.z;
      float t3 = zr[4 * k + 3] - cv.w;
      d = fmaf(t0, t0, d); d = fmaf(t1, t1, d);
      d = fmaf(t2, t2, d); d = fmaf(t3, t3, d);
    }
    if (d < best) { best = d; bi = j; }
  }
  bval[tid] = best; bidx[tid] = bi;
  __syncthreads();
  for (int sft = 128; sft > 0; sft >>= 1) {
    if (tid < sft) {
      float v2 = bval[tid + sft]; int i2 = bidx[tid + sft];
      if (v2 < bval[tid] || (v2 == bval[tid] && i2 < bidx[tid])) {
        bval[tid] = v2; bidx[tid] = i2;
      }
    }
    __syncthreads();
  }
  const int bj = bidx[0];
  if (tid < 64)
    e[(size_t)b * 1536 + s * 64 + tid] = cb[(size_t)bj * 64 + tid];
  if (tid == 0) rowloss[row] = bval[0];
}

__global__ __launch_bounds__(TPB) void zs_copy_kernel(
    const float* __restrict__ z, float* __restrict__ e)
{
  int i = blockIdx.x * TPB + threadIdx.x;
  int b = i >> 9, k = i & 511;
  e[(size_t)b * 1536 + 1024 + k] = z[(size_t)b * 1536 + 1024 + k];
}

__global__ __launch_bounds__(TPB) void loss_reduce_kernel(
    const float* __restrict__ rl, float* __restrict__ out)
{
  __shared__ float sm[TPB];
  float s = 0.f;
  for (int i = threadIdx.x; i < 4096; i += TPB) s += rl[i];
  sm[threadIdx.x] = s;
  __syncthreads();
  for (int sft = 128; sft > 0; sft >>= 1) {
    if (threadIdx.x < sft) sm[threadIdx.x] += sm[threadIdx.x + sft];
    __syncthreads();
  }
  if (threadIdx.x == 0) out[0] = sm[0] * (1.25f / 262144.f);
}

// ============================================================================
extern "C" void kernel_launch(void* const* d_in, const int* in_sizes, int n_in,
                              void* d_out, int out_size, void* d_ws, size_t ws_size,
                              hipStream_t stream)
{
  const float* x    = (const float*)d_in[0];
  const float* ew0  = (const float*)d_in[1];
  const float* eb0  = (const float*)d_in[2];
  const float* ew1  = (const float*)d_in[3];
  const float* eb1  = (const float*)d_in[4];
  const float* ew2  = (const float*)d_in[5];
  const float* eb2  = (const float*)d_in[6];
  const float* ew3  = (const float*)d_in[7];
  const float* eb3  = (const float*)d_in[8];
  const float* fw0  = (const float*)d_in[9];
  const float* fb0  = (const float*)d_in[10];
  const float* fw1  = (const float*)d_in[11];
  const float* fb1  = (const float*)d_in[12];
  const float* fw2  = (const float*)d_in[13];
  const float* fb2  = (const float*)d_in[14];
  const float* cb   = (const float*)d_in[15];
  const float* gw0  = (const float*)d_in[16];
  const float* gb0  = (const float*)d_in[17];
  const float* gw1  = (const float*)d_in[18];
  const float* gb1  = (const float*)d_in[19];
  const float* gw2  = (const float*)d_in[20];
  const float* gb2  = (const float*)d_in[21];
  const float* tw0  = (const float*)d_in[22];
  const float* tb0  = (const float*)d_in[23];
  const float* tw1  = (const float*)d_in[24];
  const float* tb1  = (const float*)d_in[25];
  const float* tw2  = (const float*)d_in[26];
  const float* tb2  = (const float*)d_in[27];
  const float* tw3  = (const float*)d_in[28];
  const float* tb3  = (const float*)d_in[29];

  float* out = (float*)d_out;
  float* ws  = (float*)d_ws;

  float* H0 = ws + 0;
  float* H1 = ws + 16777216;
  float* H2 = ws + 0;
  float* H3 = ws + 16777216;
  float* F0 = ws + 0;
  float* F1 = ws + 16777216;
  float* Z  = ws + 0;
  float* E  = ws + 16777216;
  float* G0 = ws + 0;
  float* G1 = ws + 16777216;
  float* G2 = ws + 0;
  float* T0 = ws + 16777216;
  float* T1 = ws + 0;
  float* T2 = ws + 4194304;
  float* RL = ws + 20971520;

  // ---- encoder convs (implicit GEMM) ----
  conv_ig_kernel<<<dim3(8192, 1), TPB, 0, stream>>>(x,  ew0, eb0, H0, 3,   64,  64, 5, 1);
  conv_ig_kernel<<<dim3(2048, 1), TPB, 0, stream>>>(H0, ew1, eb1, H1, 64,  64,  32, 4, 1);
  conv_ig_kernel<<<dim3(512, 2),  TPB, 0, stream>>>(H1, ew2, eb2, H2, 64,  128, 16, 3, 1);
  conv_ig_kernel<<<dim3(128, 4),  TPB, 0, stream>>>(H2, ew3, eb3, H3, 128, 256, 8,  2, 0);

  // ---- encoder FC ----
  gemm_kernel<<<dim3(8, 16), TPB, 0, stream>>>(H3, fw0, fb0, F0, 256, 4096, 1024, 1);
  gemm_kernel<<<dim3(8, 16), TPB, 0, stream>>>(F0, fw1, fb1, F1, 256, 1024, 1024, 1);
  gemm_kernel<<<dim3(8, 24), TPB, 0, stream>>>(F1, fw2, fb2, Z,  256, 1024, 1536, 0);

  // ---- VQ ----
  vq_kernel<<<dim3(4096), TPB, 0, stream>>>(Z, cb, E, RL);
  zs_copy_kernel<<<dim3(512), TPB, 0, stream>>>(Z, E);
  loss_reduce_kernel<<<dim3(1), TPB, 0, stream>>>(RL, out + (size_t)out_size - 1);

  // ---- decoder FC ----
  gemm_kernel<<<dim3(8, 8),  TPB, 0, stream>>>(E,  gw0, gb0, G0, 256, 1536, 512,  1);
  gemm_kernel<<<dim3(8, 16), TPB, 0, stream>>>(G0, gw1, gb1, G1, 256, 512,  1024, 1);
  gemm_kernel<<<dim3(8, 64), TPB, 0, stream>>>(G1, gw2, gb2, G2, 256, 1024, 4096, 0);

  // ---- decoder transposed convs (implicit GEMM per parity; t3 dedicated) ---
  convt_ig_kernel<<<dim3(128, 2, 4),  TPB, 0, stream>>>(G2, tw0, tb0, T0, 256, 128, 4,  2, 1);
  convt_ig_kernel<<<dim3(512, 1, 4),  TPB, 0, stream>>>(T0, tw1, tb1, T1, 128, 64,  8,  3, 1);
  convt_ig_kernel<<<dim3(2048, 1, 4), TPB, 0, stream>>>(T1, tw2, tb2, T2, 64,  64,  16, 4, 1);
  convt3_kernel<<<dim3(256), TPB, 0, stream>>>(T2, tw3, tb3, out);
}

// Round 3
// 1311.031 us; speedup vs baseline: 5.9474x; 1.7652x over previous
//
#include <hip/hip_runtime.h>
#include <hip/hip_bf16.h>

// ============================================================================
// VQ-VAE forward, fp32 (round 3: balanced register tiles, conflict-free LDS).
// Workspace plan unchanged. No atomics, deterministic, graph-safe.
// ============================================================================

#define TPB 256

// ---------------- conv (s2,k4,p1) implicit GEMM, templated tile -------------
// M = B*Ho*Wo cells, N = Co, K = Ci*16 (K % BK == 0 for all layers used).
// Threads 256 = (BM/TM)*(BN/TN), tm minor (cells), tn major (co).
template<int BM, int BN, int BK, int TM, int TN>
__global__ __launch_bounds__(TPB) void conv_ig2(
    const float* __restrict__ in, const float* __restrict__ w,
    const float* __restrict__ bias, float* __restrict__ out,
    int Ci, int Co, int Hi, int lwo, int relu)
{
  constexpr int NTM = BM / TM;
  constexpr int GM = TM / 4;
  constexpr int GN = TN / 4;
  static_assert((BM / TM) * (BN / TN) == TPB, "bad tile");
  const int Wi = Hi, Wo = Hi >> 1;
  const int K = Ci << 4;
  const int HW = Wo * Wo;
  __shared__ __align__(16) float As[BK][BM + 4];
  __shared__ __align__(16) float Ws[BK][BN + 4];
  const int tid = threadIdx.x;
  const int m0 = blockIdx.x * BM;
  const int n0 = blockIdx.y * BN;
  const int tm = tid % NTM;
  const int tn = tid / NTM;
  float acc[TM][TN];
#pragma unroll
  for (int i = 0; i < TM; ++i)
#pragma unroll
    for (int j = 0; j < TN; ++j) acc[i][j] = 0.f;

  for (int kt = 0; kt < K; kt += BK) {
    // A-stage: im2col gather, cell-minor (conflict-free LDS writes)
    constexpr int ACNT = BK * BM / TPB;
#pragma unroll
    for (int i = 0; i < ACNT; ++i) {
      int lin = i * TPB + tid;
      int cl = lin & (BM - 1);
      int kk = lin / BM;
      int cell = m0 + cl;
      int k = kt + kk;
      int x = cell & (Wo - 1);
      int y = (cell >> lwo) & (Wo - 1);
      int b = cell >> (lwo + lwo);
      int ci = k >> 4;
      int kh = (k >> 2) & 3, kw = k & 3;
      int gy = 2 * y - 1 + kh, gx = 2 * x - 1 + kw;
      bool ok = (gy >= 0) && (gy < Hi) && (gx >= 0) && (gx < Wi);
      float v = 0.f;
      if (ok) v = in[(((size_t)b * Ci + ci) * Hi + gy) * Wi + gx];
      As[kk][cl] = v;
    }
    // W-stage: float4 over k (w is [co][ci*16] row-major => k-contiguous),
    // transposed dword writes, bank = n-minor => ~2-way (free)
    constexpr int KQ = BK / 4;
    constexpr int WCNT = BK * BN / (TPB * 4);
#pragma unroll
    for (int f = 0; f < WCNT; ++f) {
      int idx = f * TPB + tid;
      int kq = idx % KQ;
      int n = idx / KQ;
      const float4 wv4 = *reinterpret_cast<const float4*>(
          &w[(size_t)(n0 + n) * K + kt + 4 * kq]);
      Ws[4 * kq + 0][n] = wv4.x;
      Ws[4 * kq + 1][n] = wv4.y;
      Ws[4 * kq + 2][n] = wv4.z;
      Ws[4 * kq + 3][n] = wv4.w;
    }
    __syncthreads();
#pragma unroll
    for (int k = 0; k < BK; ++k) {
      float a_[TM], w_[TN];
#pragma unroll
      for (int g = 0; g < GM; ++g) {
        const float4 av = *reinterpret_cast<const float4*>(
            &As[k][4 * tm + g * (BM / 2)]);
        a_[4 * g + 0] = av.x; a_[4 * g + 1] = av.y;
        a_[4 * g + 2] = av.z; a_[4 * g + 3] = av.w;
      }
#pragma unroll
      for (int g = 0; g < GN; ++g) {
        const float4 wv = *reinterpret_cast<const float4*>(
            &Ws[k][4 * tn + g * (BN / 2)]);
        w_[4 * g + 0] = wv.x; w_[4 * g + 1] = wv.y;
        w_[4 * g + 2] = wv.z; w_[4 * g + 3] = wv.w;
      }
#pragma unroll
      for (int mi = 0; mi < TM; ++mi)
#pragma unroll
        for (int ni = 0; ni < TN; ++ni)
          acc[mi][ni] = fmaf(a_[mi], w_[ni], acc[mi][ni]);
    }
    __syncthreads();
  }
  // store: float4 over 4 consecutive cells (same row, x 4-aligned)
#pragma unroll
  for (int g = 0; g < GM; ++g) {
    int cg = m0 + 4 * tm + g * (BM / 2);
    int x = cg & (Wo - 1);
    int y = (cg >> lwo) & (Wo - 1);
    int b = cg >> (lwo + lwo);
    float* ob = out + (size_t)b * Co * HW + y * Wo + x;
#pragma unroll
    for (int gn = 0; gn < GN; ++gn)
#pragma unroll
      for (int jj = 0; jj < 4; ++jj) {
        int co = n0 + 4 * tn + gn * (BN / 2) + jj;
        float bv = bias[co];
        int ni = 4 * gn + jj;
        float4 v = make_float4(acc[4*g+0][ni] + bv, acc[4*g+1][ni] + bv,
                               acc[4*g+2][ni] + bv, acc[4*g+3][ni] + bv);
        if (relu) {
          v.x = fmaxf(v.x, 0.f); v.y = fmaxf(v.y, 0.f);
          v.z = fmaxf(v.z, 0.f); v.w = fmaxf(v.w, 0.f);
        }
        *reinterpret_cast<float4*>(ob + (size_t)co * HW) = v;
      }
  }
}

// ---------------- convT (s2,k4,p1) implicit GEMM per parity -----------------
// K = Ci*4; grid.z = parity (py*2+px).
template<int BM, int BN, int BK, int TM, int TN>
__global__ __launch_bounds__(TPB) void convt_ig2(
    const float* __restrict__ in, const float* __restrict__ w,
    const float* __restrict__ bias, float* __restrict__ out,
    int Ci, int Co, int Hi, int lwi, int relu)
{
  constexpr int NTM = BM / TM;
  constexpr int GM = TM / 4;
  constexpr int GN = TN / 4;
  const int Wi = Hi;
  const int K = Ci << 2;
  const int py = blockIdx.z >> 1, px = blockIdx.z & 1;
  __shared__ __align__(16) float As[BK][BM + 4];
  __shared__ __align__(16) float Ws[BK][BN + 4];
  const int tid = threadIdx.x;
  const int m0 = blockIdx.x * BM;
  const int n0 = blockIdx.y * BN;
  const int tm = tid % NTM;
  const int tn = tid / NTM;
  float acc[TM][TN];
#pragma unroll
  for (int i = 0; i < TM; ++i)
#pragma unroll
    for (int j = 0; j < TN; ++j) acc[i][j] = 0.f;

  for (int kt = 0; kt < K; kt += BK) {
    constexpr int ACNT = BK * BM / TPB;
#pragma unroll
    for (int i = 0; i < ACNT; ++i) {
      int lin = i * TPB + tid;
      int cl = lin & (BM - 1);
      int kk = lin / BM;
      int cell = m0 + cl;
      int k = kt + kk;
      int X = cell & (Wi - 1);
      int Y = (cell >> lwi) & (Wi - 1);
      int b = cell >> (lwi + lwi);
      int ci = k >> 2;
      int ay = (k >> 1) & 1, ax = k & 1;
      int gy = Y + py - ay, gx = X + px - ax;
      bool ok = (gy >= 0) && (gy < Hi) && (gx >= 0) && (gx < Wi);
      float v = 0.f;
      if (ok) v = in[(((size_t)b * Ci + ci) * Hi + gy) * Wi + gx];
      As[kk][cl] = v;
    }
    // W-stage: scalar gather (w is [ci][co][16]), n-minor lanes => conflict-free
    constexpr int WCNT = BK * BN / TPB;
#pragma unroll
    for (int i = 0; i < WCNT; ++i) {
      int lin = i * TPB + tid;
      int n = lin & (BN - 1);
      int kk = lin / BN;
      int k = kt + kk;
      int ci = k >> 2;
      int ay = (k >> 1) & 1, ax = k & 1;
      int widx = ((1 - py) << 2) + (1 - px) + (ay << 3) + (ax << 1);
      Ws[kk][n] = w[(((size_t)ci * Co + n0 + n) << 4) + widx];
    }
    __syncthreads();
#pragma unroll
    for (int k = 0; k < BK; ++k) {
      float a_[TM], w_[TN];
#pragma unroll
      for (int g = 0; g < GM; ++g) {
        const float4 av = *reinterpret_cast<const float4*>(
            &As[k][4 * tm + g * (BM / 2)]);
        a_[4 * g + 0] = av.x; a_[4 * g + 1] = av.y;
        a_[4 * g + 2] = av.z; a_[4 * g + 3] = av.w;
      }
#pragma unroll
      for (int g = 0; g < GN; ++g) {
        const float4 wv = *reinterpret_cast<const float4*>(
            &Ws[k][4 * tn + g * (BN / 2)]);
        w_[4 * g + 0] = wv.x; w_[4 * g + 1] = wv.y;
        w_[4 * g + 2] = wv.z; w_[4 * g + 3] = wv.w;
      }
#pragma unroll
      for (int mi = 0; mi < TM; ++mi)
#pragma unroll
        for (int ni = 0; ni < TN; ++ni)
          acc[mi][ni] = fmaf(a_[mi], w_[ni], acc[mi][ni]);
    }
    __syncthreads();
  }
  const int Ho = Hi << 1, WoT = Wi << 1;
#pragma unroll
  for (int g = 0; g < GM; ++g) {
    int cg = m0 + 4 * tm + g * (BM / 2);
    int X0 = cg & (Wi - 1);
    int Y = (cg >> lwi) & (Wi - 1);
    int b = cg >> (lwi + lwi);
#pragma unroll
    for (int gn = 0; gn < GN; ++gn)
#pragma unroll
      for (int jj = 0; jj < 4; ++jj) {
        int co = n0 + 4 * tn + gn * (BN / 2) + jj;
        float bv = bias[co];
        int ni = 4 * gn + jj;
        float* ob = out + (((size_t)b * Co + co) * Ho + 2 * Y + py) * WoT + px;
#pragma unroll
        for (int j = 0; j < 4; ++j) {
          float v = acc[4 * g + j][ni] + bv;
          if (relu) v = fmaxf(v, 0.f);
          ob[2 * (X0 + j)] = v;
        }
      }
  }
}

// ---------------- FC GEMM: C[M,N] = A[M,K] @ W[K,N] + bias ------------------
// BM=64, BN=32, BK=32, thread 4x2, tn minor (coalesced C stores).
__global__ __launch_bounds__(TPB) void gemm_ig2(
    const float* __restrict__ A, const float* __restrict__ W,
    const float* __restrict__ bias, float* __restrict__ C,
    int M, int K, int N, int relu)
{
  constexpr int BM = 64, BN = 32, BK = 32;
  __shared__ __align__(16) float As[BK][BM + 4];
  __shared__ __align__(16) float Ws[BK][BN + 4];
  const int tid = threadIdx.x;
  const int m0 = blockIdx.x * BM;
  const int n0 = blockIdx.y * BN;
  const int tn = tid & 15;        // minor: 2 cols each
  const int tm = tid >> 4;        // 4 rows each
  float acc[4][2] = {{0.f,0.f},{0.f,0.f},{0.f,0.f},{0.f,0.f}};

  for (int kt = 0; kt < K; kt += BK) {
    // A-stage: float4 over k, transpose-write (A is [M][K])
#pragma unroll
    for (int f = 0; f < 2; ++f) {
      int idx = f * TPB + tid;
      int kq = idx & 7;
      int m = idx >> 3;
      const float4 av = *reinterpret_cast<const float4*>(
          &A[(size_t)(m0 + m) * K + kt + 4 * kq]);
      As[4 * kq + 0][m] = av.x;
      As[4 * kq + 1][m] = av.y;
      As[4 * kq + 2][m] = av.z;
      As[4 * kq + 3][m] = av.w;
    }
    // W-stage: scalar, n-minor (W is [K][N]) => coalesced + conflict-free
#pragma unroll
    for (int i = 0; i < 4; ++i) {
      int lin = i * TPB + tid;
      int n = lin & 31;
      int kk = lin >> 5;
      Ws[kk][n] = W[(size_t)(kt + kk) * N + n0 + n];
    }
    __syncthreads();
#pragma unroll
    for (int k = 0; k < BK; ++k) {
      const float4 av = *reinterpret_cast<const float4*>(&As[k][4 * tm]);
      const float2 wv = *reinterpret_cast<const float2*>(&Ws[k][2 * tn]);
      acc[0][0] = fmaf(av.x, wv.x, acc[0][0]);
      acc[0][1] = fmaf(av.x, wv.y, acc[0][1]);
      acc[1][0] = fmaf(av.y, wv.x, acc[1][0]);
      acc[1][1] = fmaf(av.y, wv.y, acc[1][1]);
      acc[2][0] = fmaf(av.z, wv.x, acc[2][0]);
      acc[2][1] = fmaf(av.z, wv.y, acc[2][1]);
      acc[3][0] = fmaf(av.w, wv.x, acc[3][0]);
      acc[3][1] = fmaf(av.w, wv.y, acc[3][1]);
    }
    __syncthreads();
  }
  const float b0 = bias[n0 + 2 * tn];
  const float b1 = bias[n0 + 2 * tn + 1];
#pragma unroll
  for (int mi = 0; mi < 4; ++mi) {
    int m = m0 + 4 * tm + mi;
    float2 v = make_float2(acc[mi][0] + b0, acc[mi][1] + b1);
    if (relu) { v.x = fmaxf(v.x, 0.f); v.y = fmaxf(v.y, 0.f); }
    *reinterpret_cast<float2*>(&C[(size_t)m * N + n0 + 2 * tn]) = v;
  }
}

// ---------------- dedicated t3: convT 64->3, 32x32 -> 64x64 -----------------
__global__ __launch_bounds__(TPB) void convt3_kernel(
    const float* __restrict__ in, const float* __restrict__ w,
    const float* __restrict__ bias, float* __restrict__ out)
{
  __shared__ float wl[3072];
  __shared__ float il[8][33 * 32];
  const int b = blockIdx.x;
  const int tid = threadIdx.x;
  for (int i = tid; i < 3072; i += TPB) wl[i] = w[i];
  const int Y = tid >> 3;
  const int X0 = (tid & 7) << 2;
  float acc[3][2][8];
#pragma unroll
  for (int o = 0; o < 3; ++o)
#pragma unroll
    for (int p = 0; p < 2; ++p)
#pragma unroll
      for (int q = 0; q < 8; ++q) acc[o][p][q] = 0.f;

  const float* ib = in + (size_t)b * 64 * 1024;
  for (int c0 = 0; c0 < 64; c0 += 8) {
    __syncthreads();
    for (int i = tid; i < 8192; i += TPB) {
      int cc = i >> 10, y = (i >> 5) & 31, x = i & 31;
      il[cc][y * 33 + x] = ib[(size_t)c0 * 1024 + i];
    }
    __syncthreads();
    for (int cc = 0; cc < 8; ++cc) {
      float iv[3][6];
#pragma unroll
      for (int j = 0; j < 3; ++j) {
        int gy = Y - 1 + j;
        int gyc = min(max(gy, 0), 31);
        float my = (gy >= 0 && gy < 32) ? 1.f : 0.f;
#pragma unroll
        for (int k = 0; k < 6; ++k) {
          int gx = X0 - 1 + k;
          int gxc = min(max(gx, 0), 31);
          float mx = (gx >= 0 && gx < 32) ? 1.f : 0.f;
          iv[j][k] = il[cc][gyc * 33 + gxc] * (my * mx);
        }
      }
      const float* wq = &wl[(c0 + cc) * 48];
#pragma unroll
      for (int o = 0; o < 3; ++o) {
        const float* wo = wq + o * 16;
#pragma unroll
        for (int c = 0; c < 4; ++c) {
          acc[o][0][2*c]   = fmaf(iv[1][c+1], wo[5],  acc[o][0][2*c]);
          acc[o][0][2*c]   = fmaf(iv[1][c],   wo[7],  acc[o][0][2*c]);
          acc[o][0][2*c]   = fmaf(iv[0][c+1], wo[13], acc[o][0][2*c]);
          acc[o][0][2*c]   = fmaf(iv[0][c],   wo[15], acc[o][0][2*c]);
          acc[o][0][2*c+1] = fmaf(iv[1][c+2], wo[4],  acc[o][0][2*c+1]);
          acc[o][0][2*c+1] = fmaf(iv[1][c+1], wo[6],  acc[o][0][2*c+1]);
          acc[o][0][2*c+1] = fmaf(iv[0][c+2], wo[12], acc[o][0][2*c+1]);
          acc[o][0][2*c+1] = fmaf(iv[0][c+1], wo[14], acc[o][0][2*c+1]);
          acc[o][1][2*c]   = fmaf(iv[2][c+1], wo[1],  acc[o][1][2*c]);
          acc[o][1][2*c]   = fmaf(iv[2][c],   wo[3],  acc[o][1][2*c]);
          acc[o][1][2*c]   = fmaf(iv[1][c+1], wo[9],  acc[o][1][2*c]);
          acc[o][1][2*c]   = fmaf(iv[1][c],   wo[11], acc[o][1][2*c]);
          acc[o][1][2*c+1] = fmaf(iv[2][c+2], wo[0],  acc[o][1][2*c+1]);
          acc[o][1][2*c+1] = fmaf(iv[2][c+1], wo[2],  acc[o][1][2*c+1]);
          acc[o][1][2*c+1] = fmaf(iv[1][c+2], wo[8],  acc[o][1][2*c+1]);
          acc[o][1][2*c+1] = fmaf(iv[1][c+1], wo[10], acc[o][1][2*c+1]);
        }
      }
    }
  }
#pragma unroll
  for (int o = 0; o < 3; ++o) {
    float bv = bias[o];
#pragma unroll
    for (int p = 0; p < 2; ++p) {
      float* op = out + (((size_t)b * 3 + o) * 64 + 2 * Y + p) * 64 + 2 * X0;
      float4 v0 = make_float4(acc[o][p][0] + bv, acc[o][p][1] + bv,
                              acc[o][p][2] + bv, acc[o][p][3] + bv);
      float4 v1 = make_float4(acc[o][p][4] + bv, acc[o][p][5] + bv,
                              acc[o][p][6] + bv, acc[o][p][7] + bv);
      *reinterpret_cast<float4*>(op)     = v0;
      *reinterpret_cast<float4*>(op + 4) = v1;
    }
  }
}

// ---------------- VQ: one block per 64-dim row ------------------------------
__global__ __launch_bounds__(TPB) void vq_kernel(
    const float* __restrict__ z, const float* __restrict__ cb,
    float* __restrict__ e, float* __restrict__ rowloss)
{
  const int row = blockIdx.x;
  const int b = row >> 4, s = row & 15;
  __shared__ float zr[64];
  __shared__ float bval[TPB];
  __shared__ int   bidx[TPB];
  const int tid = threadIdx.x;
  if (tid < 64) zr[tid] = z[(size_t)b * 1536 + s * 64 + tid];
  __syncthreads();

  float best = 3.4e38f;
  int bi = 0;
#pragma unroll
  for (int rep = 0; rep < 2; ++rep) {
    int j = tid + rep * TPB;
    const float4* c4 = reinterpret_cast<const float4*>(cb + (size_t)j * 64);
    float d = 0.f;
#pragma unroll
    for (int k = 0; k < 16; ++k) {
      float4 cv = c4[k];
      float t0 = zr[4 * k + 0] - cv.x;
      float t1 = zr[4 * k + 1] - cv.y;
      float t2 = zr[4 * k + 2] - cv.z;
      float t3 = zr[4 * k + 3] - cv.w;
      d = fmaf(t0, t0, d); d = fmaf(t1, t1, d);
      d = fmaf(t2, t2, d); d = fmaf(t3, t3, d);
    }
    if (d < best) { best = d; bi = j; }
  }
  bval[tid] = best; bidx[tid] = bi;
  __syncthreads();
  for (int sft = 128; sft > 0; sft >>= 1) {
    if (tid < sft) {
      float v2 = bval[tid + sft]; int i2 = bidx[tid + sft];
      if (v2 < bval[tid] || (v2 == bval[tid] && i2 < bidx[tid])) {
        bval[tid] = v2; bidx[tid] = i2;
      }
    }
    __syncthreads();
  }
  const int bj = bidx[0];
  if (tid < 64)
    e[(size_t)b * 1536 + s * 64 + tid] = cb[(size_t)bj * 64 + tid];
  if (tid == 0) rowloss[row] = bval[0];
}

__global__ __launch_bounds__(TPB) void zs_copy_kernel(
    const float* __restrict__ z, float* __restrict__ e)
{
  int i = blockIdx.x * TPB + threadIdx.x;
  int b = i >> 9, k = i & 511;
  e[(size_t)b * 1536 + 1024 + k] = z[(size_t)b * 1536 + 1024 + k];
}

__global__ __launch_bounds__(TPB) void loss_reduce_kernel(
    const float* __restrict__ rl, float* __restrict__ out)
{
  __shared__ float sm[TPB];
  float s = 0.f;
  for (int i = threadIdx.x; i < 4096; i += TPB) s += rl[i];
  sm[threadIdx.x] = s;
  __syncthreads();
  for (int sft = 128; sft > 0; sft >>= 1) {
    if (threadIdx.x < sft) sm[threadIdx.x] += sm[threadIdx.x + sft];
    __syncthreads();
  }
  if (threadIdx.x == 0) out[0] = sm[0] * (1.25f / 262144.f);
}

// ============================================================================
extern "C" void kernel_launch(void* const* d_in, const int* in_sizes, int n_in,
                              void* d_out, int out_size, void* d_ws, size_t ws_size,
                              hipStream_t stream)
{
  const float* x    = (const float*)d_in[0];
  const float* ew0  = (const float*)d_in[1];
  const float* eb0  = (const float*)d_in[2];
  const float* ew1  = (const float*)d_in[3];
  const float* eb1  = (const float*)d_in[4];
  const float* ew2  = (const float*)d_in[5];
  const float* eb2  = (const float*)d_in[6];
  const float* ew3  = (const float*)d_in[7];
  const float* eb3  = (const float*)d_in[8];
  const float* fw0  = (const float*)d_in[9];
  const float* fb0  = (const float*)d_in[10];
  const float* fw1  = (const float*)d_in[11];
  const float* fb1  = (const float*)d_in[12];
  const float* fw2  = (const float*)d_in[13];
  const float* fb2  = (const float*)d_in[14];
  const float* cb   = (const float*)d_in[15];
  const float* gw0  = (const float*)d_in[16];
  const float* gb0  = (const float*)d_in[17];
  const float* gw1  = (const float*)d_in[18];
  const float* gb1  = (const float*)d_in[19];
  const float* gw2  = (const float*)d_in[20];
  const float* gb2  = (const float*)d_in[21];
  const float* tw0  = (const float*)d_in[22];
  const float* tb0  = (const float*)d_in[23];
  const float* tw1  = (const float*)d_in[24];
  const float* tb1  = (const float*)d_in[25];
  const float* tw2  = (const float*)d_in[26];
  const float* tb2  = (const float*)d_in[27];
  const float* tw3  = (const float*)d_in[28];
  const float* tb3  = (const float*)d_in[29];

  float* out = (float*)d_out;
  float* ws  = (float*)d_ws;

  float* H0 = ws + 0;
  float* H1 = ws + 16777216;
  float* H2 = ws + 0;
  float* H3 = ws + 16777216;
  float* F0 = ws + 0;
  float* F1 = ws + 16777216;
  float* Z  = ws + 0;
  float* E  = ws + 16777216;
  float* G0 = ws + 0;
  float* G1 = ws + 16777216;
  float* G2 = ws + 0;
  float* T0 = ws + 16777216;
  float* T1 = ws + 0;
  float* T2 = ws + 4194304;
  float* RL = ws + 20971520;

  // ---- encoder convs ----
  conv_ig2<256,64,16,8,8><<<dim3(1024, 1), TPB, 0, stream>>>(x,  ew0, eb0, H0, 3,   64,  64, 5, 1);
  conv_ig2<128,64,16,4,8><<<dim3(512, 1),  TPB, 0, stream>>>(H0, ew1, eb1, H1, 64,  64,  32, 4, 1);
  conv_ig2<128,64,16,4,8><<<dim3(128, 2),  TPB, 0, stream>>>(H1, ew2, eb2, H2, 64,  128, 16, 3, 1);
  conv_ig2<64,64,32,4,4><<<dim3(64, 4),    TPB, 0, stream>>>(H2, ew3, eb3, H3, 128, 256, 8,  2, 0);

  // ---- encoder FC ----
  gemm_ig2<<<dim3(4, 32), TPB, 0, stream>>>(H3, fw0, fb0, F0, 256, 4096, 1024, 1);
  gemm_ig2<<<dim3(4, 32), TPB, 0, stream>>>(F0, fw1, fb1, F1, 256, 1024, 1024, 1);
  gemm_ig2<<<dim3(4, 48), TPB, 0, stream>>>(F1, fw2, fb2, Z,  256, 1024, 1536, 0);

  // ---- VQ ----
  vq_kernel<<<dim3(4096), TPB, 0, stream>>>(Z, cb, E, RL);
  zs_copy_kernel<<<dim3(512), TPB, 0, stream>>>(Z, E);
  loss_reduce_kernel<<<dim3(1), TPB, 0, stream>>>(RL, out + (size_t)out_size - 1);

  // ---- decoder FC ----
  gemm_ig2<<<dim3(4, 16),  TPB, 0, stream>>>(E,  gw0, gb0, G0, 256, 1536, 512,  1);
  gemm_ig2<<<dim3(4, 32),  TPB, 0, stream>>>(G0, gw1, gb1, G1, 256, 512,  1024, 1);
  gemm_ig2<<<dim3(4, 128), TPB, 0, stream>>>(G1, gw2, gb2, G2, 256, 1024, 4096, 0);

  // ---- decoder transposed convs ----
  convt_ig2<64,64,32,4,4><<<dim3(64, 2, 4),   TPB, 0, stream>>>(G2, tw0, tb0, T0, 256, 128, 4,  2, 1);
  convt_ig2<128,64,16,4,8><<<dim3(128, 1, 4), TPB, 0, stream>>>(T0, tw1, tb1, T1, 128, 64,  8,  3, 1);
  convt_ig2<256,64,16,8,8><<<dim3(256, 1, 4), TPB, 0, stream>>>(T1, tw2, tb2, T2, 64,  64,  16, 4, 1);
  convt3_kernel<<<dim3(256), TPB, 0, stream>>>(T2, tw3, tb3, out);
}

// Round 4
// 1304.184 us; speedup vs baseline: 5.9787x; 1.0052x over previous
//
#include <hip/hip_runtime.h>
#include <hip/hip_bf16.h>

// ============================================================================
// VQ-VAE forward, round 4: encoder fp32 (unchanged), decoder heavy layers
// (g2, t0, t1, t2) on bf16 MFMA with 2-term split (hi+lo) for ~fp32 accuracy.
// Activations between MFMA layers travel as packed u32 = (lo_bf16<<16)|hi_bf16.
//
// Workspace (4-byte slots), peak 20,975,616 (same as R1-R3):
//   encoder: H0=0  H1=16.78M  H2=0  H3=16.78M  F0=0  F1=16.78M  Z=0  E=16.78M
//   decoder: G0=0..131K  G1=262144..524288  G2hl=524288..1.57M
//            T0hl=1638400..3.74M  T1hl=16777216..20971520  T2=0..16.78M
//   RL=20971520..+4096
// All producer/consumer pairs disjoint; all buffers fully written before read.
// ============================================================================

#define TPB 256

typedef __attribute__((ext_vector_type(8))) short short8v;   // 8 bf16 = 4 VGPR
typedef __attribute__((ext_vector_type(4))) float f32x4;

__device__ inline unsigned short f2bf(float x) {
  union { float f; unsigned u; } v; v.f = x;
  unsigned r = v.u + 0x7fffu + ((v.u >> 16) & 1u);
  return (unsigned short)(r >> 16);
}
__device__ inline float bf2f(unsigned short h) {
  union { unsigned u; float f; } v; v.u = ((unsigned)h) << 16; return v.f;
}
__device__ inline unsigned packhl(float x) {
  unsigned short hi = f2bf(x);
  unsigned short lo = f2bf(x - bf2f(hi));
  return ((unsigned)lo << 16) | (unsigned)hi;
}

// ---------------- encoder conv (s2,k4,p1) implicit GEMM, fp32 ---------------
template<int BM, int BN, int BK, int TM, int TN>
__global__ __launch_bounds__(TPB) void conv_ig2(
    const float* __restrict__ in, const float* __restrict__ w,
    const float* __restrict__ bias, float* __restrict__ out,
    int Ci, int Co, int Hi, int lwo, int relu)
{
  constexpr int NTM = BM / TM;
  constexpr int GM = TM / 4;
  constexpr int GN = TN / 4;
  static_assert((BM / TM) * (BN / TN) == TPB, "bad tile");
  const int Wi = Hi, Wo = Hi >> 1;
  const int K = Ci << 4;
  const int HW = Wo * Wo;
  __shared__ __align__(16) float As[BK][BM + 4];
  __shared__ __align__(16) float Ws[BK][BN + 4];
  const int tid = threadIdx.x;
  const int m0 = blockIdx.x * BM;
  const int n0 = blockIdx.y * BN;
  const int tm = tid % NTM;
  const int tn = tid / NTM;
  float acc[TM][TN];
#pragma unroll
  for (int i = 0; i < TM; ++i)
#pragma unroll
    for (int j = 0; j < TN; ++j) acc[i][j] = 0.f;

  for (int kt = 0; kt < K; kt += BK) {
    constexpr int ACNT = BK * BM / TPB;
#pragma unroll
    for (int i = 0; i < ACNT; ++i) {
      int lin = i * TPB + tid;
      int cl = lin & (BM - 1);
      int kk = lin / BM;
      int cell = m0 + cl;
      int k = kt + kk;
      int x = cell & (Wo - 1);
      int y = (cell >> lwo) & (Wo - 1);
      int b = cell >> (lwo + lwo);
      int ci = k >> 4;
      int kh = (k >> 2) & 3, kw = k & 3;
      int gy = 2 * y - 1 + kh, gx = 2 * x - 1 + kw;
      bool ok = (gy >= 0) && (gy < Hi) && (gx >= 0) && (gx < Wi);
      float v = 0.f;
      if (ok) v = in[(((size_t)b * Ci + ci) * Hi + gy) * Wi + gx];
      As[kk][cl] = v;
    }
    constexpr int KQ = BK / 4;
    constexpr int WCNT = BK * BN / (TPB * 4);
#pragma unroll
    for (int f = 0; f < WCNT; ++f) {
      int idx = f * TPB + tid;
      int kq = idx % KQ;
      int n = idx / KQ;
      const float4 wv4 = *reinterpret_cast<const float4*>(
          &w[(size_t)(n0 + n) * K + kt + 4 * kq]);
      Ws[4 * kq + 0][n] = wv4.x;
      Ws[4 * kq + 1][n] = wv4.y;
      Ws[4 * kq + 2][n] = wv4.z;
      Ws[4 * kq + 3][n] = wv4.w;
    }
    __syncthreads();
#pragma unroll
    for (int k = 0; k < BK; ++k) {
      float a_[TM], w_[TN];
#pragma unroll
      for (int g = 0; g < GM; ++g) {
        const float4 av = *reinterpret_cast<const float4*>(
            &As[k][4 * tm + g * (BM / 2)]);
        a_[4 * g + 0] = av.x; a_[4 * g + 1] = av.y;
        a_[4 * g + 2] = av.z; a_[4 * g + 3] = av.w;
      }
#pragma unroll
      for (int g = 0; g < GN; ++g) {
        const float4 wv = *reinterpret_cast<const float4*>(
            &Ws[k][4 * tn + g * (BN / 2)]);
        w_[4 * g + 0] = wv.x; w_[4 * g + 1] = wv.y;
        w_[4 * g + 2] = wv.z; w_[4 * g + 3] = wv.w;
      }
#pragma unroll
      for (int mi = 0; mi < TM; ++mi)
#pragma unroll
        for (int ni = 0; ni < TN; ++ni)
          acc[mi][ni] = fmaf(a_[mi], w_[ni], acc[mi][ni]);
    }
    __syncthreads();
  }
#pragma unroll
  for (int g = 0; g < GM; ++g) {
    int cg = m0 + 4 * tm + g * (BM / 2);
    int x = cg & (Wo - 1);
    int y = (cg >> lwo) & (Wo - 1);
    int b = cg >> (lwo + lwo);
    float* ob = out + (size_t)b * Co * HW + y * Wo + x;
#pragma unroll
    for (int gn = 0; gn < GN; ++gn)
#pragma unroll
      for (int jj = 0; jj < 4; ++jj) {
        int co = n0 + 4 * tn + gn * (BN / 2) + jj;
        float bv = bias[co];
        int ni = 4 * gn + jj;
        float4 v = make_float4(acc[4*g+0][ni] + bv, acc[4*g+1][ni] + bv,
                               acc[4*g+2][ni] + bv, acc[4*g+3][ni] + bv);
        if (relu) {
          v.x = fmaxf(v.x, 0.f); v.y = fmaxf(v.y, 0.f);
          v.z = fmaxf(v.z, 0.f); v.w = fmaxf(v.w, 0.f);
        }
        *reinterpret_cast<float4*>(ob + (size_t)co * HW) = v;
      }
  }
}

// ---------------- FC GEMM fp32 (g0, g1, fc0-2) ------------------------------
__global__ __launch_bounds__(TPB) void gemm_ig2(
    const float* __restrict__ A, const float* __restrict__ W,
    const float* __restrict__ bias, float* __restrict__ C,
    int M, int K, int N, int relu)
{
  constexpr int BM = 64, BN = 32, BK = 32;
  __shared__ __align__(16) float As[BK][BM + 4];
  __shared__ __align__(16) float Ws[BK][BN + 4];
  const int tid = threadIdx.x;
  const int m0 = blockIdx.x * BM;
  const int n0 = blockIdx.y * BN;
  const int tn = tid & 15;
  const int tm = tid >> 4;
  float acc[4][2] = {{0.f,0.f},{0.f,0.f},{0.f,0.f},{0.f,0.f}};

  for (int kt = 0; kt < K; kt += BK) {
#pragma unroll
    for (int f = 0; f < 2; ++f) {
      int idx = f * TPB + tid;
      int kq = idx & 7;
      int m = idx >> 3;
      const float4 av = *reinterpret_cast<const float4*>(
          &A[(size_t)(m0 + m) * K + kt + 4 * kq]);
      As[4 * kq + 0][m] = av.x;
      As[4 * kq + 1][m] = av.y;
      As[4 * kq + 2][m] = av.z;
      As[4 * kq + 3][m] = av.w;
    }
#pragma unroll
    for (int i = 0; i < 4; ++i) {
      int lin = i * TPB + tid;
      int n = lin & 31;
      int kk = lin >> 5;
      Ws[kk][n] = W[(size_t)(kt + kk) * N + n0 + n];
    }
    __syncthreads();
#pragma unroll
    for (int k = 0; k < BK; ++k) {
      const float4 av = *reinterpret_cast<const float4*>(&As[k][4 * tm]);
      const float2 wv = *reinterpret_cast<const float2*>(&Ws[k][2 * tn]);
      acc[0][0] = fmaf(av.x, wv.x, acc[0][0]);
      acc[0][1] = fmaf(av.x, wv.y, acc[0][1]);
      acc[1][0] = fmaf(av.y, wv.x, acc[1][0]);
      acc[1][1] = fmaf(av.y, wv.y, acc[1][1]);
      acc[2][0] = fmaf(av.z, wv.x, acc[2][0]);
      acc[2][1] = fmaf(av.z, wv.y, acc[2][1]);
      acc[3][0] = fmaf(av.w, wv.x, acc[3][0]);
      acc[3][1] = fmaf(av.w, wv.y, acc[3][1]);
    }
    __syncthreads();
  }
  const float b0 = bias[n0 + 2 * tn];
  const float b1 = bias[n0 + 2 * tn + 1];
#pragma unroll
  for (int mi = 0; mi < 4; ++mi) {
    int m = m0 + 4 * tm + mi;
    float2 v = make_float2(acc[mi][0] + b0, acc[mi][1] + b1);
    if (relu) { v.x = fmaxf(v.x, 0.f); v.y = fmaxf(v.y, 0.f); }
    *reinterpret_cast<float2*>(&C[(size_t)m * N + n0 + 2 * tn]) = v;
  }
}

// ---------------- MFMA split-bf16 GEMM (g2): A fp32, out packed-hl ----------
// BM=64, BN=64, 4 waves; wave w: m-subtile w x 4 n-subtiles.
__global__ __launch_bounds__(TPB) void gemm_mfma(
    const float* __restrict__ A, const float* __restrict__ W,
    const float* __restrict__ bias, unsigned* __restrict__ out_hl,
    int M, int K, int N)
{
  __shared__ __align__(16) unsigned short Ah[64][40], Al[64][40];
  __shared__ __align__(16) unsigned short Bh[64][40], Bl[64][40];
  const int tid = threadIdx.x;
  const int m0 = blockIdx.x << 6;
  const int n0 = blockIdx.y << 6;
  const int lane = tid & 63, wv = tid >> 6;
  const int r = lane & 15, g = lane >> 4;
  f32x4 acc[4] = {};

  for (int kt = 0; kt < K; kt += 32) {
#pragma unroll
    for (int i = 0; i < 8; ++i) {          // A: 64m x 32k
      int lin = (i << 8) + tid;
      int kk = lin & 31, m = lin >> 5;
      float x = A[(size_t)(m0 + m) * K + kt + kk];
      unsigned short h = f2bf(x);
      Ah[m][kk] = h; Al[m][kk] = f2bf(x - bf2f(h));
    }
#pragma unroll
    for (int i = 0; i < 8; ++i) {          // W: 32k x 64n
      int lin = (i << 8) + tid;
      int n = lin & 63, kk = lin >> 6;
      float x = W[(size_t)(kt + kk) * N + n0 + n];
      unsigned short h = f2bf(x);
      Bh[n][kk] = h; Bl[n][kk] = f2bf(x - bf2f(h));
    }
    __syncthreads();
    short8v ah = *(const short8v*)&Ah[(wv << 4) + r][g << 3];
    short8v al = *(const short8v*)&Al[(wv << 4) + r][g << 3];
#pragma unroll
    for (int ns = 0; ns < 4; ++ns) {
      short8v bh = *(const short8v*)&Bh[(ns << 4) + r][g << 3];
      short8v bl = *(const short8v*)&Bl[(ns << 4) + r][g << 3];
      acc[ns] = __builtin_amdgcn_mfma_f32_16x16x32_bf16(ah, bh, acc[ns], 0, 0, 0);
      acc[ns] = __builtin_amdgcn_mfma_f32_16x16x32_bf16(ah, bl, acc[ns], 0, 0, 0);
      acc[ns] = __builtin_amdgcn_mfma_f32_16x16x32_bf16(al, bh, acc[ns], 0, 0, 0);
    }
    __syncthreads();
  }
#pragma unroll
  for (int ns = 0; ns < 4; ++ns)
#pragma unroll
    for (int q = 0; q < 4; ++q) {
      int m = m0 + (wv << 4) + (g << 2) + q;   // D row
      int n = n0 + (ns << 4) + r;              // D col
      float v = acc[ns][q] + bias[n];
      out_hl[(size_t)m * N + n] = packhl(v);
    }
}

// ---------------- MFMA split-bf16 convT (t0,t1,t2), per-parity --------------
// in packed-hl; BM=128 cells, BN=64 co; 4 waves; wave w: m-subs {2w,2w+1} x 4 n.
// EMIT: 1 -> packed-hl out, 0 -> fp32 out.
template<int EMIT>
__global__ __launch_bounds__(TPB) void convt_mfma(
    const unsigned* __restrict__ in_hl, const float* __restrict__ w,
    const float* __restrict__ bias, void* __restrict__ outv,
    int Ci, int Co, int Hi, int lwi, int relu)
{
  const int Wi = Hi;
  const int K = Ci << 2;
  const int py = blockIdx.z >> 1, px = blockIdx.z & 1;
  __shared__ __align__(16) unsigned short Ah[128][40], Al[128][40];
  __shared__ __align__(16) unsigned short Bh[64][40], Bl[64][40];
  const int tid = threadIdx.x;
  const int m0 = blockIdx.x << 7;
  const int n0 = blockIdx.y << 6;
  const int lane = tid & 63, wvi = tid >> 6;
  const int r = lane & 15, g = lane >> 4;
  f32x4 acc[2][4] = {};

  for (int kt = 0; kt < K; kt += 32) {
#pragma unroll
    for (int i = 0; i < 16; ++i) {         // A: 128 cells x 32 k
      int lin = (i << 8) + tid;
      int cl = lin & 127, kk = lin >> 7;
      int cell = m0 + cl;
      int k = kt + kk;
      int X = cell & (Wi - 1);
      int Y = (cell >> lwi) & (Wi - 1);
      int b = cell >> (lwi + lwi);
      int ci = k >> 2, ay = (k >> 1) & 1, ax = k & 1;
      int gy = Y + py - ay, gx = X + px - ax;
      unsigned v = 0u;
      if (gy >= 0 && gy < Hi && gx >= 0 && gx < Wi)
        v = in_hl[(((size_t)b * Ci + ci) * Hi + gy) * Wi + gx];
      Ah[cl][kk] = (unsigned short)(v & 0xffffu);
      Al[cl][kk] = (unsigned short)(v >> 16);
    }
#pragma unroll
    for (int i = 0; i < 8; ++i) {          // W: 32 k x 64 n (fp32 gather+split)
      int lin = (i << 8) + tid;
      int n = lin & 63, kk = lin >> 6;
      int k = kt + kk;
      int ci = k >> 2, ay = (k >> 1) & 1, ax = k & 1;
      int widx = ((1 - py) << 2) + (1 - px) + (ay << 3) + (ax << 1);
      float x = w[(((size_t)ci * Co + n0 + n) << 4) + widx];
      unsigned short h = f2bf(x);
      Bh[n][kk] = h; Bl[n][kk] = f2bf(x - bf2f(h));
    }
    __syncthreads();
    short8v ah0 = *(const short8v*)&Ah[(wvi << 5) + r][g << 3];
    short8v al0 = *(const short8v*)&Al[(wvi << 5) + r][g << 3];
    short8v ah1 = *(const short8v*)&Ah[(wvi << 5) + 16 + r][g << 3];
    short8v al1 = *(const short8v*)&Al[(wvi << 5) + 16 + r][g << 3];
#pragma unroll
    for (int ns = 0; ns < 4; ++ns) {
      short8v bh = *(const short8v*)&Bh[(ns << 4) + r][g << 3];
      short8v bl = *(const short8v*)&Bl[(ns << 4) + r][g << 3];
      acc[0][ns] = __builtin_amdgcn_mfma_f32_16x16x32_bf16(ah0, bh, acc[0][ns], 0, 0, 0);
      acc[0][ns] = __builtin_amdgcn_mfma_f32_16x16x32_bf16(ah0, bl, acc[0][ns], 0, 0, 0);
      acc[0][ns] = __builtin_amdgcn_mfma_f32_16x16x32_bf16(al0, bh, acc[0][ns], 0, 0, 0);
      acc[1][ns] = __builtin_amdgcn_mfma_f32_16x16x32_bf16(ah1, bh, acc[1][ns], 0, 0, 0);
      acc[1][ns] = __builtin_amdgcn_mfma_f32_16x16x32_bf16(ah1, bl, acc[1][ns], 0, 0, 0);
      acc[1][ns] = __builtin_amdgcn_mfma_f32_16x16x32_bf16(al1, bh, acc[1][ns], 0, 0, 0);
    }
    __syncthreads();
  }
  const int Ho = Hi << 1, Wo2 = Wi << 1;
#pragma unroll
  for (int ms = 0; ms < 2; ++ms)
#pragma unroll
    for (int ns = 0; ns < 4; ++ns)
#pragma unroll
      for (int q = 0; q < 4; ++q) {
        int m_local = ((wvi << 1) + ms) * 16 + (g << 2) + q;
        int n = n0 + (ns << 4) + r;
        int cell = m0 + m_local;
        int X = cell & (Wi - 1);
        int Y = (cell >> lwi) & (Wi - 1);
        int b = cell >> (lwi + lwi);
        float v = acc[ms][ns][q] + bias[n];
        if (relu) v = fmaxf(v, 0.f);
        size_t oidx = (((size_t)b * Co + n) * Ho + 2 * Y + py) * Wo2 + 2 * X + px;
        if (EMIT) ((unsigned*)outv)[oidx] = packhl(v);
        else      ((float*)outv)[oidx] = v;
      }
}

// ---------------- dedicated t3: convT 64->3, fp32 ---------------------------
__global__ __launch_bounds__(TPB) void convt3_kernel(
    const float* __restrict__ in, const float* __restrict__ w,
    const float* __restrict__ bias, float* __restrict__ out)
{
  __shared__ float wl[3072];
  __shared__ float il[8][33 * 32];
  const int b = blockIdx.x;
  const int tid = threadIdx.x;
  for (int i = tid; i < 3072; i += TPB) wl[i] = w[i];
  const int Y = tid >> 3;
  const int X0 = (tid & 7) << 2;
  float acc[3][2][8];
#pragma unroll
  for (int o = 0; o < 3; ++o)
#pragma unroll
    for (int p = 0; p < 2; ++p)
#pragma unroll
      for (int q = 0; q < 8; ++q) acc[o][p][q] = 0.f;

  const float* ib = in + (size_t)b * 64 * 1024;
  for (int c0 = 0; c0 < 64; c0 += 8) {
    __syncthreads();
    for (int i = tid; i < 8192; i += TPB) {
      int cc = i >> 10, y = (i >> 5) & 31, x = i & 31;
      il[cc][y * 33 + x] = ib[(size_t)c0 * 1024 + i];
    }
    __syncthreads();
    for (int cc = 0; cc < 8; ++cc) {
      float iv[3][6];
#pragma unroll
      for (int j = 0; j < 3; ++j) {
        int gy = Y - 1 + j;
        int gyc = min(max(gy, 0), 31);
        float my = (gy >= 0 && gy < 32) ? 1.f : 0.f;
#pragma unroll
        for (int k = 0; k < 6; ++k) {
          int gx = X0 - 1 + k;
          int gxc = min(max(gx, 0), 31);
          float mx = (gx >= 0 && gx < 32) ? 1.f : 0.f;
          iv[j][k] = il[cc][gyc * 33 + gxc] * (my * mx);
        }
      }
      const float* wq = &wl[(c0 + cc) * 48];
#pragma unroll
      for (int o = 0; o < 3; ++o) {
        const float* wo = wq + o * 16;
#pragma unroll
        for (int c = 0; c < 4; ++c) {
          acc[o][0][2*c]   = fmaf(iv[1][c+1], wo[5],  acc[o][0][2*c]);
          acc[o][0][2*c]   = fmaf(iv[1][c],   wo[7],  acc[o][0][2*c]);
          acc[o][0][2*c]   = fmaf(iv[0][c+1], wo[13], acc[o][0][2*c]);
          acc[o][0][2*c]   = fmaf(iv[0][c],   wo[15], acc[o][0][2*c]);
          acc[o][0][2*c+1] = fmaf(iv[1][c+2], wo[4],  acc[o][0][2*c+1]);
          acc[o][0][2*c+1] = fmaf(iv[1][c+1], wo[6],  acc[o][0][2*c+1]);
          acc[o][0][2*c+1] = fmaf(iv[0][c+2], wo[12], acc[o][0][2*c+1]);
          acc[o][0][2*c+1] = fmaf(iv[0][c+1], wo[14], acc[o][0][2*c+1]);
          acc[o][1][2*c]   = fmaf(iv[2][c+1], wo[1],  acc[o][1][2*c]);
          acc[o][1][2*c]   = fmaf(iv[2][c],   wo[3],  acc[o][1][2*c]);
          acc[o][1][2*c]   = fmaf(iv[1][c+1], wo[9],  acc[o][1][2*c]);
          acc[o][1][2*c]   = fmaf(iv[1][c],   wo[11], acc[o][1][2*c]);
          acc[o][1][2*c+1] = fmaf(iv[2][c+2], wo[0],  acc[o][1][2*c+1]);
          acc[o][1][2*c+1] = fmaf(iv[2][c+1], wo[2],  acc[o][1][2*c+1]);
          acc[o][1][2*c+1] = fmaf(iv[1][c+2], wo[8],  acc[o][1][2*c+1]);
          acc[o][1][2*c+1] = fmaf(iv[1][c+1], wo[10], acc[o][1][2*c+1]);
        }
      }
    }
  }
#pragma unroll
  for (int o = 0; o < 3; ++o) {
    float bv = bias[o];
#pragma unroll
    for (int p = 0; p < 2; ++p) {
      float* op = out + (((size_t)b * 3 + o) * 64 + 2 * Y + p) * 64 + 2 * X0;
      float4 v0 = make_float4(acc[o][p][0] + bv, acc[o][p][1] + bv,
                              acc[o][p][2] + bv, acc[o][p][3] + bv);
      float4 v1 = make_float4(acc[o][p][4] + bv, acc[o][p][5] + bv,
                              acc[o][p][6] + bv, acc[o][p][7] + bv);
      *reinterpret_cast<float4*>(op)     = v0;
      *reinterpret_cast<float4*>(op + 4) = v1;
    }
  }
}

// ---------------- VQ ---------------------------------------------------------
__global__ __launch_bounds__(TPB) void vq_kernel(
    const float* __restrict__ z, const float* __restrict__ cb,
    float* __restrict__ e, float* __restrict__ rowloss)
{
  const int row = blockIdx.x;
  const int b = row >> 4, s = row & 15;
  __shared__ float zr[64];
  __shared__ float bval[TPB];
  __shared__ int   bidx[TPB];
  const int tid = threadIdx.x;
  if (tid < 64) zr[tid] = z[(size_t)b * 1536 + s * 64 + tid];
  __syncthreads();

  float best = 3.4e38f;
  int bi = 0;
#pragma unroll
  for (int rep = 0; rep < 2; ++rep) {
    int j = tid + rep * TPB;
    const float4* c4 = reinterpret_cast<const float4*>(cb + (size_t)j * 64);
    float d = 0.f;
#pragma unroll
    for (int k = 0; k < 16; ++k) {
      float4 cv = c4[k];
      float t0 = zr[4 * k + 0] - cv.x;
      float t1 = zr[4 * k + 1] - cv.y;
      float t2 = zr[4 * k + 2] - cv.z;
      float t3 = zr[4 * k + 3] - cv.w;
      d = fmaf(t0, t0, d); d = fmaf(t1, t1, d);
      d = fmaf(t2, t2, d); d = fmaf(t3, t3, d);
    }
    if (d < best) { best = d; bi = j; }
  }
  bval[tid] = best; bidx[tid] = bi;
  __syncthreads();
  for (int sft = 128; sft > 0; sft >>= 1) {
    if (tid < sft) {
      float v2 = bval[tid + sft]; int i2 = bidx[tid + sft];
      if (v2 < bval[tid] || (v2 == bval[tid] && i2 < bidx[tid])) {
        bval[tid] = v2; bidx[tid] = i2;
      }
    }
    __syncthreads();
  }
  const int bj = bidx[0];
  if (tid < 64)
    e[(size_t)b * 1536 + s * 64 + tid] = cb[(size_t)bj * 64 + tid];
  if (tid == 0) rowloss[row] = bval[0];
}

__global__ __launch_bounds__(TPB) void zs_copy_kernel(
    const float* __restrict__ z, float* __restrict__ e)
{
  int i = blockIdx.x * TPB + threadIdx.x;
  int b = i >> 9, k = i & 511;
  e[(size_t)b * 1536 + 1024 + k] = z[(size_t)b * 1536 + 1024 + k];
}

__global__ __launch_bounds__(TPB) void loss_reduce_kernel(
    const float* __restrict__ rl, float* __restrict__ out)
{
  __shared__ float sm[TPB];
  float s = 0.f;
  for (int i = threadIdx.x; i < 4096; i += TPB) s += rl[i];
  sm[threadIdx.x] = s;
  __syncthreads();
  for (int sft = 128; sft > 0; sft >>= 1) {
    if (threadIdx.x < sft) sm[threadIdx.x] += sm[threadIdx.x + sft];
    __syncthreads();
  }
  if (threadIdx.x == 0) out[0] = sm[0] * (1.25f / 262144.f);
}

// ============================================================================
extern "C" void kernel_launch(void* const* d_in, const int* in_sizes, int n_in,
                              void* d_out, int out_size, void* d_ws, size_t ws_size,
                              hipStream_t stream)
{
  const float* x    = (const float*)d_in[0];
  const float* ew0  = (const float*)d_in[1];
  const float* eb0  = (const float*)d_in[2];
  const float* ew1  = (const float*)d_in[3];
  const float* eb1  = (const float*)d_in[4];
  const float* ew2  = (const float*)d_in[5];
  const float* eb2  = (const float*)d_in[6];
  const float* ew3  = (const float*)d_in[7];
  const float* eb3  = (const float*)d_in[8];
  const float* fw0  = (const float*)d_in[9];
  const float* fb0  = (const float*)d_in[10];
  const float* fw1  = (const float*)d_in[11];
  const float* fb1  = (const float*)d_in[12];
  const float* fw2  = (const float*)d_in[13];
  const float* fb2  = (const float*)d_in[14];
  const float* cb   = (const float*)d_in[15];
  const float* gw0  = (const float*)d_in[16];
  const float* gb0  = (const float*)d_in[17];
  const float* gw1  = (const float*)d_in[18];
  const float* gb1  = (const float*)d_in[19];
  const float* gw2  = (const float*)d_in[20];
  const float* gb2  = (const float*)d_in[21];
  const float* tw0  = (const float*)d_in[22];
  const float* tb0  = (const float*)d_in[23];
  const float* tw1  = (const float*)d_in[24];
  const float* tb1  = (const float*)d_in[25];
  const float* tw2  = (const float*)d_in[26];
  const float* tb2  = (const float*)d_in[27];
  const float* tw3  = (const float*)d_in[28];
  const float* tb3  = (const float*)d_in[29];

  float* out = (float*)d_out;
  float* ws  = (float*)d_ws;

  // encoder
  float* H0 = ws + 0;
  float* H1 = ws + 16777216;
  float* H2 = ws + 0;
  float* H3 = ws + 16777216;
  float* F0 = ws + 0;
  float* F1 = ws + 16777216;
  float* Z  = ws + 0;
  float* E  = ws + 16777216;
  // decoder
  float*    G0   = ws + 0;                              // 131072
  float*    G1   = ws + 262144;                         // 262144
  unsigned* G2hl = (unsigned*)(ws + 524288);            // 1048576
  unsigned* T0hl = (unsigned*)(ws + 1638400);           // 2097152
  unsigned* T1hl = (unsigned*)(ws + 16777216);          // 4194304 (exact fit)
  float*    T2   = ws + 0;                              // 16777216
  float*    RL   = ws + 20971520;                       // 4096

  // ---- encoder convs (fp32) ----
  conv_ig2<256,64,16,8,8><<<dim3(1024, 1), TPB, 0, stream>>>(x,  ew0, eb0, H0, 3,   64,  64, 5, 1);
  conv_ig2<128,64,16,4,8><<<dim3(512, 1),  TPB, 0, stream>>>(H0, ew1, eb1, H1, 64,  64,  32, 4, 1);
  conv_ig2<128,64,16,4,8><<<dim3(128, 2),  TPB, 0, stream>>>(H1, ew2, eb2, H2, 64,  128, 16, 3, 1);
  conv_ig2<64,64,32,4,4><<<dim3(64, 4),    TPB, 0, stream>>>(H2, ew3, eb3, H3, 128, 256, 8,  2, 0);

  // ---- encoder FC (fp32) ----
  gemm_ig2<<<dim3(4, 32), TPB, 0, stream>>>(H3, fw0, fb0, F0, 256, 4096, 1024, 1);
  gemm_ig2<<<dim3(4, 32), TPB, 0, stream>>>(F0, fw1, fb1, F1, 256, 1024, 1024, 1);
  gemm_ig2<<<dim3(4, 48), TPB, 0, stream>>>(F1, fw2, fb2, Z,  256, 1024, 1536, 0);

  // ---- VQ ----
  vq_kernel<<<dim3(4096), TPB, 0, stream>>>(Z, cb, E, RL);
  zs_copy_kernel<<<dim3(512), TPB, 0, stream>>>(Z, E);
  loss_reduce_kernel<<<dim3(1), TPB, 0, stream>>>(RL, out + (size_t)out_size - 1);

  // ---- decoder FC: g0,g1 fp32; g2 MFMA-split -> packed hl ----
  gemm_ig2<<<dim3(4, 16),  TPB, 0, stream>>>(E,  gw0, gb0, G0, 256, 1536, 512,  1);
  gemm_ig2<<<dim3(4, 32),  TPB, 0, stream>>>(G0, gw1, gb1, G1, 256, 512,  1024, 1);
  gemm_mfma<<<dim3(4, 64), TPB, 0, stream>>>(G1, gw2, gb2, G2hl, 256, 1024, 4096);

  // ---- decoder transposed convs: MFMA-split ----
  convt_mfma<1><<<dim3(32, 2, 4),  TPB, 0, stream>>>(G2hl, tw0, tb0, (void*)T0hl, 256, 128, 4,  2, 1);
  convt_mfma<1><<<dim3(128, 1, 4), TPB, 0, stream>>>(T0hl, tw1, tb1, (void*)T1hl, 128, 64,  8,  3, 1);
  convt_mfma<0><<<dim3(512, 1, 4), TPB, 0, stream>>>(T1hl, tw2, tb2, (void*)T2,   64,  64,  16, 4, 1);
  convt3_kernel<<<dim3(256), TPB, 0, stream>>>(T2, tw3, tb3, out);
}

// Round 5
// 805.386 us; speedup vs baseline: 9.6814x; 1.6193x over previous
//
#include <hip/hip_runtime.h>
#include <hip/hip_bf16.h>

// ============================================================================
// VQ-VAE forward, round 5: unified split-bf16 MFMA engine with XOR-swizzled,
// conflict-free LDS (b128 stage-writes + b128 fragment reads).
//   encoder: NS=3 split (6 MFMA terms)  -> fp32-class accuracy (argmin-safe)
//   decoder: NS=2 split (3 MFMA terms)  -> proven in R4 (absmax 2.4e-4)
// Activations fp32 in HBM (encoder) / packed u32 hi|lo<<16 (decoder heavies).
//
// LDS layout per GEMM-row: NS sub-arrays x 32 bf16 (64B each), 16B chunks,
// physical chunk = (s*4 + octet) ^ (row & 7).  Rows: NS=3 -> 256B, NS=2 ->128B.
// Writes: b128 per sub-array (8 slot-groups x 8 lanes = balanced).
// Reads:  fragment (8 bf16) = one b128 at chunk (s*4+g) ^ (row&7).
//
// Workspace (float offsets), peak 28,643,328 floats = 114.6 MB:
//  H0=0(16.78M) H1=16.78M(4.19M) H2=0(1.05M) H3=16.78M(1.05M)
//  F0=0 F1=262144 Z=524288 E=917504 G0=1310720 G1=1441792
//  G2p=1703936(u32,1.05M) T0p=2752512(2.10M) T1p=4849664(4.19M)
//  T2=9043968(16.78M) WTP0=25821184 WTP1=26345472 WTP2=26476544
//  P=26542080(2.10M) RL=28639232
// All producer/consumer pairs disjoint; every buffer fully written before read.
// ============================================================================

#define TPB 256
typedef __attribute__((ext_vector_type(8))) short short8v;
typedef __attribute__((ext_vector_type(4))) float f32x4;
typedef unsigned int u32;
typedef unsigned short u16;

__device__ inline u16 f2bf(float x){ union{float f;u32 u;}v; v.f=x; u32 r=v.u+0x7fffu+((v.u>>16)&1u); return (u16)(r>>16);}
__device__ inline float bf2f(u16 h){ union{u32 u;float f;}v; v.u=((u32)h)<<16; return v.f;}
__device__ inline u32 packhl(float x){ u16 h=f2bf(x); u16 l=f2bf(x-bf2f(h)); return ((u32)l<<16)|(u32)h;}

template<int NS>
__device__ inline void splitN(float x, u16 t[3]) {
  u16 h0 = f2bf(x); t[0] = h0;
  float r1 = x - bf2f(h0);
  u16 h1 = f2bf(r1); t[1] = h1;
  if (NS == 3) { float r2 = r1 - bf2f(h1); t[2] = f2bf(r2); }
}

// stage-write: row, octet o (8 k-elements), NS sub-arrays -> NS b128 writes
template<int NS, int ST>
__device__ inline void stW(u32* L, int row, int oct, const u16 hs[3][8]) {
  const int sw = row & 7;
#pragma unroll
  for (int s = 0; s < NS; ++s) {
    uint4 d;
    d.x = (u32)hs[s][0] | ((u32)hs[s][1] << 16);
    d.y = (u32)hs[s][2] | ((u32)hs[s][3] << 16);
    d.z = (u32)hs[s][4] | ((u32)hs[s][5] << 16);
    d.w = (u32)hs[s][6] | ((u32)hs[s][7] << 16);
    int ch = (((s << 2) | oct) ^ sw) << 2;
    *reinterpret_cast<uint4*>(&L[row * ST + ch]) = d;
  }
}

template<int ST>
__device__ inline short8v rdFrag(const u32* L, int row, int c) {
  int ph = (c ^ (row & 7)) << 2;
  return *reinterpret_cast<const short8v*>(&L[row * ST + ph]);
}

// ---------------- MFMA GEMM (BM=64, BN=64, 4 waves, split-K over grid.z) ----
// OUTM 0: partial f32 [z][M][N] (no bias); OUTM 1: packed u32 + bias (g2).
template<int NS, int OUTM>
__global__ __launch_bounds__(TPB) void gemm_mf(
    const float* __restrict__ A, const float* __restrict__ W,
    const float* __restrict__ bias, void* __restrict__ outp,
    int M, int K, int N, int KSPL)
{
  constexpr int ST = (NS == 3) ? 64 : 32;
  __shared__ __align__(16) u32 L[(64 + 64) * ST];
  u32* AL = L; u32* BL = L + 64 * ST;
  const int tid = threadIdx.x;
  const int m0 = blockIdx.x << 6, n0 = blockIdx.y << 6;
  const int lane = tid & 63, wv = tid >> 6, r = lane & 15, g = lane >> 4;
  const int kb0 = blockIdx.z * KSPL;
  const int cl = tid & 63, oct = tid >> 6;
  f32x4 acc[4] = {};

  for (int kt = kb0; kt < kb0 + KSPL; kt += 32) {
    { // A-stage: 8 consecutive k, coalesced float4 x2, split in-register
      const float* ap = &A[(size_t)(m0 + cl) * K + kt + (oct << 3)];
      float v[8];
      *reinterpret_cast<float4*>(&v[0]) = *reinterpret_cast<const float4*>(ap);
      *reinterpret_cast<float4*>(&v[4]) = *reinterpret_cast<const float4*>(ap + 4);
      u16 hs[3][8];
#pragma unroll
      for (int e = 0; e < 8; ++e) {
        u16 t3[3]; splitN<NS>(v[e], t3);
        hs[0][e] = t3[0]; hs[1][e] = t3[1]; if (NS == 3) hs[2][e] = t3[2];
      }
      stW<NS, ST>(AL, cl, oct, hs);
    }
    { // B-stage: W[K][N], lane-minor n => 256B coalesced rows
      u16 hs[3][8];
#pragma unroll
      for (int e = 0; e < 8; ++e) {
        float x = W[(size_t)(kt + (oct << 3) + e) * N + n0 + cl];
        u16 t3[3]; splitN<NS>(x, t3);
        hs[0][e] = t3[0]; hs[1][e] = t3[1]; if (NS == 3) hs[2][e] = t3[2];
      }
      stW<NS, ST>(BL, cl, oct, hs);
    }
    __syncthreads();
    short8v a_[3];
#pragma unroll
    for (int s = 0; s < NS; ++s) a_[s] = rdFrag<ST>(AL, (wv << 4) + r, (s << 2) | g);
#pragma unroll
    for (int ns = 0; ns < 4; ++ns) {
      short8v b_[3];
#pragma unroll
      for (int s = 0; s < NS; ++s) b_[s] = rdFrag<ST>(BL, (ns << 4) + r, (s << 2) | g);
      acc[ns] = __builtin_amdgcn_mfma_f32_16x16x32_bf16(a_[0], b_[0], acc[ns], 0, 0, 0);
      acc[ns] = __builtin_amdgcn_mfma_f32_16x16x32_bf16(a_[0], b_[1], acc[ns], 0, 0, 0);
      acc[ns] = __builtin_amdgcn_mfma_f32_16x16x32_bf16(a_[1], b_[0], acc[ns], 0, 0, 0);
      if (NS == 3) {
        acc[ns] = __builtin_amdgcn_mfma_f32_16x16x32_bf16(a_[1], b_[1], acc[ns], 0, 0, 0);
        acc[ns] = __builtin_amdgcn_mfma_f32_16x16x32_bf16(a_[0], b_[2], acc[ns], 0, 0, 0);
        acc[ns] = __builtin_amdgcn_mfma_f32_16x16x32_bf16(a_[2], b_[0], acc[ns], 0, 0, 0);
      }
    }
    __syncthreads();
  }
#pragma unroll
  for (int ns = 0; ns < 4; ++ns)
#pragma unroll
    for (int q = 0; q < 4; ++q) {
      int m = m0 + (wv << 4) + (g << 2) + q;
      int n = n0 + (ns << 4) + r;
      float v = acc[ns][q];
      if (OUTM == 0) ((float*)outp)[((size_t)blockIdx.z * M + m) * N + n] = v;
      else           ((u32*)outp)[(size_t)m * N + n] = packhl(v + bias[n]);
    }
}

// ---------------- MFMA conv (s2,k4,p1), NS=3, fp32 in/out -------------------
template<int BM>
__global__ __launch_bounds__(TPB) void conv_mf3(
    const float* __restrict__ in, const float* __restrict__ w,
    const float* __restrict__ bias, float* __restrict__ out,
    int Ci, int Co, int Hi, int lwo, int relu)
{
  constexpr int ST = 64, MS = BM / 64;
  __shared__ __align__(16) u32 L[(BM + 64) * ST];
  u32* AL = L; u32* BL = L + BM * ST;
  const int Wi = Hi, Wo = Hi >> 1;
  const int K = Ci << 4;
  const int tid = threadIdx.x;
  const int m0 = blockIdx.x * BM, n0 = blockIdx.y << 6;
  const int lane = tid & 63, wv = tid >> 6, r = lane & 15, g = lane >> 4;
  f32x4 acc[MS][4] = {};

  for (int kb = 0; kb < K; kb += 32) {
#pragma unroll
    for (int p = 0; p < MS; ++p) {   // A-stage: im2col gather + split3
      int cl, oct;
      if (BM == 128) { cl = tid & 127; oct = (tid >> 7) + (p << 1); }
      else           { cl = tid & 63;  oct = tid >> 6; }
      int cell = m0 + cl;
      int x = cell & (Wo - 1), y = (cell >> lwo) & (Wo - 1), b = cell >> (lwo + lwo);
      int k8 = kb + (oct << 3);
      u16 hs[3][8];
      if (k8 < K) {
        int ci = k8 >> 4, kh0 = (k8 >> 2) & 3;
        int gy0 = 2 * y - 1 + kh0, gx0 = 2 * x - 1;
        const float* ip = &in[((size_t)b * Ci + ci) * Hi * Wi];
#pragma unroll
        for (int e = 0; e < 8; ++e) {
          int gy = gy0 + (e >> 2), gx = gx0 + (e & 3);
          float v = 0.f;
          if (gy >= 0 && gy < Hi && gx >= 0 && gx < Wi) v = ip[gy * Wi + gx];
          u16 t3[3]; splitN<3>(v, t3);
          hs[0][e] = t3[0]; hs[1][e] = t3[1]; hs[2][e] = t3[2];
        }
      } else {
#pragma unroll
        for (int s = 0; s < 3; ++s)
#pragma unroll
          for (int e = 0; e < 8; ++e) hs[s][e] = 0;
      }
      stW<3, ST>(AL, cl, oct, hs);
    }
    { // B-stage: w[co][K] contiguous, float4 x2 + split3
      int n = tid & 63, oct2 = tid >> 6;
      int k8 = kb + (oct2 << 3);
      u16 hs[3][8];
      if (k8 < K) {
        const float* wp = &w[(size_t)(n0 + n) * K + k8];
        float v[8];
        *reinterpret_cast<float4*>(&v[0]) = *reinterpret_cast<const float4*>(wp);
        *reinterpret_cast<float4*>(&v[4]) = *reinterpret_cast<const float4*>(wp + 4);
#pragma unroll
        for (int e = 0; e < 8; ++e) {
          u16 t3[3]; splitN<3>(v[e], t3);
          hs[0][e] = t3[0]; hs[1][e] = t3[1]; hs[2][e] = t3[2];
        }
      } else {
#pragma unroll
        for (int s = 0; s < 3; ++s)
#pragma unroll
          for (int e = 0; e < 8; ++e) hs[s][e] = 0;
      }
      stW<3, ST>(BL, n, oct2, hs);
    }
    __syncthreads();
    short8v a_[MS][3];
#pragma unroll
    for (int mm = 0; mm < MS; ++mm)
#pragma unroll
      for (int s = 0; s < 3; ++s)
        a_[mm][s] = rdFrag<ST>(AL, (wv * MS + mm) * 16 + r, (s << 2) | g);
#pragma unroll
    for (int ns = 0; ns < 4; ++ns) {
      short8v b_[3];
#pragma unroll
      for (int s = 0; s < 3; ++s) b_[s] = rdFrag<ST>(BL, (ns << 4) + r, (s << 2) | g);
#pragma unroll
      for (int mm = 0; mm < MS; ++mm) {
        acc[mm][ns] = __builtin_amdgcn_mfma_f32_16x16x32_bf16(a_[mm][0], b_[0], acc[mm][ns], 0, 0, 0);
        acc[mm][ns] = __builtin_amdgcn_mfma_f32_16x16x32_bf16(a_[mm][0], b_[1], acc[mm][ns], 0, 0, 0);
        acc[mm][ns] = __builtin_amdgcn_mfma_f32_16x16x32_bf16(a_[mm][1], b_[0], acc[mm][ns], 0, 0, 0);
        acc[mm][ns] = __builtin_amdgcn_mfma_f32_16x16x32_bf16(a_[mm][1], b_[1], acc[mm][ns], 0, 0, 0);
        acc[mm][ns] = __builtin_amdgcn_mfma_f32_16x16x32_bf16(a_[mm][0], b_[2], acc[mm][ns], 0, 0, 0);
        acc[mm][ns] = __builtin_amdgcn_mfma_f32_16x16x32_bf16(a_[mm][2], b_[0], acc[mm][ns], 0, 0, 0);
      }
    }
    __syncthreads();
  }
#pragma unroll
  for (int mm = 0; mm < MS; ++mm)
#pragma unroll
    for (int ns = 0; ns < 4; ++ns) {
      int c0 = m0 + (wv * MS + mm) * 16 + (g << 2);
      int x0 = c0 & (Wo - 1), y = (c0 >> lwo) & (Wo - 1), b = c0 >> (lwo + lwo);
      int co = n0 + (ns << 4) + r;
      float bv = bias[co];
      float4 o;
      o.x = acc[mm][ns][0] + bv; o.y = acc[mm][ns][1] + bv;
      o.z = acc[mm][ns][2] + bv; o.w = acc[mm][ns][3] + bv;
      if (relu) { o.x = fmaxf(o.x, 0.f); o.y = fmaxf(o.y, 0.f);
                  o.z = fmaxf(o.z, 0.f); o.w = fmaxf(o.w, 0.f); }
      *reinterpret_cast<float4*>(&out[(((size_t)b * Co + co) * Wo + y) * Wo + x0]) = o;
    }
}

// ---------------- MFMA convT (s2,k4,p1) per-parity, NS=2, packed u32 in -----
// EMIT 1: packed u32 out; EMIT 0: fp32 out.  Weights pre-transformed
// per-parity to [p][co][K4] fp32 (K4 = Ci*4).
template<int BM, int EMIT>
__global__ __launch_bounds__(TPB) void convt_mf2(
    const u32* __restrict__ in, const float* __restrict__ wtp,
    const float* __restrict__ bias, void* __restrict__ outv,
    int Ci, int Co, int Hi, int lwi, int relu)
{
  constexpr int ST = 32, MS = BM / 64;
  __shared__ __align__(16) u32 L[(BM + 64) * ST];
  u32* AL = L; u32* BL = L + BM * ST;
  const int Wi = Hi, K4 = Ci << 2;
  const int par = blockIdx.z, py = par >> 1, px = par & 1;
  const int tid = threadIdx.x;
  const int m0 = blockIdx.x * BM, n0 = blockIdx.y << 6;
  const int lane = tid & 63, wv = tid >> 6, r = lane & 15, g = lane >> 4;
  f32x4 acc[MS][4] = {};

  for (int kb = 0; kb < K4; kb += 32) {
#pragma unroll
    for (int p = 0; p < MS; ++p) {   // A-stage: packed-u32 im2col gather
      int cl, oct;
      if (BM == 128) { cl = tid & 127; oct = (tid >> 7) + (p << 1); }
      else           { cl = tid & 63;  oct = tid >> 6; }
      int cell = m0 + cl;
      int X = cell & (Wi - 1), Y = (cell >> lwi) & (Wi - 1), b = cell >> (lwi + lwi);
      int k8 = kb + (oct << 3);
      int ci0 = k8 >> 2;
      u32 v[8];
#pragma unroll
      for (int e = 0; e < 8; ++e) {
        int ci = ci0 + (e >> 2), ay = (e >> 1) & 1, ax = e & 1;
        int gy = Y + py - ay, gx = X + px - ax;
        u32 t = 0u;
        if (gy >= 0 && gy < Hi && gx >= 0 && gx < Wi)
          t = in[(((size_t)b * Ci + ci) * Hi + gy) * Wi + gx];
        v[e] = t;
      }
      const int sw = cl & 7;
      uint4 dh, dl;
      dh.x = (v[0] & 0xffffu) | (v[1] << 16);  dl.x = (v[0] >> 16) | (v[1] & 0xffff0000u);
      dh.y = (v[2] & 0xffffu) | (v[3] << 16);  dl.y = (v[2] >> 16) | (v[3] & 0xffff0000u);
      dh.z = (v[4] & 0xffffu) | (v[5] << 16);  dl.z = (v[4] >> 16) | (v[5] & 0xffff0000u);
      dh.w = (v[6] & 0xffffu) | (v[7] << 16);  dl.w = (v[6] >> 16) | (v[7] & 0xffff0000u);
      *reinterpret_cast<uint4*>(&AL[cl * ST + ((oct ^ sw) << 2)]) = dh;
      *reinterpret_cast<uint4*>(&AL[cl * ST + (((4 | oct) ^ sw) << 2)]) = dl;
    }
    { // B-stage: wtp[par][co][K4] fp32, float4 x2 + split2
      int n = tid & 63, oct2 = tid >> 6;
      const float* wp = &wtp[((size_t)par * Co + n0 + n) * K4 + kb + (oct2 << 3)];
      float v[8];
      *reinterpret_cast<float4*>(&v[0]) = *reinterpret_cast<const float4*>(wp);
      *reinterpret_cast<float4*>(&v[4]) = *reinterpret_cast<const float4*>(wp + 4);
      u16 hs[3][8];
#pragma unroll
      for (int e = 0; e < 8; ++e) {
        u16 t3[3]; splitN<2>(v[e], t3);
        hs[0][e] = t3[0]; hs[1][e] = t3[1];
      }
      stW<2, ST>(BL, n, oct2, hs);
    }
    __syncthreads();
    short8v a_[MS][2];
#pragma unroll
    for (int mm = 0; mm < MS; ++mm)
#pragma unroll
      for (int s = 0; s < 2; ++s)
        a_[mm][s] = rdFrag<ST>(AL, (wv * MS + mm) * 16 + r, (s << 2) | g);
#pragma unroll
    for (int ns = 0; ns < 4; ++ns) {
      short8v b_[2];
#pragma unroll
      for (int s = 0; s < 2; ++s) b_[s] = rdFrag<ST>(BL, (ns << 4) + r, (s << 2) | g);
#pragma unroll
      for (int mm = 0; mm < MS; ++mm) {
        acc[mm][ns] = __builtin_amdgcn_mfma_f32_16x16x32_bf16(a_[mm][0], b_[0], acc[mm][ns], 0, 0, 0);
        acc[mm][ns] = __builtin_amdgcn_mfma_f32_16x16x32_bf16(a_[mm][0], b_[1], acc[mm][ns], 0, 0, 0);
        acc[mm][ns] = __builtin_amdgcn_mfma_f32_16x16x32_bf16(a_[mm][1], b_[0], acc[mm][ns], 0, 0, 0);
      }
    }
    __syncthreads();
  }
  const int Ho = Hi << 1, Wo2 = Wi << 1;
#pragma unroll
  for (int mm = 0; mm < MS; ++mm)
#pragma unroll
    for (int ns = 0; ns < 4; ++ns)
#pragma unroll
      for (int q = 0; q < 4; ++q) {
        int cell = m0 + (wv * MS + mm) * 16 + (g << 2) + q;
        int X = cell & (Wi - 1), Y = (cell >> lwi) & (Wi - 1), b = cell >> (lwi + lwi);
        int co = n0 + (ns << 4) + r;
        float v = acc[mm][ns][q] + bias[co];
        if (relu) v = fmaxf(v, 0.f);
        size_t oi = (((size_t)b * Co + co) * Ho + 2 * Y + py) * Wo2 + 2 * X + px;
        if (EMIT) ((u32*)outv)[oi] = packhl(v);
        else      ((float*)outv)[oi] = v;
      }
}

// ---------------- convT weight prep: src[Ci][Co][16] -> dst[p][Co][Ci*4] ----
__global__ __launch_bounds__(TPB) void wprep_k(
    const float* __restrict__ src, float* __restrict__ dst, int Ci, int Co)
{
  int K4 = Ci << 2;
  int tot = 4 * Co * K4;
  for (int i = blockIdx.x * TPB + threadIdx.x; i < tot; i += gridDim.x * TPB) {
    int p = i / (Co * K4); int rem = i - p * (Co * K4);
    int co = rem / K4; int k4 = rem - co * K4;
    int ci = k4 >> 2, ay = (k4 >> 1) & 1, ax = k4 & 1;
    int py = p >> 1, px = p & 1;
    int widx = ((1 - py) << 2) + (1 - px) + (ay << 3) + (ax << 1);
    dst[i] = src[(((size_t)ci * Co + co) << 4) + widx];
  }
}

// ---------------- split-K combine: out = relu(sum_z P[z] + bias) ------------
__global__ __launch_bounds__(TPB) void combine_k(
    const float* __restrict__ P, const float* __restrict__ bias,
    float* __restrict__ out, int MN, int N, int SK, int relu)
{
  int i4 = (blockIdx.x * TPB + threadIdx.x) << 2;
  if (i4 >= MN) return;
  float4 s = make_float4(0.f, 0.f, 0.f, 0.f);
  for (int z = 0; z < SK; ++z) {
    const float4 pv = *reinterpret_cast<const float4*>(&P[(size_t)z * MN + i4]);
    s.x += pv.x; s.y += pv.y; s.z += pv.z; s.w += pv.w;
  }
  int n = i4 % N;
  s.x += bias[n]; s.y += bias[n + 1]; s.z += bias[n + 2]; s.w += bias[n + 3];
  if (relu) { s.x = fmaxf(s.x, 0.f); s.y = fmaxf(s.y, 0.f);
              s.z = fmaxf(s.z, 0.f); s.w = fmaxf(s.w, 0.f); }
  *reinterpret_cast<float4*>(&out[i4]) = s;
}

// ---------------- fp32 FC GEMM (g0, g1 only) --------------------------------
__global__ __launch_bounds__(TPB) void gemm_ig2(
    const float* __restrict__ A, const float* __restrict__ W,
    const float* __restrict__ bias, float* __restrict__ C,
    int M, int K, int N, int relu)
{
  constexpr int BM = 64, BN = 32, BK = 32;
  __shared__ __align__(16) float As[BK][BM + 4];
  __shared__ __align__(16) float Ws[BK][BN + 4];
  const int tid = threadIdx.x;
  const int m0 = blockIdx.x * BM;
  const int n0 = blockIdx.y * BN;
  const int tn = tid & 15;
  const int tm = tid >> 4;
  float acc[4][2] = {{0.f,0.f},{0.f,0.f},{0.f,0.f},{0.f,0.f}};

  for (int kt = 0; kt < K; kt += BK) {
#pragma unroll
    for (int f = 0; f < 2; ++f) {
      int idx = f * TPB + tid;
      int kq = idx & 7;
      int m = idx >> 3;
      const float4 av = *reinterpret_cast<const float4*>(
          &A[(size_t)(m0 + m) * K + kt + 4 * kq]);
      As[4 * kq + 0][m] = av.x;
      As[4 * kq + 1][m] = av.y;
      As[4 * kq + 2][m] = av.z;
      As[4 * kq + 3][m] = av.w;
    }
#pragma unroll
    for (int i = 0; i < 4; ++i) {
      int lin = i * TPB + tid;
      int n = lin & 31;
      int kk = lin >> 5;
      Ws[kk][n] = W[(size_t)(kt + kk) * N + n0 + n];
    }
    __syncthreads();
#pragma unroll
    for (int k = 0; k < BK; ++k) {
      const float4 av = *reinterpret_cast<const float4*>(&As[k][4 * tm]);
      const float2 wv = *reinterpret_cast<const float2*>(&Ws[k][2 * tn]);
      acc[0][0] = fmaf(av.x, wv.x, acc[0][0]);
      acc[0][1] = fmaf(av.x, wv.y, acc[0][1]);
      acc[1][0] = fmaf(av.y, wv.x, acc[1][0]);
      acc[1][1] = fmaf(av.y, wv.y, acc[1][1]);
      acc[2][0] = fmaf(av.z, wv.x, acc[2][0]);
      acc[2][1] = fmaf(av.z, wv.y, acc[2][1]);
      acc[3][0] = fmaf(av.w, wv.x, acc[3][0]);
      acc[3][1] = fmaf(av.w, wv.y, acc[3][1]);
    }
    __syncthreads();
  }
  const float b0 = bias[n0 + 2 * tn];
  const float b1 = bias[n0 + 2 * tn + 1];
#pragma unroll
  for (int mi = 0; mi < 4; ++mi) {
    int m = m0 + 4 * tm + mi;
    float2 v = make_float2(acc[mi][0] + b0, acc[mi][1] + b1);
    if (relu) { v.x = fmaxf(v.x, 0.f); v.y = fmaxf(v.y, 0.f); }
    *reinterpret_cast<float2*>(&C[(size_t)m * N + n0 + 2 * tn]) = v;
  }
}

// ---------------- dedicated t3: convT 64->3, fp32 ---------------------------
__global__ __launch_bounds__(TPB) void convt3_kernel(
    const float* __restrict__ in, const float* __restrict__ w,
    const float* __restrict__ bias, float* __restrict__ out)
{
  __shared__ float wl[3072];
  __shared__ float il[8][33 * 32];
  const int b = blockIdx.x;
  const int tid = threadIdx.x;
  for (int i = tid; i < 3072; i += TPB) wl[i] = w[i];
  const int Y = tid >> 3;
  const int X0 = (tid & 7) << 2;
  float acc[3][2][8];
#pragma unroll
  for (int o = 0; o < 3; ++o)
#pragma unroll
    for (int p = 0; p < 2; ++p)
#pragma unroll
      for (int q = 0; q < 8; ++q) acc[o][p][q] = 0.f;

  const float* ib = in + (size_t)b * 64 * 1024;
  for (int c0 = 0; c0 < 64; c0 += 8) {
    __syncthreads();
    for (int i = tid; i < 8192; i += TPB) {
      int cc = i >> 10, y = (i >> 5) & 31, x = i & 31;
      il[cc][y * 33 + x] = ib[(size_t)c0 * 1024 + i];
    }
    __syncthreads();
    for (int cc = 0; cc < 8; ++cc) {
      float iv[3][6];
#pragma unroll
      for (int j = 0; j < 3; ++j) {
        int gy = Y - 1 + j;
        int gyc = min(max(gy, 0), 31);
        float my = (gy >= 0 && gy < 32) ? 1.f : 0.f;
#pragma unroll
        for (int k = 0; k < 6; ++k) {
          int gx = X0 - 1 + k;
          int gxc = min(max(gx, 0), 31);
          float mx = (gx >= 0 && gx < 32) ? 1.f : 0.f;
          iv[j][k] = il[cc][gyc * 33 + gxc] * (my * mx);
        }
      }
      const float* wq = &wl[(c0 + cc) * 48];
#pragma unroll
      for (int o = 0; o < 3; ++o) {
        const float* wo = wq + o * 16;
#pragma unroll
        for (int c = 0; c < 4; ++c) {
          acc[o][0][2*c]   = fmaf(iv[1][c+1], wo[5],  acc[o][0][2*c]);
          acc[o][0][2*c]   = fmaf(iv[1][c],   wo[7],  acc[o][0][2*c]);
          acc[o][0][2*c]   = fmaf(iv[0][c+1], wo[13], acc[o][0][2*c]);
          acc[o][0][2*c]   = fmaf(iv[0][c],   wo[15], acc[o][0][2*c]);
          acc[o][0][2*c+1] = fmaf(iv[1][c+2], wo[4],  acc[o][0][2*c+1]);
          acc[o][0][2*c+1] = fmaf(iv[1][c+1], wo[6],  acc[o][0][2*c+1]);
          acc[o][0][2*c+1] = fmaf(iv[0][c+2], wo[12], acc[o][0][2*c+1]);
          acc[o][0][2*c+1] = fmaf(iv[0][c+1], wo[14], acc[o][0][2*c+1]);
          acc[o][1][2*c]   = fmaf(iv[2][c+1], wo[1],  acc[o][1][2*c]);
          acc[o][1][2*c]   = fmaf(iv[2][c],   wo[3],  acc[o][1][2*c]);
          acc[o][1][2*c]   = fmaf(iv[1][c+1], wo[9],  acc[o][1][2*c]);
          acc[o][1][2*c]   = fmaf(iv[1][c],   wo[11], acc[o][1][2*c]);
          acc[o][1][2*c+1] = fmaf(iv[2][c+2], wo[0],  acc[o][1][2*c+1]);
          acc[o][1][2*c+1] = fmaf(iv[2][c+1], wo[2],  acc[o][1][2*c+1]);
          acc[o][1][2*c+1] = fmaf(iv[1][c+2], wo[8],  acc[o][1][2*c+1]);
          acc[o][1][2*c+1] = fmaf(iv[1][c+1], wo[10], acc[o][1][2*c+1]);
        }
      }
    }
  }
#pragma unroll
  for (int o = 0; o < 3; ++o) {
    float bv = bias[o];
#pragma unroll
    for (int p = 0; p < 2; ++p) {
      float* op = out + (((size_t)b * 3 + o) * 64 + 2 * Y + p) * 64 + 2 * X0;
      float4 v0 = make_float4(acc[o][p][0] + bv, acc[o][p][1] + bv,
                              acc[o][p][2] + bv, acc[o][p][3] + bv);
      float4 v1 = make_float4(acc[o][p][4] + bv, acc[o][p][5] + bv,
                              acc[o][p][6] + bv, acc[o][p][7] + bv);
      *reinterpret_cast<float4*>(op)     = v0;
      *reinterpret_cast<float4*>(op + 4) = v1;
    }
  }
}

// ---------------- VQ ---------------------------------------------------------
__global__ __launch_bounds__(TPB) void vq_kernel(
    const float* __restrict__ z, const float* __restrict__ cb,
    float* __restrict__ e, float* __restrict__ rowloss)
{
  const int row = blockIdx.x;
  const int b = row >> 4, s = row & 15;
  __shared__ float zr[64];
  __shared__ float bval[TPB];
  __shared__ int   bidx[TPB];
  const int tid = threadIdx.x;
  if (tid < 64) zr[tid] = z[(size_t)b * 1536 + s * 64 + tid];
  __syncthreads();

  float best = 3.4e38f;
  int bi = 0;
#pragma unroll
  for (int rep = 0; rep < 2; ++rep) {
    int j = tid + rep * TPB;
    const float4* c4 = reinterpret_cast<const float4*>(cb + (size_t)j * 64);
    float d = 0.f;
#pragma unroll
    for (int k = 0; k < 16; ++k) {
      float4 cv = c4[k];
      float t0 = zr[4 * k + 0] - cv.x;
      float t1 = zr[4 * k + 1] - cv.y;
      float t2 = zr[4 * k + 2] - cv.z;
      float t3 = zr[4 * k + 3] - cv.w;
      d = fmaf(t0, t0, d); d = fmaf(t1, t1, d);
      d = fmaf(t2, t2, d); d = fmaf(t3, t3, d);
    }
    if (d < best) { best = d; bi = j; }
  }
  bval[tid] = best; bidx[tid] = bi;
  __syncthreads();
  for (int sft = 128; sft > 0; sft >>= 1) {
    if (tid < sft) {
      float v2 = bval[tid + sft]; int i2 = bidx[tid + sft];
      if (v2 < bval[tid] || (v2 == bval[tid] && i2 < bidx[tid])) {
        bval[tid] = v2; bidx[tid] = i2;
      }
    }
    __syncthreads();
  }
  const int bj = bidx[0];
  if (tid < 64)
    e[(size_t)b * 1536 + s * 64 + tid] = cb[(size_t)bj * 64 + tid];
  if (tid == 0) rowloss[row] = bval[0];
}

__global__ __launch_bounds__(TPB) void zs_copy_kernel(
    const float* __restrict__ z, float* __restrict__ e)
{
  int i = blockIdx.x * TPB + threadIdx.x;
  int b = i >> 9, k = i & 511;
  e[(size_t)b * 1536 + 1024 + k] = z[(size_t)b * 1536 + 1024 + k];
}

__global__ __launch_bounds__(TPB) void loss_reduce_kernel(
    const float* __restrict__ rl, float* __restrict__ out)
{
  __shared__ float sm[TPB];
  float s = 0.f;
  for (int i = threadIdx.x; i < 4096; i += TPB) s += rl[i];
  sm[threadIdx.x] = s;
  __syncthreads();
  for (int sft = 128; sft > 0; sft >>= 1) {
    if (threadIdx.x < sft) sm[threadIdx.x] += sm[threadIdx.x + sft];
    __syncthreads();
  }
  if (threadIdx.x == 0) out[0] = sm[0] * (1.25f / 262144.f);
}

// ============================================================================
extern "C" void kernel_launch(void* const* d_in, const int* in_sizes, int n_in,
                              void* d_out, int out_size, void* d_ws, size_t ws_size,
                              hipStream_t stream)
{
  const float* x    = (const float*)d_in[0];
  const float* ew0  = (const float*)d_in[1];
  const float* eb0  = (const float*)d_in[2];
  const float* ew1  = (const float*)d_in[3];
  const float* eb1  = (const float*)d_in[4];
  const float* ew2  = (const float*)d_in[5];
  const float* eb2  = (const float*)d_in[6];
  const float* ew3  = (const float*)d_in[7];
  const float* eb3  = (const float*)d_in[8];
  const float* fw0  = (const float*)d_in[9];
  const float* fb0  = (const float*)d_in[10];
  const float* fw1  = (const float*)d_in[11];
  const float* fb1  = (const float*)d_in[12];
  const float* fw2  = (const float*)d_in[13];
  const float* fb2  = (const float*)d_in[14];
  const float* cb   = (const float*)d_in[15];
  const float* gw0  = (const float*)d_in[16];
  const float* gb0  = (const float*)d_in[17];
  const float* gw1  = (const float*)d_in[18];
  const float* gb1  = (const float*)d_in[19];
  const float* gw2  = (const float*)d_in[20];
  const float* gb2  = (const float*)d_in[21];
  const float* tw0  = (const float*)d_in[22];
  const float* tb0  = (const float*)d_in[23];
  const float* tw1  = (const float*)d_in[24];
  const float* tb1  = (const float*)d_in[25];
  const float* tw2  = (const float*)d_in[26];
  const float* tb2  = (const float*)d_in[27];
  const float* tw3  = (const float*)d_in[28];
  const float* tb3  = (const float*)d_in[29];

  float* out = (float*)d_out;
  float* ws  = (float*)d_ws;

  float* H0   = ws + 0;
  float* H1   = ws + 16777216;
  float* H2   = ws + 0;
  float* H3   = ws + 16777216;
  float* F0   = ws + 0;
  float* F1   = ws + 262144;
  float* Z    = ws + 524288;
  float* E    = ws + 917504;
  float* G0   = ws + 1310720;
  float* G1   = ws + 1441792;
  u32*   G2p  = (u32*)(ws + 1703936);
  u32*   T0p  = (u32*)(ws + 2752512);
  u32*   T1p  = (u32*)(ws + 4849664);
  float* T2   = ws + 9043968;
  float* WTP0 = ws + 25821184;
  float* WTP1 = ws + 26345472;
  float* WTP2 = ws + 26476544;
  float* P    = ws + 26542080;
  float* RL   = ws + 28639232;

  // ---- convT weight prep (per-parity GEMM layout) ----
  wprep_k<<<dim3(512), TPB, 0, stream>>>(tw0, WTP0, 256, 128);
  wprep_k<<<dim3(128), TPB, 0, stream>>>(tw1, WTP1, 128, 64);
  wprep_k<<<dim3(64),  TPB, 0, stream>>>(tw2, WTP2, 64, 64);

  // ---- encoder convs (MFMA, NS=3) ----
  conv_mf3<128><<<dim3(2048, 1), TPB, 0, stream>>>(x,  ew0, eb0, H0, 3,   64,  64, 5, 1);
  conv_mf3<128><<<dim3(512, 1),  TPB, 0, stream>>>(H0, ew1, eb1, H1, 64,  64,  32, 4, 1);
  conv_mf3<128><<<dim3(128, 2),  TPB, 0, stream>>>(H1, ew2, eb2, H2, 64,  128, 16, 3, 1);
  conv_mf3<64><<<dim3(64, 4),    TPB, 0, stream>>>(H2, ew3, eb3, H3, 128, 256, 8,  2, 0);

  // ---- encoder FC (MFMA NS=3, split-K + combine) ----
  gemm_mf<3,0><<<dim3(4, 16, 8), TPB, 0, stream>>>(H3, fw0, fb0, (void*)P, 256, 4096, 1024, 512);
  combine_k<<<dim3(256), TPB, 0, stream>>>(P, fb0, F0, 262144, 1024, 8, 1);
  gemm_mf<3,0><<<dim3(4, 16, 4), TPB, 0, stream>>>(F0, fw1, fb1, (void*)P, 256, 1024, 1024, 256);
  combine_k<<<dim3(256), TPB, 0, stream>>>(P, fb1, F1, 262144, 1024, 4, 1);
  gemm_mf<3,0><<<dim3(4, 24, 4), TPB, 0, stream>>>(F1, fw2, fb2, (void*)P, 256, 1024, 1536, 256);
  combine_k<<<dim3(384), TPB, 0, stream>>>(P, fb2, Z, 393216, 1536, 4, 0);

  // ---- VQ ----
  vq_kernel<<<dim3(4096), TPB, 0, stream>>>(Z, cb, E, RL);
  zs_copy_kernel<<<dim3(512), TPB, 0, stream>>>(Z, E);
  loss_reduce_kernel<<<dim3(1), TPB, 0, stream>>>(RL, out + (size_t)out_size - 1);

  // ---- decoder FC ----
  gemm_ig2<<<dim3(4, 16), TPB, 0, stream>>>(E,  gw0, gb0, G0, 256, 1536, 512,  1);
  gemm_ig2<<<dim3(4, 32), TPB, 0, stream>>>(G0, gw1, gb1, G1, 256, 512,  1024, 1);
  gemm_mf<2,1><<<dim3(4, 64, 1), TPB, 0, stream>>>(G1, gw2, gb2, (void*)G2p, 256, 1024, 4096, 1024);

  // ---- decoder transposed convs (MFMA NS=2) ----
  convt_mf2<64,1><<<dim3(64, 2, 4),   TPB, 0, stream>>>(G2p, WTP0, tb0, (void*)T0p, 256, 128, 4,  2, 1);
  convt_mf2<128,1><<<dim3(128, 1, 4), TPB, 0, stream>>>(T0p, WTP1, tb1, (void*)T1p, 128, 64,  8,  3, 1);
  convt_mf2<128,0><<<dim3(512, 1, 4), TPB, 0, stream>>>(T1p, WTP2, tb2, (void*)T2,  64,  64,  16, 4, 1);
  convt3_kernel<<<dim3(256), TPB, 0, stream>>>(T2, tw3, tb3, out);
}

// Round 6
// 737.920 us; speedup vs baseline: 10.5666x; 1.0914x over previous
//
#include <hip/hip_runtime.h>
#include <hip/hip_bf16.h>

// ============================================================================
// VQ-VAE forward, round 6: R5 engine + register prefetch (async-stage split)
// in every MFMA kernel + split-K for conv2/conv3 (the 1-block/CU layers).
//   encoder: NS=3 split (6 MFMA terms)  decoder: NS=2 split (3 terms)
// Conv split-K partials: [z][Co][M] (float4 in m), conv_combine -> NCHW.
// Workspace same plan as R5 (peak 114.6 MB) + PC=ws+2097152 (8.4M floats,
// disjoint from live buffers at its use sites). No atomics, deterministic.
// ============================================================================

#define TPB 256
typedef __attribute__((ext_vector_type(8))) short short8v;
typedef __attribute__((ext_vector_type(4))) float f32x4;
typedef unsigned int u32;
typedef unsigned short u16;

__device__ inline u16 f2bf(float x){ union{float f;u32 u;}v; v.f=x; u32 r=v.u+0x7fffu+((v.u>>16)&1u); return (u16)(r>>16);}
__device__ inline float bf2f(u16 h){ union{u32 u;float f;}v; v.u=((u32)h)<<16; return v.f;}
__device__ inline u32 packhl(float x){ u16 h=f2bf(x); u16 l=f2bf(x-bf2f(h)); return ((u32)l<<16)|(u32)h;}

template<int NS>
__device__ inline void splitN(float x, u16 t[3]) {
  u16 h0 = f2bf(x); t[0] = h0;
  float r1 = x - bf2f(h0);
  u16 h1 = f2bf(r1); t[1] = h1;
  if (NS == 3) { float r2 = r1 - bf2f(h1); t[2] = f2bf(r2); }
}

template<int NS, int ST>
__device__ inline void stW(u32* L, int row, int oct, const u16 hs[3][8]) {
  const int sw = row & 7;
#pragma unroll
  for (int s = 0; s < NS; ++s) {
    uint4 d;
    d.x = (u32)hs[s][0] | ((u32)hs[s][1] << 16);
    d.y = (u32)hs[s][2] | ((u32)hs[s][3] << 16);
    d.z = (u32)hs[s][4] | ((u32)hs[s][5] << 16);
    d.w = (u32)hs[s][6] | ((u32)hs[s][7] << 16);
    int ch = (((s << 2) | oct) ^ sw) << 2;
    *reinterpret_cast<uint4*>(&L[row * ST + ch]) = d;
  }
}

template<int NS, int ST>
__device__ inline void stWf(u32* L, int row, int oct, const float v[8]) {
  u16 hs[3][8];
#pragma unroll
  for (int e = 0; e < 8; ++e) {
    u16 t3[3]; splitN<NS>(v[e], t3);
    hs[0][e] = t3[0]; hs[1][e] = t3[1]; if (NS == 3) hs[2][e] = t3[2];
  }
  stW<NS, ST>(L, row, oct, hs);
}

template<int ST>
__device__ inline short8v rdFrag(const u32* L, int row, int c) {
  int ph = (c ^ (row & 7)) << 2;
  return *reinterpret_cast<const short8v*>(&L[row * ST + ph]);
}

// ---------------- MFMA GEMM (BM=64, BN=64, 4 waves, split-K, prefetched) ----
// OUTM 0: partial f32 [z][M][N] (no bias); OUTM 1: packed u32 + bias (g2).
template<int NS, int OUTM>
__global__ __launch_bounds__(TPB) void gemm_mf(
    const float* __restrict__ A, const float* __restrict__ W,
    const float* __restrict__ bias, void* __restrict__ outp,
    int M, int K, int N, int KSPL)
{
  constexpr int ST = (NS == 3) ? 64 : 32;
  __shared__ __align__(16) u32 L[(64 + 64) * ST];
  u32* AL = L; u32* BL = L + 64 * ST;
  const int tid = threadIdx.x;
  const int m0 = blockIdx.x << 6, n0 = blockIdx.y << 6;
  const int lane = tid & 63, wv = tid >> 6, r = lane & 15, g = lane >> 4;
  const int kb0 = blockIdx.z * KSPL;
  const int kbN = kb0 + KSPL;
  const int cl = tid & 63, oct = tid >> 6;
  f32x4 acc[4] = {};

  float vA[8], vB[8], vA2[8], vB2[8];
  auto gA = [&](int kt, float* v) {
    const float* ap = &A[(size_t)(m0 + cl) * K + kt + (oct << 3)];
    *reinterpret_cast<float4*>(&v[0]) = *reinterpret_cast<const float4*>(ap);
    *reinterpret_cast<float4*>(&v[4]) = *reinterpret_cast<const float4*>(ap + 4);
  };
  auto gB = [&](int kt, float* v) {
#pragma unroll
    for (int e = 0; e < 8; ++e)
      v[e] = W[(size_t)(kt + (oct << 3) + e) * N + n0 + cl];
  };

  gA(kb0, vA); gB(kb0, vB);
  for (int kt = kb0; kt < kbN; kt += 32) {
    const bool more = (kt + 32) < kbN;
    if (more) { gA(kt + 32, vA2); gB(kt + 32, vB2); }
    stWf<NS, ST>(AL, cl, oct, vA);
    stWf<NS, ST>(BL, cl, oct, vB);
    __syncthreads();
    short8v a_[3];
#pragma unroll
    for (int s = 0; s < NS; ++s) a_[s] = rdFrag<ST>(AL, (wv << 4) + r, (s << 2) | g);
#pragma unroll
    for (int ns = 0; ns < 4; ++ns) {
      short8v b_[3];
#pragma unroll
      for (int s = 0; s < NS; ++s) b_[s] = rdFrag<ST>(BL, (ns << 4) + r, (s << 2) | g);
      acc[ns] = __builtin_amdgcn_mfma_f32_16x16x32_bf16(a_[0], b_[0], acc[ns], 0, 0, 0);
      acc[ns] = __builtin_amdgcn_mfma_f32_16x16x32_bf16(a_[0], b_[1], acc[ns], 0, 0, 0);
      acc[ns] = __builtin_amdgcn_mfma_f32_16x16x32_bf16(a_[1], b_[0], acc[ns], 0, 0, 0);
      if (NS == 3) {
        acc[ns] = __builtin_amdgcn_mfma_f32_16x16x32_bf16(a_[1], b_[1], acc[ns], 0, 0, 0);
        acc[ns] = __builtin_amdgcn_mfma_f32_16x16x32_bf16(a_[0], b_[2], acc[ns], 0, 0, 0);
        acc[ns] = __builtin_amdgcn_mfma_f32_16x16x32_bf16(a_[2], b_[0], acc[ns], 0, 0, 0);
      }
    }
    __syncthreads();
    if (more) {
#pragma unroll
      for (int e = 0; e < 8; ++e) { vA[e] = vA2[e]; vB[e] = vB2[e]; }
    }
  }
#pragma unroll
  for (int ns = 0; ns < 4; ++ns)
#pragma unroll
    for (int q = 0; q < 4; ++q) {
      int m = m0 + (wv << 4) + (g << 2) + q;
      int n = n0 + (ns << 4) + r;
      float v = acc[ns][q];
      if (OUTM == 0) ((float*)outp)[((size_t)blockIdx.z * M + m) * N + n] = v;
      else           ((u32*)outp)[(size_t)m * N + n] = packhl(v + bias[n]);
    }
}

// ---------------- MFMA conv (s2,k4,p1), NS=3, prefetched, split-K opt -------
// OUTM 0: direct NCHW + bias/relu. OUTM 1: partial [z][Co][M] (float4 in m).
template<int BM, int OUTM>
__global__ __launch_bounds__(TPB) void conv_mf3(
    const float* __restrict__ in, const float* __restrict__ w,
    const float* __restrict__ bias, float* __restrict__ outp,
    int Ci, int Co, int Hi, int lwo, int relu, int KSPL)
{
  constexpr int ST = 64, MS = BM / 64;
  __shared__ __align__(16) u32 L[(BM + 64) * ST];
  u32* AL = L; u32* BL = L + BM * ST;
  const int Wi = Hi, Wo = Hi >> 1;
  const int K = Ci << 4;
  const int tid = threadIdx.x;
  const int m0 = blockIdx.x * BM, n0 = blockIdx.y << 6;
  const int lane = tid & 63, wv = tid >> 6, r = lane & 15, g = lane >> 4;
  const int kb0 = blockIdx.z * KSPL;
  const int kbN = min(kb0 + KSPL, K);
  f32x4 acc[MS][4] = {};

  float vA[MS][8], vB[8], vA2[MS][8], vB2[8];
  auto gA = [&](int kb, float v[][8]) {
#pragma unroll
    for (int p = 0; p < MS; ++p) {
      int cl  = (BM == 128) ? (tid & 127) : (tid & 63);
      int oc  = (BM == 128) ? ((tid >> 7) + (p << 1)) : (tid >> 6);
      int cell = m0 + cl;
      int x = cell & (Wo - 1), y = (cell >> lwo) & (Wo - 1), b = cell >> (lwo + lwo);
      int k8 = kb + (oc << 3);
      if (k8 < K) {
        int ci = k8 >> 4, kh0 = (k8 >> 2) & 3;
        int gy0 = 2 * y - 1 + kh0, gx0 = 2 * x - 1;
        const float* ip = &in[((size_t)b * Ci + ci) * Hi * Wi];
#pragma unroll
        for (int e = 0; e < 8; ++e) {
          int gy = gy0 + (e >> 2), gx = gx0 + (e & 3);
          v[p][e] = (gy >= 0 && gy < Hi && gx >= 0 && gx < Wi) ? ip[gy * Wi + gx] : 0.f;
        }
      } else {
#pragma unroll
        for (int e = 0; e < 8; ++e) v[p][e] = 0.f;
      }
    }
  };
  auto gB = [&](int kb, float* v) {
    int n = tid & 63, oc2 = tid >> 6;
    int k8 = kb + (oc2 << 3);
    if (k8 < K) {
      const float* wp = &w[(size_t)(n0 + n) * K + k8];
      *reinterpret_cast<float4*>(&v[0]) = *reinterpret_cast<const float4*>(wp);
      *reinterpret_cast<float4*>(&v[4]) = *reinterpret_cast<const float4*>(wp + 4);
    } else {
#pragma unroll
      for (int e = 0; e < 8; ++e) v[e] = 0.f;
    }
  };

  gA(kb0, vA); gB(kb0, vB);
  for (int kb = kb0; kb < kbN; kb += 32) {
    const bool more = (kb + 32) < kbN;
    if (more) { gA(kb + 32, vA2); gB(kb + 32, vB2); }
#pragma unroll
    for (int p = 0; p < MS; ++p) {
      int cl  = (BM == 128) ? (tid & 127) : (tid & 63);
      int oc  = (BM == 128) ? ((tid >> 7) + (p << 1)) : (tid >> 6);
      stWf<3, ST>(AL, cl, oc, vA[p]);
    }
    stWf<3, ST>(BL, tid & 63, tid >> 6, vB);
    __syncthreads();
    short8v a_[MS][3];
#pragma unroll
    for (int mm = 0; mm < MS; ++mm)
#pragma unroll
      for (int s = 0; s < 3; ++s)
        a_[mm][s] = rdFrag<ST>(AL, (wv * MS + mm) * 16 + r, (s << 2) | g);
#pragma unroll
    for (int ns = 0; ns < 4; ++ns) {
      short8v b_[3];
#pragma unroll
      for (int s = 0; s < 3; ++s) b_[s] = rdFrag<ST>(BL, (ns << 4) + r, (s << 2) | g);
#pragma unroll
      for (int mm = 0; mm < MS; ++mm) {
        acc[mm][ns] = __builtin_amdgcn_mfma_f32_16x16x32_bf16(a_[mm][0], b_[0], acc[mm][ns], 0, 0, 0);
        acc[mm][ns] = __builtin_amdgcn_mfma_f32_16x16x32_bf16(a_[mm][0], b_[1], acc[mm][ns], 0, 0, 0);
        acc[mm][ns] = __builtin_amdgcn_mfma_f32_16x16x32_bf16(a_[mm][1], b_[0], acc[mm][ns], 0, 0, 0);
        acc[mm][ns] = __builtin_amdgcn_mfma_f32_16x16x32_bf16(a_[mm][1], b_[1], acc[mm][ns], 0, 0, 0);
        acc[mm][ns] = __builtin_amdgcn_mfma_f32_16x16x32_bf16(a_[mm][0], b_[2], acc[mm][ns], 0, 0, 0);
        acc[mm][ns] = __builtin_amdgcn_mfma_f32_16x16x32_bf16(a_[mm][2], b_[0], acc[mm][ns], 0, 0, 0);
      }
    }
    __syncthreads();
    if (more) {
#pragma unroll
      for (int p = 0; p < MS; ++p)
#pragma unroll
        for (int e = 0; e < 8; ++e) vA[p][e] = vA2[p][e];
#pragma unroll
      for (int e = 0; e < 8; ++e) vB[e] = vB2[e];
    }
  }
#pragma unroll
  for (int mm = 0; mm < MS; ++mm)
#pragma unroll
    for (int ns = 0; ns < 4; ++ns) {
      int c0 = m0 + (wv * MS + mm) * 16 + (g << 2);
      int co = n0 + (ns << 4) + r;
      if (OUTM == 0) {
        int x0 = c0 & (Wo - 1), y = (c0 >> lwo) & (Wo - 1), b = c0 >> (lwo + lwo);
        float bv = bias[co];
        float4 o;
        o.x = acc[mm][ns][0] + bv; o.y = acc[mm][ns][1] + bv;
        o.z = acc[mm][ns][2] + bv; o.w = acc[mm][ns][3] + bv;
        if (relu) { o.x = fmaxf(o.x, 0.f); o.y = fmaxf(o.y, 0.f);
                    o.z = fmaxf(o.z, 0.f); o.w = fmaxf(o.w, 0.f); }
        *reinterpret_cast<float4*>(&outp[(((size_t)b * Co + co) * Wo + y) * Wo + x0]) = o;
      } else {
        const int Mtot = 256 << (lwo + lwo);
        float4 o;
        o.x = acc[mm][ns][0]; o.y = acc[mm][ns][1];
        o.z = acc[mm][ns][2]; o.w = acc[mm][ns][3];
        *reinterpret_cast<float4*>(
            &outp[((size_t)blockIdx.z * Co + co) * Mtot + c0]) = o;
      }
    }
}

// ---------------- conv split-K combine: P[z][Co][M] -> NCHW + bias/relu -----
__global__ __launch_bounds__(TPB) void conv_combine(
    const float* __restrict__ P, const float* __restrict__ bias,
    float* __restrict__ out, int Mtot, int N, int SK, int lwo, int relu)
{
  int idx = blockIdx.x * TPB + threadIdx.x;
  int mq = Mtot >> 2;
  int co = idx / mq;
  int cell0 = (idx - co * mq) << 2;
  if (co >= N) return;
  float4 s = make_float4(0.f, 0.f, 0.f, 0.f);
  for (int z = 0; z < SK; ++z) {
    const float4 pv = *reinterpret_cast<const float4*>(
        &P[((size_t)z * N + co) * Mtot + cell0]);
    s.x += pv.x; s.y += pv.y; s.z += pv.z; s.w += pv.w;
  }
  float bv = bias[co];
  s.x += bv; s.y += bv; s.z += bv; s.w += bv;
  if (relu) { s.x = fmaxf(s.x, 0.f); s.y = fmaxf(s.y, 0.f);
              s.z = fmaxf(s.z, 0.f); s.w = fmaxf(s.w, 0.f); }
  int Wo = 1 << lwo;
  int x = cell0 & (Wo - 1), y = (cell0 >> lwo) & (Wo - 1), b = cell0 >> (lwo + lwo);
  *reinterpret_cast<float4*>(&out[(((size_t)b * N + co) * Wo + y) * Wo + x]) = s;
}

// ---------------- MFMA convT (s2,k4,p1) per-parity, NS=2, prefetched --------
template<int BM, int EMIT>
__global__ __launch_bounds__(TPB) void convt_mf2(
    const u32* __restrict__ in, const float* __restrict__ wtp,
    const float* __restrict__ bias, void* __restrict__ outv,
    int Ci, int Co, int Hi, int lwi, int relu)
{
  constexpr int ST = 32, MS = BM / 64;
  __shared__ __align__(16) u32 L[(BM + 64) * ST];
  u32* AL = L; u32* BL = L + BM * ST;
  const int Wi = Hi, K4 = Ci << 2;
  const int par = blockIdx.z, py = par >> 1, px = par & 1;
  const int tid = threadIdx.x;
  const int m0 = blockIdx.x * BM, n0 = blockIdx.y << 6;
  const int lane = tid & 63, wv = tid >> 6, r = lane & 15, g = lane >> 4;
  f32x4 acc[MS][4] = {};

  u32 vA[MS][8], vA2[MS][8];
  float vB[8], vB2[8];
  auto gA = [&](int kb, u32 v[][8]) {
#pragma unroll
    for (int p = 0; p < MS; ++p) {
      int cl = (BM == 128) ? (tid & 127) : (tid & 63);
      int oc = (BM == 128) ? ((tid >> 7) + (p << 1)) : (tid >> 6);
      int cell = m0 + cl;
      int X = cell & (Wi - 1), Y = (cell >> lwi) & (Wi - 1), b = cell >> (lwi + lwi);
      int ci0 = (kb + (oc << 3)) >> 2;
#pragma unroll
      for (int e = 0; e < 8; ++e) {
        int ci = ci0 + (e >> 2), ay = (e >> 1) & 1, ax = e & 1;
        int gy = Y + py - ay, gx = X + px - ax;
        u32 t = 0u;
        if (gy >= 0 && gy < Hi && gx >= 0 && gx < Wi)
          t = in[(((size_t)b * Ci + ci) * Hi + gy) * Wi + gx];
        v[p][e] = t;
      }
    }
  };
  auto gB = [&](int kb, float* v) {
    int n = tid & 63, oc2 = tid >> 6;
    const float* wp = &wtp[((size_t)par * Co + n0 + n) * K4 + kb + (oc2 << 3)];
    *reinterpret_cast<float4*>(&v[0]) = *reinterpret_cast<const float4*>(wp);
    *reinterpret_cast<float4*>(&v[4]) = *reinterpret_cast<const float4*>(wp + 4);
  };

  gA(0, vA); gB(0, vB);
  for (int kb = 0; kb < K4; kb += 32) {
    const bool more = (kb + 32) < K4;
    if (more) { gA(kb + 32, vA2); gB(kb + 32, vB2); }
#pragma unroll
    for (int p = 0; p < MS; ++p) {
      int cl = (BM == 128) ? (tid & 127) : (tid & 63);
      int oc = (BM == 128) ? ((tid >> 7) + (p << 1)) : (tid >> 6);
      const int sw = cl & 7;
      const u32* v = vA[p];
      uint4 dh, dl;
      dh.x = (v[0] & 0xffffu) | (v[1] << 16);  dl.x = (v[0] >> 16) | (v[1] & 0xffff0000u);
      dh.y = (v[2] & 0xffffu) | (v[3] << 16);  dl.y = (v[2] >> 16) | (v[3] & 0xffff0000u);
      dh.z = (v[4] & 0xffffu) | (v[5] << 16);  dl.z = (v[4] >> 16) | (v[5] & 0xffff0000u);
      dh.w = (v[6] & 0xffffu) | (v[7] << 16);  dl.w = (v[6] >> 16) | (v[7] & 0xffff0000u);
      *reinterpret_cast<uint4*>(&AL[cl * ST + ((oc ^ sw) << 2)]) = dh;
      *reinterpret_cast<uint4*>(&AL[cl * ST + (((4 | oc) ^ sw) << 2)]) = dl;
    }
    stWf<2, ST>(BL, tid & 63, tid >> 6, vB);
    __syncthreads();
    short8v a_[MS][2];
#pragma unroll
    for (int mm = 0; mm < MS; ++mm)
#pragma unroll
      for (int s = 0; s < 2; ++s)
        a_[mm][s] = rdFrag<ST>(AL, (wv * MS + mm) * 16 + r, (s << 2) | g);
#pragma unroll
    for (int ns = 0; ns < 4; ++ns) {
      short8v b_[2];
#pragma unroll
      for (int s = 0; s < 2; ++s) b_[s] = rdFrag<ST>(BL, (ns << 4) + r, (s << 2) | g);
#pragma unroll
      for (int mm = 0; mm < MS; ++mm) {
        acc[mm][ns] = __builtin_amdgcn_mfma_f32_16x16x32_bf16(a_[mm][0], b_[0], acc[mm][ns], 0, 0, 0);
        acc[mm][ns] = __builtin_amdgcn_mfma_f32_16x16x32_bf16(a_[mm][0], b_[1], acc[mm][ns], 0, 0, 0);
        acc[mm][ns] = __builtin_amdgcn_mfma_f32_16x16x32_bf16(a_[mm][1], b_[0], acc[mm][ns], 0, 0, 0);
      }
    }
    __syncthreads();
    if (more) {
#pragma unroll
      for (int p = 0; p < MS; ++p)
#pragma unroll
        for (int e = 0; e < 8; ++e) vA[p][e] = vA2[p][e];
#pragma unroll
      for (int e = 0; e < 8; ++e) vB[e] = vB2[e];
    }
  }
  const int Ho = Hi << 1, Wo2 = Wi << 1;
#pragma unroll
  for (int mm = 0; mm < MS; ++mm)
#pragma unroll
    for (int ns = 0; ns < 4; ++ns)
#pragma unroll
      for (int q = 0; q < 4; ++q) {
        int cell = m0 + (wv * MS + mm) * 16 + (g << 2) + q;
        int X = cell & (Wi - 1), Y = (cell >> lwi) & (Wi - 1), b = cell >> (lwi + lwi);
        int co = n0 + (ns << 4) + r;
        float v = acc[mm][ns][q] + bias[co];
        if (relu) v = fmaxf(v, 0.f);
        size_t oi = (((size_t)b * Co + co) * Ho + 2 * Y + py) * Wo2 + 2 * X + px;
        if (EMIT) ((u32*)outv)[oi] = packhl(v);
        else      ((float*)outv)[oi] = v;
      }
}

// ---------------- convT weight prep: src[Ci][Co][16] -> dst[p][Co][Ci*4] ----
__global__ __launch_bounds__(TPB) void wprep_k(
    const float* __restrict__ src, float* __restrict__ dst, int Ci, int Co)
{
  int K4 = Ci << 2;
  int tot = 4 * Co * K4;
  for (int i = blockIdx.x * TPB + threadIdx.x; i < tot; i += gridDim.x * TPB) {
    int p = i / (Co * K4); int rem = i - p * (Co * K4);
    int co = rem / K4; int k4 = rem - co * K4;
    int ci = k4 >> 2, ay = (k4 >> 1) & 1, ax = k4 & 1;
    int py = p >> 1, px = p & 1;
    int widx = ((1 - py) << 2) + (1 - px) + (ay << 3) + (ax << 1);
    dst[i] = src[(((size_t)ci * Co + co) << 4) + widx];
  }
}

// ---------------- fc split-K combine: out = relu(sum_z P[z] + bias) ---------
__global__ __launch_bounds__(TPB) void combine_k(
    const float* __restrict__ P, const float* __restrict__ bias,
    float* __restrict__ out, int MN, int N, int SK, int relu)
{
  int i4 = (blockIdx.x * TPB + threadIdx.x) << 2;
  if (i4 >= MN) return;
  float4 s = make_float4(0.f, 0.f, 0.f, 0.f);
  for (int z = 0; z < SK; ++z) {
    const float4 pv = *reinterpret_cast<const float4*>(&P[(size_t)z * MN + i4]);
    s.x += pv.x; s.y += pv.y; s.z += pv.z; s.w += pv.w;
  }
  int n = i4 % N;
  s.x += bias[n]; s.y += bias[n + 1]; s.z += bias[n + 2]; s.w += bias[n + 3];
  if (relu) { s.x = fmaxf(s.x, 0.f); s.y = fmaxf(s.y, 0.f);
              s.z = fmaxf(s.z, 0.f); s.w = fmaxf(s.w, 0.f); }
  *reinterpret_cast<float4*>(&out[i4]) = s;
}

// ---------------- fp32 FC GEMM (g0, g1 only) --------------------------------
__global__ __launch_bounds__(TPB) void gemm_ig2(
    const float* __restrict__ A, const float* __restrict__ W,
    const float* __restrict__ bias, float* __restrict__ C,
    int M, int K, int N, int relu)
{
  constexpr int BM = 64, BN = 32, BK = 32;
  __shared__ __align__(16) float As[BK][BM + 4];
  __shared__ __align__(16) float Ws[BK][BN + 4];
  const int tid = threadIdx.x;
  const int m0 = blockIdx.x * BM;
  const int n0 = blockIdx.y * BN;
  const int tn = tid & 15;
  const int tm = tid >> 4;
  float acc[4][2] = {{0.f,0.f},{0.f,0.f},{0.f,0.f},{0.f,0.f}};

  for (int kt = 0; kt < K; kt += BK) {
#pragma unroll
    for (int f = 0; f < 2; ++f) {
      int idx = f * TPB + tid;
      int kq = idx & 7;
      int m = idx >> 3;
      const float4 av = *reinterpret_cast<const float4*>(
          &A[(size_t)(m0 + m) * K + kt + 4 * kq]);
      As[4 * kq + 0][m] = av.x;
      As[4 * kq + 1][m] = av.y;
      As[4 * kq + 2][m] = av.z;
      As[4 * kq + 3][m] = av.w;
    }
#pragma unroll
    for (int i = 0; i < 4; ++i) {
      int lin = i * TPB + tid;
      int n = lin & 31;
      int kk = lin >> 5;
      Ws[kk][n] = W[(size_t)(kt + kk) * N + n0 + n];
    }
    __syncthreads();
#pragma unroll
    for (int k = 0; k < BK; ++k) {
      const float4 av = *reinterpret_cast<const float4*>(&As[k][4 * tm]);
      const float2 wv = *reinterpret_cast<const float2*>(&Ws[k][2 * tn]);
      acc[0][0] = fmaf(av.x, wv.x, acc[0][0]);
      acc[0][1] = fmaf(av.x, wv.y, acc[0][1]);
      acc[1][0] = fmaf(av.y, wv.x, acc[1][0]);
      acc[1][1] = fmaf(av.y, wv.y, acc[1][1]);
      acc[2][0] = fmaf(av.z, wv.x, acc[2][0]);
      acc[2][1] = fmaf(av.z, wv.y, acc[2][1]);
      acc[3][0] = fmaf(av.w, wv.x, acc[3][0]);
      acc[3][1] = fmaf(av.w, wv.y, acc[3][1]);
    }
    __syncthreads();
  }
  const float b0 = bias[n0 + 2 * tn];
  const float b1 = bias[n0 + 2 * tn + 1];
#pragma unroll
  for (int mi = 0; mi < 4; ++mi) {
    int m = m0 + 4 * tm + mi;
    float2 v = make_float2(acc[mi][0] + b0, acc[mi][1] + b1);
    if (relu) { v.x = fmaxf(v.x, 0.f); v.y = fmaxf(v.y, 0.f); }
    *reinterpret_cast<float2*>(&C[(size_t)m * N + n0 + 2 * tn]) = v;
  }
}

// ---------------- dedicated t3: convT 64->3, fp32 ---------------------------
__global__ __launch_bounds__(TPB) void convt3_kernel(
    const float* __restrict__ in, const float* __restrict__ w,
    const float* __restrict__ bias, float* __restrict__ out)
{
  __shared__ float wl[3072];
  __shared__ float il[8][33 * 32];
  const int b = blockIdx.x;
  const int tid = threadIdx.x;
  for (int i = tid; i < 3072; i += TPB) wl[i] = w[i];
  const int Y = tid >> 3;
  const int X0 = (tid & 7) << 2;
  float acc[3][2][8];
#pragma unroll
  for (int o = 0; o < 3; ++o)
#pragma unroll
    for (int p = 0; p < 2; ++p)
#pragma unroll
      for (int q = 0; q < 8; ++q) acc[o][p][q] = 0.f;

  const float* ib = in + (size_t)b * 64 * 1024;
  for (int c0 = 0; c0 < 64; c0 += 8) {
    __syncthreads();
    for (int i = tid; i < 8192; i += TPB) {
      int cc = i >> 10, y = (i >> 5) & 31, x = i & 31;
      il[cc][y * 33 + x] = ib[(size_t)c0 * 1024 + i];
    }
    __syncthreads();
    for (int cc = 0; cc < 8; ++cc) {
      float iv[3][6];
#pragma unroll
      for (int j = 0; j < 3; ++j) {
        int gy = Y - 1 + j;
        int gyc = min(max(gy, 0), 31);
        float my = (gy >= 0 && gy < 32) ? 1.f : 0.f;
#pragma unroll
        for (int k = 0; k < 6; ++k) {
          int gx = X0 - 1 + k;
          int gxc = min(max(gx, 0), 31);
          float mx = (gx >= 0 && gx < 32) ? 1.f : 0.f;
          iv[j][k] = il[cc][gyc * 33 + gxc] * (my * mx);
        }
      }
      const float* wq = &wl[(c0 + cc) * 48];
#pragma unroll
      for (int o = 0; o < 3; ++o) {
        const float* wo = wq + o * 16;
#pragma unroll
        for (int c = 0; c < 4; ++c) {
          acc[o][0][2*c]   = fmaf(iv[1][c+1], wo[5],  acc[o][0][2*c]);
          acc[o][0][2*c]   = fmaf(iv[1][c],   wo[7],  acc[o][0][2*c]);
          acc[o][0][2*c]   = fmaf(iv[0][c+1], wo[13], acc[o][0][2*c]);
          acc[o][0][2*c]   = fmaf(iv[0][c],   wo[15], acc[o][0][2*c]);
          acc[o][0][2*c+1] = fmaf(iv[1][c+2], wo[4],  acc[o][0][2*c+1]);
          acc[o][0][2*c+1] = fmaf(iv[1][c+1], wo[6],  acc[o][0][2*c+1]);
          acc[o][0][2*c+1] = fmaf(iv[0][c+2], wo[12], acc[o][0][2*c+1]);
          acc[o][0][2*c+1] = fmaf(iv[0][c+1], wo[14], acc[o][0][2*c+1]);
          acc[o][1][2*c]   = fmaf(iv[2][c+1], wo[1],  acc[o][1][2*c]);
          acc[o][1][2*c]   = fmaf(iv[2][c],   wo[3],  acc[o][1][2*c]);
          acc[o][1][2*c]   = fmaf(iv[1][c+1], wo[9],  acc[o][1][2*c]);
          acc[o][1][2*c]   = fmaf(iv[1][c],   wo[11], acc[o][1][2*c]);
          acc[o][1][2*c+1] = fmaf(iv[2][c+2], wo[0],  acc[o][1][2*c+1]);
          acc[o][1][2*c+1] = fmaf(iv[2][c+1], wo[2],  acc[o][1][2*c+1]);
          acc[o][1][2*c+1] = fmaf(iv[1][c+2], wo[8],  acc[o][1][2*c+1]);
          acc[o][1][2*c+1] = fmaf(iv[1][c+1], wo[10], acc[o][1][2*c+1]);
        }
      }
    }
  }
#pragma unroll
  for (int o = 0; o < 3; ++o) {
    float bv = bias[o];
#pragma unroll
    for (int p = 0; p < 2; ++p) {
      float* op = out + (((size_t)b * 3 + o) * 64 + 2 * Y + p) * 64 + 2 * X0;
      float4 v0 = make_float4(acc[o][p][0] + bv, acc[o][p][1] + bv,
                              acc[o][p][2] + bv, acc[o][p][3] + bv);
      float4 v1 = make_float4(acc[o][p][4] + bv, acc[o][p][5] + bv,
                              acc[o][p][6] + bv, acc[o][p][7] + bv);
      *reinterpret_cast<float4*>(op)     = v0;
      *reinterpret_cast<float4*>(op + 4) = v1;
    }
  }
}

// ---------------- VQ ---------------------------------------------------------
__global__ __launch_bounds__(TPB) void vq_kernel(
    const float* __restrict__ z, const float* __restrict__ cb,
    float* __restrict__ e, float* __restrict__ rowloss)
{
  const int row = blockIdx.x;
  const int b = row >> 4, s = row & 15;
  __shared__ float zr[64];
  __shared__ float bval[TPB];
  __shared__ int   bidx[TPB];
  const int tid = threadIdx.x;
  if (tid < 64) zr[tid] = z[(size_t)b * 1536 + s * 64 + tid];
  __syncthreads();

  float best = 3.4e38f;
  int bi = 0;
#pragma unroll
  for (int rep = 0; rep < 2; ++rep) {
    int j = tid + rep * TPB;
    const float4* c4 = reinterpret_cast<const float4*>(cb + (size_t)j * 64);
    float d = 0.f;
#pragma unroll
    for (int k = 0; k < 16; ++k) {
      float4 cv = c4[k];
      float t0 = zr[4 * k + 0] - cv.x;
      float t1 = zr[4 * k + 1] - cv.y;
      float t2 = zr[4 * k + 2] - cv.z;
      float t3 = zr[4 * k + 3] - cv.w;
      d = fmaf(t0, t0, d); d = fmaf(t1, t1, d);
      d = fmaf(t2, t2, d); d = fmaf(t3, t3, d);
    }
    if (d < best) { best = d; bi = j; }
  }
  bval[tid] = best; bidx[tid] = bi;
  __syncthreads();
  for (int sft = 128; sft > 0; sft >>= 1) {
    if (tid < sft) {
      float v2 = bval[tid + sft]; int i2 = bidx[tid + sft];
      if (v2 < bval[tid] || (v2 == bval[tid] && i2 < bidx[tid])) {
        bval[tid] = v2; bidx[tid] = i2;
      }
    }
    __syncthreads();
  }
  const int bj = bidx[0];
  if (tid < 64)
    e[(size_t)b * 1536 + s * 64 + tid] = cb[(size_t)bj * 64 + tid];
  if (tid == 0) rowloss[row] = bval[0];
}

__global__ __launch_bounds__(TPB) void zs_copy_kernel(
    const float* __restrict__ z, float* __restrict__ e)
{
  int i = blockIdx.x * TPB + threadIdx.x;
  int b = i >> 9, k = i & 511;
  e[(size_t)b * 1536 + 1024 + k] = z[(size_t)b * 1536 + 1024 + k];
}

__global__ __launch_bounds__(TPB) void loss_reduce_kernel(
    const float* __restrict__ rl, float* __restrict__ out)
{
  __shared__ float sm[TPB];
  float s = 0.f;
  for (int i = threadIdx.x; i < 4096; i += TPB) s += rl[i];
  sm[threadIdx.x] = s;
  __syncthreads();
  for (int sft = 128; sft > 0; sft >>= 1) {
    if (threadIdx.x < sft) sm[threadIdx.x] += sm[threadIdx.x + sft];
    __syncthreads();
  }
  if (threadIdx.x == 0) out[0] = sm[0] * (1.25f / 262144.f);
}

// ============================================================================
extern "C" void kernel_launch(void* const* d_in, const int* in_sizes, int n_in,
                              void* d_out, int out_size, void* d_ws, size_t ws_size,
                              hipStream_t stream)
{
  const float* x    = (const float*)d_in[0];
  const float* ew0  = (const float*)d_in[1];
  const float* eb0  = (const float*)d_in[2];
  const float* ew1  = (const float*)d_in[3];
  const float* eb1  = (const float*)d_in[4];
  const float* ew2  = (const float*)d_in[5];
  const float* eb2  = (const float*)d_in[6];
  const float* ew3  = (const float*)d_in[7];
  const float* eb3  = (const float*)d_in[8];
  const float* fw0  = (const float*)d_in[9];
  const float* fb0  = (const float*)d_in[10];
  const float* fw1  = (const float*)d_in[11];
  const float* fb1  = (const float*)d_in[12];
  const float* fw2  = (const float*)d_in[13];
  const float* fb2  = (const float*)d_in[14];
  const float* cb   = (const float*)d_in[15];
  const float* gw0  = (const float*)d_in[16];
  const float* gb0  = (const float*)d_in[17];
  const float* gw1  = (const float*)d_in[18];
  const float* gb1  = (const float*)d_in[19];
  const float* gw2  = (const float*)d_in[20];
  const float* gb2  = (const float*)d_in[21];
  const float* tw0  = (const float*)d_in[22];
  const float* tb0  = (const float*)d_in[23];
  const float* tw1  = (const float*)d_in[24];
  const float* tb1  = (const float*)d_in[25];
  const float* tw2  = (const float*)d_in[26];
  const float* tb2  = (const float*)d_in[27];
  const float* tw3  = (const float*)d_in[28];
  const float* tb3  = (const float*)d_in[29];

  float* out = (float*)d_out;
  float* ws  = (float*)d_ws;

  float* H0   = ws + 0;
  float* H1   = ws + 16777216;
  float* H2   = ws + 0;
  float* H3   = ws + 16777216;
  float* PC   = ws + 2097152;      // conv split-K partials (8.39M floats max)
  float* F0   = ws + 0;
  float* F1   = ws + 262144;
  float* Z    = ws + 524288;
  float* E    = ws + 917504;
  float* G0   = ws + 1310720;
  float* G1   = ws + 1441792;
  u32*   G2p  = (u32*)(ws + 1703936);
  u32*   T0p  = (u32*)(ws + 2752512);
  u32*   T1p  = (u32*)(ws + 4849664);
  float* T2   = ws + 9043968;
  float* WTP0 = ws + 25821184;
  float* WTP1 = ws + 26345472;
  float* WTP2 = ws + 26476544;
  float* P    = ws + 26542080;
  float* RL   = ws + 28639232;

  // ---- convT weight prep ----
  wprep_k<<<dim3(512), TPB, 0, stream>>>(tw0, WTP0, 256, 128);
  wprep_k<<<dim3(128), TPB, 0, stream>>>(tw1, WTP1, 128, 64);
  wprep_k<<<dim3(64),  TPB, 0, stream>>>(tw2, WTP2, 64, 64);

  // ---- encoder convs (MFMA NS=3, prefetched; conv2/conv3 split-K) ----
  conv_mf3<128,0><<<dim3(2048, 1, 1), TPB, 0, stream>>>(x,  ew0, eb0, H0, 3,  64,  64, 5, 1, 48);
  conv_mf3<128,0><<<dim3(512, 1, 1),  TPB, 0, stream>>>(H0, ew1, eb1, H1, 64, 64,  32, 4, 1, 1024);
  conv_mf3<128,1><<<dim3(128, 2, 4),  TPB, 0, stream>>>(H1, ew2, eb2, PC, 64, 128, 16, 3, 1, 256);
  conv_combine<<<dim3(2048), TPB, 0, stream>>>(PC, eb2, H2, 16384, 128, 4, 3, 1);
  conv_mf3<64,1><<<dim3(64, 4, 4),    TPB, 0, stream>>>(H2, ew3, eb3, PC, 128, 256, 8, 2, 0, 512);
  conv_combine<<<dim3(1024), TPB, 0, stream>>>(PC, eb3, H3, 4096, 256, 4, 2, 0);

  // ---- encoder FC (MFMA NS=3, split-K + combine, prefetched) ----
  gemm_mf<3,0><<<dim3(4, 16, 8), TPB, 0, stream>>>(H3, fw0, fb0, (void*)P, 256, 4096, 1024, 512);
  combine_k<<<dim3(256), TPB, 0, stream>>>(P, fb0, F0, 262144, 1024, 8, 1);
  gemm_mf<3,0><<<dim3(4, 16, 4), TPB, 0, stream>>>(F0, fw1, fb1, (void*)P, 256, 1024, 1024, 256);
  combine_k<<<dim3(256), TPB, 0, stream>>>(P, fb1, F1, 262144, 1024, 4, 1);
  gemm_mf<3,0><<<dim3(4, 24, 4), TPB, 0, stream>>>(F1, fw2, fb2, (void*)P, 256, 1024, 1536, 256);
  combine_k<<<dim3(384), TPB, 0, stream>>>(P, fb2, Z, 393216, 1536, 4, 0);

  // ---- VQ ----
  vq_kernel<<<dim3(4096), TPB, 0, stream>>>(Z, cb, E, RL);
  zs_copy_kernel<<<dim3(512), TPB, 0, stream>>>(Z, E);
  loss_reduce_kernel<<<dim3(1), TPB, 0, stream>>>(RL, out + (size_t)out_size - 1);

  // ---- decoder FC ----
  gemm_ig2<<<dim3(4, 16), TPB, 0, stream>>>(E,  gw0, gb0, G0, 256, 1536, 512,  1);
  gemm_ig2<<<dim3(4, 32), TPB, 0, stream>>>(G0, gw1, gb1, G1, 256, 512,  1024, 1);
  gemm_mf<2,1><<<dim3(4, 64, 1), TPB, 0, stream>>>(G1, gw2, gb2, (void*)G2p, 256, 1024, 4096, 1024);

  // ---- decoder transposed convs (MFMA NS=2, prefetched) ----
  convt_mf2<64,1><<<dim3(64, 2, 4),   TPB, 0, stream>>>(G2p, WTP0, tb0, (void*)T0p, 256, 128, 4,  2, 1);
  convt_mf2<128,1><<<dim3(128, 1, 4), TPB, 0, stream>>>(T0p, WTP1, tb1, (void*)T1p, 128, 64,  8,  3, 1);
  convt_mf2<128,0><<<dim3(512, 1, 4), TPB, 0, stream>>>(T1p, WTP2, tb2, (void*)T2,  64,  64,  16, 4, 1);
  convt3_kernel<<<dim3(256), TPB, 0, stream>>>(T2, tw3, tb3, out);
}

// Round 7
// 714.512 us; speedup vs baseline: 10.9127x; 1.0328x over previous
//
#include <hip/hip_runtime.h>
#include <hip/hip_bf16.h>

// ============================================================================
// VQ-VAE forward, round 7:
//  - hoisted im2col addressing (tap offsets/masks k-invariant, out of k-loop)
//  - pre-split weights: encoder conv -> 3 bf16 planes; convT -> h/l bf16 planes
//    (B-stage = uint4 load -> swizzled LDS store, zero split math in loop)
//  - convT outputs in parity-quadrant layout [par][b][co][Y][X] with
//    LDS-transpose epilogue -> fully coalesced writes; consumers translated.
// Encoder NS=3 (6 MFMA terms, argmin-safe), decoder NS=2 (3 terms).
//
// Workspace (float offsets), peak 28,643,328 floats (same as R5/R6):
//  H0=0 H1/H3=16777216 H2=0 PC=2097152(8.39M) F0=0 F1=262144 Z=524288
//  E=917504 G0=1310720 G1=1441792 G2p=1703936(u32) T0s=2752512(u32,quad)
//  T1s=4849664(u32,quad) T2s=9043968(f32,quad)
//  WE0=20971520 WE1=20976128 WE2=21074432 WE3=21271040 (u16 x3 planes)
//  WT0h=25821184 WT0l=26083328 WT1h=26345472 WT1l=26411008
//  WT2h=26476544 WT2l=26509312  P=26542080 RL=28639232
// All producer/consumer pairs time-disjoint; no atomics; deterministic.
// ============================================================================

#define TPB 256
typedef __attribute__((ext_vector_type(8))) short short8v;
typedef __attribute__((ext_vector_type(4))) float f32x4;
typedef unsigned int u32;
typedef unsigned short u16;

__device__ inline u16 f2bf(float x){ union{float f;u32 u;}v; v.f=x; u32 r=v.u+0x7fffu+((v.u>>16)&1u); return (u16)(r>>16);}
__device__ inline float bf2f(u16 h){ union{u32 u;float f;}v; v.u=((u32)h)<<16; return v.f;}
__device__ inline u32 packhl(float x){ u16 h=f2bf(x); u16 l=f2bf(x-bf2f(h)); return ((u32)l<<16)|(u32)h;}

template<int NS>
__device__ inline void splitN(float x, u16 t[3]) {
  u16 h0 = f2bf(x); t[0] = h0;
  float r1 = x - bf2f(h0);
  u16 h1 = f2bf(r1); t[1] = h1;
  if (NS == 3) { float r2 = r1 - bf2f(h1); t[2] = f2bf(r2); }
}

template<int NS, int ST>
__device__ inline void stW(u32* L, int row, int oct, const u16 hs[3][8]) {
  const int sw = row & 7;
#pragma unroll
  for (int s = 0; s < NS; ++s) {
    uint4 d;
    d.x = (u32)hs[s][0] | ((u32)hs[s][1] << 16);
    d.y = (u32)hs[s][2] | ((u32)hs[s][3] << 16);
    d.z = (u32)hs[s][4] | ((u32)hs[s][5] << 16);
    d.w = (u32)hs[s][6] | ((u32)hs[s][7] << 16);
    int ch = (((s << 2) | oct) ^ sw) << 2;
    *reinterpret_cast<uint4*>(&L[row * ST + ch]) = d;
  }
}

template<int NS, int ST>
__device__ inline void stWf(u32* L, int row, int oct, const float v[8]) {
  u16 hs[3][8];
#pragma unroll
  for (int e = 0; e < 8; ++e) {
    u16 t3[3]; splitN<NS>(v[e], t3);
    hs[0][e] = t3[0]; hs[1][e] = t3[1]; if (NS == 3) hs[2][e] = t3[2];
  }
  stW<NS, ST>(L, row, oct, hs);
}

template<int ST>
__device__ inline void stWp(u32* L, int row, int oct, int s, uint4 d) {
  int ch = (((s << 2) | oct) ^ (row & 7)) << 2;
  *reinterpret_cast<uint4*>(&L[row * ST + ch]) = d;
}

template<int ST>
__device__ inline short8v rdFrag(const u32* L, int row, int c) {
  int ph = (c ^ (row & 7)) << 2;
  return *reinterpret_cast<const short8v*>(&L[row * ST + ph]);
}

// ---------------- weight prep -----------------------------------------------
// encoder conv: w[Co][K] fp32 -> 3 planes u16 (stride n)
__global__ __launch_bounds__(TPB) void wsplit3_k(
    const float* __restrict__ src, u16* __restrict__ dst, int n)
{
  for (int i = blockIdx.x * TPB + threadIdx.x; i < n; i += gridDim.x * TPB) {
    u16 t3[3]; splitN<3>(src[i], t3);
    dst[i] = t3[0]; dst[i + n] = t3[1]; dst[i + 2 * n] = t3[2];
  }
}
// convT: src[Ci][Co][16] -> h/l planes u16 [par][Co][K4]
__global__ __launch_bounds__(TPB) void wprep2_k(
    const float* __restrict__ src, u16* __restrict__ dh, u16* __restrict__ dl,
    int Ci, int Co)
{
  int K4 = Ci << 2;
  int tot = 4 * Co * K4;
  for (int i = blockIdx.x * TPB + threadIdx.x; i < tot; i += gridDim.x * TPB) {
    int par = i / (Co * K4); int rem = i - par * (Co * K4);
    int co = rem / K4; int k4 = rem - co * K4;
    int ci = k4 >> 2, ay = (k4 >> 1) & 1, ax = k4 & 1;
    int py = par >> 1, px = par & 1;
    int widx = ((1 - py) << 2) + (1 - px) + (ay << 3) + (ax << 1);
    float x = src[(((size_t)ci * Co + co) << 4) + widx];
    u16 h = f2bf(x);
    dh[i] = h; dl[i] = f2bf(x - bf2f(h));
  }
}

// ---------------- MFMA conv (s2,k4,p1), NS=3, hoisted gather, plane-B -------
// OUTM 0: direct NCHW + bias/relu. OUTM 1: partial [z][Co][M] (float4 in m).
template<int BM, int OUTM>
__global__ __launch_bounds__(TPB) void conv_mf3(
    const float* __restrict__ in, const u16* __restrict__ wsp,
    const float* __restrict__ bias, float* __restrict__ outp,
    int Ci, int Co, int Hi, int lwo, int relu, int KSPL, int PS)
{
  constexpr int ST = 64, MS = BM / 64;
  __shared__ __align__(16) u32 L[(BM + 64) * ST];
  u32* AL = L; u32* BL = L + BM * ST;
  const int Wi = Hi, Wo = Hi >> 1;
  const int K = Ci << 4;
  const int HW = Hi * Wi;
  const int tid = threadIdx.x;
  const int m0 = blockIdx.x * BM, n0 = blockIdx.y << 6;
  const int lane = tid & 63, wv = tid >> 6, r = lane & 15, g = lane >> 4;
  const int kb0 = blockIdx.z * KSPL;
  const int kbN = min(kb0 + KSPL, K);
  f32x4 acc[MS][4] = {};

  const int cl  = (BM == 128) ? (tid & 127) : (tid & 63);
  const int oc0 = (BM == 128) ? (tid >> 7) : (tid >> 6);
  int off8[8]; float fm8[8];
  {
    int cell = m0 + cl;
    int x = cell & (Wo - 1), y = (cell >> lwo) & (Wo - 1), b = cell >> (lwo + lwo);
    int kh0 = (oc0 & 1) << 1;
    int gy0 = 2 * y - 1 + kh0, gx0 = 2 * x - 1;
#pragma unroll
    for (int e = 0; e < 8; ++e) {
      int gy = gy0 + (e >> 2), gx = gx0 + (e & 3);
      bool ok = (gy >= 0 && gy < Hi && gx >= 0 && gx < Wi);
      int gyc = min(max(gy, 0), Hi - 1), gxc = min(max(gx, 0), Wi - 1);
      off8[e] = b * Ci * HW + gyc * Wi + gxc;
      fm8[e] = ok ? 1.f : 0.f;
    }
  }
  auto gA = [&](int kb, float v[][8]) {
#pragma unroll
    for (int p = 0; p < MS; ++p) {
      int oc = oc0 + (p << 1);
      int k8 = kb + (oc << 3);
      if (k8 < K) {
        int base = (k8 >> 4) * HW;
#pragma unroll
        for (int e = 0; e < 8; ++e) v[p][e] = in[off8[e] + base] * fm8[e];
      } else {
#pragma unroll
        for (int e = 0; e < 8; ++e) v[p][e] = 0.f;
      }
    }
  };
  auto gB = [&](int kb, uint4* d) {
    int n = tid & 63, oc2 = tid >> 6;
    int k8 = kb + (oc2 << 3);
    if (k8 < K) {
      const u16* wp = wsp + (size_t)(n0 + n) * K + k8;
      d[0] = *reinterpret_cast<const uint4*>(wp);
      d[1] = *reinterpret_cast<const uint4*>(wp + PS);
      d[2] = *reinterpret_cast<const uint4*>(wp + 2 * PS);
    } else {
      d[0] = d[1] = d[2] = make_uint4(0u, 0u, 0u, 0u);
    }
  };

  float vA[MS][8], vA2[MS][8];
  uint4 vB[3], vB2[3];
  gA(kb0, vA); gB(kb0, vB);
  for (int kb = kb0; kb < kbN; kb += 32) {
    const bool more = (kb + 32) < kbN;
    if (more) { gA(kb + 32, vA2); gB(kb + 32, vB2); }
#pragma unroll
    for (int p = 0; p < MS; ++p)
      stWf<3, ST>(AL, cl, oc0 + (p << 1), vA[p]);
    {
      int n = tid & 63, oc2 = tid >> 6;
      stWp<ST>(BL, n, oc2, 0, vB[0]);
      stWp<ST>(BL, n, oc2, 1, vB[1]);
      stWp<ST>(BL, n, oc2, 2, vB[2]);
    }
    __syncthreads();
    short8v a_[MS][3];
#pragma unroll
    for (int mm = 0; mm < MS; ++mm)
#pragma unroll
      for (int s = 0; s < 3; ++s)
        a_[mm][s] = rdFrag<ST>(AL, (wv * MS + mm) * 16 + r, (s << 2) | g);
#pragma unroll
    for (int ns = 0; ns < 4; ++ns) {
      short8v b_[3];
#pragma unroll
      for (int s = 0; s < 3; ++s) b_[s] = rdFrag<ST>(BL, (ns << 4) + r, (s << 2) | g);
#pragma unroll
      for (int mm = 0; mm < MS; ++mm) {
        acc[mm][ns] = __builtin_amdgcn_mfma_f32_16x16x32_bf16(a_[mm][0], b_[0], acc[mm][ns], 0, 0, 0);
        acc[mm][ns] = __builtin_amdgcn_mfma_f32_16x16x32_bf16(a_[mm][0], b_[1], acc[mm][ns], 0, 0, 0);
        acc[mm][ns] = __builtin_amdgcn_mfma_f32_16x16x32_bf16(a_[mm][1], b_[0], acc[mm][ns], 0, 0, 0);
        acc[mm][ns] = __builtin_amdgcn_mfma_f32_16x16x32_bf16(a_[mm][1], b_[1], acc[mm][ns], 0, 0, 0);
        acc[mm][ns] = __builtin_amdgcn_mfma_f32_16x16x32_bf16(a_[mm][0], b_[2], acc[mm][ns], 0, 0, 0);
        acc[mm][ns] = __builtin_amdgcn_mfma_f32_16x16x32_bf16(a_[mm][2], b_[0], acc[mm][ns], 0, 0, 0);
      }
    }
    __syncthreads();
    if (more) {
#pragma unroll
      for (int p = 0; p < MS; ++p)
#pragma unroll
        for (int e = 0; e < 8; ++e) vA[p][e] = vA2[p][e];
#pragma unroll
      for (int s = 0; s < 3; ++s) vB[s] = vB2[s];
    }
  }
#pragma unroll
  for (int mm = 0; mm < MS; ++mm)
#pragma unroll
    for (int ns = 0; ns < 4; ++ns) {
      int c0 = m0 + (wv * MS + mm) * 16 + (g << 2);
      int co = n0 + (ns << 4) + r;
      if (OUTM == 0) {
        int x0 = c0 & (Wo - 1), y = (c0 >> lwo) & (Wo - 1), b = c0 >> (lwo + lwo);
        float bv = bias[co];
        float4 o;
        o.x = acc[mm][ns][0] + bv; o.y = acc[mm][ns][1] + bv;
        o.z = acc[mm][ns][2] + bv; o.w = acc[mm][ns][3] + bv;
        if (relu) { o.x = fmaxf(o.x, 0.f); o.y = fmaxf(o.y, 0.f);
                    o.z = fmaxf(o.z, 0.f); o.w = fmaxf(o.w, 0.f); }
        *reinterpret_cast<float4*>(&outp[(((size_t)b * Co + co) * Wo + y) * Wo + x0]) = o;
      } else {
        const int Mtot = 256 << (lwo + lwo);
        float4 o;
        o.x = acc[mm][ns][0]; o.y = acc[mm][ns][1];
        o.z = acc[mm][ns][2]; o.w = acc[mm][ns][3];
        *reinterpret_cast<float4*>(
            &outp[((size_t)blockIdx.z * Co + co) * Mtot + c0]) = o;
      }
    }
}

// ---------------- conv split-K combine: P[z][Co][M] -> NCHW + bias/relu -----
__global__ __launch_bounds__(TPB) void conv_combine(
    const float* __restrict__ P, const float* __restrict__ bias,
    float* __restrict__ out, int Mtot, int N, int SK, int lwo, int relu)
{
  int idx = blockIdx.x * TPB + threadIdx.x;
  int mq = Mtot >> 2;
  int co = idx / mq;
  int cell0 = (idx - co * mq) << 2;
  if (co >= N) return;
  float4 s = make_float4(0.f, 0.f, 0.f, 0.f);
  for (int z = 0; z < SK; ++z) {
    const float4 pv = *reinterpret_cast<const float4*>(
        &P[((size_t)z * N + co) * Mtot + cell0]);
    s.x += pv.x; s.y += pv.y; s.z += pv.z; s.w += pv.w;
  }
  float bv = bias[co];
  s.x += bv; s.y += bv; s.z += bv; s.w += bv;
  if (relu) { s.x = fmaxf(s.x, 0.f); s.y = fmaxf(s.y, 0.f);
              s.z = fmaxf(s.z, 0.f); s.w = fmaxf(s.w, 0.f); }
  int Wo = 1 << lwo;
  int x = cell0 & (Wo - 1), y = (cell0 >> lwo) & (Wo - 1), b = cell0 >> (lwo + lwo);
  *reinterpret_cast<float4*>(&out[(((size_t)b * N + co) * Wo + y) * Wo + x]) = s;
}

// ---------------- MFMA GEMM (BM=64, BN=64, 4 waves, split-K, prefetched) ----
template<int NS, int OUTM>
__global__ __launch_bounds__(TPB) void gemm_mf(
    const float* __restrict__ A, const float* __restrict__ W,
    const float* __restrict__ bias, void* __restrict__ outp,
    int M, int K, int N, int KSPL)
{
  constexpr int ST = (NS == 3) ? 64 : 32;
  __shared__ __align__(16) u32 L[(64 + 64) * ST];
  u32* AL = L; u32* BL = L + 64 * ST;
  const int tid = threadIdx.x;
  const int m0 = blockIdx.x << 6, n0 = blockIdx.y << 6;
  const int lane = tid & 63, wv = tid >> 6, r = lane & 15, g = lane >> 4;
  const int kb0 = blockIdx.z * KSPL;
  const int kbN = kb0 + KSPL;
  const int cl = tid & 63, oct = tid >> 6;
  f32x4 acc[4] = {};

  float vA[8], vB[8], vA2[8], vB2[8];
  auto gA = [&](int kt, float* v) {
    const float* ap = &A[(size_t)(m0 + cl) * K + kt + (oct << 3)];
    *reinterpret_cast<float4*>(&v[0]) = *reinterpret_cast<const float4*>(ap);
    *reinterpret_cast<float4*>(&v[4]) = *reinterpret_cast<const float4*>(ap + 4);
  };
  auto gB = [&](int kt, float* v) {
#pragma unroll
    for (int e = 0; e < 8; ++e)
      v[e] = W[(size_t)(kt + (oct << 3) + e) * N + n0 + cl];
  };

  gA(kb0, vA); gB(kb0, vB);
  for (int kt = kb0; kt < kbN; kt += 32) {
    const bool more = (kt + 32) < kbN;
    if (more) { gA(kt + 32, vA2); gB(kt + 32, vB2); }
    stWf<NS, ST>(AL, cl, oct, vA);
    stWf<NS, ST>(BL, cl, oct, vB);
    __syncthreads();
    short8v a_[3];
#pragma unroll
    for (int s = 0; s < NS; ++s) a_[s] = rdFrag<ST>(AL, (wv << 4) + r, (s << 2) | g);
#pragma unroll
    for (int ns = 0; ns < 4; ++ns) {
      short8v b_[3];
#pragma unroll
      for (int s = 0; s < NS; ++s) b_[s] = rdFrag<ST>(BL, (ns << 4) + r, (s << 2) | g);
      acc[ns] = __builtin_amdgcn_mfma_f32_16x16x32_bf16(a_[0], b_[0], acc[ns], 0, 0, 0);
      acc[ns] = __builtin_amdgcn_mfma_f32_16x16x32_bf16(a_[0], b_[1], acc[ns], 0, 0, 0);
      acc[ns] = __builtin_amdgcn_mfma_f32_16x16x32_bf16(a_[1], b_[0], acc[ns], 0, 0, 0);
      if (NS == 3) {
        acc[ns] = __builtin_amdgcn_mfma_f32_16x16x32_bf16(a_[1], b_[1], acc[ns], 0, 0, 0);
        acc[ns] = __builtin_amdgcn_mfma_f32_16x16x32_bf16(a_[0], b_[2], acc[ns], 0, 0, 0);
        acc[ns] = __builtin_amdgcn_mfma_f32_16x16x32_bf16(a_[2], b_[0], acc[ns], 0, 0, 0);
      }
    }
    __syncthreads();
    if (more) {
#pragma unroll
      for (int e = 0; e < 8; ++e) { vA[e] = vA2[e]; vB[e] = vB2[e]; }
    }
  }
#pragma unroll
  for (int ns = 0; ns < 4; ++ns)
#pragma unroll
    for (int q = 0; q < 4; ++q) {
      int m = m0 + (wv << 4) + (g << 2) + q;
      int n = n0 + (ns << 4) + r;
      float v = acc[ns][q];
      if (OUTM == 0) ((float*)outp)[((size_t)blockIdx.z * M + m) * N + n] = v;
      else           ((u32*)outp)[(size_t)m * N + n] = packhl(v + bias[n]);
    }
}

// ---------------- MFMA convT, NS=2, hoisted gather, quadrant in/out ---------
// input: SPLITIN 0 -> standard u32 [b][Ci][Hi][Wi]; 1 -> quadrant u32 layout.
// output: quadrant layout [par][b][Co][Hi][Wi] (EMIT 1: u32 hl, 0: f32 bits).
template<int BM, int EMIT, int SPLITIN>
__global__ __launch_bounds__(TPB) void convt_mf2(
    const u32* __restrict__ in, const u16* __restrict__ wth,
    const u16* __restrict__ wtl, const float* __restrict__ bias,
    u32* __restrict__ outq, int Ci, int Co, int Hi, int lwi, int relu)
{
  constexpr int ST = 32, MS = BM / 64;
  constexpr int STC = BM + 4;
  constexpr int LSZ = ((BM + 64) * ST > 64 * STC) ? (BM + 64) * ST : 64 * STC;
  __shared__ __align__(16) u32 L[LSZ];
  u32* AL = L; u32* BL = L + BM * ST;
  const int Wi = Hi, K4 = Ci << 2;
  const int HW = Hi * Wi, HWq = HW >> 2, Wiq = Wi >> 1;
  const int par = blockIdx.z, py = par >> 1, px = par & 1;
  const int tid = threadIdx.x;
  const int m0 = blockIdx.x * BM, n0 = blockIdx.y << 6;
  const int lane = tid & 63, wv = tid >> 6, r = lane & 15, g = lane >> 4;
  f32x4 acc[MS][4] = {};

  const int cl  = (BM == 128) ? (tid & 127) : (tid & 63);
  const int oc0 = (BM == 128) ? (tid >> 7) : (tid >> 6);
  int offT[4]; u32 mskT[4];
  {
    int cell = m0 + cl;
    int X = cell & (Wi - 1), Y = (cell >> lwi) & (Wi - 1), b = cell >> (lwi + lwi);
#pragma unroll
    for (int t = 0; t < 4; ++t) {
      int ay = t >> 1, ax = t & 1;
      int gy = Y + py - ay, gx = X + px - ax;
      bool ok = (gy >= 0 && gy < Hi && gx >= 0 && gx < Wi);
      int gyc = min(max(gy, 0), Hi - 1), gxc = min(max(gx, 0), Wi - 1);
      if (SPLITIN) {
        int q = ((gyc & 1) << 1) | (gxc & 1);
        offT[t] = q * (256 * Ci * HWq) + b * Ci * HWq + (gyc >> 1) * Wiq + (gxc >> 1);
      } else {
        offT[t] = b * Ci * HW + gyc * Wi + gxc;
      }
      mskT[t] = ok ? 0xffffffffu : 0u;
    }
  }
  const int stepCi = SPLITIN ? HWq : HW;

  auto gA = [&](int kb, u32 v[][8]) {
#pragma unroll
    for (int p = 0; p < MS; ++p) {
      int oc = oc0 + (p << 1);
      int cibase = ((kb >> 2) + (oc << 1)) * stepCi;
#pragma unroll
      for (int e = 0; e < 8; ++e) {
        int t = e & 3;
        v[p][e] = in[offT[t] + cibase + ((e >> 2) ? stepCi : 0)] & mskT[t];
      }
    }
  };
  auto gB = [&](int kb, uint4* d) {
    int n = tid & 63, oc2 = tid >> 6;
    size_t base = (size_t)(par * Co + n0 + n) * K4 + kb + (oc2 << 3);
    d[0] = *reinterpret_cast<const uint4*>(wth + base);
    d[1] = *reinterpret_cast<const uint4*>(wtl + base);
  };

  u32 vA[MS][8], vA2[MS][8];
  uint4 vB[2], vB2[2];
  gA(0, vA); gB(0, vB);
  for (int kb = 0; kb < K4; kb += 32) {
    const bool more = (kb + 32) < K4;
    if (more) { gA(kb + 32, vA2); gB(kb + 32, vB2); }
#pragma unroll
    for (int p = 0; p < MS; ++p) {
      const u32* v = vA[p];
      const int sw = cl & 7;
      int oc = oc0 + (p << 1);
      uint4 dh, dl;
      dh.x = (v[0] & 0xffffu) | (v[1] << 16);  dl.x = (v[0] >> 16) | (v[1] & 0xffff0000u);
      dh.y = (v[2] & 0xffffu) | (v[3] << 16);  dl.y = (v[2] >> 16) | (v[3] & 0xffff0000u);
      dh.z = (v[4] & 0xffffu) | (v[5] << 16);  dl.z = (v[4] >> 16) | (v[5] & 0xffff0000u);
      dh.w = (v[6] & 0xffffu) | (v[7] << 16);  dl.w = (v[6] >> 16) | (v[7] & 0xffff0000u);
      *reinterpret_cast<uint4*>(&AL[cl * ST + ((oc ^ sw) << 2)]) = dh;
      *reinterpret_cast<uint4*>(&AL[cl * ST + (((4 | oc) ^ sw) << 2)]) = dl;
    }
    {
      int n = tid & 63, oc2 = tid >> 6;
      stWp<ST>(BL, n, oc2, 0, vB[0]);
      stWp<ST>(BL, n, oc2, 1, vB[1]);
    }
    __syncthreads();
    short8v a_[MS][2];
#pragma unroll
    for (int mm = 0; mm < MS; ++mm)
#pragma unroll
      for (int s = 0; s < 2; ++s)
        a_[mm][s] = rdFrag<ST>(AL, (wv * MS + mm) * 16 + r, (s << 2) | g);
#pragma unroll
    for (int ns = 0; ns < 4; ++ns) {
      short8v b_[2];
#pragma unroll
      for (int s = 0; s < 2; ++s) b_[s] = rdFrag<ST>(BL, (ns << 4) + r, (s << 2) | g);
#pragma unroll
      for (int mm = 0; mm < MS; ++mm) {
        acc[mm][ns] = __builtin_amdgcn_mfma_f32_16x16x32_bf16(a_[mm][0], b_[0], acc[mm][ns], 0, 0, 0);
        acc[mm][ns] = __builtin_amdgcn_mfma_f32_16x16x32_bf16(a_[mm][0], b_[1], acc[mm][ns], 0, 0, 0);
        acc[mm][ns] = __builtin_amdgcn_mfma_f32_16x16x32_bf16(a_[mm][1], b_[0], acc[mm][ns], 0, 0, 0);
      }
    }
    __syncthreads();
    if (more) {
#pragma unroll
      for (int p = 0; p < MS; ++p)
#pragma unroll
        for (int e = 0; e < 8; ++e) vA[p][e] = vA2[p][e];
      vB[0] = vB2[0]; vB[1] = vB2[1];
    }
  }
  // ---- epilogue: LDS transpose -> coalesced quadrant writes ----
#pragma unroll
  for (int mm = 0; mm < MS; ++mm)
#pragma unroll
    for (int ns = 0; ns < 4; ++ns)
#pragma unroll
      for (int q = 0; q < 4; ++q) {
        int cell = (wv * MS + mm) * 16 + (g << 2) + q;
        int col = (ns << 4) + r;
        float v = acc[mm][ns][q] + bias[n0 + col];
        if (relu) v = fmaxf(v, 0.f);
        L[col * STC + cell] = EMIT ? packhl(v) : __float_as_uint(v);
      }
  __syncthreads();
  const size_t QO = (size_t)256 * Co * HW;
  u32* op = outq + (size_t)par * QO;
  constexpr int C4N = BM / 4;
  constexpr int NCH = (BM * 64) / (TPB * 4);
#pragma unroll
  for (int it = 0; it < NCH; ++it) {
    int lin = it * TPB + tid;
    int c4 = lin & (C4N - 1);
    int col = lin / C4N;
    int cell0 = c4 << 2;
    uint4 d = *reinterpret_cast<const uint4*>(&L[col * STC + cell0]);
    int gc = m0 + cell0;
    int Xo = gc & (Wi - 1), Yo = (gc >> lwi) & (Wi - 1), bo = gc >> (lwi + lwi);
    *reinterpret_cast<uint4*>(
        &op[((size_t)(bo * Co + n0 + col) * Hi + Yo) * Wi + Xo]) = d;
  }
}

// ---------------- fc split-K combine ----------------------------------------
__global__ __launch_bounds__(TPB) void combine_k(
    const float* __restrict__ P, const float* __restrict__ bias,
    float* __restrict__ out, int MN, int N, int SK, int relu)
{
  int i4 = (blockIdx.x * TPB + threadIdx.x) << 2;
  if (i4 >= MN) return;
  float4 s = make_float4(0.f, 0.f, 0.f, 0.f);
  for (int z = 0; z < SK; ++z) {
    const float4 pv = *reinterpret_cast<const float4*>(&P[(size_t)z * MN + i4]);
    s.x += pv.x; s.y += pv.y; s.z += pv.z; s.w += pv.w;
  }
  int n = i4 % N;
  s.x += bias[n]; s.y += bias[n + 1]; s.z += bias[n + 2]; s.w += bias[n + 3];
  if (relu) { s.x = fmaxf(s.x, 0.f); s.y = fmaxf(s.y, 0.f);
              s.z = fmaxf(s.z, 0.f); s.w = fmaxf(s.w, 0.f); }
  *reinterpret_cast<float4*>(&out[i4]) = s;
}

// ---------------- fp32 FC GEMM (g0, g1 only) --------------------------------
__global__ __launch_bounds__(TPB) void gemm_ig2(
    const float* __restrict__ A, const float* __restrict__ W,
    const float* __restrict__ bias, float* __restrict__ C,
    int M, int K, int N, int relu)
{
  constexpr int BM = 64, BN = 32, BK = 32;
  __shared__ __align__(16) float As[BK][BM + 4];
  __shared__ __align__(16) float Ws[BK][BN + 4];
  const int tid = threadIdx.x;
  const int m0 = blockIdx.x * BM;
  const int n0 = blockIdx.y * BN;
  const int tn = tid & 15;
  const int tm = tid >> 4;
  float acc[4][2] = {{0.f,0.f},{0.f,0.f},{0.f,0.f},{0.f,0.f}};

  for (int kt = 0; kt < K; kt += BK) {
#pragma unroll
    for (int f = 0; f < 2; ++f) {
      int idx = f * TPB + tid;
      int kq = idx & 7;
      int m = idx >> 3;
      const float4 av = *reinterpret_cast<const float4*>(
          &A[(size_t)(m0 + m) * K + kt + 4 * kq]);
      As[4 * kq + 0][m] = av.x;
      As[4 * kq + 1][m] = av.y;
      As[4 * kq + 2][m] = av.z;
      As[4 * kq + 3][m] = av.w;
    }
#pragma unroll
    for (int i = 0; i < 4; ++i) {
      int lin = i * TPB + tid;
      int n = lin & 31;
      int kk = lin >> 5;
      Ws[kk][n] = W[(size_t)(kt + kk) * N + n0 + n];
    }
    __syncthreads();
#pragma unroll
    for (int k = 0; k < BK; ++k) {
      const float4 av = *reinterpret_cast<const float4*>(&As[k][4 * tm]);
      const float2 wv = *reinterpret_cast<const float2*>(&Ws[k][2 * tn]);
      acc[0][0] = fmaf(av.x, wv.x, acc[0][0]);
      acc[0][1] = fmaf(av.x, wv.y, acc[0][1]);
      acc[1][0] = fmaf(av.y, wv.x, acc[1][0]);
      acc[1][1] = fmaf(av.y, wv.y, acc[1][1]);
      acc[2][0] = fmaf(av.z, wv.x, acc[2][0]);
      acc[2][1] = fmaf(av.z, wv.y, acc[2][1]);
      acc[3][0] = fmaf(av.w, wv.x, acc[3][0]);
      acc[3][1] = fmaf(av.w, wv.y, acc[3][1]);
    }
    __syncthreads();
  }
  const float b0 = bias[n0 + 2 * tn];
  const float b1 = bias[n0 + 2 * tn + 1];
#pragma unroll
  for (int mi = 0; mi < 4; ++mi) {
    int m = m0 + 4 * tm + mi;
    float2 v = make_float2(acc[mi][0] + b0, acc[mi][1] + b1);
    if (relu) { v.x = fmaxf(v.x, 0.f); v.y = fmaxf(v.y, 0.f); }
    *reinterpret_cast<float2*>(&C[(size_t)m * N + n0 + 2 * tn]) = v;
  }
}

// ---------------- dedicated t3: convT 64->3, fp32, quadrant input -----------
__global__ __launch_bounds__(TPB) void convt3_kernel(
    const float* __restrict__ inq, const float* __restrict__ w,
    const float* __restrict__ bias, float* __restrict__ out)
{
  __shared__ float wl[3072];
  __shared__ float il[8][33 * 32];
  const int b = blockIdx.x;
  const int tid = threadIdx.x;
  for (int i = tid; i < 3072; i += TPB) wl[i] = w[i];
  const int Y = tid >> 3;
  const int X0 = (tid & 7) << 2;
  float acc[3][2][8];
#pragma unroll
  for (int o = 0; o < 3; ++o)
#pragma unroll
    for (int p = 0; p < 2; ++p)
#pragma unroll
      for (int q = 0; q < 8; ++q) acc[o][p][q] = 0.f;

  for (int c0 = 0; c0 < 64; c0 += 8) {
    __syncthreads();
    for (int i = tid; i < 8192; i += TPB) {
      int cc = i >> 10, yy = (i >> 5) & 31, xx = i & 31;
      int q = ((yy & 1) << 1) | (xx & 1);
      il[cc][yy * 33 + xx] = inq[(size_t)q * 4194304 +
          (((size_t)b * 64 + c0 + cc) * 16 + (yy >> 1)) * 16 + (xx >> 1)];
    }
    __syncthreads();
    for (int cc = 0; cc < 8; ++cc) {
      float iv[3][6];
#pragma unroll
      for (int j = 0; j < 3; ++j) {
        int gy = Y - 1 + j;
        int gyc = min(max(gy, 0), 31);
        float my = (gy >= 0 && gy < 32) ? 1.f : 0.f;
#pragma unroll
        for (int k = 0; k < 6; ++k) {
          int gx = X0 - 1 + k;
          int gxc = min(max(gx, 0), 31);
          float mx = (gx >= 0 && gx < 32) ? 1.f : 0.f;
          iv[j][k] = il[cc][gyc * 33 + gxc] * (my * mx);
        }
      }
      const float* wq = &wl[(c0 + cc) * 48];
#pragma unroll
      for (int o = 0; o < 3; ++o) {
        const float* wo = wq + o * 16;
#pragma unroll
        for (int c = 0; c < 4; ++c) {
          acc[o][0][2*c]   = fmaf(iv[1][c+1], wo[5],  acc[o][0][2*c]);
          acc[o][0][2*c]   = fmaf(iv[1][c],   wo[7],  acc[o][0][2*c]);
          acc[o][0][2*c]   = fmaf(iv[0][c+1], wo[13], acc[o][0][2*c]);
          acc[o][0][2*c]   = fmaf(iv[0][c],   wo[15], acc[o][0][2*c]);
          acc[o][0][2*c+1] = fmaf(iv[1][c+2], wo[4],  acc[o][0][2*c+1]);
          acc[o][0][2*c+1] = fmaf(iv[1][c+1], wo[6],  acc[o][0][2*c+1]);
          acc[o][0][2*c+1] = fmaf(iv[0][c+2], wo[12], acc[o][0][2*c+1]);
          acc[o][0][2*c+1] = fmaf(iv[0][c+1], wo[14], acc[o][0][2*c+1]);
          acc[o][1][2*c]   = fmaf(iv[2][c+1], wo[1],  acc[o][1][2*c]);
          acc[o][1][2*c]   = fmaf(iv[2][c],   wo[3],  acc[o][1][2*c]);
          acc[o][1][2*c]   = fmaf(iv[1][c+1], wo[9],  acc[o][1][2*c]);
          acc[o][1][2*c]   = fmaf(iv[1][c],   wo[11], acc[o][1][2*c]);
          acc[o][1][2*c+1] = fmaf(iv[2][c+2], wo[0],  acc[o][1][2*c+1]);
          acc[o][1][2*c+1] = fmaf(iv[2][c+1], wo[2],  acc[o][1][2*c+1]);
          acc[o][1][2*c+1] = fmaf(iv[1][c+2], wo[8],  acc[o][1][2*c+1]);
          acc[o][1][2*c+1] = fmaf(iv[1][c+1], wo[10], acc[o][1][2*c+1]);
        }
      }
    }
  }
#pragma unroll
  for (int o = 0; o < 3; ++o) {
    float bv = bias[o];
#pragma unroll
    for (int p = 0; p < 2; ++p) {
      float* op = out + (((size_t)b * 3 + o) * 64 + 2 * Y + p) * 64 + 2 * X0;
      float4 v0 = make_float4(acc[o][p][0] + bv, acc[o][p][1] + bv,
                              acc[o][p][2] + bv, acc[o][p][3] + bv);
      float4 v1 = make_float4(acc[o][p][4] + bv, acc[o][p][5] + bv,
                              acc[o][p][6] + bv, acc[o][p][7] + bv);
      *reinterpret_cast<float4*>(op)     = v0;
      *reinterpret_cast<float4*>(op + 4) = v1;
    }
  }
}

// ---------------- VQ ---------------------------------------------------------
__global__ __launch_bounds__(TPB) void vq_kernel(
    const float* __restrict__ z, const float* __restrict__ cb,
    float* __restrict__ e, float* __restrict__ rowloss)
{
  const int row = blockIdx.x;
  const int b = row >> 4, s = row & 15;
  __shared__ float zr[64];
  __shared__ float bval[TPB];
  __shared__ int   bidx[TPB];
  const int tid = threadIdx.x;
  if (tid < 64) zr[tid] = z[(size_t)b * 1536 + s * 64 + tid];
  __syncthreads();

  float best = 3.4e38f;
  int bi = 0;
#pragma unroll
  for (int rep = 0; rep < 2; ++rep) {
    int j = tid + rep * TPB;
    const float4* c4 = reinterpret_cast<const float4*>(cb + (size_t)j * 64);
    float d = 0.f;
#pragma unroll
    for (int k = 0; k < 16; ++k) {
      float4 cv = c4[k];
      float t0 = zr[4 * k + 0] - cv.x;
      float t1 = zr[4 * k + 1] - cv.y;
      float t2 = zr[4 * k + 2] - cv.z;
      float t3 = zr[4 * k + 3] - cv.w;
      d = fmaf(t0, t0, d); d = fmaf(t1, t1, d);
      d = fmaf(t2, t2, d); d = fmaf(t3, t3, d);
    }
    if (d < best) { best = d; bi = j; }
  }
  bval[tid] = best; bidx[tid] = bi;
  __syncthreads();
  for (int sft = 128; sft > 0; sft >>= 1) {
    if (tid < sft) {
      float v2 = bval[tid + sft]; int i2 = bidx[tid + sft];
      if (v2 < bval[tid] || (v2 == bval[tid] && i2 < bidx[tid])) {
        bval[tid] = v2; bidx[tid] = i2;
      }
    }
    __syncthreads();
  }
  const int bj = bidx[0];
  if (tid < 64)
    e[(size_t)b * 1536 + s * 64 + tid] = cb[(size_t)bj * 64 + tid];
  if (tid == 0) rowloss[row] = bval[0];
}

__global__ __launch_bounds__(TPB) void zs_copy_kernel(
    const float* __restrict__ z, float* __restrict__ e)
{
  int i = blockIdx.x * TPB + threadIdx.x;
  int b = i >> 9, k = i & 511;
  e[(size_t)b * 1536 + 1024 + k] = z[(size_t)b * 1536 + 1024 + k];
}

__global__ __launch_bounds__(TPB) void loss_reduce_kernel(
    const float* __restrict__ rl, float* __restrict__ out)
{
  __shared__ float sm[TPB];
  float s = 0.f;
  for (int i = threadIdx.x; i < 4096; i += TPB) s += rl[i];
  sm[threadIdx.x] = s;
  __syncthreads();
  for (int sft = 128; sft > 0; sft >>= 1) {
    if (threadIdx.x < sft) sm[threadIdx.x] += sm[threadIdx.x + sft];
    __syncthreads();
  }
  if (threadIdx.x == 0) out[0] = sm[0] * (1.25f / 262144.f);
}

// ============================================================================
extern "C" void kernel_launch(void* const* d_in, const int* in_sizes, int n_in,
                              void* d_out, int out_size, void* d_ws, size_t ws_size,
                              hipStream_t stream)
{
  const float* x    = (const float*)d_in[0];
  const float* ew0  = (const float*)d_in[1];
  const float* eb0  = (const float*)d_in[2];
  const float* ew1  = (const float*)d_in[3];
  const float* eb1  = (const float*)d_in[4];
  const float* ew2  = (const float*)d_in[5];
  const float* eb2  = (const float*)d_in[6];
  const float* ew3  = (const float*)d_in[7];
  const float* eb3  = (const float*)d_in[8];
  const float* fw0  = (const float*)d_in[9];
  const float* fb0  = (const float*)d_in[10];
  const float* fw1  = (const float*)d_in[11];
  const float* fb1  = (const float*)d_in[12];
  const float* fw2  = (const float*)d_in[13];
  const float* fb2  = (const float*)d_in[14];
  const float* cb   = (const float*)d_in[15];
  const float* gw0  = (const float*)d_in[16];
  const float* gb0  = (const float*)d_in[17];
  const float* gw1  = (const float*)d_in[18];
  const float* gb1  = (const float*)d_in[19];
  const float* gw2  = (const float*)d_in[20];
  const float* gb2  = (const float*)d_in[21];
  const float* tw0  = (const float*)d_in[22];
  const float* tb0  = (const float*)d_in[23];
  const float* tw1  = (const float*)d_in[24];
  const float* tb1  = (const float*)d_in[25];
  const float* tw2  = (const float*)d_in[26];
  const float* tb2  = (const float*)d_in[27];
  const float* tw3  = (const float*)d_in[28];
  const float* tb3  = (const float*)d_in[29];

  float* out = (float*)d_out;
  float* ws  = (float*)d_ws;

  float* H0   = ws + 0;
  float* H1   = ws + 16777216;
  float* H2   = ws + 0;
  float* H3   = ws + 16777216;
  float* PC   = ws + 2097152;
  float* F0   = ws + 0;
  float* F1   = ws + 262144;
  float* Z    = ws + 524288;
  float* E    = ws + 917504;
  float* G0   = ws + 1310720;
  float* G1   = ws + 1441792;
  u32*   G2p  = (u32*)(ws + 1703936);
  u32*   T0s  = (u32*)(ws + 2752512);
  u32*   T1s  = (u32*)(ws + 4849664);
  float* T2s  = ws + 9043968;
  u16*   WE0  = (u16*)(ws + 20971520);
  u16*   WE1  = (u16*)(ws + 20976128);
  u16*   WE2  = (u16*)(ws + 21074432);
  u16*   WE3  = (u16*)(ws + 21271040);
  u16*   WT0h = (u16*)(ws + 25821184);
  u16*   WT0l = (u16*)(ws + 26083328);
  u16*   WT1h = (u16*)(ws + 26345472);
  u16*   WT1l = (u16*)(ws + 26411008);
  u16*   WT2h = (u16*)(ws + 26476544);
  u16*   WT2l = (u16*)(ws + 26509312);
  float* P    = ws + 26542080;
  float* RL   = ws + 28639232;

  // ---- weight prep ----
  wsplit3_k<<<dim3(12),  TPB, 0, stream>>>(ew0, WE0, 3072);
  wsplit3_k<<<dim3(256), TPB, 0, stream>>>(ew1, WE1, 65536);
  wsplit3_k<<<dim3(512), TPB, 0, stream>>>(ew2, WE2, 131072);
  wsplit3_k<<<dim3(1024),TPB, 0, stream>>>(ew3, WE3, 524288);
  wprep2_k<<<dim3(512), TPB, 0, stream>>>(tw0, WT0h, WT0l, 256, 128);
  wprep2_k<<<dim3(128), TPB, 0, stream>>>(tw1, WT1h, WT1l, 128, 64);
  wprep2_k<<<dim3(64),  TPB, 0, stream>>>(tw2, WT2h, WT2l, 64, 64);

  // ---- encoder convs (MFMA NS=3, hoisted, plane-B; conv2/3 split-K) ----
  conv_mf3<128,0><<<dim3(2048, 1, 1), TPB, 0, stream>>>(x,  WE0, eb0, H0, 3,  64,  64, 5, 1, 48,   3072);
  conv_mf3<128,0><<<dim3(512, 1, 1),  TPB, 0, stream>>>(H0, WE1, eb1, H1, 64, 64,  32, 4, 1, 1024, 65536);
  conv_mf3<128,1><<<dim3(128, 2, 4),  TPB, 0, stream>>>(H1, WE2, eb2, PC, 64, 128, 16, 3, 1, 256,  131072);
  conv_combine<<<dim3(2048), TPB, 0, stream>>>(PC, eb2, H2, 16384, 128, 4, 3, 1);
  conv_mf3<64,1><<<dim3(64, 4, 4),    TPB, 0, stream>>>(H2, WE3, eb3, PC, 128, 256, 8, 2, 0, 512,  524288);
  conv_combine<<<dim3(1024), TPB, 0, stream>>>(PC, eb3, H3, 4096, 256, 4, 2, 0);

  // ---- encoder FC (MFMA NS=3, split-K + combine) ----
  gemm_mf<3,0><<<dim3(4, 16, 8), TPB, 0, stream>>>(H3, fw0, fb0, (void*)P, 256, 4096, 1024, 512);
  combine_k<<<dim3(256), TPB, 0, stream>>>(P, fb0, F0, 262144, 1024, 8, 1);
  gemm_mf<3,0><<<dim3(4, 16, 4), TPB, 0, stream>>>(F0, fw1, fb1, (void*)P, 256, 1024, 1024, 256);
  combine_k<<<dim3(256), TPB, 0, stream>>>(P, fb1, F1, 262144, 1024, 4, 1);
  gemm_mf<3,0><<<dim3(4, 24, 4), TPB, 0, stream>>>(F1, fw2, fb2, (void*)P, 256, 1024, 1536, 256);
  combine_k<<<dim3(384), TPB, 0, stream>>>(P, fb2, Z, 393216, 1536, 4, 0);

  // ---- VQ ----
  vq_kernel<<<dim3(4096), TPB, 0, stream>>>(Z, cb, E, RL);
  zs_copy_kernel<<<dim3(512), TPB, 0, stream>>>(Z, E);
  loss_reduce_kernel<<<dim3(1), TPB, 0, stream>>>(RL, out + (size_t)out_size - 1);

  // ---- decoder FC ----
  gemm_ig2<<<dim3(4, 16), TPB, 0, stream>>>(E,  gw0, gb0, G0, 256, 1536, 512,  1);
  gemm_ig2<<<dim3(4, 32), TPB, 0, stream>>>(G0, gw1, gb1, G1, 256, 512,  1024, 1);
  gemm_mf<2,1><<<dim3(4, 64, 1), TPB, 0, stream>>>(G1, gw2, gb2, (void*)G2p, 256, 1024, 4096, 1024);

  // ---- decoder transposed convs (MFMA NS=2, quadrant layouts) ----
  convt_mf2<64,1,0><<<dim3(64, 2, 4),   TPB, 0, stream>>>(G2p, WT0h, WT0l, tb0, T0s, 256, 128, 4,  2, 1);
  convt_mf2<128,1,1><<<dim3(128, 1, 4), TPB, 0, stream>>>(T0s, WT1h, WT1l, tb1, T1s, 128, 64,  8,  3, 1);
  convt_mf2<128,0,1><<<dim3(512, 1, 4), TPB, 0, stream>>>(T1s, WT2h, WT2l, tb2, (u32*)T2s, 64, 64, 16, 4, 1);
  convt3_kernel<<<dim3(256), TPB, 0, stream>>>(T2s, tw3, tb3, out);
}

// Round 8
// 682.961 us; speedup vs baseline: 11.4169x; 1.0462x over previous
//
#include <hip/hip_runtime.h>
#include <hip/hip_bf16.h>

// ============================================================================
// VQ-VAE forward, round 8:
//  - f2bf now uses HW bf16 conversion (v_cvt_pk_bf16_f32) instead of integer
//    RNE emulation: split cost drops ~4x (was the VALU critical path, R7 PMC:
//    VALUBusy 38% vs MfmaUtil 21% on conv1).
//  - LDS swizzle widened to row&15 for 16-chunk (ST=64) tiles: A-stage write
//    conflicts 8-way -> 4-way. ST=32 paths keep &7 (8 chunks).
//  - convt3 split over ci (x2): 512 blocks (2/CU) + bias-combine.
// Encoder NS=3 (6 MFMA terms, argmin-safe), decoder NS=2 (3 terms).
// Workspace plan unchanged from R7; convt3 partial PT3=ws[0..6,291,456) is
// dead-region reuse. No atomics; deterministic; graph-safe.
// ============================================================================

#define TPB 256
typedef __attribute__((ext_vector_type(8))) short short8v;
typedef __attribute__((ext_vector_type(4))) float f32x4;
typedef unsigned int u32;
typedef unsigned short u16;

__device__ inline u16 f2bf(float x){
  union { __hip_bfloat16 b; u16 u; } cv;
  cv.b = __float2bfloat16(x);
  return cv.u;
}
__device__ inline float bf2f(u16 h){ union{u32 u;float f;}v; v.u=((u32)h)<<16; return v.f;}
__device__ inline u32 packhl(float x){ u16 h=f2bf(x); u16 l=f2bf(x-bf2f(h)); return ((u32)l<<16)|(u32)h;}

template<int NS>
__device__ inline void splitN(float x, u16 t[3]) {
  u16 h0 = f2bf(x); t[0] = h0;
  float r1 = x - bf2f(h0);
  u16 h1 = f2bf(r1); t[1] = h1;
  if (NS == 3) { float r2 = r1 - bf2f(h1); t[2] = f2bf(r2); }
}

template<int NS, int ST>
__device__ inline void stW(u32* L, int row, int oct, const u16 hs[3][8]) {
  constexpr int SWM = (ST == 64) ? 15 : 7;
  const int sw = row & SWM;
#pragma unroll
  for (int s = 0; s < NS; ++s) {
    uint4 d;
    d.x = (u32)hs[s][0] | ((u32)hs[s][1] << 16);
    d.y = (u32)hs[s][2] | ((u32)hs[s][3] << 16);
    d.z = (u32)hs[s][4] | ((u32)hs[s][5] << 16);
    d.w = (u32)hs[s][6] | ((u32)hs[s][7] << 16);
    int ch = (((s << 2) | oct) ^ sw) << 2;
    *reinterpret_cast<uint4*>(&L[row * ST + ch]) = d;
  }
}

template<int NS, int ST>
__device__ inline void stWf(u32* L, int row, int oct, const float v[8]) {
  u16 hs[3][8];
#pragma unroll
  for (int e = 0; e < 8; ++e) {
    u16 t3[3]; splitN<NS>(v[e], t3);
    hs[0][e] = t3[0]; hs[1][e] = t3[1]; if (NS == 3) hs[2][e] = t3[2];
  }
  stW<NS, ST>(L, row, oct, hs);
}

template<int ST>
__device__ inline void stWp(u32* L, int row, int oct, int s, uint4 d) {
  constexpr int SWM = (ST == 64) ? 15 : 7;
  int ch = (((s << 2) | oct) ^ (row & SWM)) << 2;
  *reinterpret_cast<uint4*>(&L[row * ST + ch]) = d;
}

template<int ST>
__device__ inline short8v rdFrag(const u32* L, int row, int c) {
  constexpr int SWM = (ST == 64) ? 15 : 7;
  int ph = (c ^ (row & SWM)) << 2;
  return *reinterpret_cast<const short8v*>(&L[row * ST + ph]);
}

// ---------------- weight prep -----------------------------------------------
__global__ __launch_bounds__(TPB) void wsplit3_k(
    const float* __restrict__ src, u16* __restrict__ dst, int n)
{
  for (int i = blockIdx.x * TPB + threadIdx.x; i < n; i += gridDim.x * TPB) {
    u16 t3[3]; splitN<3>(src[i], t3);
    dst[i] = t3[0]; dst[i + n] = t3[1]; dst[i + 2 * n] = t3[2];
  }
}
__global__ __launch_bounds__(TPB) void wprep2_k(
    const float* __restrict__ src, u16* __restrict__ dh, u16* __restrict__ dl,
    int Ci, int Co)
{
  int K4 = Ci << 2;
  int tot = 4 * Co * K4;
  for (int i = blockIdx.x * TPB + threadIdx.x; i < tot; i += gridDim.x * TPB) {
    int par = i / (Co * K4); int rem = i - par * (Co * K4);
    int co = rem / K4; int k4 = rem - co * K4;
    int ci = k4 >> 2, ay = (k4 >> 1) & 1, ax = k4 & 1;
    int py = par >> 1, px = par & 1;
    int widx = ((1 - py) << 2) + (1 - px) + (ay << 3) + (ax << 1);
    float x = src[(((size_t)ci * Co + co) << 4) + widx];
    u16 h = f2bf(x);
    dh[i] = h; dl[i] = f2bf(x - bf2f(h));
  }
}

// ---------------- MFMA conv (s2,k4,p1), NS=3, hoisted gather, plane-B -------
template<int BM, int OUTM>
__global__ __launch_bounds__(TPB) void conv_mf3(
    const float* __restrict__ in, const u16* __restrict__ wsp,
    const float* __restrict__ bias, float* __restrict__ outp,
    int Ci, int Co, int Hi, int lwo, int relu, int KSPL, int PS)
{
  constexpr int ST = 64, MS = BM / 64;
  __shared__ __align__(16) u32 L[(BM + 64) * ST];
  u32* AL = L; u32* BL = L + BM * ST;
  const int Wi = Hi, Wo = Hi >> 1;
  const int K = Ci << 4;
  const int HW = Hi * Wi;
  const int tid = threadIdx.x;
  const int m0 = blockIdx.x * BM, n0 = blockIdx.y << 6;
  const int lane = tid & 63, wv = tid >> 6, r = lane & 15, g = lane >> 4;
  const int kb0 = blockIdx.z * KSPL;
  const int kbN = min(kb0 + KSPL, K);
  f32x4 acc[MS][4] = {};

  const int cl  = (BM == 128) ? (tid & 127) : (tid & 63);
  const int oc0 = (BM == 128) ? (tid >> 7) : (tid >> 6);
  int off8[8]; float fm8[8];
  {
    int cell = m0 + cl;
    int x = cell & (Wo - 1), y = (cell >> lwo) & (Wo - 1), b = cell >> (lwo + lwo);
    int kh0 = (oc0 & 1) << 1;
    int gy0 = 2 * y - 1 + kh0, gx0 = 2 * x - 1;
#pragma unroll
    for (int e = 0; e < 8; ++e) {
      int gy = gy0 + (e >> 2), gx = gx0 + (e & 3);
      bool ok = (gy >= 0 && gy < Hi && gx >= 0 && gx < Wi);
      int gyc = min(max(gy, 0), Hi - 1), gxc = min(max(gx, 0), Wi - 1);
      off8[e] = b * Ci * HW + gyc * Wi + gxc;
      fm8[e] = ok ? 1.f : 0.f;
    }
  }
  auto gA = [&](int kb, float v[][8]) {
#pragma unroll
    for (int p = 0; p < MS; ++p) {
      int oc = oc0 + (p << 1);
      int k8 = kb + (oc << 3);
      if (k8 < K) {
        int base = (k8 >> 4) * HW;
#pragma unroll
        for (int e = 0; e < 8; ++e) v[p][e] = in[off8[e] + base] * fm8[e];
      } else {
#pragma unroll
        for (int e = 0; e < 8; ++e) v[p][e] = 0.f;
      }
    }
  };
  auto gB = [&](int kb, uint4* d) {
    int n = tid & 63, oc2 = tid >> 6;
    int k8 = kb + (oc2 << 3);
    if (k8 < K) {
      const u16* wp = wsp + (size_t)(n0 + n) * K + k8;
      d[0] = *reinterpret_cast<const uint4*>(wp);
      d[1] = *reinterpret_cast<const uint4*>(wp + PS);
      d[2] = *reinterpret_cast<const uint4*>(wp + 2 * PS);
    } else {
      d[0] = d[1] = d[2] = make_uint4(0u, 0u, 0u, 0u);
    }
  };

  float vA[MS][8], vA2[MS][8];
  uint4 vB[3], vB2[3];
  gA(kb0, vA); gB(kb0, vB);
  for (int kb = kb0; kb < kbN; kb += 32) {
    const bool more = (kb + 32) < kbN;
    if (more) { gA(kb + 32, vA2); gB(kb + 32, vB2); }
#pragma unroll
    for (int p = 0; p < MS; ++p)
      stWf<3, ST>(AL, cl, oc0 + (p << 1), vA[p]);
    {
      int n = tid & 63, oc2 = tid >> 6;
      stWp<ST>(BL, n, oc2, 0, vB[0]);
      stWp<ST>(BL, n, oc2, 1, vB[1]);
      stWp<ST>(BL, n, oc2, 2, vB[2]);
    }
    __syncthreads();
    short8v a_[MS][3];
#pragma unroll
    for (int mm = 0; mm < MS; ++mm)
#pragma unroll
      for (int s = 0; s < 3; ++s)
        a_[mm][s] = rdFrag<ST>(AL, (wv * MS + mm) * 16 + r, (s << 2) | g);
#pragma unroll
    for (int ns = 0; ns < 4; ++ns) {
      short8v b_[3];
#pragma unroll
      for (int s = 0; s < 3; ++s) b_[s] = rdFrag<ST>(BL, (ns << 4) + r, (s << 2) | g);
#pragma unroll
      for (int mm = 0; mm < MS; ++mm) {
        acc[mm][ns] = __builtin_amdgcn_mfma_f32_16x16x32_bf16(a_[mm][0], b_[0], acc[mm][ns], 0, 0, 0);
        acc[mm][ns] = __builtin_amdgcn_mfma_f32_16x16x32_bf16(a_[mm][0], b_[1], acc[mm][ns], 0, 0, 0);
        acc[mm][ns] = __builtin_amdgcn_mfma_f32_16x16x32_bf16(a_[mm][1], b_[0], acc[mm][ns], 0, 0, 0);
        acc[mm][ns] = __builtin_amdgcn_mfma_f32_16x16x32_bf16(a_[mm][1], b_[1], acc[mm][ns], 0, 0, 0);
        acc[mm][ns] = __builtin_amdgcn_mfma_f32_16x16x32_bf16(a_[mm][0], b_[2], acc[mm][ns], 0, 0, 0);
        acc[mm][ns] = __builtin_amdgcn_mfma_f32_16x16x32_bf16(a_[mm][2], b_[0], acc[mm][ns], 0, 0, 0);
      }
    }
    __syncthreads();
    if (more) {
#pragma unroll
      for (int p = 0; p < MS; ++p)
#pragma unroll
        for (int e = 0; e < 8; ++e) vA[p][e] = vA2[p][e];
#pragma unroll
      for (int s = 0; s < 3; ++s) vB[s] = vB2[s];
    }
  }
#pragma unroll
  for (int mm = 0; mm < MS; ++mm)
#pragma unroll
    for (int ns = 0; ns < 4; ++ns) {
      int c0 = m0 + (wv * MS + mm) * 16 + (g << 2);
      int co = n0 + (ns << 4) + r;
      if (OUTM == 0) {
        int x0 = c0 & (Wo - 1), y = (c0 >> lwo) & (Wo - 1), b = c0 >> (lwo + lwo);
        float bv = bias[co];
        float4 o;
        o.x = acc[mm][ns][0] + bv; o.y = acc[mm][ns][1] + bv;
        o.z = acc[mm][ns][2] + bv; o.w = acc[mm][ns][3] + bv;
        if (relu) { o.x = fmaxf(o.x, 0.f); o.y = fmaxf(o.y, 0.f);
                    o.z = fmaxf(o.z, 0.f); o.w = fmaxf(o.w, 0.f); }
        *reinterpret_cast<float4*>(&outp[(((size_t)b * Co + co) * Wo + y) * Wo + x0]) = o;
      } else {
        const int Mtot = 256 << (lwo + lwo);
        float4 o;
        o.x = acc[mm][ns][0]; o.y = acc[mm][ns][1];
        o.z = acc[mm][ns][2]; o.w = acc[mm][ns][3];
        *reinterpret_cast<float4*>(
            &outp[((size_t)blockIdx.z * Co + co) * Mtot + c0]) = o;
      }
    }
}

// ---------------- conv split-K combine: P[z][Co][M] -> NCHW + bias/relu -----
__global__ __launch_bounds__(TPB) void conv_combine(
    const float* __restrict__ P, const float* __restrict__ bias,
    float* __restrict__ out, int Mtot, int N, int SK, int lwo, int relu)
{
  int idx = blockIdx.x * TPB + threadIdx.x;
  int mq = Mtot >> 2;
  int co = idx / mq;
  int cell0 = (idx - co * mq) << 2;
  if (co >= N) return;
  float4 s = make_float4(0.f, 0.f, 0.f, 0.f);
  for (int z = 0; z < SK; ++z) {
    const float4 pv = *reinterpret_cast<const float4*>(
        &P[((size_t)z * N + co) * Mtot + cell0]);
    s.x += pv.x; s.y += pv.y; s.z += pv.z; s.w += pv.w;
  }
  float bv = bias[co];
  s.x += bv; s.y += bv; s.z += bv; s.w += bv;
  if (relu) { s.x = fmaxf(s.x, 0.f); s.y = fmaxf(s.y, 0.f);
              s.z = fmaxf(s.z, 0.f); s.w = fmaxf(s.w, 0.f); }
  int Wo = 1 << lwo;
  int x = cell0 & (Wo - 1), y = (cell0 >> lwo) & (Wo - 1), b = cell0 >> (lwo + lwo);
  *reinterpret_cast<float4*>(&out[(((size_t)b * N + co) * Wo + y) * Wo + x]) = s;
}

// ---------------- MFMA GEMM (BM=64, BN=64, 4 waves, split-K, prefetched) ----
template<int NS, int OUTM>
__global__ __launch_bounds__(TPB) void gemm_mf(
    const float* __restrict__ A, const float* __restrict__ W,
    const float* __restrict__ bias, void* __restrict__ outp,
    int M, int K, int N, int KSPL)
{
  constexpr int ST = (NS == 3) ? 64 : 32;
  __shared__ __align__(16) u32 L[(64 + 64) * ST];
  u32* AL = L; u32* BL = L + 64 * ST;
  const int tid = threadIdx.x;
  const int m0 = blockIdx.x << 6, n0 = blockIdx.y << 6;
  const int lane = tid & 63, wv = tid >> 6, r = lane & 15, g = lane >> 4;
  const int kb0 = blockIdx.z * KSPL;
  const int kbN = kb0 + KSPL;
  const int cl = tid & 63, oct = tid >> 6;
  f32x4 acc[4] = {};

  float vA[8], vB[8], vA2[8], vB2[8];
  auto gA = [&](int kt, float* v) {
    const float* ap = &A[(size_t)(m0 + cl) * K + kt + (oct << 3)];
    *reinterpret_cast<float4*>(&v[0]) = *reinterpret_cast<const float4*>(ap);
    *reinterpret_cast<float4*>(&v[4]) = *reinterpret_cast<const float4*>(ap + 4);
  };
  auto gB = [&](int kt, float* v) {
#pragma unroll
    for (int e = 0; e < 8; ++e)
      v[e] = W[(size_t)(kt + (oct << 3) + e) * N + n0 + cl];
  };

  gA(kb0, vA); gB(kb0, vB);
  for (int kt = kb0; kt < kbN; kt += 32) {
    const bool more = (kt + 32) < kbN;
    if (more) { gA(kt + 32, vA2); gB(kt + 32, vB2); }
    stWf<NS, ST>(AL, cl, oct, vA);
    stWf<NS, ST>(BL, cl, oct, vB);
    __syncthreads();
    short8v a_[3];
#pragma unroll
    for (int s = 0; s < NS; ++s) a_[s] = rdFrag<ST>(AL, (wv << 4) + r, (s << 2) | g);
#pragma unroll
    for (int ns = 0; ns < 4; ++ns) {
      short8v b_[3];
#pragma unroll
      for (int s = 0; s < NS; ++s) b_[s] = rdFrag<ST>(BL, (ns << 4) + r, (s << 2) | g);
      acc[ns] = __builtin_amdgcn_mfma_f32_16x16x32_bf16(a_[0], b_[0], acc[ns], 0, 0, 0);
      acc[ns] = __builtin_amdgcn_mfma_f32_16x16x32_bf16(a_[0], b_[1], acc[ns], 0, 0, 0);
      acc[ns] = __builtin_amdgcn_mfma_f32_16x16x32_bf16(a_[1], b_[0], acc[ns], 0, 0, 0);
      if (NS == 3) {
        acc[ns] = __builtin_amdgcn_mfma_f32_16x16x32_bf16(a_[1], b_[1], acc[ns], 0, 0, 0);
        acc[ns] = __builtin_amdgcn_mfma_f32_16x16x32_bf16(a_[0], b_[2], acc[ns], 0, 0, 0);
        acc[ns] = __builtin_amdgcn_mfma_f32_16x16x32_bf16(a_[2], b_[0], acc[ns], 0, 0, 0);
      }
    }
    __syncthreads();
    if (more) {
#pragma unroll
      for (int e = 0; e < 8; ++e) { vA[e] = vA2[e]; vB[e] = vB2[e]; }
    }
  }
#pragma unroll
  for (int ns = 0; ns < 4; ++ns)
#pragma unroll
    for (int q = 0; q < 4; ++q) {
      int m = m0 + (wv << 4) + (g << 2) + q;
      int n = n0 + (ns << 4) + r;
      float v = acc[ns][q];
      if (OUTM == 0) ((float*)outp)[((size_t)blockIdx.z * M + m) * N + n] = v;
      else           ((u32*)outp)[(size_t)m * N + n] = packhl(v + bias[n]);
    }
}

// ---------------- MFMA convT, NS=2, hoisted gather, quadrant in/out ---------
template<int BM, int EMIT, int SPLITIN>
__global__ __launch_bounds__(TPB) void convt_mf2(
    const u32* __restrict__ in, const u16* __restrict__ wth,
    const u16* __restrict__ wtl, const float* __restrict__ bias,
    u32* __restrict__ outq, int Ci, int Co, int Hi, int lwi, int relu)
{
  constexpr int ST = 32, MS = BM / 64;
  constexpr int STC = BM + 4;
  constexpr int LSZ = ((BM + 64) * ST > 64 * STC) ? (BM + 64) * ST : 64 * STC;
  __shared__ __align__(16) u32 L[LSZ];
  u32* AL = L; u32* BL = L + BM * ST;
  const int Wi = Hi, K4 = Ci << 2;
  const int HW = Hi * Wi, HWq = HW >> 2, Wiq = Wi >> 1;
  const int par = blockIdx.z, py = par >> 1, px = par & 1;
  const int tid = threadIdx.x;
  const int m0 = blockIdx.x * BM, n0 = blockIdx.y << 6;
  const int lane = tid & 63, wv = tid >> 6, r = lane & 15, g = lane >> 4;
  f32x4 acc[MS][4] = {};

  const int cl  = (BM == 128) ? (tid & 127) : (tid & 63);
  const int oc0 = (BM == 128) ? (tid >> 7) : (tid >> 6);
  int offT[4]; u32 mskT[4];
  {
    int cell = m0 + cl;
    int X = cell & (Wi - 1), Y = (cell >> lwi) & (Wi - 1), b = cell >> (lwi + lwi);
#pragma unroll
    for (int t = 0; t < 4; ++t) {
      int ay = t >> 1, ax = t & 1;
      int gy = Y + py - ay, gx = X + px - ax;
      bool ok = (gy >= 0 && gy < Hi && gx >= 0 && gx < Wi);
      int gyc = min(max(gy, 0), Hi - 1), gxc = min(max(gx, 0), Wi - 1);
      if (SPLITIN) {
        int q = ((gyc & 1) << 1) | (gxc & 1);
        offT[t] = q * (256 * Ci * HWq) + b * Ci * HWq + (gyc >> 1) * Wiq + (gxc >> 1);
      } else {
        offT[t] = b * Ci * HW + gyc * Wi + gxc;
      }
      mskT[t] = ok ? 0xffffffffu : 0u;
    }
  }
  const int stepCi = SPLITIN ? HWq : HW;

  auto gA = [&](int kb, u32 v[][8]) {
#pragma unroll
    for (int p = 0; p < MS; ++p) {
      int oc = oc0 + (p << 1);
      int cibase = ((kb >> 2) + (oc << 1)) * stepCi;
#pragma unroll
      for (int e = 0; e < 8; ++e) {
        int t = e & 3;
        v[p][e] = in[offT[t] + cibase + ((e >> 2) ? stepCi : 0)] & mskT[t];
      }
    }
  };
  auto gB = [&](int kb, uint4* d) {
    int n = tid & 63, oc2 = tid >> 6;
    size_t base = (size_t)(par * Co + n0 + n) * K4 + kb + (oc2 << 3);
    d[0] = *reinterpret_cast<const uint4*>(wth + base);
    d[1] = *reinterpret_cast<const uint4*>(wtl + base);
  };

  u32 vA[MS][8], vA2[MS][8];
  uint4 vB[2], vB2[2];
  gA(0, vA); gB(0, vB);
  for (int kb = 0; kb < K4; kb += 32) {
    const bool more = (kb + 32) < K4;
    if (more) { gA(kb + 32, vA2); gB(kb + 32, vB2); }
#pragma unroll
    for (int p = 0; p < MS; ++p) {
      const u32* v = vA[p];
      const int sw = cl & 7;
      int oc = oc0 + (p << 1);
      uint4 dh, dl;
      dh.x = (v[0] & 0xffffu) | (v[1] << 16);  dl.x = (v[0] >> 16) | (v[1] & 0xffff0000u);
      dh.y = (v[2] & 0xffffu) | (v[3] << 16);  dl.y = (v[2] >> 16) | (v[3] & 0xffff0000u);
      dh.z = (v[4] & 0xffffu) | (v[5] << 16);  dl.z = (v[4] >> 16) | (v[5] & 0xffff0000u);
      dh.w = (v[6] & 0xffffu) | (v[7] << 16);  dl.w = (v[6] >> 16) | (v[7] & 0xffff0000u);
      *reinterpret_cast<uint4*>(&AL[cl * ST + ((oc ^ sw) << 2)]) = dh;
      *reinterpret_cast<uint4*>(&AL[cl * ST + (((4 | oc) ^ sw) << 2)]) = dl;
    }
    {
      int n = tid & 63, oc2 = tid >> 6;
      stWp<ST>(BL, n, oc2, 0, vB[0]);
      stWp<ST>(BL, n, oc2, 1, vB[1]);
    }
    __syncthreads();
    short8v a_[MS][2];
#pragma unroll
    for (int mm = 0; mm < MS; ++mm)
#pragma unroll
      for (int s = 0; s < 2; ++s)
        a_[mm][s] = rdFrag<ST>(AL, (wv * MS + mm) * 16 + r, (s << 2) | g);
#pragma unroll
    for (int ns = 0; ns < 4; ++ns) {
      short8v b_[2];
#pragma unroll
      for (int s = 0; s < 2; ++s) b_[s] = rdFrag<ST>(BL, (ns << 4) + r, (s << 2) | g);
#pragma unroll
      for (int mm = 0; mm < MS; ++mm) {
        acc[mm][ns] = __builtin_amdgcn_mfma_f32_16x16x32_bf16(a_[mm][0], b_[0], acc[mm][ns], 0, 0, 0);
        acc[mm][ns] = __builtin_amdgcn_mfma_f32_16x16x32_bf16(a_[mm][0], b_[1], acc[mm][ns], 0, 0, 0);
        acc[mm][ns] = __builtin_amdgcn_mfma_f32_16x16x32_bf16(a_[mm][1], b_[0], acc[mm][ns], 0, 0, 0);
      }
    }
    __syncthreads();
    if (more) {
#pragma unroll
      for (int p = 0; p < MS; ++p)
#pragma unroll
        for (int e = 0; e < 8; ++e) vA[p][e] = vA2[p][e];
      vB[0] = vB2[0]; vB[1] = vB2[1];
    }
  }
#pragma unroll
  for (int mm = 0; mm < MS; ++mm)
#pragma unroll
    for (int ns = 0; ns < 4; ++ns)
#pragma unroll
      for (int q = 0; q < 4; ++q) {
        int cell = (wv * MS + mm) * 16 + (g << 2) + q;
        int col = (ns << 4) + r;
        float v = acc[mm][ns][q] + bias[n0 + col];
        if (relu) v = fmaxf(v, 0.f);
        L[col * STC + cell] = EMIT ? packhl(v) : __float_as_uint(v);
      }
  __syncthreads();
  const size_t QO = (size_t)256 * Co * HW;
  u32* op = outq + (size_t)par * QO;
  constexpr int C4N = BM / 4;
  constexpr int NCH = (BM * 64) / (TPB * 4);
#pragma unroll
  for (int it = 0; it < NCH; ++it) {
    int lin = it * TPB + tid;
    int c4 = lin & (C4N - 1);
    int col = lin / C4N;
    int cell0 = c4 << 2;
    uint4 d = *reinterpret_cast<const uint4*>(&L[col * STC + cell0]);
    int gc = m0 + cell0;
    int Xo = gc & (Wi - 1), Yo = (gc >> lwi) & (Wi - 1), bo = gc >> (lwi + lwi);
    *reinterpret_cast<uint4*>(
        &op[((size_t)(bo * Co + n0 + col) * Hi + Yo) * Wi + Xo]) = d;
  }
}

// ---------------- fc split-K combine ----------------------------------------
__global__ __launch_bounds__(TPB) void combine_k(
    const float* __restrict__ P, const float* __restrict__ bias,
    float* __restrict__ out, int MN, int N, int SK, int relu)
{
  int i4 = (blockIdx.x * TPB + threadIdx.x) << 2;
  if (i4 >= MN) return;
  float4 s = make_float4(0.f, 0.f, 0.f, 0.f);
  for (int z = 0; z < SK; ++z) {
    const float4 pv = *reinterpret_cast<const float4*>(&P[(size_t)z * MN + i4]);
    s.x += pv.x; s.y += pv.y; s.z += pv.z; s.w += pv.w;
  }
  int n = i4 % N;
  s.x += bias[n]; s.y += bias[n + 1]; s.z += bias[n + 2]; s.w += bias[n + 3];
  if (relu) { s.x = fmaxf(s.x, 0.f); s.y = fmaxf(s.y, 0.f);
              s.z = fmaxf(s.z, 0.f); s.w = fmaxf(s.w, 0.f); }
  *reinterpret_cast<float4*>(&out[i4]) = s;
}

// ---------------- fp32 FC GEMM (g0, g1 only) --------------------------------
__global__ __launch_bounds__(TPB) void gemm_ig2(
    const float* __restrict__ A, const float* __restrict__ W,
    const float* __restrict__ bias, float* __restrict__ C,
    int M, int K, int N, int relu)
{
  constexpr int BM = 64, BN = 32, BK = 32;
  __shared__ __align__(16) float As[BK][BM + 4];
  __shared__ __align__(16) float Ws[BK][BN + 4];
  const int tid = threadIdx.x;
  const int m0 = blockIdx.x * BM;
  const int n0 = blockIdx.y * BN;
  const int tn = tid & 15;
  const int tm = tid >> 4;
  float acc[4][2] = {{0.f,0.f},{0.f,0.f},{0.f,0.f},{0.f,0.f}};

  for (int kt = 0; kt < K; kt += BK) {
#pragma unroll
    for (int f = 0; f < 2; ++f) {
      int idx = f * TPB + tid;
      int kq = idx & 7;
      int m = idx >> 3;
      const float4 av = *reinterpret_cast<const float4*>(
          &A[(size_t)(m0 + m) * K + kt + 4 * kq]);
      As[4 * kq + 0][m] = av.x;
      As[4 * kq + 1][m] = av.y;
      As[4 * kq + 2][m] = av.z;
      As[4 * kq + 3][m] = av.w;
    }
#pragma unroll
    for (int i = 0; i < 4; ++i) {
      int lin = i * TPB + tid;
      int n = lin & 31;
      int kk = lin >> 5;
      Ws[kk][n] = W[(size_t)(kt + kk) * N + n0 + n];
    }
    __syncthreads();
#pragma unroll
    for (int k = 0; k < BK; ++k) {
      const float4 av = *reinterpret_cast<const float4*>(&As[k][4 * tm]);
      const float2 wv = *reinterpret_cast<const float2*>(&Ws[k][2 * tn]);
      acc[0][0] = fmaf(av.x, wv.x, acc[0][0]);
      acc[0][1] = fmaf(av.x, wv.y, acc[0][1]);
      acc[1][0] = fmaf(av.y, wv.x, acc[1][0]);
      acc[1][1] = fmaf(av.y, wv.y, acc[1][1]);
      acc[2][0] = fmaf(av.z, wv.x, acc[2][0]);
      acc[2][1] = fmaf(av.z, wv.y, acc[2][1]);
      acc[3][0] = fmaf(av.w, wv.x, acc[3][0]);
      acc[3][1] = fmaf(av.w, wv.y, acc[3][1]);
    }
    __syncthreads();
  }
  const float b0 = bias[n0 + 2 * tn];
  const float b1 = bias[n0 + 2 * tn + 1];
#pragma unroll
  for (int mi = 0; mi < 4; ++mi) {
    int m = m0 + 4 * tm + mi;
    float2 v = make_float2(acc[mi][0] + b0, acc[mi][1] + b1);
    if (relu) { v.x = fmaxf(v.x, 0.f); v.y = fmaxf(v.y, 0.f); }
    *reinterpret_cast<float2*>(&C[(size_t)m * N + n0 + 2 * tn]) = v;
  }
}

// ---------------- dedicated t3: convT 64->3, fp32, quadrant input -----------
// ci-split: blockIdx.y = z (0/1), each handles 32 ci, writes partial (no bias).
__global__ __launch_bounds__(TPB) void convt3_kernel(
    const float* __restrict__ inq, const float* __restrict__ w,
    float* __restrict__ part)
{
  __shared__ float wl[3072];
  __shared__ float il[8][33 * 32];
  const int b = blockIdx.x;
  const int z = blockIdx.y;
  const int tid = threadIdx.x;
  for (int i = tid; i < 3072; i += TPB) wl[i] = w[i];
  const int Y = tid >> 3;
  const int X0 = (tid & 7) << 2;
  float acc[3][2][8];
#pragma unroll
  for (int o = 0; o < 3; ++o)
#pragma unroll
    for (int p = 0; p < 2; ++p)
#pragma unroll
      for (int q = 0; q < 8; ++q) acc[o][p][q] = 0.f;

  const int cbeg = z << 5, cend = cbeg + 32;
  for (int c0 = cbeg; c0 < cend; c0 += 8) {
    __syncthreads();
    for (int i = tid; i < 8192; i += TPB) {
      int cc = i >> 10, yy = (i >> 5) & 31, xx = i & 31;
      int q = ((yy & 1) << 1) | (xx & 1);
      il[cc][yy * 33 + xx] = inq[(size_t)q * 4194304 +
          (((size_t)b * 64 + c0 + cc) * 16 + (yy >> 1)) * 16 + (xx >> 1)];
    }
    __syncthreads();
    for (int cc = 0; cc < 8; ++cc) {
      float iv[3][6];
#pragma unroll
      for (int j = 0; j < 3; ++j) {
        int gy = Y - 1 + j;
        int gyc = min(max(gy, 0), 31);
        float my = (gy >= 0 && gy < 32) ? 1.f : 0.f;
#pragma unroll
        for (int k = 0; k < 6; ++k) {
          int gx = X0 - 1 + k;
          int gxc = min(max(gx, 0), 31);
          float mx = (gx >= 0 && gx < 32) ? 1.f : 0.f;
          iv[j][k] = il[cc][gyc * 33 + gxc] * (my * mx);
        }
      }
      const float* wq = &wl[(c0 + cc) * 48];
#pragma unroll
      for (int o = 0; o < 3; ++o) {
        const float* wo = wq + o * 16;
#pragma unroll
        for (int c = 0; c < 4; ++c) {
          acc[o][0][2*c]   = fmaf(iv[1][c+1], wo[5],  acc[o][0][2*c]);
          acc[o][0][2*c]   = fmaf(iv[1][c],   wo[7],  acc[o][0][2*c]);
          acc[o][0][2*c]   = fmaf(iv[0][c+1], wo[13], acc[o][0][2*c]);
          acc[o][0][2*c]   = fmaf(iv[0][c],   wo[15], acc[o][0][2*c]);
          acc[o][0][2*c+1] = fmaf(iv[1][c+2], wo[4],  acc[o][0][2*c+1]);
          acc[o][0][2*c+1] = fmaf(iv[1][c+1], wo[6],  acc[o][0][2*c+1]);
          acc[o][0][2*c+1] = fmaf(iv[0][c+2], wo[12], acc[o][0][2*c+1]);
          acc[o][0][2*c+1] = fmaf(iv[0][c+1], wo[14], acc[o][0][2*c+1]);
          acc[o][1][2*c]   = fmaf(iv[2][c+1], wo[1],  acc[o][1][2*c]);
          acc[o][1][2*c]   = fmaf(iv[2][c],   wo[3],  acc[o][1][2*c]);
          acc[o][1][2*c]   = fmaf(iv[1][c+1], wo[9],  acc[o][1][2*c]);
          acc[o][1][2*c]   = fmaf(iv[1][c],   wo[11], acc[o][1][2*c]);
          acc[o][1][2*c+1] = fmaf(iv[2][c+2], wo[0],  acc[o][1][2*c+1]);
          acc[o][1][2*c+1] = fmaf(iv[2][c+1], wo[2],  acc[o][1][2*c+1]);
          acc[o][1][2*c+1] = fmaf(iv[1][c+2], wo[8],  acc[o][1][2*c+1]);
          acc[o][1][2*c+1] = fmaf(iv[1][c+1], wo[10], acc[o][1][2*c+1]);
        }
      }
    }
  }
  float* pz = part + (size_t)z * 3145728;
#pragma unroll
  for (int o = 0; o < 3; ++o) {
#pragma unroll
    for (int p = 0; p < 2; ++p) {
      float* op = pz + (((size_t)b * 3 + o) * 64 + 2 * Y + p) * 64 + 2 * X0;
      *reinterpret_cast<float4*>(op) =
          make_float4(acc[o][p][0], acc[o][p][1], acc[o][p][2], acc[o][p][3]);
      *reinterpret_cast<float4*>(op + 4) =
          make_float4(acc[o][p][4], acc[o][p][5], acc[o][p][6], acc[o][p][7]);
    }
  }
}

__global__ __launch_bounds__(TPB) void c3_combine(
    const float* __restrict__ part, const float* __restrict__ bias,
    float* __restrict__ out)
{
  int i4 = (blockIdx.x * TPB + threadIdx.x) << 2;
  const float4 p0 = *reinterpret_cast<const float4*>(&part[i4]);
  const float4 p1 = *reinterpret_cast<const float4*>(&part[i4 + 3145728]);
  int o = (i4 >> 12) % 3;
  float bv = bias[o];
  float4 s = make_float4(p0.x + p1.x + bv, p0.y + p1.y + bv,
                         p0.z + p1.z + bv, p0.w + p1.w + bv);
  *reinterpret_cast<float4*>(&out[i4]) = s;
}

// ---------------- VQ ---------------------------------------------------------
__global__ __launch_bounds__(TPB) void vq_kernel(
    const float* __restrict__ z, const float* __restrict__ cb,
    float* __restrict__ e, float* __restrict__ rowloss)
{
  const int row = blockIdx.x;
  const int b = row >> 4, s = row & 15;
  __shared__ float zr[64];
  __shared__ float bval[TPB];
  __shared__ int   bidx[TPB];
  const int tid = threadIdx.x;
  if (tid < 64) zr[tid] = z[(size_t)b * 1536 + s * 64 + tid];
  __syncthreads();

  float best = 3.4e38f;
  int bi = 0;
#pragma unroll
  for (int rep = 0; rep < 2; ++rep) {
    int j = tid + rep * TPB;
    const float4* c4 = reinterpret_cast<const float4*>(cb + (size_t)j * 64);
    float d = 0.f;
#pragma unroll
    for (int k = 0; k < 16; ++k) {
      float4 cv = c4[k];
      float t0 = zr[4 * k + 0] - cv.x;
      float t1 = zr[4 * k + 1] - cv.y;
      float t2 = zr[4 * k + 2] - cv.z;
      float t3 = zr[4 * k + 3] - cv.w;
      d = fmaf(t0, t0, d); d = fmaf(t1, t1, d);
      d = fmaf(t2, t2, d); d = fmaf(t3, t3, d);
    }
    if (d < best) { best = d; bi = j; }
  }
  bval[tid] = best; bidx[tid] = bi;
  __syncthreads();
  for (int sft = 128; sft > 0; sft >>= 1) {
    if (tid < sft) {
      float v2 = bval[tid + sft]; int i2 = bidx[tid + sft];
      if (v2 < bval[tid] || (v2 == bval[tid] && i2 < bidx[tid])) {
        bval[tid] = v2; bidx[tid] = i2;
      }
    }
    __syncthreads();
  }
  const int bj = bidx[0];
  if (tid < 64)
    e[(size_t)b * 1536 + s * 64 + tid] = cb[(size_t)bj * 64 + tid];
  if (tid == 0) rowloss[row] = bval[0];
}

__global__ __launch_bounds__(TPB) void zs_copy_kernel(
    const float* __restrict__ z, float* __restrict__ e)
{
  int i = blockIdx.x * TPB + threadIdx.x;
  int b = i >> 9, k = i & 511;
  e[(size_t)b * 1536 + 1024 + k] = z[(size_t)b * 1536 + 1024 + k];
}

__global__ __launch_bounds__(TPB) void loss_reduce_kernel(
    const float* __restrict__ rl, float* __restrict__ out)
{
  __shared__ float sm[TPB];
  float s = 0.f;
  for (int i = threadIdx.x; i < 4096; i += TPB) s += rl[i];
  sm[threadIdx.x] = s;
  __syncthreads();
  for (int sft = 128; sft > 0; sft >>= 1) {
    if (threadIdx.x < sft) sm[threadIdx.x] += sm[threadIdx.x + sft];
    __syncthreads();
  }
  if (threadIdx.x == 0) out[0] = sm[0] * (1.25f / 262144.f);
}

// ============================================================================
extern "C" void kernel_launch(void* const* d_in, const int* in_sizes, int n_in,
                              void* d_out, int out_size, void* d_ws, size_t ws_size,
                              hipStream_t stream)
{
  const float* x    = (const float*)d_in[0];
  const float* ew0  = (const float*)d_in[1];
  const float* eb0  = (const float*)d_in[2];
  const float* ew1  = (const float*)d_in[3];
  const float* eb1  = (const float*)d_in[4];
  const float* ew2  = (const float*)d_in[5];
  const float* eb2  = (const float*)d_in[6];
  const float* ew3  = (const float*)d_in[7];
  const float* eb3  = (const float*)d_in[8];
  const float* fw0  = (const float*)d_in[9];
  const float* fb0  = (const float*)d_in[10];
  const float* fw1  = (const float*)d_in[11];
  const float* fb1  = (const float*)d_in[12];
  const float* fw2  = (const float*)d_in[13];
  const float* fb2  = (const float*)d_in[14];
  const float* cb   = (const float*)d_in[15];
  const float* gw0  = (const float*)d_in[16];
  const float* gb0  = (const float*)d_in[17];
  const float* gw1  = (const float*)d_in[18];
  const float* gb1  = (const float*)d_in[19];
  const float* gw2  = (const float*)d_in[20];
  const float* gb2  = (const float*)d_in[21];
  const float* tw0  = (const float*)d_in[22];
  const float* tb0  = (const float*)d_in[23];
  const float* tw1  = (const float*)d_in[24];
  const float* tb1  = (const float*)d_in[25];
  const float* tw2  = (const float*)d_in[26];
  const float* tb2  = (const float*)d_in[27];
  const float* tw3  = (const float*)d_in[28];
  const float* tb3  = (const float*)d_in[29];

  float* out = (float*)d_out;
  float* ws  = (float*)d_ws;

  float* H0   = ws + 0;
  float* H1   = ws + 16777216;
  float* H2   = ws + 0;
  float* H3   = ws + 16777216;
  float* PC   = ws + 2097152;
  float* F0   = ws + 0;
  float* F1   = ws + 262144;
  float* Z    = ws + 524288;
  float* E    = ws + 917504;
  float* G0   = ws + 1310720;
  float* G1   = ws + 1441792;
  u32*   G2p  = (u32*)(ws + 1703936);
  u32*   T0s  = (u32*)(ws + 2752512);
  u32*   T1s  = (u32*)(ws + 4849664);
  float* T2s  = ws + 9043968;
  float* PT3  = ws + 0;            // convt3 ci-split partials (6.29M floats)
  u16*   WE0  = (u16*)(ws + 20971520);
  u16*   WE1  = (u16*)(ws + 20976128);
  u16*   WE2  = (u16*)(ws + 21074432);
  u16*   WE3  = (u16*)(ws + 21271040);
  u16*   WT0h = (u16*)(ws + 25821184);
  u16*   WT0l = (u16*)(ws + 26083328);
  u16*   WT1h = (u16*)(ws + 26345472);
  u16*   WT1l = (u16*)(ws + 26411008);
  u16*   WT2h = (u16*)(ws + 26476544);
  u16*   WT2l = (u16*)(ws + 26509312);
  float* P    = ws + 26542080;
  float* RL   = ws + 28639232;

  // ---- weight prep ----
  wsplit3_k<<<dim3(12),  TPB, 0, stream>>>(ew0, WE0, 3072);
  wsplit3_k<<<dim3(256), TPB, 0, stream>>>(ew1, WE1, 65536);
  wsplit3_k<<<dim3(512), TPB, 0, stream>>>(ew2, WE2, 131072);
  wsplit3_k<<<dim3(1024),TPB, 0, stream>>>(ew3, WE3, 524288);
  wprep2_k<<<dim3(512), TPB, 0, stream>>>(tw0, WT0h, WT0l, 256, 128);
  wprep2_k<<<dim3(128), TPB, 0, stream>>>(tw1, WT1h, WT1l, 128, 64);
  wprep2_k<<<dim3(64),  TPB, 0, stream>>>(tw2, WT2h, WT2l, 64, 64);

  // ---- encoder convs (MFMA NS=3; conv2/3 split-K) ----
  conv_mf3<128,0><<<dim3(2048, 1, 1), TPB, 0, stream>>>(x,  WE0, eb0, H0, 3,  64,  64, 5, 1, 48,   3072);
  conv_mf3<128,0><<<dim3(512, 1, 1),  TPB, 0, stream>>>(H0, WE1, eb1, H1, 64, 64,  32, 4, 1, 1024, 65536);
  conv_mf3<128,1><<<dim3(128, 2, 4),  TPB, 0, stream>>>(H1, WE2, eb2, PC, 64, 128, 16, 3, 1, 256,  131072);
  conv_combine<<<dim3(2048), TPB, 0, stream>>>(PC, eb2, H2, 16384, 128, 4, 3, 1);
  conv_mf3<64,1><<<dim3(64, 4, 4),    TPB, 0, stream>>>(H2, WE3, eb3, PC, 128, 256, 8, 2, 0, 512,  524288);
  conv_combine<<<dim3(1024), TPB, 0, stream>>>(PC, eb3, H3, 4096, 256, 4, 2, 0);

  // ---- encoder FC (MFMA NS=3, split-K + combine) ----
  gemm_mf<3,0><<<dim3(4, 16, 8), TPB, 0, stream>>>(H3, fw0, fb0, (void*)P, 256, 4096, 1024, 512);
  combine_k<<<dim3(256), TPB, 0, stream>>>(P, fb0, F0, 262144, 1024, 8, 1);
  gemm_mf<3,0><<<dim3(4, 16, 4), TPB, 0, stream>>>(F0, fw1, fb1, (void*)P, 256, 1024, 1024, 256);
  combine_k<<<dim3(256), TPB, 0, stream>>>(P, fb1, F1, 262144, 1024, 4, 1);
  gemm_mf<3,0><<<dim3(4, 24, 4), TPB, 0, stream>>>(F1, fw2, fb2, (void*)P, 256, 1024, 1536, 256);
  combine_k<<<dim3(384), TPB, 0, stream>>>(P, fb2, Z, 393216, 1536, 4, 0);

  // ---- VQ ----
  vq_kernel<<<dim3(4096), TPB, 0, stream>>>(Z, cb, E, RL);
  zs_copy_kernel<<<dim3(512), TPB, 0, stream>>>(Z, E);
  loss_reduce_kernel<<<dim3(1), TPB, 0, stream>>>(RL, out + (size_t)out_size - 1);

  // ---- decoder FC ----
  gemm_ig2<<<dim3(4, 16), TPB, 0, stream>>>(E,  gw0, gb0, G0, 256, 1536, 512,  1);
  gemm_ig2<<<dim3(4, 32), TPB, 0, stream>>>(G0, gw1, gb1, G1, 256, 512,  1024, 1);
  gemm_mf<2,1><<<dim3(4, 64, 1), TPB, 0, stream>>>(G1, gw2, gb2, (void*)G2p, 256, 1024, 4096, 1024);

  // ---- decoder transposed convs (MFMA NS=2, quadrant layouts) ----
  convt_mf2<64,1,0><<<dim3(64, 2, 4),   TPB, 0, stream>>>(G2p, WT0h, WT0l, tb0, T0s, 256, 128, 4,  2, 1);
  convt_mf2<128,1,1><<<dim3(128, 1, 4), TPB, 0, stream>>>(T0s, WT1h, WT1l, tb1, T1s, 128, 64,  8,  3, 1);
  convt_mf2<128,0,1><<<dim3(512, 1, 4), TPB, 0, stream>>>(T1s, WT2h, WT2l, tb2, (u32*)T2s, 64, 64, 16, 4, 1);
  convt3_kernel<<<dim3(256, 2), TPB, 0, stream>>>(T2s, tw3, PT3);
  c3_combine<<<dim3(3072), TPB, 0, stream>>>(PT3, tb3, out);
}

// Round 9
// 616.177 us; speedup vs baseline: 12.6543x; 1.1084x over previous
//
#include <hip/hip_runtime.h>
#include <hip/hip_bf16.h>

// ============================================================================
// VQ-VAE forward, round 9: "A-direct" conv engine.
//  - A operand: per-lane direct global gather (each fragment has exactly one
//    consumer), in-register split3 -> zero LDS traffic / barriers for A.
//  - B operand: prepped u16 planes staged in double-buffered LDS (16KBx2),
//    ONE barrier per k-tile. rm=4 per wave (BM=256): LDS:MFMA ratio 1.25.
//  - All conv inputs zero-PADDED (no masks, 1 hoisted base reg per sub-tile):
//    xp[b][3][66][66], H0p[b][64][34][34], H1p co-major [64][256][18][18],
//    H2p[b][128][10][10]. Borders zeroed by x_pad/zb0/combines.
//  - Split-K: conv1 z2, conv2 z4, conv3 z8, fc0 z16, fc1/2 z8, g2 z2(+pack).
//  - Decoder convT/convt3/VQ kernels unchanged from R8 (offsets only).
// Workspace re-plan (float offsets), all regions time-disjoint, peak < 28.64M.
// No atomics; deterministic; graph-safe.
// ============================================================================

#define TPB 256
typedef __attribute__((ext_vector_type(8))) short short8v;
typedef __attribute__((ext_vector_type(4))) float f32x4;
typedef unsigned int u32;
typedef unsigned short u16;

__device__ inline u16 f2bf(float x){
  union { __hip_bfloat16 b; u16 u; } cv;
  cv.b = __float2bfloat16(x);
  return cv.u;
}
__device__ inline float bf2f(u16 h){ union{u32 u;float f;}v; v.u=((u32)h)<<16; return v.f;}
__device__ inline u32 packhl(float x){ u16 h=f2bf(x); u16 l=f2bf(x-bf2f(h)); return ((u32)l<<16)|(u32)h;}

template<int NS>
__device__ inline void splitN(float x, u16 t[3]) {
  u16 h0 = f2bf(x); t[0] = h0;
  float r1 = x - bf2f(h0);
  u16 h1 = f2bf(r1); t[1] = h1;
  if (NS == 3) { float r2 = r1 - bf2f(h1); t[2] = f2bf(r2); }
}

template<int NS, int ST>
__device__ inline void stW(u32* L, int row, int oct, const u16 hs[3][8]) {
  constexpr int SWM = (ST == 64) ? 15 : 7;
  const int sw = row & SWM;
#pragma unroll
  for (int s = 0; s < NS; ++s) {
    uint4 d;
    d.x = (u32)hs[s][0] | ((u32)hs[s][1] << 16);
    d.y = (u32)hs[s][2] | ((u32)hs[s][3] << 16);
    d.z = (u32)hs[s][4] | ((u32)hs[s][5] << 16);
    d.w = (u32)hs[s][6] | ((u32)hs[s][7] << 16);
    int ch = (((s << 2) | oct) ^ sw) << 2;
    *reinterpret_cast<uint4*>(&L[row * ST + ch]) = d;
  }
}

template<int NS, int ST>
__device__ inline void stWf(u32* L, int row, int oct, const float v[8]) {
  u16 hs[3][8];
#pragma unroll
  for (int e = 0; e < 8; ++e) {
    u16 t3[3]; splitN<NS>(v[e], t3);
    hs[0][e] = t3[0]; hs[1][e] = t3[1]; if (NS == 3) hs[2][e] = t3[2];
  }
  stW<NS, ST>(L, row, oct, hs);
}

template<int ST>
__device__ inline void stWp(u32* L, int row, int oct, int s, uint4 d) {
  constexpr int SWM = (ST == 64) ? 15 : 7;
  int ch = (((s << 2) | oct) ^ (row & SWM)) << 2;
  *reinterpret_cast<uint4*>(&L[row * ST + ch]) = d;
}

template<int ST>
__device__ inline short8v rdFrag(const u32* L, int row, int c) {
  constexpr int SWM = (ST == 64) ? 15 : 7;
  int ph = (c ^ (row & SWM)) << 2;
  return *reinterpret_cast<const short8v*>(&L[row * ST + ph]);
}

// ---------------- weight prep -----------------------------------------------
__global__ __launch_bounds__(TPB) void wsplit3_k(
    const float* __restrict__ src, u16* __restrict__ dst, int n)
{
  for (int i = blockIdx.x * TPB + threadIdx.x; i < n; i += gridDim.x * TPB) {
    u16 t3[3]; splitN<3>(src[i], t3);
    dst[i] = t3[0]; dst[i + n] = t3[1]; dst[i + 2 * n] = t3[2];
  }
}
__global__ __launch_bounds__(TPB) void wprep2_k(
    const float* __restrict__ src, u16* __restrict__ dh, u16* __restrict__ dl,
    int Ci, int Co)
{
  int K4 = Ci << 2;
  int tot = 4 * Co * K4;
  for (int i = blockIdx.x * TPB + threadIdx.x; i < tot; i += gridDim.x * TPB) {
    int par = i / (Co * K4); int rem = i - par * (Co * K4);
    int co = rem / K4; int k4 = rem - co * K4;
    int ci = k4 >> 2, ay = (k4 >> 1) & 1, ax = k4 & 1;
    int py = par >> 1, px = par & 1;
    int widx = ((1 - py) << 2) + (1 - px) + (ay << 3) + (ax << 1);
    float x = src[(((size_t)ci * Co + co) << 4) + widx];
    u16 h = f2bf(x);
    dh[i] = h; dl[i] = f2bf(x - bf2f(h));
  }
}

// ---------------- input pad / border-zero ------------------------------------
__global__ __launch_bounds__(TPB) void x_pad_k(
    const float* __restrict__ x, float* __restrict__ xp)
{
  int idx = blockIdx.x * TPB + threadIdx.x;     // 256*3*4356 = 3,345,408
  if (idx >= 3345408) return;
  int px = idx % 66; int t = idx / 66; int py = t % 66; int p = t / 66;
  float v = 0.f;
  if (py >= 1 && py <= 64 && px >= 1 && px <= 64)
    v = x[(size_t)p * 4096 + (py - 1) * 64 + (px - 1)];
  xp[idx] = v;
}
__global__ __launch_bounds__(TPB) void zb0_k(float* __restrict__ h0p)
{
  int idx = blockIdx.x * TPB + threadIdx.x;     // 16384*132 = 2,162,688
  if (idx >= 2162688) return;
  int p = idx / 132, k = idx % 132;
  int py, px;
  if (k < 34)       { py = 0;           px = k; }
  else if (k < 68)  { py = 33;          px = k - 34; }
  else if (k < 100) { py = k - 68 + 1;  px = 0; }
  else              { py = k - 100 + 1; px = 33; }
  h0p[(size_t)p * 1156 + py * 34 + px] = 0.f;
}

// ---------------- A-direct MFMA conv (s2,k4,p1), NS=3 ------------------------
// OUTM 0: padded-NCHW out (+bias/relu, scalar stores). OUTM 1: partial
// [z][Co][Mtot] (float4). Input is zero-PADDED: addr = b*bS + ci*ciS
// + (2y+kh)*PW + (2x+kw); no masks. B via prepped u16 planes -> dbuf LDS.
template<int RM, int OUTM>
__global__ __launch_bounds__(TPB, 2) void conv_ad(
    const float* __restrict__ in, const u16* __restrict__ wsp,
    const float* __restrict__ bias, float* __restrict__ outp,
    int Ci, int Co, int Wi, int lwo, int relu, int KSPL, int PS,
    int bS, int ciS, int Mtot)
{
  constexpr int BM = RM * 64;
  __shared__ __align__(16) u32 BL[2][64 * 64];
  const int K = Ci << 4;
  const int PW = Wi + 2;
  const int Wo = Wi >> 1;
  const int tid = threadIdx.x;
  const int m0 = blockIdx.x * BM, n0 = blockIdx.y << 6;
  const int lane = tid & 63, wv = tid >> 6, r = lane & 15, g = lane >> 4;
  const int kb0 = blockIdx.z * KSPL;
  const int kbN = min(kb0 + KSPL, K);
  const int khsel = g & 1;
  const int cig = g >> 1;
  f32x4 acc[RM][4] = {};

  int base[RM];
#pragma unroll
  for (int mm = 0; mm < RM; ++mm) {
    int cell = m0 + (wv * RM + mm) * 16 + r;
    int x = cell & (Wo - 1), y = (cell >> lwo) & (Wo - 1), b = cell >> (lwo + lwo);
    base[mm] = b * bS + (2 * y + 2 * khsel) * PW + 2 * x;
  }

  auto gA = [&](int kb, float v[RM][8]) {
    if ((kb + (g << 3)) < K) {
      int cioff = ((kb >> 4) + cig) * ciS;
#pragma unroll
      for (int mm = 0; mm < RM; ++mm) {
        const float* p = in + base[mm] + cioff;
#pragma unroll
        for (int e = 0; e < 8; ++e)
          v[mm][e] = p[(e >> 2) * PW + (e & 3)];
      }
    } else {
#pragma unroll
      for (int mm = 0; mm < RM; ++mm)
#pragma unroll
        for (int e = 0; e < 8; ++e) v[mm][e] = 0.f;
    }
  };
  auto gB = [&](int kb, uint4* d) {
    int n = tid & 63, oc2 = tid >> 6;
    int k8 = kb + (oc2 << 3);
    if (k8 < K) {
      const u16* wp = wsp + (size_t)(n0 + n) * K + k8;
      d[0] = *reinterpret_cast<const uint4*>(wp);
      d[1] = *reinterpret_cast<const uint4*>(wp + PS);
      d[2] = *reinterpret_cast<const uint4*>(wp + 2 * PS);
    } else {
      d[0] = d[1] = d[2] = make_uint4(0u, 0u, 0u, 0u);
    }
  };
  auto mkfrags = [&](const float v[8], short8v f[3]) {
    u16 hs[3][8];
#pragma unroll
    for (int e = 0; e < 8; ++e) {
      u16 t3[3]; splitN<3>(v[e], t3);
      hs[0][e] = t3[0]; hs[1][e] = t3[1]; hs[2][e] = t3[2];
    }
#pragma unroll
    for (int s = 0; s < 3; ++s) {
      union { u16 u[8]; short8v sv; } cv;
#pragma unroll
      for (int e = 0; e < 8; ++e) cv.u[e] = hs[s][e];
      f[s] = cv.sv;
    }
  };

  float vA[RM][8], vA2[RM][8];
  uint4 vB[3], vB2[3];
  gA(kb0, vA); gB(kb0, vB);
  for (int kb = kb0; kb < kbN; kb += 32) {
    u32* BLc = BL[((kb - kb0) >> 5) & 1];
    {
      int n = tid & 63, oc2 = tid >> 6;
      stWp<64>(BLc, n, oc2, 0, vB[0]);
      stWp<64>(BLc, n, oc2, 1, vB[1]);
      stWp<64>(BLc, n, oc2, 2, vB[2]);
    }
    const bool more = (kb + 32) < kbN;
    if (more) { gB(kb + 32, vB2); gA(kb + 32, vA2); }
    short8v a_[RM][3];
#pragma unroll
    for (int mm = 0; mm < RM; ++mm) mkfrags(vA[mm], a_[mm]);
    __syncthreads();
#pragma unroll
    for (int ns = 0; ns < 4; ++ns) {
      short8v b_[3];
#pragma unroll
      for (int s = 0; s < 3; ++s) b_[s] = rdFrag<64>(BLc, (ns << 4) + r, (s << 2) | g);
#pragma unroll
      for (int mm = 0; mm < RM; ++mm) {
        acc[mm][ns] = __builtin_amdgcn_mfma_f32_16x16x32_bf16(a_[mm][0], b_[0], acc[mm][ns], 0, 0, 0);
        acc[mm][ns] = __builtin_amdgcn_mfma_f32_16x16x32_bf16(a_[mm][0], b_[1], acc[mm][ns], 0, 0, 0);
        acc[mm][ns] = __builtin_amdgcn_mfma_f32_16x16x32_bf16(a_[mm][1], b_[0], acc[mm][ns], 0, 0, 0);
        acc[mm][ns] = __builtin_amdgcn_mfma_f32_16x16x32_bf16(a_[mm][1], b_[1], acc[mm][ns], 0, 0, 0);
        acc[mm][ns] = __builtin_amdgcn_mfma_f32_16x16x32_bf16(a_[mm][0], b_[2], acc[mm][ns], 0, 0, 0);
        acc[mm][ns] = __builtin_amdgcn_mfma_f32_16x16x32_bf16(a_[mm][2], b_[0], acc[mm][ns], 0, 0, 0);
      }
    }
    if (more) {
#pragma unroll
      for (int mm = 0; mm < RM; ++mm)
#pragma unroll
        for (int e = 0; e < 8; ++e) vA[mm][e] = vA2[mm][e];
#pragma unroll
      for (int s = 0; s < 3; ++s) vB[s] = vB2[s];
    }
  }
#pragma unroll
  for (int mm = 0; mm < RM; ++mm)
#pragma unroll
    for (int ns = 0; ns < 4; ++ns) {
      int c0 = m0 + (wv * RM + mm) * 16 + (g << 2);
      int co = n0 + (ns << 4) + r;
      if (OUTM == 0) {
        float bv = bias[co];
        const int PHW = PW * PW;   // padded plane (Wo+2 == PW/... note: Wo=Wi/2, out pad dims (Wo+2)
        const int OPW = Wo + 2;
        const int OPHW = OPW * OPW;
#pragma unroll
        for (int q = 0; q < 4; ++q) {
          int cell = c0 + q;
          int x = cell & (Wo - 1), y = (cell >> lwo) & (Wo - 1), b = cell >> (lwo + lwo);
          float v = acc[mm][ns][q] + bv;
          if (relu) v = fmaxf(v, 0.f);
          outp[((size_t)(b * Co + co)) * OPHW + (y + 1) * OPW + (x + 1)] = v;
        }
        (void)PHW;
      } else {
        float4 o;
        o.x = acc[mm][ns][0]; o.y = acc[mm][ns][1];
        o.z = acc[mm][ns][2]; o.w = acc[mm][ns][3];
        *reinterpret_cast<float4*>(
            &outp[((size_t)(blockIdx.z * Co + co)) * Mtot + c0]) = o;
      }
    }
}

// ---------------- conv1 combine: P[2][64][65536] -> H1p co-major padded ------
__global__ __launch_bounds__(TPB) void combine_cm_k(
    const float* __restrict__ P, const float* __restrict__ bias,
    float* __restrict__ out)
{
  int idx = blockIdx.x * TPB + threadIdx.x;   // 64*256*324 = 5,308,416
  if (idx >= 5308416) return;
  int px = idx % 18; int t = idx / 18; int py = t % 18; t /= 18;
  int b = t % 256; int co = t / 256;
  float v = 0.f;
  if (py >= 1 && py <= 16 && px >= 1 && px <= 16) {
    int cell = b * 256 + (py - 1) * 16 + (px - 1);
    v = P[(size_t)co * 65536 + cell] + P[(size_t)(64 + co) * 65536 + cell] + bias[co];
    v = fmaxf(v, 0.f);
  }
  out[idx] = v;
}

// ---------------- conv2 combine: P[4][128][16384] -> H2p NCHW padded ---------
__global__ __launch_bounds__(TPB) void combine_pad_k(
    const float* __restrict__ P, const float* __restrict__ bias,
    float* __restrict__ out)
{
  int idx = blockIdx.x * TPB + threadIdx.x;   // 256*128*100 = 3,276,800
  if (idx >= 3276800) return;
  int px = idx % 10; int t = idx / 10; int py = t % 10; t /= 10;
  int co = t % 128; int b = t / 128;
  float v = 0.f;
  if (py >= 1 && py <= 8 && px >= 1 && px <= 8) {
    int cell = b * 64 + (py - 1) * 8 + (px - 1);
    float s = 0.f;
#pragma unroll
    for (int z = 0; z < 4; ++z)
      s += P[((size_t)(z * 128 + co)) * 16384 + cell];
    v = fmaxf(s + bias[co], 0.f);
  }
  out[idx] = v;
}

// ---------------- conv3 combine: P[z][Co][M] -> NCHW flat --------------------
__global__ __launch_bounds__(TPB) void conv_combine(
    const float* __restrict__ P, const float* __restrict__ bias,
    float* __restrict__ out, int Mtot, int N, int SK, int lwo, int relu)
{
  int idx = blockIdx.x * TPB + threadIdx.x;
  int mq = Mtot >> 2;
  int co = idx / mq;
  int cell0 = (idx - co * mq) << 2;
  if (co >= N) return;
  float4 s = make_float4(0.f, 0.f, 0.f, 0.f);
  for (int z = 0; z < SK; ++z) {
    const float4 pv = *reinterpret_cast<const float4*>(
        &P[((size_t)z * N + co) * Mtot + cell0]);
    s.x += pv.x; s.y += pv.y; s.z += pv.z; s.w += pv.w;
  }
  float bv = bias[co];
  s.x += bv; s.y += bv; s.z += bv; s.w += bv;
  if (relu) { s.x = fmaxf(s.x, 0.f); s.y = fmaxf(s.y, 0.f);
              s.z = fmaxf(s.z, 0.f); s.w = fmaxf(s.w, 0.f); }
  int Wo = 1 << lwo;
  int x = cell0 & (Wo - 1), y = (cell0 >> lwo) & (Wo - 1), b = cell0 >> (lwo + lwo);
  *reinterpret_cast<float4*>(&out[(((size_t)b * N + co) * Wo + y) * Wo + x]) = s;
}

// ---------------- MFMA GEMM (BM=64, BN=64, 4 waves, split-K, prefetched) ----
template<int NS, int OUTM>
__global__ __launch_bounds__(TPB) void gemm_mf(
    const float* __restrict__ A, const float* __restrict__ W,
    const float* __restrict__ bias, void* __restrict__ outp,
    int M, int K, int N, int KSPL)
{
  constexpr int ST = (NS == 3) ? 64 : 32;
  __shared__ __align__(16) u32 L[(64 + 64) * ST];
  u32* AL = L; u32* BL = L + 64 * ST;
  const int tid = threadIdx.x;
  const int m0 = blockIdx.x << 6, n0 = blockIdx.y << 6;
  const int lane = tid & 63, wv = tid >> 6, r = lane & 15, g = lane >> 4;
  const int kb0 = blockIdx.z * KSPL;
  const int kbN = kb0 + KSPL;
  const int cl = tid & 63, oct = tid >> 6;
  f32x4 acc[4] = {};

  float vA[8], vB[8], vA2[8], vB2[8];
  auto gA = [&](int kt, float* v) {
    const float* ap = &A[(size_t)(m0 + cl) * K + kt + (oct << 3)];
    *reinterpret_cast<float4*>(&v[0]) = *reinterpret_cast<const float4*>(ap);
    *reinterpret_cast<float4*>(&v[4]) = *reinterpret_cast<const float4*>(ap + 4);
  };
  auto gB = [&](int kt, float* v) {
#pragma unroll
    for (int e = 0; e < 8; ++e)
      v[e] = W[(size_t)(kt + (oct << 3) + e) * N + n0 + cl];
  };

  gA(kb0, vA); gB(kb0, vB);
  for (int kt = kb0; kt < kbN; kt += 32) {
    const bool more = (kt + 32) < kbN;
    if (more) { gA(kt + 32, vA2); gB(kt + 32, vB2); }
    stWf<NS, ST>(AL, cl, oct, vA);
    stWf<NS, ST>(BL, cl, oct, vB);
    __syncthreads();
    short8v a_[3];
#pragma unroll
    for (int s = 0; s < NS; ++s) a_[s] = rdFrag<ST>(AL, (wv << 4) + r, (s << 2) | g);
#pragma unroll
    for (int ns = 0; ns < 4; ++ns) {
      short8v b_[3];
#pragma unroll
      for (int s = 0; s < NS; ++s) b_[s] = rdFrag<ST>(BL, (ns << 4) + r, (s << 2) | g);
      acc[ns] = __builtin_amdgcn_mfma_f32_16x16x32_bf16(a_[0], b_[0], acc[ns], 0, 0, 0);
      acc[ns] = __builtin_amdgcn_mfma_f32_16x16x32_bf16(a_[0], b_[1], acc[ns], 0, 0, 0);
      acc[ns] = __builtin_amdgcn_mfma_f32_16x16x32_bf16(a_[1], b_[0], acc[ns], 0, 0, 0);
      if (NS == 3) {
        acc[ns] = __builtin_amdgcn_mfma_f32_16x16x32_bf16(a_[1], b_[1], acc[ns], 0, 0, 0);
        acc[ns] = __builtin_amdgcn_mfma_f32_16x16x32_bf16(a_[0], b_[2], acc[ns], 0, 0, 0);
        acc[ns] = __builtin_amdgcn_mfma_f32_16x16x32_bf16(a_[2], b_[0], acc[ns], 0, 0, 0);
      }
    }
    __syncthreads();
    if (more) {
#pragma unroll
      for (int e = 0; e < 8; ++e) { vA[e] = vA2[e]; vB[e] = vB2[e]; }
    }
  }
#pragma unroll
  for (int ns = 0; ns < 4; ++ns)
#pragma unroll
    for (int q = 0; q < 4; ++q) {
      int m = m0 + (wv << 4) + (g << 2) + q;
      int n = n0 + (ns << 4) + r;
      float v = acc[ns][q];
      if (OUTM == 0) ((float*)outp)[((size_t)blockIdx.z * M + m) * N + n] = v;
      else           ((u32*)outp)[(size_t)m * N + n] = packhl(v + bias[n]);
    }
}

// ---------------- fc split-K combine ----------------------------------------
__global__ __launch_bounds__(TPB) void combine_k(
    const float* __restrict__ P, const float* __restrict__ bias,
    float* __restrict__ out, int MN, int N, int SK, int relu)
{
  int i4 = (blockIdx.x * TPB + threadIdx.x) << 2;
  if (i4 >= MN) return;
  float4 s = make_float4(0.f, 0.f, 0.f, 0.f);
  for (int z = 0; z < SK; ++z) {
    const float4 pv = *reinterpret_cast<const float4*>(&P[(size_t)z * MN + i4]);
    s.x += pv.x; s.y += pv.y; s.z += pv.z; s.w += pv.w;
  }
  int n = i4 % N;
  s.x += bias[n]; s.y += bias[n + 1]; s.z += bias[n + 2]; s.w += bias[n + 3];
  if (relu) { s.x = fmaxf(s.x, 0.f); s.y = fmaxf(s.y, 0.f);
              s.z = fmaxf(s.z, 0.f); s.w = fmaxf(s.w, 0.f); }
  *reinterpret_cast<float4*>(&out[i4]) = s;
}

// ---------------- g2 combine: sum 2 partials -> packed u32 ------------------
__global__ __launch_bounds__(TPB) void combine_pk_k(
    const float* __restrict__ P, const float* __restrict__ bias,
    u32* __restrict__ out)
{
  int i4 = (blockIdx.x * TPB + threadIdx.x) << 2;
  if (i4 >= 1048576) return;
  const float4 p0 = *reinterpret_cast<const float4*>(&P[i4]);
  const float4 p1 = *reinterpret_cast<const float4*>(&P[1048576 + i4]);
  int n = i4 % 4096;
  uint4 o;
  o.x = packhl(p0.x + p1.x + bias[n]);
  o.y = packhl(p0.y + p1.y + bias[n + 1]);
  o.z = packhl(p0.z + p1.z + bias[n + 2]);
  o.w = packhl(p0.w + p1.w + bias[n + 3]);
  *reinterpret_cast<uint4*>(&out[i4]) = o;
}

// ---------------- fp32 FC GEMM (g0, g1 only) --------------------------------
__global__ __launch_bounds__(TPB) void gemm_ig2(
    const float* __restrict__ A, const float* __restrict__ W,
    const float* __restrict__ bias, float* __restrict__ C,
    int M, int K, int N, int relu)
{
  constexpr int BM = 64, BN = 32, BK = 32;
  __shared__ __align__(16) float As[BK][BM + 4];
  __shared__ __align__(16) float Ws[BK][BN + 4];
  const int tid = threadIdx.x;
  const int m0 = blockIdx.x * BM;
  const int n0 = blockIdx.y * BN;
  const int tn = tid & 15;
  const int tm = tid >> 4;
  float acc[4][2] = {{0.f,0.f},{0.f,0.f},{0.f,0.f},{0.f,0.f}};

  for (int kt = 0; kt < K; kt += BK) {
#pragma unroll
    for (int f = 0; f < 2; ++f) {
      int idx = f * TPB + tid;
      int kq = idx & 7;
      int m = idx >> 3;
      const float4 av = *reinterpret_cast<const float4*>(
          &A[(size_t)(m0 + m) * K + kt + 4 * kq]);
      As[4 * kq + 0][m] = av.x;
      As[4 * kq + 1][m] = av.y;
      As[4 * kq + 2][m] = av.z;
      As[4 * kq + 3][m] = av.w;
    }
#pragma unroll
    for (int i = 0; i < 4; ++i) {
      int lin = i * TPB + tid;
      int n = lin & 31;
      int kk = lin >> 5;
      Ws[kk][n] = W[(size_t)(kt + kk) * N + n0 + n];
    }
    __syncthreads();
#pragma unroll
    for (int k = 0; k < BK; ++k) {
      const float4 av = *reinterpret_cast<const float4*>(&As[k][4 * tm]);
      const float2 wv = *reinterpret_cast<const float2*>(&Ws[k][2 * tn]);
      acc[0][0] = fmaf(av.x, wv.x, acc[0][0]);
      acc[0][1] = fmaf(av.x, wv.y, acc[0][1]);
      acc[1][0] = fmaf(av.y, wv.x, acc[1][0]);
      acc[1][1] = fmaf(av.y, wv.y, acc[1][1]);
      acc[2][0] = fmaf(av.z, wv.x, acc[2][0]);
      acc[2][1] = fmaf(av.z, wv.y, acc[2][1]);
      acc[3][0] = fmaf(av.w, wv.x, acc[3][0]);
      acc[3][1] = fmaf(av.w, wv.y, acc[3][1]);
    }
    __syncthreads();
  }
  const float b0 = bias[n0 + 2 * tn];
  const float b1 = bias[n0 + 2 * tn + 1];
#pragma unroll
  for (int mi = 0; mi < 4; ++mi) {
    int m = m0 + 4 * tm + mi;
    float2 v = make_float2(acc[mi][0] + b0, acc[mi][1] + b1);
    if (relu) { v.x = fmaxf(v.x, 0.f); v.y = fmaxf(v.y, 0.f); }
    *reinterpret_cast<float2*>(&C[(size_t)m * N + n0 + 2 * tn]) = v;
  }
}

// ---------------- MFMA convT, NS=2 (unchanged from R8) ----------------------
template<int BM, int EMIT, int SPLITIN>
__global__ __launch_bounds__(TPB) void convt_mf2(
    const u32* __restrict__ in, const u16* __restrict__ wth,
    const u16* __restrict__ wtl, const float* __restrict__ bias,
    u32* __restrict__ outq, int Ci, int Co, int Hi, int lwi, int relu)
{
  constexpr int ST = 32, MS = BM / 64;
  constexpr int STC = BM + 4;
  constexpr int LSZ = ((BM + 64) * ST > 64 * STC) ? (BM + 64) * ST : 64 * STC;
  __shared__ __align__(16) u32 L[LSZ];
  u32* AL = L; u32* BL = L + BM * ST;
  const int Wi = Hi, K4 = Ci << 2;
  const int HW = Hi * Wi, HWq = HW >> 2, Wiq = Wi >> 1;
  const int par = blockIdx.z, py = par >> 1, px = par & 1;
  const int tid = threadIdx.x;
  const int m0 = blockIdx.x * BM, n0 = blockIdx.y << 6;
  const int lane = tid & 63, wv = tid >> 6, r = lane & 15, g = lane >> 4;
  f32x4 acc[MS][4] = {};

  const int cl  = (BM == 128) ? (tid & 127) : (tid & 63);
  const int oc0 = (BM == 128) ? (tid >> 7) : (tid >> 6);
  int offT[4]; u32 mskT[4];
  {
    int cell = m0 + cl;
    int X = cell & (Wi - 1), Y = (cell >> lwi) & (Wi - 1), b = cell >> (lwi + lwi);
#pragma unroll
    for (int t = 0; t < 4; ++t) {
      int ay = t >> 1, ax = t & 1;
      int gy = Y + py - ay, gx = X + px - ax;
      bool ok = (gy >= 0 && gy < Hi && gx >= 0 && gx < Wi);
      int gyc = min(max(gy, 0), Hi - 1), gxc = min(max(gx, 0), Wi - 1);
      if (SPLITIN) {
        int q = ((gyc & 1) << 1) | (gxc & 1);
        offT[t] = q * (256 * Ci * HWq) + b * Ci * HWq + (gyc >> 1) * Wiq + (gxc >> 1);
      } else {
        offT[t] = b * Ci * HW + gyc * Wi + gxc;
      }
      mskT[t] = ok ? 0xffffffffu : 0u;
    }
  }
  const int stepCi = SPLITIN ? HWq : HW;

  auto gA = [&](int kb, u32 v[][8]) {
#pragma unroll
    for (int p = 0; p < MS; ++p) {
      int oc = oc0 + (p << 1);
      int cibase = ((kb >> 2) + (oc << 1)) * stepCi;
#pragma unroll
      for (int e = 0; e < 8; ++e) {
        int t = e & 3;
        v[p][e] = in[offT[t] + cibase + ((e >> 2) ? stepCi : 0)] & mskT[t];
      }
    }
  };
  auto gB = [&](int kb, uint4* d) {
    int n = tid & 63, oc2 = tid >> 6;
    size_t base = (size_t)(par * Co + n0 + n) * K4 + kb + (oc2 << 3);
    d[0] = *reinterpret_cast<const uint4*>(wth + base);
    d[1] = *reinterpret_cast<const uint4*>(wtl + base);
  };

  u32 vA[MS][8], vA2[MS][8];
  uint4 vB[2], vB2[2];
  gA(0, vA); gB(0, vB);
  for (int kb = 0; kb < K4; kb += 32) {
    const bool more = (kb + 32) < K4;
    if (more) { gA(kb + 32, vA2); gB(kb + 32, vB2); }
#pragma unroll
    for (int p = 0; p < MS; ++p) {
      const u32* v = vA[p];
      const int sw = cl & 7;
      int oc = oc0 + (p << 1);
      uint4 dh, dl;
      dh.x = (v[0] & 0xffffu) | (v[1] << 16);  dl.x = (v[0] >> 16) | (v[1] & 0xffff0000u);
      dh.y = (v[2] & 0xffffu) | (v[3] << 16);  dl.y = (v[2] >> 16) | (v[3] & 0xffff0000u);
      dh.z = (v[4] & 0xffffu) | (v[5] << 16);  dl.z = (v[4] >> 16) | (v[5] & 0xffff0000u);
      dh.w = (v[6] & 0xffffu) | (v[7] << 16);  dl.w = (v[6] >> 16) | (v[7] & 0xffff0000u);
      *reinterpret_cast<uint4*>(&AL[cl * ST + ((oc ^ sw) << 2)]) = dh;
      *reinterpret_cast<uint4*>(&AL[cl * ST + (((4 | oc) ^ sw) << 2)]) = dl;
    }
    {
      int n = tid & 63, oc2 = tid >> 6;
      stWp<ST>(BL, n, oc2, 0, vB[0]);
      stWp<ST>(BL, n, oc2, 1, vB[1]);
    }
    __syncthreads();
    short8v a_[MS][2];
#pragma unroll
    for (int mm = 0; mm < MS; ++mm)
#pragma unroll
      for (int s = 0; s < 2; ++s)
        a_[mm][s] = rdFrag<ST>(AL, (wv * MS + mm) * 16 + r, (s << 2) | g);
#pragma unroll
    for (int ns = 0; ns < 4; ++ns) {
      short8v b_[2];
#pragma unroll
      for (int s = 0; s < 2; ++s) b_[s] = rdFrag<ST>(BL, (ns << 4) + r, (s << 2) | g);
#pragma unroll
      for (int mm = 0; mm < MS; ++mm) {
        acc[mm][ns] = __builtin_amdgcn_mfma_f32_16x16x32_bf16(a_[mm][0], b_[0], acc[mm][ns], 0, 0, 0);
        acc[mm][ns] = __builtin_amdgcn_mfma_f32_16x16x32_bf16(a_[mm][0], b_[1], acc[mm][ns], 0, 0, 0);
        acc[mm][ns] = __builtin_amdgcn_mfma_f32_16x16x32_bf16(a_[mm][1], b_[0], acc[mm][ns], 0, 0, 0);
      }
    }
    __syncthreads();
    if (more) {
#pragma unroll
      for (int p = 0; p < MS; ++p)
#pragma unroll
        for (int e = 0; e < 8; ++e) vA[p][e] = vA2[p][e];
      vB[0] = vB2[0]; vB[1] = vB2[1];
    }
  }
#pragma unroll
  for (int mm = 0; mm < MS; ++mm)
#pragma unroll
    for (int ns = 0; ns < 4; ++ns)
#pragma unroll
      for (int q = 0; q < 4; ++q) {
        int cell = (wv * MS + mm) * 16 + (g << 2) + q;
        int col = (ns << 4) + r;
        float v = acc[mm][ns][q] + bias[n0 + col];
        if (relu) v = fmaxf(v, 0.f);
        L[col * STC + cell] = EMIT ? packhl(v) : __float_as_uint(v);
      }
  __syncthreads();
  const size_t QO = (size_t)256 * Co * HW;
  u32* op = outq + (size_t)par * QO;
  constexpr int C4N = BM / 4;
  constexpr int NCH = (BM * 64) / (TPB * 4);
#pragma unroll
  for (int it = 0; it < NCH; ++it) {
    int lin = it * TPB + tid;
    int c4 = lin & (C4N - 1);
    int col = lin / C4N;
    int cell0 = c4 << 2;
    uint4 d = *reinterpret_cast<const uint4*>(&L[col * STC + cell0]);
    int gc = m0 + cell0;
    int Xo = gc & (Wi - 1), Yo = (gc >> lwi) & (Wi - 1), bo = gc >> (lwi + lwi);
    *reinterpret_cast<uint4*>(
        &op[((size_t)(bo * Co + n0 + col) * Hi + Yo) * Wi + Xo]) = d;
  }
}

// ---------------- dedicated t3 (unchanged from R8) ---------------------------
__global__ __launch_bounds__(TPB) void convt3_kernel(
    const float* __restrict__ inq, const float* __restrict__ w,
    float* __restrict__ part)
{
  __shared__ float wl[3072];
  __shared__ float il[8][33 * 32];
  const int b = blockIdx.x;
  const int z = blockIdx.y;
  const int tid = threadIdx.x;
  for (int i = tid; i < 3072; i += TPB) wl[i] = w[i];
  const int Y = tid >> 3;
  const int X0 = (tid & 7) << 2;
  float acc[3][2][8];
#pragma unroll
  for (int o = 0; o < 3; ++o)
#pragma unroll
    for (int p = 0; p < 2; ++p)
#pragma unroll
      for (int q = 0; q < 8; ++q) acc[o][p][q] = 0.f;

  const int cbeg = z << 5, cend = cbeg + 32;
  for (int c0 = cbeg; c0 < cend; c0 += 8) {
    __syncthreads();
    for (int i = tid; i < 8192; i += TPB) {
      int cc = i >> 10, yy = (i >> 5) & 31, xx = i & 31;
      int q = ((yy & 1) << 1) | (xx & 1);
      il[cc][yy * 33 + xx] = inq[(size_t)q * 4194304 +
          (((size_t)b * 64 + c0 + cc) * 16 + (yy >> 1)) * 16 + (xx >> 1)];
    }
    __syncthreads();
    for (int cc = 0; cc < 8; ++cc) {
      float iv[3][6];
#pragma unroll
      for (int j = 0; j < 3; ++j) {
        int gy = Y - 1 + j;
        int gyc = min(max(gy, 0), 31);
        float my = (gy >= 0 && gy < 32) ? 1.f : 0.f;
#pragma unroll
        for (int k = 0; k < 6; ++k) {
          int gx = X0 - 1 + k;
          int gxc = min(max(gx, 0), 31);
          float mx = (gx >= 0 && gx < 32) ? 1.f : 0.f;
          iv[j][k] = il[cc][gyc * 33 + gxc] * (my * mx);
        }
      }
      const float* wq = &wl[(c0 + cc) * 48];
#pragma unroll
      for (int o = 0; o < 3; ++o) {
        const float* wo = wq + o * 16;
#pragma unroll
        for (int c = 0; c < 4; ++c) {
          acc[o][0][2*c]   = fmaf(iv[1][c+1], wo[5],  acc[o][0][2*c]);
          acc[o][0][2*c]   = fmaf(iv[1][c],   wo[7],  acc[o][0][2*c]);
          acc[o][0][2*c]   = fmaf(iv[0][c+1], wo[13], acc[o][0][2*c]);
          acc[o][0][2*c]   = fmaf(iv[0][c],   wo[15], acc[o][0][2*c]);
          acc[o][0][2*c+1] = fmaf(iv[1][c+2], wo[4],  acc[o][0][2*c+1]);
          acc[o][0][2*c+1] = fmaf(iv[1][c+1], wo[6],  acc[o][0][2*c+1]);
          acc[o][0][2*c+1] = fmaf(iv[0][c+2], wo[12], acc[o][0][2*c+1]);
          acc[o][0][2*c+1] = fmaf(iv[0][c+1], wo[14], acc[o][0][2*c+1]);
          acc[o][1][2*c]   = fmaf(iv[2][c+1], wo[1],  acc[o][1][2*c]);
          acc[o][1][2*c]   = fmaf(iv[2][c],   wo[3],  acc[o][1][2*c]);
          acc[o][1][2*c]   = fmaf(iv[1][c+1], wo[9],  acc[o][1][2*c]);
          acc[o][1][2*c]   = fmaf(iv[1][c],   wo[11], acc[o][1][2*c]);
          acc[o][1][2*c+1] = fmaf(iv[2][c+2], wo[0],  acc[o][1][2*c+1]);
          acc[o][1][2*c+1] = fmaf(iv[2][c+1], wo[2],  acc[o][1][2*c+1]);
          acc[o][1][2*c+1] = fmaf(iv[1][c+2], wo[8],  acc[o][1][2*c+1]);
          acc[o][1][2*c+1] = fmaf(iv[1][c+1], wo[10], acc[o][1][2*c+1]);
        }
      }
    }
  }
  float* pz = part + (size_t)z * 3145728;
#pragma unroll
  for (int o = 0; o < 3; ++o) {
#pragma unroll
    for (int p = 0; p < 2; ++p) {
      float* op = pz + (((size_t)b * 3 + o) * 64 + 2 * Y + p) * 64 + 2 * X0;
      *reinterpret_cast<float4*>(op) =
          make_float4(acc[o][p][0], acc[o][p][1], acc[o][p][2], acc[o][p][3]);
      *reinterpret_cast<float4*>(op + 4) =
          make_float4(acc[o][p][4], acc[o][p][5], acc[o][p][6], acc[o][p][7]);
    }
  }
}

__global__ __launch_bounds__(TPB) void c3_combine(
    const float* __restrict__ part, const float* __restrict__ bias,
    float* __restrict__ out)
{
  int i4 = (blockIdx.x * TPB + threadIdx.x) << 2;
  const float4 p0 = *reinterpret_cast<const float4*>(&part[i4]);
  const float4 p1 = *reinterpret_cast<const float4*>(&part[i4 + 3145728]);
  int o = (i4 >> 12) % 3;
  float bv = bias[o];
  float4 s = make_float4(p0.x + p1.x + bv, p0.y + p1.y + bv,
                         p0.z + p1.z + bv, p0.w + p1.w + bv);
  *reinterpret_cast<float4*>(&out[i4]) = s;
}

// ---------------- VQ ---------------------------------------------------------
__global__ __launch_bounds__(TPB) void vq_kernel(
    const float* __restrict__ z, const float* __restrict__ cb,
    float* __restrict__ e, float* __restrict__ rowloss)
{
  const int row = blockIdx.x;
  const int b = row >> 4, s = row & 15;
  __shared__ float zr[64];
  __shared__ float bval[TPB];
  __shared__ int   bidx[TPB];
  const int tid = threadIdx.x;
  if (tid < 64) zr[tid] = z[(size_t)b * 1536 + s * 64 + tid];
  __syncthreads();

  float best = 3.4e38f;
  int bi = 0;
#pragma unroll
  for (int rep = 0; rep < 2; ++rep) {
    int j = tid + rep * TPB;
    const float4* c4 = reinterpret_cast<const float4*>(cb + (size_t)j * 64);
    float d = 0.f;
#pragma unroll
    for (int k = 0; k < 16; ++k) {
      float4 cv = c4[k];
      float t0 = zr[4 * k + 0] - cv.x;
      float t1 = zr[4 * k + 1] - cv.y;
      float t2 = zr[4 * k + 2] - cv.z;
      float t3 = zr[4 * k + 3] - cv.w;
      d = fmaf(t0, t0, d); d = fmaf(t1, t1, d);
      d = fmaf(t2, t2, d); d = fmaf(t3, t3, d);
    }
    if (d < best) { best = d; bi = j; }
  }
  bval[tid] = best; bidx[tid] = bi;
  __syncthreads();
  for (int sft = 128; sft > 0; sft >>= 1) {
    if (tid < sft) {
      float v2 = bval[tid + sft]; int i2 = bidx[tid + sft];
      if (v2 < bval[tid] || (v2 == bval[tid] && i2 < bidx[tid])) {
        bval[tid] = v2; bidx[tid] = i2;
      }
    }
    __syncthreads();
  }
  const int bj = bidx[0];
  if (tid < 64)
    e[(size_t)b * 1536 + s * 64 + tid] = cb[(size_t)bj * 64 + tid];
  if (tid == 0) rowloss[row] = bval[0];
}

__global__ __launch_bounds__(TPB) void zs_copy_kernel(
    const float* __restrict__ z, float* __restrict__ e)
{
  int i = blockIdx.x * TPB + threadIdx.x;
  int b = i >> 9, k = i & 511;
  e[(size_t)b * 1536 + 1024 + k] = z[(size_t)b * 1536 + 1024 + k];
}

__global__ __launch_bounds__(TPB) void loss_reduce_kernel(
    const float* __restrict__ rl, float* __restrict__ out)
{
  __shared__ float sm[TPB];
  float s = 0.f;
  for (int i = threadIdx.x; i < 4096; i += TPB) s += rl[i];
  sm[threadIdx.x] = s;
  __syncthreads();
  for (int sft = 128; sft > 0; sft >>= 1) {
    if (threadIdx.x < sft) sm[threadIdx.x] += sm[threadIdx.x + sft];
    __syncthreads();
  }
  if (threadIdx.x == 0) out[0] = sm[0] * (1.25f / 262144.f);
}

// ============================================================================
extern "C" void kernel_launch(void* const* d_in, const int* in_sizes, int n_in,
                              void* d_out, int out_size, void* d_ws, size_t ws_size,
                              hipStream_t stream)
{
  const float* x    = (const float*)d_in[0];
  const float* ew0  = (const float*)d_in[1];
  const float* eb0  = (const float*)d_in[2];
  const float* ew1  = (const float*)d_in[3];
  const float* eb1  = (const float*)d_in[4];
  const float* ew2  = (const float*)d_in[5];
  const float* eb2  = (const float*)d_in[6];
  const float* ew3  = (const float*)d_in[7];
  const float* eb3  = (const float*)d_in[8];
  const float* fw0  = (const float*)d_in[9];
  const float* fb0  = (const float*)d_in[10];
  const float* fw1  = (const float*)d_in[11];
  const float* fb1  = (const float*)d_in[12];
  const float* fw2  = (const float*)d_in[13];
  const float* fb2  = (const float*)d_in[14];
  const float* cb   = (const float*)d_in[15];
  const float* gw0  = (const float*)d_in[16];
  const float* gb0  = (const float*)d_in[17];
  const float* gw1  = (const float*)d_in[18];
  const float* gb1  = (const float*)d_in[19];
  const float* gw2  = (const float*)d_in[20];
  const float* gb2  = (const float*)d_in[21];
  const float* tw0  = (const float*)d_in[22];
  const float* tb0  = (const float*)d_in[23];
  const float* tw1  = (const float*)d_in[24];
  const float* tb1  = (const float*)d_in[25];
  const float* tw2  = (const float*)d_in[26];
  const float* tb2  = (const float*)d_in[27];
  const float* tw3  = (const float*)d_in[28];
  const float* tb3  = (const float*)d_in[29];

  float* out = (float*)d_out;
  float* ws  = (float*)d_ws;

  // ---- workspace plan (float offsets; time-disjoint regions) ----
  u16*   WE0  = (u16*)(ws + 0);            // 4608
  u16*   WE1  = (u16*)(ws + 4608);         // 98304
  u16*   WE2  = (u16*)(ws + 102912);       // 196608
  u16*   WE3  = (u16*)(ws + 299520);       // 786432
  float* RL   = ws + 1085952;              // 4096
  float* H0P  = ws + 1090048;              // 18,939,904 = 256*64*34*34
  float* PC1  = ws + 20029952;             // 8,388,608 (conv1 partials)
  float* XP   = ws + 20029952;             // 3,345,408 (xp; dead before PC1)
  float* H1P  = ws + 1090048;              // 5,308,416 (co-major padded; H0P dead)
  float* PC23 = ws + 6398464;              // 8,388,608 (conv2 then conv3 partials)
  float* H2P  = ws + 14787072;             // 3,276,800
  float* H3   = ws + 18063872;             // 1,048,576
  float* P    = ws + 1090048;              // fc partials (<=4,194,304; H1P dead)
  float* F0   = ws + 5284352;              // 262144
  float* F1   = ws + 5546496;              // 262144
  float* Z    = ws + 5808640;              // 393216
  float* E    = ws + 6201856;              // 393216
  float* G0   = ws + 6595072;              // 131072
  float* G1   = ws + 6726144;              // 262144
  float* T2S  = ws + 1090048;              // 16,777,216 (t2 out, quadrant f32)
  u16*   WT0h = (u16*)(ws + 17867264);     // 524288 u16
  u16*   WT0l = (u16*)(ws + 18129408);
  u16*   WT1h = (u16*)(ws + 18391552);
  u16*   WT1l = (u16*)(ws + 18457088);
  u16*   WT2h = (u16*)(ws + 18522624);
  u16*   WT2l = (u16*)(ws + 18555392);
  float* PG2  = ws + 18588160;             // 2,097,152 (g2 partials)
  u32*   G2P  = (u32*)(ws + 20685312);     // 1,048,576
  u32*   T0S  = (u32*)(ws + 21733888);     // 2,097,152
  u32*   T1S  = (u32*)(ws + 23831040);     // 4,194,304 -> end 28,025,344
  float* PT3  = ws + 18588160;             // 6,291,456 (convt3 partials; Pg2..T1S dead)

  // ---- encoder weight prep + input pad ----
  wsplit3_k<<<dim3(12),  TPB, 0, stream>>>(ew0, WE0, 3072);
  wsplit3_k<<<dim3(256), TPB, 0, stream>>>(ew1, WE1, 65536);
  wsplit3_k<<<dim3(512), TPB, 0, stream>>>(ew2, WE2, 131072);
  wsplit3_k<<<dim3(1024),TPB, 0, stream>>>(ew3, WE3, 524288);
  x_pad_k<<<dim3(13068), TPB, 0, stream>>>(x, XP);
  zb0_k<<<dim3(8448), TPB, 0, stream>>>(H0P);

  // ---- encoder convs (A-direct MFMA NS=3) ----
  // conv0: 3->64, 64x64 -> padded H0P
  conv_ad<4,0><<<dim3(1024, 1, 1), TPB, 0, stream>>>(
      XP, WE0, eb0, H0P, 3, 64, 64, 5, 1, 48, 3072, 13068, 4356, 0);
  // conv1: 64->64, 32x32, split-K z2 -> PC1; combine -> H1P co-major padded
  conv_ad<4,1><<<dim3(256, 1, 2), TPB, 0, stream>>>(
      H0P, WE1, eb1, PC1, 64, 64, 32, 4, 1, 512, 65536, 73984, 1156, 65536);
  combine_cm_k<<<dim3(20736), TPB, 0, stream>>>(PC1, eb1, H1P);
  // conv2: 64->128, 16x16 (co-major input), z4 -> PC23; combine -> H2P padded
  conv_ad<4,1><<<dim3(64, 2, 4), TPB, 0, stream>>>(
      H1P, WE2, eb2, PC23, 64, 128, 16, 3, 1, 256, 131072, 324, 82944, 16384);
  combine_pad_k<<<dim3(12800), TPB, 0, stream>>>(PC23, eb2, H2P);
  // conv3: 128->256, 8x8, z8 -> PC23; combine -> H3 flat NCHW
  conv_ad<4,1><<<dim3(16, 4, 8), TPB, 0, stream>>>(
      H2P, WE3, eb3, PC23, 128, 256, 8, 2, 0, 256, 524288, 12800, 100, 4096);
  conv_combine<<<dim3(1024), TPB, 0, stream>>>(PC23, eb3, H3, 4096, 256, 8, 2, 0);

  // ---- encoder FC (MFMA NS=3, split-K + combine) ----
  gemm_mf<3,0><<<dim3(4, 16, 16), TPB, 0, stream>>>(H3, fw0, fb0, (void*)P, 256, 4096, 1024, 256);
  combine_k<<<dim3(256), TPB, 0, stream>>>(P, fb0, F0, 262144, 1024, 16, 1);
  gemm_mf<3,0><<<dim3(4, 16, 8), TPB, 0, stream>>>(F0, fw1, fb1, (void*)P, 256, 1024, 1024, 128);
  combine_k<<<dim3(256), TPB, 0, stream>>>(P, fb1, F1, 262144, 1024, 8, 1);
  gemm_mf<3,0><<<dim3(4, 24, 8), TPB, 0, stream>>>(F1, fw2, fb2, (void*)P, 256, 1024, 1536, 128);
  combine_k<<<dim3(384), TPB, 0, stream>>>(P, fb2, Z, 393216, 1536, 8, 0);

  // ---- VQ ----
  vq_kernel<<<dim3(4096), TPB, 0, stream>>>(Z, cb, E, RL);
  zs_copy_kernel<<<dim3(512), TPB, 0, stream>>>(Z, E);
  loss_reduce_kernel<<<dim3(1), TPB, 0, stream>>>(RL, out + (size_t)out_size - 1);

  // ---- decoder FC ----
  gemm_ig2<<<dim3(4, 16), TPB, 0, stream>>>(E,  gw0, gb0, G0, 256, 1536, 512,  1);
  gemm_ig2<<<dim3(4, 32), TPB, 0, stream>>>(G0, gw1, gb1, G1, 256, 512,  1024, 1);

  // ---- decoder weight prep (inputs static; H3/fc regions dead now) ----
  wprep2_k<<<dim3(512), TPB, 0, stream>>>(tw0, WT0h, WT0l, 256, 128);
  wprep2_k<<<dim3(128), TPB, 0, stream>>>(tw1, WT1h, WT1l, 128, 64);
  wprep2_k<<<dim3(64),  TPB, 0, stream>>>(tw2, WT2h, WT2l, 64, 64);

  // g2: split-K z2 -> PG2; combine -> packed G2P
  gemm_mf<2,0><<<dim3(4, 64, 2), TPB, 0, stream>>>(G1, gw2, gb2, (void*)PG2, 256, 1024, 4096, 512);
  combine_pk_k<<<dim3(1024), TPB, 0, stream>>>(PG2, gb2, G2P);

  // ---- decoder transposed convs (MFMA NS=2, quadrant layouts) ----
  convt_mf2<64,1,0><<<dim3(64, 2, 4),   TPB, 0, stream>>>(G2P, WT0h, WT0l, tb0, T0S, 256, 128, 4,  2, 1);
  convt_mf2<128,1,1><<<dim3(128, 1, 4), TPB, 0, stream>>>(T0S, WT1h, WT1l, tb1, T1S, 128, 64,  8,  3, 1);
  convt_mf2<128,0,1><<<dim3(512, 1, 4), TPB, 0, stream>>>(T1S, WT2h, WT2l, tb2, (u32*)T2S, 64, 64, 16, 4, 1);
  convt3_kernel<<<dim3(256, 2), TPB, 0, stream>>>(T2S, tw3, PT3);
  c3_combine<<<dim3(3072), TPB, 0, stream>>>(PT3, tb3, out);
}

// Round 10
// 565.009 us; speedup vs baseline: 13.8003x; 1.0906x over previous
//
#include <hip/hip_runtime.h>
#include <hip/hip_bf16.h>

// ============================================================================
// VQ-VAE forward, round 10: R9 + g0/g1 moved from fp32 gemm_ig2 (64 blocks,
// 2.6% occupancy, 65us each) to MFMA NS=2 split-K (256 blocks) + combine.
// Everything else identical to R9.
// ============================================================================

#define TPB 256
typedef __attribute__((ext_vector_type(8))) short short8v;
typedef __attribute__((ext_vector_type(4))) float f32x4;
typedef unsigned int u32;
typedef unsigned short u16;

__device__ inline u16 f2bf(float x){
  union { __hip_bfloat16 b; u16 u; } cv;
  cv.b = __float2bfloat16(x);
  return cv.u;
}
__device__ inline float bf2f(u16 h){ union{u32 u;float f;}v; v.u=((u32)h)<<16; return v.f;}
__device__ inline u32 packhl(float x){ u16 h=f2bf(x); u16 l=f2bf(x-bf2f(h)); return ((u32)l<<16)|(u32)h;}

template<int NS>
__device__ inline void splitN(float x, u16 t[3]) {
  u16 h0 = f2bf(x); t[0] = h0;
  float r1 = x - bf2f(h0);
  u16 h1 = f2bf(r1); t[1] = h1;
  if (NS == 3) { float r2 = r1 - bf2f(h1); t[2] = f2bf(r2); }
}

template<int NS, int ST>
__device__ inline void stW(u32* L, int row, int oct, const u16 hs[3][8]) {
  constexpr int SWM = (ST == 64) ? 15 : 7;
  const int sw = row & SWM;
#pragma unroll
  for (int s = 0; s < NS; ++s) {
    uint4 d;
    d.x = (u32)hs[s][0] | ((u32)hs[s][1] << 16);
    d.y = (u32)hs[s][2] | ((u32)hs[s][3] << 16);
    d.z = (u32)hs[s][4] | ((u32)hs[s][5] << 16);
    d.w = (u32)hs[s][6] | ((u32)hs[s][7] << 16);
    int ch = (((s << 2) | oct) ^ sw) << 2;
    *reinterpret_cast<uint4*>(&L[row * ST + ch]) = d;
  }
}

template<int NS, int ST>
__device__ inline void stWf(u32* L, int row, int oct, const float v[8]) {
  u16 hs[3][8];
#pragma unroll
  for (int e = 0; e < 8; ++e) {
    u16 t3[3]; splitN<NS>(v[e], t3);
    hs[0][e] = t3[0]; hs[1][e] = t3[1]; if (NS == 3) hs[2][e] = t3[2];
  }
  stW<NS, ST>(L, row, oct, hs);
}

template<int ST>
__device__ inline void stWp(u32* L, int row, int oct, int s, uint4 d) {
  constexpr int SWM = (ST == 64) ? 15 : 7;
  int ch = (((s << 2) | oct) ^ (row & SWM)) << 2;
  *reinterpret_cast<uint4*>(&L[row * ST + ch]) = d;
}

template<int ST>
__device__ inline short8v rdFrag(const u32* L, int row, int c) {
  constexpr int SWM = (ST == 64) ? 15 : 7;
  int ph = (c ^ (row & SWM)) << 2;
  return *reinterpret_cast<const short8v*>(&L[row * ST + ph]);
}

// ---------------- weight prep -----------------------------------------------
__global__ __launch_bounds__(TPB) void wsplit3_k(
    const float* __restrict__ src, u16* __restrict__ dst, int n)
{
  for (int i = blockIdx.x * TPB + threadIdx.x; i < n; i += gridDim.x * TPB) {
    u16 t3[3]; splitN<3>(src[i], t3);
    dst[i] = t3[0]; dst[i + n] = t3[1]; dst[i + 2 * n] = t3[2];
  }
}
__global__ __launch_bounds__(TPB) void wprep2_k(
    const float* __restrict__ src, u16* __restrict__ dh, u16* __restrict__ dl,
    int Ci, int Co)
{
  int K4 = Ci << 2;
  int tot = 4 * Co * K4;
  for (int i = blockIdx.x * TPB + threadIdx.x; i < tot; i += gridDim.x * TPB) {
    int par = i / (Co * K4); int rem = i - par * (Co * K4);
    int co = rem / K4; int k4 = rem - co * K4;
    int ci = k4 >> 2, ay = (k4 >> 1) & 1, ax = k4 & 1;
    int py = par >> 1, px = par & 1;
    int widx = ((1 - py) << 2) + (1 - px) + (ay << 3) + (ax << 1);
    float x = src[(((size_t)ci * Co + co) << 4) + widx];
    u16 h = f2bf(x);
    dh[i] = h; dl[i] = f2bf(x - bf2f(h));
  }
}

// ---------------- input pad / border-zero ------------------------------------
__global__ __launch_bounds__(TPB) void x_pad_k(
    const float* __restrict__ x, float* __restrict__ xp)
{
  int idx = blockIdx.x * TPB + threadIdx.x;
  if (idx >= 3345408) return;
  int px = idx % 66; int t = idx / 66; int py = t % 66; int p = t / 66;
  float v = 0.f;
  if (py >= 1 && py <= 64 && px >= 1 && px <= 64)
    v = x[(size_t)p * 4096 + (py - 1) * 64 + (px - 1)];
  xp[idx] = v;
}
__global__ __launch_bounds__(TPB) void zb0_k(float* __restrict__ h0p)
{
  int idx = blockIdx.x * TPB + threadIdx.x;
  if (idx >= 2162688) return;
  int p = idx / 132, k = idx % 132;
  int py, px;
  if (k < 34)       { py = 0;           px = k; }
  else if (k < 68)  { py = 33;          px = k - 34; }
  else if (k < 100) { py = k - 68 + 1;  px = 0; }
  else              { py = k - 100 + 1; px = 33; }
  h0p[(size_t)p * 1156 + py * 34 + px] = 0.f;
}

// ---------------- A-direct MFMA conv (s2,k4,p1), NS=3 ------------------------
template<int RM, int OUTM>
__global__ __launch_bounds__(TPB, 2) void conv_ad(
    const float* __restrict__ in, const u16* __restrict__ wsp,
    const float* __restrict__ bias, float* __restrict__ outp,
    int Ci, int Co, int Wi, int lwo, int relu, int KSPL, int PS,
    int bS, int ciS, int Mtot)
{
  constexpr int BM = RM * 64;
  __shared__ __align__(16) u32 BL[2][64 * 64];
  const int K = Ci << 4;
  const int PW = Wi + 2;
  const int Wo = Wi >> 1;
  const int tid = threadIdx.x;
  const int m0 = blockIdx.x * BM, n0 = blockIdx.y << 6;
  const int lane = tid & 63, wv = tid >> 6, r = lane & 15, g = lane >> 4;
  const int kb0 = blockIdx.z * KSPL;
  const int kbN = min(kb0 + KSPL, K);
  const int khsel = g & 1;
  const int cig = g >> 1;
  f32x4 acc[RM][4] = {};

  int base[RM];
#pragma unroll
  for (int mm = 0; mm < RM; ++mm) {
    int cell = m0 + (wv * RM + mm) * 16 + r;
    int x = cell & (Wo - 1), y = (cell >> lwo) & (Wo - 1), b = cell >> (lwo + lwo);
    base[mm] = b * bS + (2 * y + 2 * khsel) * PW + 2 * x;
  }

  auto gA = [&](int kb, float v[RM][8]) {
    if ((kb + (g << 3)) < K) {
      int cioff = ((kb >> 4) + cig) * ciS;
#pragma unroll
      for (int mm = 0; mm < RM; ++mm) {
        const float* p = in + base[mm] + cioff;
#pragma unroll
        for (int e = 0; e < 8; ++e)
          v[mm][e] = p[(e >> 2) * PW + (e & 3)];
      }
    } else {
#pragma unroll
      for (int mm = 0; mm < RM; ++mm)
#pragma unroll
        for (int e = 0; e < 8; ++e) v[mm][e] = 0.f;
    }
  };
  auto gB = [&](int kb, uint4* d) {
    int n = tid & 63, oc2 = tid >> 6;
    int k8 = kb + (oc2 << 3);
    if (k8 < K) {
      const u16* wp = wsp + (size_t)(n0 + n) * K + k8;
      d[0] = *reinterpret_cast<const uint4*>(wp);
      d[1] = *reinterpret_cast<const uint4*>(wp + PS);
      d[2] = *reinterpret_cast<const uint4*>(wp + 2 * PS);
    } else {
      d[0] = d[1] = d[2] = make_uint4(0u, 0u, 0u, 0u);
    }
  };
  auto mkfrags = [&](const float v[8], short8v f[3]) {
    u16 hs[3][8];
#pragma unroll
    for (int e = 0; e < 8; ++e) {
      u16 t3[3]; splitN<3>(v[e], t3);
      hs[0][e] = t3[0]; hs[1][e] = t3[1]; hs[2][e] = t3[2];
    }
#pragma unroll
    for (int s = 0; s < 3; ++s) {
      union { u16 u[8]; short8v sv; } cv;
#pragma unroll
      for (int e = 0; e < 8; ++e) cv.u[e] = hs[s][e];
      f[s] = cv.sv;
    }
  };

  float vA[RM][8], vA2[RM][8];
  uint4 vB[3], vB2[3];
  gA(kb0, vA); gB(kb0, vB);
  for (int kb = kb0; kb < kbN; kb += 32) {
    u32* BLc = BL[((kb - kb0) >> 5) & 1];
    {
      int n = tid & 63, oc2 = tid >> 6;
      stWp<64>(BLc, n, oc2, 0, vB[0]);
      stWp<64>(BLc, n, oc2, 1, vB[1]);
      stWp<64>(BLc, n, oc2, 2, vB[2]);
    }
    const bool more = (kb + 32) < kbN;
    if (more) { gB(kb + 32, vB2); gA(kb + 32, vA2); }
    short8v a_[RM][3];
#pragma unroll
    for (int mm = 0; mm < RM; ++mm) mkfrags(vA[mm], a_[mm]);
    __syncthreads();
#pragma unroll
    for (int ns = 0; ns < 4; ++ns) {
      short8v b_[3];
#pragma unroll
      for (int s = 0; s < 3; ++s) b_[s] = rdFrag<64>(BLc, (ns << 4) + r, (s << 2) | g);
#pragma unroll
      for (int mm = 0; mm < RM; ++mm) {
        acc[mm][ns] = __builtin_amdgcn_mfma_f32_16x16x32_bf16(a_[mm][0], b_[0], acc[mm][ns], 0, 0, 0);
        acc[mm][ns] = __builtin_amdgcn_mfma_f32_16x16x32_bf16(a_[mm][0], b_[1], acc[mm][ns], 0, 0, 0);
        acc[mm][ns] = __builtin_amdgcn_mfma_f32_16x16x32_bf16(a_[mm][1], b_[0], acc[mm][ns], 0, 0, 0);
        acc[mm][ns] = __builtin_amdgcn_mfma_f32_16x16x32_bf16(a_[mm][1], b_[1], acc[mm][ns], 0, 0, 0);
        acc[mm][ns] = __builtin_amdgcn_mfma_f32_16x16x32_bf16(a_[mm][0], b_[2], acc[mm][ns], 0, 0, 0);
        acc[mm][ns] = __builtin_amdgcn_mfma_f32_16x16x32_bf16(a_[mm][2], b_[0], acc[mm][ns], 0, 0, 0);
      }
    }
    if (more) {
#pragma unroll
      for (int mm = 0; mm < RM; ++mm)
#pragma unroll
        for (int e = 0; e < 8; ++e) vA[mm][e] = vA2[mm][e];
#pragma unroll
      for (int s = 0; s < 3; ++s) vB[s] = vB2[s];
    }
  }
#pragma unroll
  for (int mm = 0; mm < RM; ++mm)
#pragma unroll
    for (int ns = 0; ns < 4; ++ns) {
      int c0 = m0 + (wv * RM + mm) * 16 + (g << 2);
      int co = n0 + (ns << 4) + r;
      if (OUTM == 0) {
        float bv = bias[co];
        const int OPW = Wo + 2;
        const int OPHW = OPW * OPW;
#pragma unroll
        for (int q = 0; q < 4; ++q) {
          int cell = c0 + q;
          int x = cell & (Wo - 1), y = (cell >> lwo) & (Wo - 1), b = cell >> (lwo + lwo);
          float v = acc[mm][ns][q] + bv;
          if (relu) v = fmaxf(v, 0.f);
          outp[((size_t)(b * Co + co)) * OPHW + (y + 1) * OPW + (x + 1)] = v;
        }
      } else {
        float4 o;
        o.x = acc[mm][ns][0]; o.y = acc[mm][ns][1];
        o.z = acc[mm][ns][2]; o.w = acc[mm][ns][3];
        *reinterpret_cast<float4*>(
            &outp[((size_t)(blockIdx.z * Co + co)) * Mtot + c0]) = o;
      }
    }
}

// ---------------- conv combines ----------------------------------------------
__global__ __launch_bounds__(TPB) void combine_cm_k(
    const float* __restrict__ P, const float* __restrict__ bias,
    float* __restrict__ out)
{
  int idx = blockIdx.x * TPB + threadIdx.x;
  if (idx >= 5308416) return;
  int px = idx % 18; int t = idx / 18; int py = t % 18; t /= 18;
  int b = t % 256; int co = t / 256;
  float v = 0.f;
  if (py >= 1 && py <= 16 && px >= 1 && px <= 16) {
    int cell = b * 256 + (py - 1) * 16 + (px - 1);
    v = P[(size_t)co * 65536 + cell] + P[(size_t)(64 + co) * 65536 + cell] + bias[co];
    v = fmaxf(v, 0.f);
  }
  out[idx] = v;
}

__global__ __launch_bounds__(TPB) void combine_pad_k(
    const float* __restrict__ P, const float* __restrict__ bias,
    float* __restrict__ out)
{
  int idx = blockIdx.x * TPB + threadIdx.x;
  if (idx >= 3276800) return;
  int px = idx % 10; int t = idx / 10; int py = t % 10; t /= 10;
  int co = t % 128; int b = t / 128;
  float v = 0.f;
  if (py >= 1 && py <= 8 && px >= 1 && px <= 8) {
    int cell = b * 64 + (py - 1) * 8 + (px - 1);
    float s = 0.f;
#pragma unroll
    for (int z = 0; z < 4; ++z)
      s += P[((size_t)(z * 128 + co)) * 16384 + cell];
    v = fmaxf(s + bias[co], 0.f);
  }
  out[idx] = v;
}

__global__ __launch_bounds__(TPB) void conv_combine(
    const float* __restrict__ P, const float* __restrict__ bias,
    float* __restrict__ out, int Mtot, int N, int SK, int lwo, int relu)
{
  int idx = blockIdx.x * TPB + threadIdx.x;
  int mq = Mtot >> 2;
  int co = idx / mq;
  int cell0 = (idx - co * mq) << 2;
  if (co >= N) return;
  float4 s = make_float4(0.f, 0.f, 0.f, 0.f);
  for (int z = 0; z < SK; ++z) {
    const float4 pv = *reinterpret_cast<const float4*>(
        &P[((size_t)z * N + co) * Mtot + cell0]);
    s.x += pv.x; s.y += pv.y; s.z += pv.z; s.w += pv.w;
  }
  float bv = bias[co];
  s.x += bv; s.y += bv; s.z += bv; s.w += bv;
  if (relu) { s.x = fmaxf(s.x, 0.f); s.y = fmaxf(s.y, 0.f);
              s.z = fmaxf(s.z, 0.f); s.w = fmaxf(s.w, 0.f); }
  int Wo = 1 << lwo;
  int x = cell0 & (Wo - 1), y = (cell0 >> lwo) & (Wo - 1), b = cell0 >> (lwo + lwo);
  *reinterpret_cast<float4*>(&out[(((size_t)b * N + co) * Wo + y) * Wo + x]) = s;
}

// ---------------- MFMA GEMM (BM=64, BN=64, 4 waves, split-K, prefetched) ----
template<int NS, int OUTM>
__global__ __launch_bounds__(TPB) void gemm_mf(
    const float* __restrict__ A, const float* __restrict__ W,
    const float* __restrict__ bias, void* __restrict__ outp,
    int M, int K, int N, int KSPL)
{
  constexpr int ST = (NS == 3) ? 64 : 32;
  __shared__ __align__(16) u32 L[(64 + 64) * ST];
  u32* AL = L; u32* BL = L + 64 * ST;
  const int tid = threadIdx.x;
  const int m0 = blockIdx.x << 6, n0 = blockIdx.y << 6;
  const int lane = tid & 63, wv = tid >> 6, r = lane & 15, g = lane >> 4;
  const int kb0 = blockIdx.z * KSPL;
  const int kbN = kb0 + KSPL;
  const int cl = tid & 63, oct = tid >> 6;
  f32x4 acc[4] = {};

  float vA[8], vB[8], vA2[8], vB2[8];
  auto gA = [&](int kt, float* v) {
    const float* ap = &A[(size_t)(m0 + cl) * K + kt + (oct << 3)];
    *reinterpret_cast<float4*>(&v[0]) = *reinterpret_cast<const float4*>(ap);
    *reinterpret_cast<float4*>(&v[4]) = *reinterpret_cast<const float4*>(ap + 4);
  };
  auto gB = [&](int kt, float* v) {
#pragma unroll
    for (int e = 0; e < 8; ++e)
      v[e] = W[(size_t)(kt + (oct << 3) + e) * N + n0 + cl];
  };

  gA(kb0, vA); gB(kb0, vB);
  for (int kt = kb0; kt < kbN; kt += 32) {
    const bool more = (kt + 32) < kbN;
    if (more) { gA(kt + 32, vA2); gB(kt + 32, vB2); }
    stWf<NS, ST>(AL, cl, oct, vA);
    stWf<NS, ST>(BL, cl, oct, vB);
    __syncthreads();
    short8v a_[3];
#pragma unroll
    for (int s = 0; s < NS; ++s) a_[s] = rdFrag<ST>(AL, (wv << 4) + r, (s << 2) | g);
#pragma unroll
    for (int ns = 0; ns < 4; ++ns) {
      short8v b_[3];
#pragma unroll
      for (int s = 0; s < NS; ++s) b_[s] = rdFrag<ST>(BL, (ns << 4) + r, (s << 2) | g);
      acc[ns] = __builtin_amdgcn_mfma_f32_16x16x32_bf16(a_[0], b_[0], acc[ns], 0, 0, 0);
      acc[ns] = __builtin_amdgcn_mfma_f32_16x16x32_bf16(a_[0], b_[1], acc[ns], 0, 0, 0);
      acc[ns] = __builtin_amdgcn_mfma_f32_16x16x32_bf16(a_[1], b_[0], acc[ns], 0, 0, 0);
      if (NS == 3) {
        acc[ns] = __builtin_amdgcn_mfma_f32_16x16x32_bf16(a_[1], b_[1], acc[ns], 0, 0, 0);
        acc[ns] = __builtin_amdgcn_mfma_f32_16x16x32_bf16(a_[0], b_[2], acc[ns], 0, 0, 0);
        acc[ns] = __builtin_amdgcn_mfma_f32_16x16x32_bf16(a_[2], b_[0], acc[ns], 0, 0, 0);
      }
    }
    __syncthreads();
    if (more) {
#pragma unroll
      for (int e = 0; e < 8; ++e) { vA[e] = vA2[e]; vB[e] = vB2[e]; }
    }
  }
#pragma unroll
  for (int ns = 0; ns < 4; ++ns)
#pragma unroll
    for (int q = 0; q < 4; ++q) {
      int m = m0 + (wv << 4) + (g << 2) + q;
      int n = n0 + (ns << 4) + r;
      float v = acc[ns][q];
      if (OUTM == 0) ((float*)outp)[((size_t)blockIdx.z * M + m) * N + n] = v;
      else           ((u32*)outp)[(size_t)m * N + n] = packhl(v + bias[n]);
    }
}

// ---------------- fc split-K combine ----------------------------------------
__global__ __launch_bounds__(TPB) void combine_k(
    const float* __restrict__ P, const float* __restrict__ bias,
    float* __restrict__ out, int MN, int N, int SK, int relu)
{
  int i4 = (blockIdx.x * TPB + threadIdx.x) << 2;
  if (i4 >= MN) return;
  float4 s = make_float4(0.f, 0.f, 0.f, 0.f);
  for (int z = 0; z < SK; ++z) {
    const float4 pv = *reinterpret_cast<const float4*>(&P[(size_t)z * MN + i4]);
    s.x += pv.x; s.y += pv.y; s.z += pv.z; s.w += pv.w;
  }
  int n = i4 % N;
  s.x += bias[n]; s.y += bias[n + 1]; s.z += bias[n + 2]; s.w += bias[n + 3];
  if (relu) { s.x = fmaxf(s.x, 0.f); s.y = fmaxf(s.y, 0.f);
              s.z = fmaxf(s.z, 0.f); s.w = fmaxf(s.w, 0.f); }
  *reinterpret_cast<float4*>(&out[i4]) = s;
}

// ---------------- g2 combine: sum 2 partials -> packed u32 ------------------
__global__ __launch_bounds__(TPB) void combine_pk_k(
    const float* __restrict__ P, const float* __restrict__ bias,
    u32* __restrict__ out)
{
  int i4 = (blockIdx.x * TPB + threadIdx.x) << 2;
  if (i4 >= 1048576) return;
  const float4 p0 = *reinterpret_cast<const float4*>(&P[i4]);
  const float4 p1 = *reinterpret_cast<const float4*>(&P[1048576 + i4]);
  int n = i4 % 4096;
  uint4 o;
  o.x = packhl(p0.x + p1.x + bias[n]);
  o.y = packhl(p0.y + p1.y + bias[n + 1]);
  o.z = packhl(p0.z + p1.z + bias[n + 2]);
  o.w = packhl(p0.w + p1.w + bias[n + 3]);
  *reinterpret_cast<uint4*>(&out[i4]) = o;
}

// ---------------- MFMA convT, NS=2 ------------------------------------------
template<int BM, int EMIT, int SPLITIN>
__global__ __launch_bounds__(TPB) void convt_mf2(
    const u32* __restrict__ in, const u16* __restrict__ wth,
    const u16* __restrict__ wtl, const float* __restrict__ bias,
    u32* __restrict__ outq, int Ci, int Co, int Hi, int lwi, int relu)
{
  constexpr int ST = 32, MS = BM / 64;
  constexpr int STC = BM + 4;
  constexpr int LSZ = ((BM + 64) * ST > 64 * STC) ? (BM + 64) * ST : 64 * STC;
  __shared__ __align__(16) u32 L[LSZ];
  u32* AL = L; u32* BL = L + BM * ST;
  const int Wi = Hi, K4 = Ci << 2;
  const int HW = Hi * Wi, HWq = HW >> 2, Wiq = Wi >> 1;
  const int par = blockIdx.z, py = par >> 1, px = par & 1;
  const int tid = threadIdx.x;
  const int m0 = blockIdx.x * BM, n0 = blockIdx.y << 6;
  const int lane = tid & 63, wv = tid >> 6, r = lane & 15, g = lane >> 4;
  f32x4 acc[MS][4] = {};

  const int cl  = (BM == 128) ? (tid & 127) : (tid & 63);
  const int oc0 = (BM == 128) ? (tid >> 7) : (tid >> 6);
  int offT[4]; u32 mskT[4];
  {
    int cell = m0 + cl;
    int X = cell & (Wi - 1), Y = (cell >> lwi) & (Wi - 1), b = cell >> (lwi + lwi);
#pragma unroll
    for (int t = 0; t < 4; ++t) {
      int ay = t >> 1, ax = t & 1;
      int gy = Y + py - ay, gx = X + px - ax;
      bool ok = (gy >= 0 && gy < Hi && gx >= 0 && gx < Wi);
      int gyc = min(max(gy, 0), Hi - 1), gxc = min(max(gx, 0), Wi - 1);
      if (SPLITIN) {
        int q = ((gyc & 1) << 1) | (gxc & 1);
        offT[t] = q * (256 * Ci * HWq) + b * Ci * HWq + (gyc >> 1) * Wiq + (gxc >> 1);
      } else {
        offT[t] = b * Ci * HW + gyc * Wi + gxc;
      }
      mskT[t] = ok ? 0xffffffffu : 0u;
    }
  }
  const int stepCi = SPLITIN ? HWq : HW;

  auto gA = [&](int kb, u32 v[][8]) {
#pragma unroll
    for (int p = 0; p < MS; ++p) {
      int oc = oc0 + (p << 1);
      int cibase = ((kb >> 2) + (oc << 1)) * stepCi;
#pragma unroll
      for (int e = 0; e < 8; ++e) {
        int t = e & 3;
        v[p][e] = in[offT[t] + cibase + ((e >> 2) ? stepCi : 0)] & mskT[t];
      }
    }
  };
  auto gB = [&](int kb, uint4* d) {
    int n = tid & 63, oc2 = tid >> 6;
    size_t base = (size_t)(par * Co + n0 + n) * K4 + kb + (oc2 << 3);
    d[0] = *reinterpret_cast<const uint4*>(wth + base);
    d[1] = *reinterpret_cast<const uint4*>(wtl + base);
  };

  u32 vA[MS][8], vA2[MS][8];
  uint4 vB[2], vB2[2];
  gA(0, vA); gB(0, vB);
  for (int kb = 0; kb < K4; kb += 32) {
    const bool more = (kb + 32) < K4;
    if (more) { gA(kb + 32, vA2); gB(kb + 32, vB2); }
#pragma unroll
    for (int p = 0; p < MS; ++p) {
      const u32* v = vA[p];
      const int sw = cl & 7;
      int oc = oc0 + (p << 1);
      uint4 dh, dl;
      dh.x = (v[0] & 0xffffu) | (v[1] << 16);  dl.x = (v[0] >> 16) | (v[1] & 0xffff0000u);
      dh.y = (v[2] & 0xffffu) | (v[3] << 16);  dl.y = (v[2] >> 16) | (v[3] & 0xffff0000u);
      dh.z = (v[4] & 0xffffu) | (v[5] << 16);  dl.z = (v[4] >> 16) | (v[5] & 0xffff0000u);
      dh.w = (v[6] & 0xffffu) | (v[7] << 16);  dl.w = (v[6] >> 16) | (v[7] & 0xffff0000u);
      *reinterpret_cast<uint4*>(&AL[cl * ST + ((oc ^ sw) << 2)]) = dh;
      *reinterpret_cast<uint4*>(&AL[cl * ST + (((4 | oc) ^ sw) << 2)]) = dl;
    }
    {
      int n = tid & 63, oc2 = tid >> 6;
      stWp<ST>(BL, n, oc2, 0, vB[0]);
      stWp<ST>(BL, n, oc2, 1, vB[1]);
    }
    __syncthreads();
    short8v a_[MS][2];
#pragma unroll
    for (int mm = 0; mm < MS; ++mm)
#pragma unroll
      for (int s = 0; s < 2; ++s)
        a_[mm][s] = rdFrag<ST>(AL, (wv * MS + mm) * 16 + r, (s << 2) | g);
#pragma unroll
    for (int ns = 0; ns < 4; ++ns) {
      short8v b_[2];
#pragma unroll
      for (int s = 0; s < 2; ++s) b_[s] = rdFrag<ST>(BL, (ns << 4) + r, (s << 2) | g);
#pragma unroll
      for (int mm = 0; mm < MS; ++mm) {
        acc[mm][ns] = __builtin_amdgcn_mfma_f32_16x16x32_bf16(a_[mm][0], b_[0], acc[mm][ns], 0, 0, 0);
        acc[mm][ns] = __builtin_amdgcn_mfma_f32_16x16x32_bf16(a_[mm][0], b_[1], acc[mm][ns], 0, 0, 0);
        acc[mm][ns] = __builtin_amdgcn_mfma_f32_16x16x32_bf16(a_[mm][1], b_[0], acc[mm][ns], 0, 0, 0);
      }
    }
    __syncthreads();
    if (more) {
#pragma unroll
      for (int p = 0; p < MS; ++p)
#pragma unroll
        for (int e = 0; e < 8; ++e) vA[p][e] = vA2[p][e];
      vB[0] = vB2[0]; vB[1] = vB2[1];
    }
  }
#pragma unroll
  for (int mm = 0; mm < MS; ++mm)
#pragma unroll
    for (int ns = 0; ns < 4; ++ns)
#pragma unroll
      for (int q = 0; q < 4; ++q) {
        int cell = (wv * MS + mm) * 16 + (g << 2) + q;
        int col = (ns << 4) + r;
        float v = acc[mm][ns][q] + bias[n0 + col];
        if (relu) v = fmaxf(v, 0.f);
        L[col * STC + cell] = EMIT ? packhl(v) : __float_as_uint(v);
      }
  __syncthreads();
  const size_t QO = (size_t)256 * Co * HW;
  u32* op = outq + (size_t)par * QO;
  constexpr int C4N = BM / 4;
  constexpr int NCH = (BM * 64) / (TPB * 4);
#pragma unroll
  for (int it = 0; it < NCH; ++it) {
    int lin = it * TPB + tid;
    int c4 = lin & (C4N - 1);
    int col = lin / C4N;
    int cell0 = c4 << 2;
    uint4 d = *reinterpret_cast<const uint4*>(&L[col * STC + cell0]);
    int gc = m0 + cell0;
    int Xo = gc & (Wi - 1), Yo = (gc >> lwi) & (Wi - 1), bo = gc >> (lwi + lwi);
    *reinterpret_cast<uint4*>(
        &op[((size_t)(bo * Co + n0 + col) * Hi + Yo) * Wi + Xo]) = d;
  }
}

// ---------------- dedicated t3 ----------------------------------------------
__global__ __launch_bounds__(TPB) void convt3_kernel(
    const float* __restrict__ inq, const float* __restrict__ w,
    float* __restrict__ part)
{
  __shared__ float wl[3072];
  __shared__ float il[8][33 * 32];
  const int b = blockIdx.x;
  const int z = blockIdx.y;
  const int tid = threadIdx.x;
  for (int i = tid; i < 3072; i += TPB) wl[i] = w[i];
  const int Y = tid >> 3;
  const int X0 = (tid & 7) << 2;
  float acc[3][2][8];
#pragma unroll
  for (int o = 0; o < 3; ++o)
#pragma unroll
    for (int p = 0; p < 2; ++p)
#pragma unroll
      for (int q = 0; q < 8; ++q) acc[o][p][q] = 0.f;

  const int cbeg = z << 5, cend = cbeg + 32;
  for (int c0 = cbeg; c0 < cend; c0 += 8) {
    __syncthreads();
    for (int i = tid; i < 8192; i += TPB) {
      int cc = i >> 10, yy = (i >> 5) & 31, xx = i & 31;
      int q = ((yy & 1) << 1) | (xx & 1);
      il[cc][yy * 33 + xx] = inq[(size_t)q * 4194304 +
          (((size_t)b * 64 + c0 + cc) * 16 + (yy >> 1)) * 16 + (xx >> 1)];
    }
    __syncthreads();
    for (int cc = 0; cc < 8; ++cc) {
      float iv[3][6];
#pragma unroll
      for (int j = 0; j < 3; ++j) {
        int gy = Y - 1 + j;
        int gyc = min(max(gy, 0), 31);
        float my = (gy >= 0 && gy < 32) ? 1.f : 0.f;
#pragma unroll
        for (int k = 0; k < 6; ++k) {
          int gx = X0 - 1 + k;
          int gxc = min(max(gx, 0), 31);
          float mx = (gx >= 0 && gx < 32) ? 1.f : 0.f;
          iv[j][k] = il[cc][gyc * 33 + gxc] * (my * mx);
        }
      }
      const float* wq = &wl[(c0 + cc) * 48];
#pragma unroll
      for (int o = 0; o < 3; ++o) {
        const float* wo = wq + o * 16;
#pragma unroll
        for (int c = 0; c < 4; ++c) {
          acc[o][0][2*c]   = fmaf(iv[1][c+1], wo[5],  acc[o][0][2*c]);
          acc[o][0][2*c]   = fmaf(iv[1][c],   wo[7],  acc[o][0][2*c]);
          acc[o][0][2*c]   = fmaf(iv[0][c+1], wo[13], acc[o][0][2*c]);
          acc[o][0][2*c]   = fmaf(iv[0][c],   wo[15], acc[o][0][2*c]);
          acc[o][0][2*c+1] = fmaf(iv[1][c+2], wo[4],  acc[o][0][2*c+1]);
          acc[o][0][2*c+1] = fmaf(iv[1][c+1], wo[6],  acc[o][0][2*c+1]);
          acc[o][0][2*c+1] = fmaf(iv[0][c+2], wo[12], acc[o][0][2*c+1]);
          acc[o][0][2*c+1] = fmaf(iv[0][c+1], wo[14], acc[o][0][2*c+1]);
          acc[o][1][2*c]   = fmaf(iv[2][c+1], wo[1],  acc[o][1][2*c]);
          acc[o][1][2*c]   = fmaf(iv[2][c],   wo[3],  acc[o][1][2*c]);
          acc[o][1][2*c]   = fmaf(iv[1][c+1], wo[9],  acc[o][1][2*c]);
          acc[o][1][2*c]   = fmaf(iv[1][c],   wo[11], acc[o][1][2*c]);
          acc[o][1][2*c+1] = fmaf(iv[2][c+2], wo[0],  acc[o][1][2*c+1]);
          acc[o][1][2*c+1] = fmaf(iv[2][c+1], wo[2],  acc[o][1][2*c+1]);
          acc[o][1][2*c+1] = fmaf(iv[1][c+2], wo[8],  acc[o][1][2*c+1]);
          acc[o][1][2*c+1] = fmaf(iv[1][c+1], wo[10], acc[o][1][2*c+1]);
        }
      }
    }
  }
  float* pz = part + (size_t)z * 3145728;
#pragma unroll
  for (int o = 0; o < 3; ++o) {
#pragma unroll
    for (int p = 0; p < 2; ++p) {
      float* op = pz + (((size_t)b * 3 + o) * 64 + 2 * Y + p) * 64 + 2 * X0;
      *reinterpret_cast<float4*>(op) =
          make_float4(acc[o][p][0], acc[o][p][1], acc[o][p][2], acc[o][p][3]);
      *reinterpret_cast<float4*>(op + 4) =
          make_float4(acc[o][p][4], acc[o][p][5], acc[o][p][6], acc[o][p][7]);
    }
  }
}

__global__ __launch_bounds__(TPB) void c3_combine(
    const float* __restrict__ part, const float* __restrict__ bias,
    float* __restrict__ out)
{
  int i4 = (blockIdx.x * TPB + threadIdx.x) << 2;
  const float4 p0 = *reinterpret_cast<const float4*>(&part[i4]);
  const float4 p1 = *reinterpret_cast<const float4*>(&part[i4 + 3145728]);
  int o = (i4 >> 12) % 3;
  float bv = bias[o];
  float4 s = make_float4(p0.x + p1.x + bv, p0.y + p1.y + bv,
                         p0.z + p1.z + bv, p0.w + p1.w + bv);
  *reinterpret_cast<float4*>(&out[i4]) = s;
}

// ---------------- VQ ---------------------------------------------------------
__global__ __launch_bounds__(TPB) void vq_kernel(
    const float* __restrict__ z, const float* __restrict__ cb,
    float* __restrict__ e, float* __restrict__ rowloss)
{
  const int row = blockIdx.x;
  const int b = row >> 4, s = row & 15;
  __shared__ float zr[64];
  __shared__ float bval[TPB];
  __shared__ int   bidx[TPB];
  const int tid = threadIdx.x;
  if (tid < 64) zr[tid] = z[(size_t)b * 1536 + s * 64 + tid];
  __syncthreads();

  float best = 3.4e38f;
  int bi = 0;
#pragma unroll
  for (int rep = 0; rep < 2; ++rep) {
    int j = tid + rep * TPB;
    const float4* c4 = reinterpret_cast<const float4*>(cb + (size_t)j * 64);
    float d = 0.f;
#pragma unroll
    for (int k = 0; k < 16; ++k) {
      float4 cv = c4[k];
      float t0 = zr[4 * k + 0] - cv.x;
      float t1 = zr[4 * k + 1] - cv.y;
      float t2 = zr[4 * k + 2] - cv.z;
      float t3 = zr[4 * k + 3] - cv.w;
      d = fmaf(t0, t0, d); d = fmaf(t1, t1, d);
      d = fmaf(t2, t2, d); d = fmaf(t3, t3, d);
    }
    if (d < best) { best = d; bi = j; }
  }
  bval[tid] = best; bidx[tid] = bi;
  __syncthreads();
  for (int sft = 128; sft > 0; sft >>= 1) {
    if (tid < sft) {
      float v2 = bval[tid + sft]; int i2 = bidx[tid + sft];
      if (v2 < bval[tid] || (v2 == bval[tid] && i2 < bidx[tid])) {
        bval[tid] = v2; bidx[tid] = i2;
      }
    }
    __syncthreads();
  }
  const int bj = bidx[0];
  if (tid < 64)
    e[(size_t)b * 1536 + s * 64 + tid] = cb[(size_t)bj * 64 + tid];
  if (tid == 0) rowloss[row] = bval[0];
}

__global__ __launch_bounds__(TPB) void zs_copy_kernel(
    const float* __restrict__ z, float* __restrict__ e)
{
  int i = blockIdx.x * TPB + threadIdx.x;
  int b = i >> 9, k = i & 511;
  e[(size_t)b * 1536 + 1024 + k] = z[(size_t)b * 1536 + 1024 + k];
}

__global__ __launch_bounds__(TPB) void loss_reduce_kernel(
    const float* __restrict__ rl, float* __restrict__ out)
{
  __shared__ float sm[TPB];
  float s = 0.f;
  for (int i = threadIdx.x; i < 4096; i += TPB) s += rl[i];
  sm[threadIdx.x] = s;
  __syncthreads();
  for (int sft = 128; sft > 0; sft >>= 1) {
    if (threadIdx.x < sft) sm[threadIdx.x] += sm[threadIdx.x + sft];
    __syncthreads();
  }
  if (threadIdx.x == 0) out[0] = sm[0] * (1.25f / 262144.f);
}

// ============================================================================
extern "C" void kernel_launch(void* const* d_in, const int* in_sizes, int n_in,
                              void* d_out, int out_size, void* d_ws, size_t ws_size,
                              hipStream_t stream)
{
  const float* x    = (const float*)d_in[0];
  const float* ew0  = (const float*)d_in[1];
  const float* eb0  = (const float*)d_in[2];
  const float* ew1  = (const float*)d_in[3];
  const float* eb1  = (const float*)d_in[4];
  const float* ew2  = (const float*)d_in[5];
  const float* eb2  = (const float*)d_in[6];
  const float* ew3  = (const float*)d_in[7];
  const float* eb3  = (const float*)d_in[8];
  const float* fw0  = (const float*)d_in[9];
  const float* fb0  = (const float*)d_in[10];
  const float* fw1  = (const float*)d_in[11];
  const float* fb1  = (const float*)d_in[12];
  const float* fw2  = (const float*)d_in[13];
  const float* fb2  = (const float*)d_in[14];
  const float* cb   = (const float*)d_in[15];
  const float* gw0  = (const float*)d_in[16];
  const float* gb0  = (const float*)d_in[17];
  const float* gw1  = (const float*)d_in[18];
  const float* gb1  = (const float*)d_in[19];
  const float* gw2  = (const float*)d_in[20];
  const float* gb2  = (const float*)d_in[21];
  const float* tw0  = (const float*)d_in[22];
  const float* tb0  = (const float*)d_in[23];
  const float* tw1  = (const float*)d_in[24];
  const float* tb1  = (const float*)d_in[25];
  const float* tw2  = (const float*)d_in[26];
  const float* tb2  = (const float*)d_in[27];
  const float* tw3  = (const float*)d_in[28];
  const float* tb3  = (const float*)d_in[29];

  float* out = (float*)d_out;
  float* ws  = (float*)d_ws;

  // ---- workspace plan (float offsets; time-disjoint regions) ----
  u16*   WE0  = (u16*)(ws + 0);
  u16*   WE1  = (u16*)(ws + 4608);
  u16*   WE2  = (u16*)(ws + 102912);
  u16*   WE3  = (u16*)(ws + 299520);
  float* RL   = ws + 1085952;
  float* H0P  = ws + 1090048;
  float* PC1  = ws + 20029952;
  float* XP   = ws + 20029952;
  float* H1P  = ws + 1090048;
  float* PC23 = ws + 6398464;
  float* H2P  = ws + 14787072;
  float* H3   = ws + 18063872;
  float* P    = ws + 1090048;
  float* F0   = ws + 5284352;
  float* F1   = ws + 5546496;
  float* Z    = ws + 5808640;
  float* E    = ws + 6201856;
  float* G0   = ws + 6595072;
  float* G1   = ws + 6726144;
  float* T2S  = ws + 1090048;
  u16*   WT0h = (u16*)(ws + 17867264);
  u16*   WT0l = (u16*)(ws + 18129408);
  u16*   WT1h = (u16*)(ws + 18391552);
  u16*   WT1l = (u16*)(ws + 18457088);
  u16*   WT2h = (u16*)(ws + 18522624);
  u16*   WT2l = (u16*)(ws + 18555392);
  float* PG2  = ws + 18588160;
  u32*   G2P  = (u32*)(ws + 20685312);
  u32*   T0S  = (u32*)(ws + 21733888);
  u32*   T1S  = (u32*)(ws + 23831040);
  float* PT3  = ws + 18588160;

  // ---- encoder weight prep + input pad ----
  wsplit3_k<<<dim3(12),  TPB, 0, stream>>>(ew0, WE0, 3072);
  wsplit3_k<<<dim3(256), TPB, 0, stream>>>(ew1, WE1, 65536);
  wsplit3_k<<<dim3(512), TPB, 0, stream>>>(ew2, WE2, 131072);
  wsplit3_k<<<dim3(1024),TPB, 0, stream>>>(ew3, WE3, 524288);
  x_pad_k<<<dim3(13068), TPB, 0, stream>>>(x, XP);
  zb0_k<<<dim3(8448), TPB, 0, stream>>>(H0P);

  // ---- encoder convs (A-direct MFMA NS=3) ----
  conv_ad<4,0><<<dim3(1024, 1, 1), TPB, 0, stream>>>(
      XP, WE0, eb0, H0P, 3, 64, 64, 5, 1, 48, 3072, 13068, 4356, 0);
  conv_ad<4,1><<<dim3(256, 1, 2), TPB, 0, stream>>>(
      H0P, WE1, eb1, PC1, 64, 64, 32, 4, 1, 512, 65536, 73984, 1156, 65536);
  combine_cm_k<<<dim3(20736), TPB, 0, stream>>>(PC1, eb1, H1P);
  conv_ad<4,1><<<dim3(64, 2, 4), TPB, 0, stream>>>(
      H1P, WE2, eb2, PC23, 64, 128, 16, 3, 1, 256, 131072, 324, 82944, 16384);
  combine_pad_k<<<dim3(12800), TPB, 0, stream>>>(PC23, eb2, H2P);
  conv_ad<4,1><<<dim3(16, 4, 8), TPB, 0, stream>>>(
      H2P, WE3, eb3, PC23, 128, 256, 8, 2, 0, 256, 524288, 12800, 100, 4096);
  conv_combine<<<dim3(1024), TPB, 0, stream>>>(PC23, eb3, H3, 4096, 256, 8, 2, 0);

  // ---- encoder FC (MFMA NS=3, split-K + combine) ----
  gemm_mf<3,0><<<dim3(4, 16, 16), TPB, 0, stream>>>(H3, fw0, fb0, (void*)P, 256, 4096, 1024, 256);
  combine_k<<<dim3(256), TPB, 0, stream>>>(P, fb0, F0, 262144, 1024, 16, 1);
  gemm_mf<3,0><<<dim3(4, 16, 8), TPB, 0, stream>>>(F0, fw1, fb1, (void*)P, 256, 1024, 1024, 128);
  combine_k<<<dim3(256), TPB, 0, stream>>>(P, fb1, F1, 262144, 1024, 8, 1);
  gemm_mf<3,0><<<dim3(4, 24, 8), TPB, 0, stream>>>(F1, fw2, fb2, (void*)P, 256, 1024, 1536, 128);
  combine_k<<<dim3(384), TPB, 0, stream>>>(P, fb2, Z, 393216, 1536, 8, 0);

  // ---- VQ ----
  vq_kernel<<<dim3(4096), TPB, 0, stream>>>(Z, cb, E, RL);
  zs_copy_kernel<<<dim3(512), TPB, 0, stream>>>(Z, E);
  loss_reduce_kernel<<<dim3(1), TPB, 0, stream>>>(RL, out + (size_t)out_size - 1);

  // ---- decoder FC: g0/g1 now MFMA NS=2 split-K + combine ----
  gemm_mf<2,0><<<dim3(4, 8, 8), TPB, 0, stream>>>(E,  gw0, gb0, (void*)P, 256, 1536, 512, 192);
  combine_k<<<dim3(128), TPB, 0, stream>>>(P, gb0, G0, 131072, 512, 8, 1);
  gemm_mf<2,0><<<dim3(4, 16, 4), TPB, 0, stream>>>(G0, gw1, gb1, (void*)P, 256, 512, 1024, 128);
  combine_k<<<dim3(256), TPB, 0, stream>>>(P, gb1, G1, 262144, 1024, 4, 1);

  // ---- decoder weight prep ----
  wprep2_k<<<dim3(512), TPB, 0, stream>>>(tw0, WT0h, WT0l, 256, 128);
  wprep2_k<<<dim3(128), TPB, 0, stream>>>(tw1, WT1h, WT1l, 128, 64);
  wprep2_k<<<dim3(64),  TPB, 0, stream>>>(tw2, WT2h, WT2l, 64, 64);

  // g2: split-K z2 -> PG2; combine -> packed G2P
  gemm_mf<2,0><<<dim3(4, 64, 2), TPB, 0, stream>>>(G1, gw2, gb2, (void*)PG2, 256, 1024, 4096, 512);
  combine_pk_k<<<dim3(1024), TPB, 0, stream>>>(PG2, gb2, G2P);

  // ---- decoder transposed convs (MFMA NS=2, quadrant layouts) ----
  convt_mf2<64,1,0><<<dim3(64, 2, 4),   TPB, 0, stream>>>(G2P, WT0h, WT0l, tb0, T0S, 256, 128, 4,  2, 1);
  convt_mf2<128,1,1><<<dim3(128, 1, 4), TPB, 0, stream>>>(T0S, WT1h, WT1l, tb1, T1S, 128, 64,  8,  3, 1);
  convt_mf2<128,0,1><<<dim3(512, 1, 4), TPB, 0, stream>>>(T1S, WT2h, WT2l, tb2, (u32*)T2S, 64, 64, 16, 4, 1);
  convt3_kernel<<<dim3(256, 2), TPB, 0, stream>>>(T2S, tw3, PT3);
  c3_combine<<<dim3(3072), TPB, 0, stream>>>(PT3, tb3, out);
}

// Round 11
// 532.047 us; speedup vs baseline: 14.6552x; 1.0620x over previous
//
#include <hip/hip_runtime.h>
#include <hip/hip_bf16.h>

// ============================================================================
// VQ-VAE forward, round 11: R10 +
//  (1) vq8_kernel: 8 rows/block, codebook staged transposed in LDS
//      (conflict-free), wave-parallel distance scan + shfl argmin reduce.
//      Replaces 4096-block uncoalesced vq (63us, 11% VALU).
//  (2) convt_mf2 epilogue split into two 32-col phases reusing the main LDS
//      region: LDS 33792 -> 24576 B => 6 blocks/CU (was 4).
// Everything else identical to R10.
// ============================================================================

#define TPB 256
typedef __attribute__((ext_vector_type(8))) short short8v;
typedef __attribute__((ext_vector_type(4))) float f32x4;
typedef unsigned int u32;
typedef unsigned short u16;

__device__ inline u16 f2bf(float x){
  union { __hip_bfloat16 b; u16 u; } cv;
  cv.b = __float2bfloat16(x);
  return cv.u;
}
__device__ inline float bf2f(u16 h){ union{u32 u;float f;}v; v.u=((u32)h)<<16; return v.f;}
__device__ inline u32 packhl(float x){ u16 h=f2bf(x); u16 l=f2bf(x-bf2f(h)); return ((u32)l<<16)|(u32)h;}

template<int NS>
__device__ inline void splitN(float x, u16 t[3]) {
  u16 h0 = f2bf(x); t[0] = h0;
  float r1 = x - bf2f(h0);
  u16 h1 = f2bf(r1); t[1] = h1;
  if (NS == 3) { float r2 = r1 - bf2f(h1); t[2] = f2bf(r2); }
}

template<int NS, int ST>
__device__ inline void stW(u32* L, int row, int oct, const u16 hs[3][8]) {
  constexpr int SWM = (ST == 64) ? 15 : 7;
  const int sw = row & SWM;
#pragma unroll
  for (int s = 0; s < NS; ++s) {
    uint4 d;
    d.x = (u32)hs[s][0] | ((u32)hs[s][1] << 16);
    d.y = (u32)hs[s][2] | ((u32)hs[s][3] << 16);
    d.z = (u32)hs[s][4] | ((u32)hs[s][5] << 16);
    d.w = (u32)hs[s][6] | ((u32)hs[s][7] << 16);
    int ch = (((s << 2) | oct) ^ sw) << 2;
    *reinterpret_cast<uint4*>(&L[row * ST + ch]) = d;
  }
}

template<int NS, int ST>
__device__ inline void stWf(u32* L, int row, int oct, const float v[8]) {
  u16 hs[3][8];
#pragma unroll
  for (int e = 0; e < 8; ++e) {
    u16 t3[3]; splitN<NS>(v[e], t3);
    hs[0][e] = t3[0]; hs[1][e] = t3[1]; if (NS == 3) hs[2][e] = t3[2];
  }
  stW<NS, ST>(L, row, oct, hs);
}

template<int ST>
__device__ inline void stWp(u32* L, int row, int oct, int s, uint4 d) {
  constexpr int SWM = (ST == 64) ? 15 : 7;
  int ch = (((s << 2) | oct) ^ (row & SWM)) << 2;
  *reinterpret_cast<uint4*>(&L[row * ST + ch]) = d;
}

template<int ST>
__device__ inline short8v rdFrag(const u32* L, int row, int c) {
  constexpr int SWM = (ST == 64) ? 15 : 7;
  int ph = (c ^ (row & SWM)) << 2;
  return *reinterpret_cast<const short8v*>(&L[row * ST + ph]);
}

// ---------------- weight prep -----------------------------------------------
__global__ __launch_bounds__(TPB) void wsplit3_k(
    const float* __restrict__ src, u16* __restrict__ dst, int n)
{
  for (int i = blockIdx.x * TPB + threadIdx.x; i < n; i += gridDim.x * TPB) {
    u16 t3[3]; splitN<3>(src[i], t3);
    dst[i] = t3[0]; dst[i + n] = t3[1]; dst[i + 2 * n] = t3[2];
  }
}
__global__ __launch_bounds__(TPB) void wprep2_k(
    const float* __restrict__ src, u16* __restrict__ dh, u16* __restrict__ dl,
    int Ci, int Co)
{
  int K4 = Ci << 2;
  int tot = 4 * Co * K4;
  for (int i = blockIdx.x * TPB + threadIdx.x; i < tot; i += gridDim.x * TPB) {
    int par = i / (Co * K4); int rem = i - par * (Co * K4);
    int co = rem / K4; int k4 = rem - co * K4;
    int ci = k4 >> 2, ay = (k4 >> 1) & 1, ax = k4 & 1;
    int py = par >> 1, px = par & 1;
    int widx = ((1 - py) << 2) + (1 - px) + (ay << 3) + (ax << 1);
    float x = src[(((size_t)ci * Co + co) << 4) + widx];
    u16 h = f2bf(x);
    dh[i] = h; dl[i] = f2bf(x - bf2f(h));
  }
}

// ---------------- input pad / border-zero ------------------------------------
__global__ __launch_bounds__(TPB) void x_pad_k(
    const float* __restrict__ x, float* __restrict__ xp)
{
  int idx = blockIdx.x * TPB + threadIdx.x;
  if (idx >= 3345408) return;
  int px = idx % 66; int t = idx / 66; int py = t % 66; int p = t / 66;
  float v = 0.f;
  if (py >= 1 && py <= 64 && px >= 1 && px <= 64)
    v = x[(size_t)p * 4096 + (py - 1) * 64 + (px - 1)];
  xp[idx] = v;
}
__global__ __launch_bounds__(TPB) void zb0_k(float* __restrict__ h0p)
{
  int idx = blockIdx.x * TPB + threadIdx.x;
  if (idx >= 2162688) return;
  int p = idx / 132, k = idx % 132;
  int py, px;
  if (k < 34)       { py = 0;           px = k; }
  else if (k < 68)  { py = 33;          px = k - 34; }
  else if (k < 100) { py = k - 68 + 1;  px = 0; }
  else              { py = k - 100 + 1; px = 33; }
  h0p[(size_t)p * 1156 + py * 34 + px] = 0.f;
}

// ---------------- A-direct MFMA conv (s2,k4,p1), NS=3 ------------------------
template<int RM, int OUTM>
__global__ __launch_bounds__(TPB, 2) void conv_ad(
    const float* __restrict__ in, const u16* __restrict__ wsp,
    const float* __restrict__ bias, float* __restrict__ outp,
    int Ci, int Co, int Wi, int lwo, int relu, int KSPL, int PS,
    int bS, int ciS, int Mtot)
{
  constexpr int BM = RM * 64;
  __shared__ __align__(16) u32 BL[2][64 * 64];
  const int K = Ci << 4;
  const int PW = Wi + 2;
  const int Wo = Wi >> 1;
  const int tid = threadIdx.x;
  const int m0 = blockIdx.x * BM, n0 = blockIdx.y << 6;
  const int lane = tid & 63, wv = tid >> 6, r = lane & 15, g = lane >> 4;
  const int kb0 = blockIdx.z * KSPL;
  const int kbN = min(kb0 + KSPL, K);
  const int khsel = g & 1;
  const int cig = g >> 1;
  f32x4 acc[RM][4] = {};

  int base[RM];
#pragma unroll
  for (int mm = 0; mm < RM; ++mm) {
    int cell = m0 + (wv * RM + mm) * 16 + r;
    int x = cell & (Wo - 1), y = (cell >> lwo) & (Wo - 1), b = cell >> (lwo + lwo);
    base[mm] = b * bS + (2 * y + 2 * khsel) * PW + 2 * x;
  }

  auto gA = [&](int kb, float v[RM][8]) {
    if ((kb + (g << 3)) < K) {
      int cioff = ((kb >> 4) + cig) * ciS;
#pragma unroll
      for (int mm = 0; mm < RM; ++mm) {
        const float* p = in + base[mm] + cioff;
#pragma unroll
        for (int e = 0; e < 8; ++e)
          v[mm][e] = p[(e >> 2) * PW + (e & 3)];
      }
    } else {
#pragma unroll
      for (int mm = 0; mm < RM; ++mm)
#pragma unroll
        for (int e = 0; e < 8; ++e) v[mm][e] = 0.f;
    }
  };
  auto gB = [&](int kb, uint4* d) {
    int n = tid & 63, oc2 = tid >> 6;
    int k8 = kb + (oc2 << 3);
    if (k8 < K) {
      const u16* wp = wsp + (size_t)(n0 + n) * K + k8;
      d[0] = *reinterpret_cast<const uint4*>(wp);
      d[1] = *reinterpret_cast<const uint4*>(wp + PS);
      d[2] = *reinterpret_cast<const uint4*>(wp + 2 * PS);
    } else {
      d[0] = d[1] = d[2] = make_uint4(0u, 0u, 0u, 0u);
    }
  };
  auto mkfrags = [&](const float v[8], short8v f[3]) {
    u16 hs[3][8];
#pragma unroll
    for (int e = 0; e < 8; ++e) {
      u16 t3[3]; splitN<3>(v[e], t3);
      hs[0][e] = t3[0]; hs[1][e] = t3[1]; hs[2][e] = t3[2];
    }
#pragma unroll
    for (int s = 0; s < 3; ++s) {
      union { u16 u[8]; short8v sv; } cv;
#pragma unroll
      for (int e = 0; e < 8; ++e) cv.u[e] = hs[s][e];
      f[s] = cv.sv;
    }
  };

  float vA[RM][8], vA2[RM][8];
  uint4 vB[3], vB2[3];
  gA(kb0, vA); gB(kb0, vB);
  for (int kb = kb0; kb < kbN; kb += 32) {
    u32* BLc = BL[((kb - kb0) >> 5) & 1];
    {
      int n = tid & 63, oc2 = tid >> 6;
      stWp<64>(BLc, n, oc2, 0, vB[0]);
      stWp<64>(BLc, n, oc2, 1, vB[1]);
      stWp<64>(BLc, n, oc2, 2, vB[2]);
    }
    const bool more = (kb + 32) < kbN;
    if (more) { gB(kb + 32, vB2); gA(kb + 32, vA2); }
    short8v a_[RM][3];
#pragma unroll
    for (int mm = 0; mm < RM; ++mm) mkfrags(vA[mm], a_[mm]);
    __syncthreads();
#pragma unroll
    for (int ns = 0; ns < 4; ++ns) {
      short8v b_[3];
#pragma unroll
      for (int s = 0; s < 3; ++s) b_[s] = rdFrag<64>(BLc, (ns << 4) + r, (s << 2) | g);
#pragma unroll
      for (int mm = 0; mm < RM; ++mm) {
        acc[mm][ns] = __builtin_amdgcn_mfma_f32_16x16x32_bf16(a_[mm][0], b_[0], acc[mm][ns], 0, 0, 0);
        acc[mm][ns] = __builtin_amdgcn_mfma_f32_16x16x32_bf16(a_[mm][0], b_[1], acc[mm][ns], 0, 0, 0);
        acc[mm][ns] = __builtin_amdgcn_mfma_f32_16x16x32_bf16(a_[mm][1], b_[0], acc[mm][ns], 0, 0, 0);
        acc[mm][ns] = __builtin_amdgcn_mfma_f32_16x16x32_bf16(a_[mm][1], b_[1], acc[mm][ns], 0, 0, 0);
        acc[mm][ns] = __builtin_amdgcn_mfma_f32_16x16x32_bf16(a_[mm][0], b_[2], acc[mm][ns], 0, 0, 0);
        acc[mm][ns] = __builtin_amdgcn_mfma_f32_16x16x32_bf16(a_[mm][2], b_[0], acc[mm][ns], 0, 0, 0);
      }
    }
    if (more) {
#pragma unroll
      for (int mm = 0; mm < RM; ++mm)
#pragma unroll
        for (int e = 0; e < 8; ++e) vA[mm][e] = vA2[mm][e];
#pragma unroll
      for (int s = 0; s < 3; ++s) vB[s] = vB2[s];
    }
  }
#pragma unroll
  for (int mm = 0; mm < RM; ++mm)
#pragma unroll
    for (int ns = 0; ns < 4; ++ns) {
      int c0 = m0 + (wv * RM + mm) * 16 + (g << 2);
      int co = n0 + (ns << 4) + r;
      if (OUTM == 0) {
        float bv = bias[co];
        const int OPW = Wo + 2;
        const int OPHW = OPW * OPW;
#pragma unroll
        for (int q = 0; q < 4; ++q) {
          int cell = c0 + q;
          int x = cell & (Wo - 1), y = (cell >> lwo) & (Wo - 1), b = cell >> (lwo + lwo);
          float v = acc[mm][ns][q] + bv;
          if (relu) v = fmaxf(v, 0.f);
          outp[((size_t)(b * Co + co)) * OPHW + (y + 1) * OPW + (x + 1)] = v;
        }
      } else {
        float4 o;
        o.x = acc[mm][ns][0]; o.y = acc[mm][ns][1];
        o.z = acc[mm][ns][2]; o.w = acc[mm][ns][3];
        *reinterpret_cast<float4*>(
            &outp[((size_t)(blockIdx.z * Co + co)) * Mtot + c0]) = o;
      }
    }
}

// ---------------- conv combines ----------------------------------------------
__global__ __launch_bounds__(TPB) void combine_cm_k(
    const float* __restrict__ P, const float* __restrict__ bias,
    float* __restrict__ out)
{
  int idx = blockIdx.x * TPB + threadIdx.x;
  if (idx >= 5308416) return;
  int px = idx % 18; int t = idx / 18; int py = t % 18; t /= 18;
  int b = t % 256; int co = t / 256;
  float v = 0.f;
  if (py >= 1 && py <= 16 && px >= 1 && px <= 16) {
    int cell = b * 256 + (py - 1) * 16 + (px - 1);
    v = P[(size_t)co * 65536 + cell] + P[(size_t)(64 + co) * 65536 + cell] + bias[co];
    v = fmaxf(v, 0.f);
  }
  out[idx] = v;
}

__global__ __launch_bounds__(TPB) void combine_pad_k(
    const float* __restrict__ P, const float* __restrict__ bias,
    float* __restrict__ out)
{
  int idx = blockIdx.x * TPB + threadIdx.x;
  if (idx >= 3276800) return;
  int px = idx % 10; int t = idx / 10; int py = t % 10; t /= 10;
  int co = t % 128; int b = t / 128;
  float v = 0.f;
  if (py >= 1 && py <= 8 && px >= 1 && px <= 8) {
    int cell = b * 64 + (py - 1) * 8 + (px - 1);
    float s = 0.f;
#pragma unroll
    for (int z = 0; z < 4; ++z)
      s += P[((size_t)(z * 128 + co)) * 16384 + cell];
    v = fmaxf(s + bias[co], 0.f);
  }
  out[idx] = v;
}

__global__ __launch_bounds__(TPB) void conv_combine(
    const float* __restrict__ P, const float* __restrict__ bias,
    float* __restrict__ out, int Mtot, int N, int SK, int lwo, int relu)
{
  int idx = blockIdx.x * TPB + threadIdx.x;
  int mq = Mtot >> 2;
  int co = idx / mq;
  int cell0 = (idx - co * mq) << 2;
  if (co >= N) return;
  float4 s = make_float4(0.f, 0.f, 0.f, 0.f);
  for (int z = 0; z < SK; ++z) {
    const float4 pv = *reinterpret_cast<const float4*>(
        &P[((size_t)z * N + co) * Mtot + cell0]);
    s.x += pv.x; s.y += pv.y; s.z += pv.z; s.w += pv.w;
  }
  float bv = bias[co];
  s.x += bv; s.y += bv; s.z += bv; s.w += bv;
  if (relu) { s.x = fmaxf(s.x, 0.f); s.y = fmaxf(s.y, 0.f);
              s.z = fmaxf(s.z, 0.f); s.w = fmaxf(s.w, 0.f); }
  int Wo = 1 << lwo;
  int x = cell0 & (Wo - 1), y = (cell0 >> lwo) & (Wo - 1), b = cell0 >> (lwo + lwo);
  *reinterpret_cast<float4*>(&out[(((size_t)b * N + co) * Wo + y) * Wo + x]) = s;
}

// ---------------- MFMA GEMM (BM=64, BN=64, 4 waves, split-K, prefetched) ----
template<int NS, int OUTM>
__global__ __launch_bounds__(TPB) void gemm_mf(
    const float* __restrict__ A, const float* __restrict__ W,
    const float* __restrict__ bias, void* __restrict__ outp,
    int M, int K, int N, int KSPL)
{
  constexpr int ST = (NS == 3) ? 64 : 32;
  __shared__ __align__(16) u32 L[(64 + 64) * ST];
  u32* AL = L; u32* BL = L + 64 * ST;
  const int tid = threadIdx.x;
  const int m0 = blockIdx.x << 6, n0 = blockIdx.y << 6;
  const int lane = tid & 63, wv = tid >> 6, r = lane & 15, g = lane >> 4;
  const int kb0 = blockIdx.z * KSPL;
  const int kbN = kb0 + KSPL;
  const int cl = tid & 63, oct = tid >> 6;
  f32x4 acc[4] = {};

  float vA[8], vB[8], vA2[8], vB2[8];
  auto gA = [&](int kt, float* v) {
    const float* ap = &A[(size_t)(m0 + cl) * K + kt + (oct << 3)];
    *reinterpret_cast<float4*>(&v[0]) = *reinterpret_cast<const float4*>(ap);
    *reinterpret_cast<float4*>(&v[4]) = *reinterpret_cast<const float4*>(ap + 4);
  };
  auto gB = [&](int kt, float* v) {
#pragma unroll
    for (int e = 0; e < 8; ++e)
      v[e] = W[(size_t)(kt + (oct << 3) + e) * N + n0 + cl];
  };

  gA(kb0, vA); gB(kb0, vB);
  for (int kt = kb0; kt < kbN; kt += 32) {
    const bool more = (kt + 32) < kbN;
    if (more) { gA(kt + 32, vA2); gB(kt + 32, vB2); }
    stWf<NS, ST>(AL, cl, oct, vA);
    stWf<NS, ST>(BL, cl, oct, vB);
    __syncthreads();
    short8v a_[3];
#pragma unroll
    for (int s = 0; s < NS; ++s) a_[s] = rdFrag<ST>(AL, (wv << 4) + r, (s << 2) | g);
#pragma unroll
    for (int ns = 0; ns < 4; ++ns) {
      short8v b_[3];
#pragma unroll
      for (int s = 0; s < NS; ++s) b_[s] = rdFrag<ST>(BL, (ns << 4) + r, (s << 2) | g);
      acc[ns] = __builtin_amdgcn_mfma_f32_16x16x32_bf16(a_[0], b_[0], acc[ns], 0, 0, 0);
      acc[ns] = __builtin_amdgcn_mfma_f32_16x16x32_bf16(a_[0], b_[1], acc[ns], 0, 0, 0);
      acc[ns] = __builtin_amdgcn_mfma_f32_16x16x32_bf16(a_[1], b_[0], acc[ns], 0, 0, 0);
      if (NS == 3) {
        acc[ns] = __builtin_amdgcn_mfma_f32_16x16x32_bf16(a_[1], b_[1], acc[ns], 0, 0, 0);
        acc[ns] = __builtin_amdgcn_mfma_f32_16x16x32_bf16(a_[0], b_[2], acc[ns], 0, 0, 0);
        acc[ns] = __builtin_amdgcn_mfma_f32_16x16x32_bf16(a_[2], b_[0], acc[ns], 0, 0, 0);
      }
    }
    __syncthreads();
    if (more) {
#pragma unroll
      for (int e = 0; e < 8; ++e) { vA[e] = vA2[e]; vB[e] = vB2[e]; }
    }
  }
#pragma unroll
  for (int ns = 0; ns < 4; ++ns)
#pragma unroll
    for (int q = 0; q < 4; ++q) {
      int m = m0 + (wv << 4) + (g << 2) + q;
      int n = n0 + (ns << 4) + r;
      float v = acc[ns][q];
      if (OUTM == 0) ((float*)outp)[((size_t)blockIdx.z * M + m) * N + n] = v;
      else           ((u32*)outp)[(size_t)m * N + n] = packhl(v + bias[n]);
    }
}

// ---------------- fc split-K combine ----------------------------------------
__global__ __launch_bounds__(TPB) void combine_k(
    const float* __restrict__ P, const float* __restrict__ bias,
    float* __restrict__ out, int MN, int N, int SK, int relu)
{
  int i4 = (blockIdx.x * TPB + threadIdx.x) << 2;
  if (i4 >= MN) return;
  float4 s = make_float4(0.f, 0.f, 0.f, 0.f);
  for (int z = 0; z < SK; ++z) {
    const float4 pv = *reinterpret_cast<const float4*>(&P[(size_t)z * MN + i4]);
    s.x += pv.x; s.y += pv.y; s.z += pv.z; s.w += pv.w;
  }
  int n = i4 % N;
  s.x += bias[n]; s.y += bias[n + 1]; s.z += bias[n + 2]; s.w += bias[n + 3];
  if (relu) { s.x = fmaxf(s.x, 0.f); s.y = fmaxf(s.y, 0.f);
              s.z = fmaxf(s.z, 0.f); s.w = fmaxf(s.w, 0.f); }
  *reinterpret_cast<float4*>(&out[i4]) = s;
}

// ---------------- g2 combine: sum 2 partials -> packed u32 ------------------
__global__ __launch_bounds__(TPB) void combine_pk_k(
    const float* __restrict__ P, const float* __restrict__ bias,
    u32* __restrict__ out)
{
  int i4 = (blockIdx.x * TPB + threadIdx.x) << 2;
  if (i4 >= 1048576) return;
  const float4 p0 = *reinterpret_cast<const float4*>(&P[i4]);
  const float4 p1 = *reinterpret_cast<const float4*>(&P[1048576 + i4]);
  int n = i4 % 4096;
  uint4 o;
  o.x = packhl(p0.x + p1.x + bias[n]);
  o.y = packhl(p0.y + p1.y + bias[n + 1]);
  o.z = packhl(p0.z + p1.z + bias[n + 2]);
  o.w = packhl(p0.w + p1.w + bias[n + 3]);
  *reinterpret_cast<uint4*>(&out[i4]) = o;
}

// ---------------- MFMA convT, NS=2; epilogue in two 32-col phases -----------
template<int BM, int EMIT, int SPLITIN>
__global__ __launch_bounds__(TPB) void convt_mf2(
    const u32* __restrict__ in, const u16* __restrict__ wth,
    const u16* __restrict__ wtl, const float* __restrict__ bias,
    u32* __restrict__ outq, int Ci, int Co, int Hi, int lwi, int relu)
{
  constexpr int ST = 32, MS = BM / 64;
  constexpr int STC = BM + 4;
  constexpr int LSZ = (BM + 64) * ST;
  static_assert(32 * STC <= LSZ, "epilogue phase must fit main LDS");
  __shared__ __align__(16) u32 L[LSZ];
  u32* AL = L; u32* BL = L + BM * ST;
  const int Wi = Hi, K4 = Ci << 2;
  const int HW = Hi * Wi, HWq = HW >> 2, Wiq = Wi >> 1;
  const int par = blockIdx.z, py = par >> 1, px = par & 1;
  const int tid = threadIdx.x;
  const int m0 = blockIdx.x * BM, n0 = blockIdx.y << 6;
  const int lane = tid & 63, wv = tid >> 6, r = lane & 15, g = lane >> 4;
  f32x4 acc[MS][4] = {};

  const int cl  = (BM == 128) ? (tid & 127) : (tid & 63);
  const int oc0 = (BM == 128) ? (tid >> 7) : (tid >> 6);
  int offT[4]; u32 mskT[4];
  {
    int cell = m0 + cl;
    int X = cell & (Wi - 1), Y = (cell >> lwi) & (Wi - 1), b = cell >> (lwi + lwi);
#pragma unroll
    for (int t = 0; t < 4; ++t) {
      int ay = t >> 1, ax = t & 1;
      int gy = Y + py - ay, gx = X + px - ax;
      bool ok = (gy >= 0 && gy < Hi && gx >= 0 && gx < Wi);
      int gyc = min(max(gy, 0), Hi - 1), gxc = min(max(gx, 0), Wi - 1);
      if (SPLITIN) {
        int q = ((gyc & 1) << 1) | (gxc & 1);
        offT[t] = q * (256 * Ci * HWq) + b * Ci * HWq + (gyc >> 1) * Wiq + (gxc >> 1);
      } else {
        offT[t] = b * Ci * HW + gyc * Wi + gxc;
      }
      mskT[t] = ok ? 0xffffffffu : 0u;
    }
  }
  const int stepCi = SPLITIN ? HWq : HW;

  auto gA = [&](int kb, u32 v[][8]) {
#pragma unroll
    for (int p = 0; p < MS; ++p) {
      int oc = oc0 + (p << 1);
      int cibase = ((kb >> 2) + (oc << 1)) * stepCi;
#pragma unroll
      for (int e = 0; e < 8; ++e) {
        int t = e & 3;
        v[p][e] = in[offT[t] + cibase + ((e >> 2) ? stepCi : 0)] & mskT[t];
      }
    }
  };
  auto gB = [&](int kb, uint4* d) {
    int n = tid & 63, oc2 = tid >> 6;
    size_t base = (size_t)(par * Co + n0 + n) * K4 + kb + (oc2 << 3);
    d[0] = *reinterpret_cast<const uint4*>(wth + base);
    d[1] = *reinterpret_cast<const uint4*>(wtl + base);
  };

  u32 vA[MS][8], vA2[MS][8];
  uint4 vB[2], vB2[2];
  gA(0, vA); gB(0, vB);
  for (int kb = 0; kb < K4; kb += 32) {
    const bool more = (kb + 32) < K4;
    if (more) { gA(kb + 32, vA2); gB(kb + 32, vB2); }
#pragma unroll
    for (int p = 0; p < MS; ++p) {
      const u32* v = vA[p];
      const int sw = cl & 7;
      int oc = oc0 + (p << 1);
      uint4 dh, dl;
      dh.x = (v[0] & 0xffffu) | (v[1] << 16);  dl.x = (v[0] >> 16) | (v[1] & 0xffff0000u);
      dh.y = (v[2] & 0xffffu) | (v[3] << 16);  dl.y = (v[2] >> 16) | (v[3] & 0xffff0000u);
      dh.z = (v[4] & 0xffffu) | (v[5] << 16);  dl.z = (v[4] >> 16) | (v[5] & 0xffff0000u);
      dh.w = (v[6] & 0xffffu) | (v[7] << 16);  dl.w = (v[6] >> 16) | (v[7] & 0xffff0000u);
      *reinterpret_cast<uint4*>(&AL[cl * ST + ((oc ^ sw) << 2)]) = dh;
      *reinterpret_cast<uint4*>(&AL[cl * ST + (((4 | oc) ^ sw) << 2)]) = dl;
    }
    {
      int n = tid & 63, oc2 = tid >> 6;
      stWp<ST>(BL, n, oc2, 0, vB[0]);
      stWp<ST>(BL, n, oc2, 1, vB[1]);
    }
    __syncthreads();
    short8v a_[MS][2];
#pragma unroll
    for (int mm = 0; mm < MS; ++mm)
#pragma unroll
      for (int s = 0; s < 2; ++s)
        a_[mm][s] = rdFrag<ST>(AL, (wv * MS + mm) * 16 + r, (s << 2) | g);
#pragma unroll
    for (int ns = 0; ns < 4; ++ns) {
      short8v b_[2];
#pragma unroll
      for (int s = 0; s < 2; ++s) b_[s] = rdFrag<ST>(BL, (ns << 4) + r, (s << 2) | g);
#pragma unroll
      for (int mm = 0; mm < MS; ++mm) {
        acc[mm][ns] = __builtin_amdgcn_mfma_f32_16x16x32_bf16(a_[mm][0], b_[0], acc[mm][ns], 0, 0, 0);
        acc[mm][ns] = __builtin_amdgcn_mfma_f32_16x16x32_bf16(a_[mm][0], b_[1], acc[mm][ns], 0, 0, 0);
        acc[mm][ns] = __builtin_amdgcn_mfma_f32_16x16x32_bf16(a_[mm][1], b_[0], acc[mm][ns], 0, 0, 0);
      }
    }
    __syncthreads();
    if (more) {
#pragma unroll
      for (int p = 0; p < MS; ++p)
#pragma unroll
        for (int e = 0; e < 8; ++e) vA[p][e] = vA2[p][e];
      vB[0] = vB2[0]; vB[1] = vB2[1];
    }
  }
  // ---- epilogue: two 32-col phases through the (reused) main LDS region ----
  const size_t QO = (size_t)256 * Co * HW;
  u32* op = outq + (size_t)par * QO;
  constexpr int C4N = BM / 4;
  constexpr int NCH = (BM * 32) / (TPB * 4);
#pragma unroll
  for (int ph = 0; ph < 2; ++ph) {
    __syncthreads();
#pragma unroll
    for (int mm = 0; mm < MS; ++mm)
#pragma unroll
      for (int nn = 0; nn < 2; ++nn) {
        int ns = (ph << 1) + nn;
#pragma unroll
        for (int q = 0; q < 4; ++q) {
          int cell = (wv * MS + mm) * 16 + (g << 2) + q;
          int colL = (nn << 4) + r;
          float v = acc[mm][ns][q] + bias[n0 + (ph << 5) + colL];
          if (relu) v = fmaxf(v, 0.f);
          L[colL * STC + cell] = EMIT ? packhl(v) : __float_as_uint(v);
        }
      }
    __syncthreads();
#pragma unroll
    for (int it = 0; it < NCH; ++it) {
      int lin = it * TPB + tid;
      int c4 = lin & (C4N - 1);
      int colL = lin / C4N;
      int col = (ph << 5) + colL;
      int cell0 = c4 << 2;
      uint4 d = *reinterpret_cast<const uint4*>(&L[colL * STC + cell0]);
      int gc = m0 + cell0;
      int Xo = gc & (Wi - 1), Yo = (gc >> lwi) & (Wi - 1), bo = gc >> (lwi + lwi);
      *reinterpret_cast<uint4*>(
          &op[((size_t)(bo * Co + n0 + col) * Hi + Yo) * Wi + Xo]) = d;
    }
  }
}

// ---------------- dedicated t3 ----------------------------------------------
__global__ __launch_bounds__(TPB) void convt3_kernel(
    const float* __restrict__ inq, const float* __restrict__ w,
    float* __restrict__ part)
{
  __shared__ float wl[3072];
  __shared__ float il[8][33 * 32];
  const int b = blockIdx.x;
  const int z = blockIdx.y;
  const int tid = threadIdx.x;
  for (int i = tid; i < 3072; i += TPB) wl[i] = w[i];
  const int Y = tid >> 3;
  const int X0 = (tid & 7) << 2;
  float acc[3][2][8];
#pragma unroll
  for (int o = 0; o < 3; ++o)
#pragma unroll
    for (int p = 0; p < 2; ++p)
#pragma unroll
      for (int q = 0; q < 8; ++q) acc[o][p][q] = 0.f;

  const int cbeg = z << 5, cend = cbeg + 32;
  for (int c0 = cbeg; c0 < cend; c0 += 8) {
    __syncthreads();
    for (int i = tid; i < 8192; i += TPB) {
      int cc = i >> 10, yy = (i >> 5) & 31, xx = i & 31;
      int q = ((yy & 1) << 1) | (xx & 1);
      il[cc][yy * 33 + xx] = inq[(size_t)q * 4194304 +
          (((size_t)b * 64 + c0 + cc) * 16 + (yy >> 1)) * 16 + (xx >> 1)];
    }
    __syncthreads();
    for (int cc = 0; cc < 8; ++cc) {
      float iv[3][6];
#pragma unroll
      for (int j = 0; j < 3; ++j) {
        int gy = Y - 1 + j;
        int gyc = min(max(gy, 0), 31);
        float my = (gy >= 0 && gy < 32) ? 1.f : 0.f;
#pragma unroll
        for (int k = 0; k < 6; ++k) {
          int gx = X0 - 1 + k;
          int gxc = min(max(gx, 0), 31);
          float mx = (gx >= 0 && gx < 32) ? 1.f : 0.f;
          iv[j][k] = il[cc][gyc * 33 + gxc] * (my * mx);
        }
      }
      const float* wq = &wl[(c0 + cc) * 48];
#pragma unroll
      for (int o = 0; o < 3; ++o) {
        const float* wo = wq + o * 16;
#pragma unroll
        for (int c = 0; c < 4; ++c) {
          acc[o][0][2*c]   = fmaf(iv[1][c+1], wo[5],  acc[o][0][2*c]);
          acc[o][0][2*c]   = fmaf(iv[1][c],   wo[7],  acc[o][0][2*c]);
          acc[o][0][2*c]   = fmaf(iv[0][c+1], wo[13], acc[o][0][2*c]);
          acc[o][0][2*c]   = fmaf(iv[0][c],   wo[15], acc[o][0][2*c]);
          acc[o][0][2*c+1] = fmaf(iv[1][c+2], wo[4],  acc[o][0][2*c+1]);
          acc[o][0][2*c+1] = fmaf(iv[1][c+1], wo[6],  acc[o][0][2*c+1]);
          acc[o][0][2*c+1] = fmaf(iv[0][c+2], wo[12], acc[o][0][2*c+1]);
          acc[o][0][2*c+1] = fmaf(iv[0][c+1], wo[14], acc[o][0][2*c+1]);
          acc[o][1][2*c]   = fmaf(iv[2][c+1], wo[1],  acc[o][1][2*c]);
          acc[o][1][2*c]   = fmaf(iv[2][c],   wo[3],  acc[o][1][2*c]);
          acc[o][1][2*c]   = fmaf(iv[1][c+1], wo[9],  acc[o][1][2*c]);
          acc[o][1][2*c]   = fmaf(iv[1][c],   wo[11], acc[o][1][2*c]);
          acc[o][1][2*c+1] = fmaf(iv[2][c+2], wo[0],  acc[o][1][2*c+1]);
          acc[o][1][2*c+1] = fmaf(iv[2][c+1], wo[2],  acc[o][1][2*c+1]);
          acc[o][1][2*c+1] = fmaf(iv[1][c+2], wo[8],  acc[o][1][2*c+1]);
          acc[o][1][2*c+1] = fmaf(iv[1][c+1], wo[10], acc[o][1][2*c+1]);
        }
      }
    }
  }
  float* pz = part + (size_t)z * 3145728;
#pragma unroll
  for (int o = 0; o < 3; ++o) {
#pragma unroll
    for (int p = 0; p < 2; ++p) {
      float* op = pz + (((size_t)b * 3 + o) * 64 + 2 * Y + p) * 64 + 2 * X0;
      *reinterpret_cast<float4*>(op) =
          make_float4(acc[o][p][0], acc[o][p][1], acc[o][p][2], acc[o][p][3]);
      *reinterpret_cast<float4*>(op + 4) =
          make_float4(acc[o][p][4], acc[o][p][5], acc[o][p][6], acc[o][p][7]);
    }
  }
}

__global__ __launch_bounds__(TPB) void c3_combine(
    const float* __restrict__ part, const float* __restrict__ bias,
    float* __restrict__ out)
{
  int i4 = (blockIdx.x * TPB + threadIdx.x) << 2;
  const float4 p0 = *reinterpret_cast<const float4*>(&part[i4]);
  const float4 p1 = *reinterpret_cast<const float4*>(&part[i4 + 3145728]);
  int o = (i4 >> 12) % 3;
  float bv = bias[o];
  float4 s = make_float4(p0.x + p1.x + bv, p0.y + p1.y + bv,
                         p0.z + p1.z + bv, p0.w + p1.w + bv);
  *reinterpret_cast<float4*>(&out[i4]) = s;
}

// ---------------- VQ: 8 rows/block, LDS-transposed codebook ------------------
// Wave wid handles rows r0+wid (rep0) and r0+4+wid (rep1): z value is a
// wave-uniform LDS broadcast; cbL[k][code] read lane-minor (conflict-free).
// Strict-< scan in ascending code order + shfl argmin => JAX first-min.
__global__ __launch_bounds__(TPB) void vq8_kernel(
    const float* __restrict__ z, const float* __restrict__ cb,
    float* __restrict__ e, float* __restrict__ rowloss)
{
  __shared__ float cbL[64][65];
  __shared__ float zr[8][64];
  const int tid = threadIdx.x;
  const int lane = tid & 63, wid = tid >> 6;
  const int r0 = blockIdx.x << 3;

  for (int i = tid; i < 512; i += TPB) {
    int rr = i >> 6, k = i & 63;
    int row = r0 + rr;
    int b = row >> 4, s = row & 15;
    zr[rr][k] = z[(size_t)b * 1536 + s * 64 + k];
  }

  float best[2] = {3.4e38f, 3.4e38f};
  int bi[2] = {0, 0};

  for (int c0 = 0; c0 < 512; c0 += 64) {
    __syncthreads();
#pragma unroll
    for (int i = 0; i < 4; ++i) {
      int j = (tid >> 4) + (i << 4);
      int kq = tid & 15;
      const float4 v = *reinterpret_cast<const float4*>(
          &cb[(size_t)(c0 + j) * 64 + (kq << 2)]);
      cbL[(kq << 2) + 0][j] = v.x;
      cbL[(kq << 2) + 1][j] = v.y;
      cbL[(kq << 2) + 2][j] = v.z;
      cbL[(kq << 2) + 3][j] = v.w;
    }
    __syncthreads();
#pragma unroll
    for (int rep = 0; rep < 2; ++rep) {
      const float* zp = zr[wid + (rep << 2)];
      float d = 0.f;
#pragma unroll
      for (int k = 0; k < 64; ++k) {
        float t = zp[k] - cbL[k][lane];
        d = fmaf(t, t, d);
      }
      if (d < best[rep]) { best[rep] = d; bi[rep] = c0 + lane; }
    }
  }
  // 64-lane argmin reduce (tie-break: smaller index)
#pragma unroll
  for (int rep = 0; rep < 2; ++rep) {
#pragma unroll
    for (int off = 32; off > 0; off >>= 1) {
      float ob = __shfl_xor(best[rep], off);
      int   oi = __shfl_xor(bi[rep], off);
      if (ob < best[rep] || (ob == best[rep] && oi < bi[rep])) {
        best[rep] = ob; bi[rep] = oi;
      }
    }
    int row = r0 + wid + (rep << 2);
    int b = row >> 4, s = row & 15;
    e[(size_t)b * 1536 + s * 64 + lane] = cb[(size_t)bi[rep] * 64 + lane];
    if (lane == 0) rowloss[row] = best[rep];
  }
}

__global__ __launch_bounds__(TPB) void zs_copy_kernel(
    const float* __restrict__ z, float* __restrict__ e)
{
  int i = blockIdx.x * TPB + threadIdx.x;
  int b = i >> 9, k = i & 511;
  e[(size_t)b * 1536 + 1024 + k] = z[(size_t)b * 1536 + 1024 + k];
}

__global__ __launch_bounds__(TPB) void loss_reduce_kernel(
    const float* __restrict__ rl, float* __restrict__ out)
{
  __shared__ float sm[TPB];
  float s = 0.f;
  for (int i = threadIdx.x; i < 4096; i += TPB) s += rl[i];
  sm[threadIdx.x] = s;
  __syncthreads();
  for (int sft = 128; sft > 0; sft >>= 1) {
    if (threadIdx.x < sft) sm[threadIdx.x] += sm[threadIdx.x + sft];
    __syncthreads();
  }
  if (threadIdx.x == 0) out[0] = sm[0] * (1.25f / 262144.f);
}

// ============================================================================
extern "C" void kernel_launch(void* const* d_in, const int* in_sizes, int n_in,
                              void* d_out, int out_size, void* d_ws, size_t ws_size,
                              hipStream_t stream)
{
  const float* x    = (const float*)d_in[0];
  const float* ew0  = (const float*)d_in[1];
  const float* eb0  = (const float*)d_in[2];
  const float* ew1  = (const float*)d_in[3];
  const float* eb1  = (const float*)d_in[4];
  const float* ew2  = (const float*)d_in[5];
  const float* eb2  = (const float*)d_in[6];
  const float* ew3  = (const float*)d_in[7];
  const float* eb3  = (const float*)d_in[8];
  const float* fw0  = (const float*)d_in[9];
  const float* fb0  = (const float*)d_in[10];
  const float* fw1  = (const float*)d_in[11];
  const float* fb1  = (const float*)d_in[12];
  const float* fw2  = (const float*)d_in[13];
  const float* fb2  = (const float*)d_in[14];
  const float* cb   = (const float*)d_in[15];
  const float* gw0  = (const float*)d_in[16];
  const float* gb0  = (const float*)d_in[17];
  const float* gw1  = (const float*)d_in[18];
  const float* gb1  = (const float*)d_in[19];
  const float* gw2  = (const float*)d_in[20];
  const float* gb2  = (const float*)d_in[21];
  const float* tw0  = (const float*)d_in[22];
  const float* tb0  = (const float*)d_in[23];
  const float* tw1  = (const float*)d_in[24];
  const float* tb1  = (const float*)d_in[25];
  const float* tw2  = (const float*)d_in[26];
  const float* tb2  = (const float*)d_in[27];
  const float* tw3  = (const float*)d_in[28];
  const float* tb3  = (const float*)d_in[29];

  float* out = (float*)d_out;
  float* ws  = (float*)d_ws;

  // ---- workspace plan (float offsets; time-disjoint regions) ----
  u16*   WE0  = (u16*)(ws + 0);
  u16*   WE1  = (u16*)(ws + 4608);
  u16*   WE2  = (u16*)(ws + 102912);
  u16*   WE3  = (u16*)(ws + 299520);
  float* RL   = ws + 1085952;
  float* H0P  = ws + 1090048;
  float* PC1  = ws + 20029952;
  float* XP   = ws + 20029952;
  float* H1P  = ws + 1090048;
  float* PC23 = ws + 6398464;
  float* H2P  = ws + 14787072;
  float* H3   = ws + 18063872;
  float* P    = ws + 1090048;
  float* F0   = ws + 5284352;
  float* F1   = ws + 5546496;
  float* Z    = ws + 5808640;
  float* E    = ws + 6201856;
  float* G0   = ws + 6595072;
  float* G1   = ws + 6726144;
  float* T2S  = ws + 1090048;
  u16*   WT0h = (u16*)(ws + 17867264);
  u16*   WT0l = (u16*)(ws + 18129408);
  u16*   WT1h = (u16*)(ws + 18391552);
  u16*   WT1l = (u16*)(ws + 18457088);
  u16*   WT2h = (u16*)(ws + 18522624);
  u16*   WT2l = (u16*)(ws + 18555392);
  float* PG2  = ws + 18588160;
  u32*   G2P  = (u32*)(ws + 20685312);
  u32*   T0S  = (u32*)(ws + 21733888);
  u32*   T1S  = (u32*)(ws + 23831040);
  float* PT3  = ws + 18588160;

  // ---- encoder weight prep + input pad ----
  wsplit3_k<<<dim3(12),  TPB, 0, stream>>>(ew0, WE0, 3072);
  wsplit3_k<<<dim3(256), TPB, 0, stream>>>(ew1, WE1, 65536);
  wsplit3_k<<<dim3(512), TPB, 0, stream>>>(ew2, WE2, 131072);
  wsplit3_k<<<dim3(1024),TPB, 0, stream>>>(ew3, WE3, 524288);
  x_pad_k<<<dim3(13068), TPB, 0, stream>>>(x, XP);
  zb0_k<<<dim3(8448), TPB, 0, stream>>>(H0P);

  // ---- encoder convs (A-direct MFMA NS=3) ----
  conv_ad<4,0><<<dim3(1024, 1, 1), TPB, 0, stream>>>(
      XP, WE0, eb0, H0P, 3, 64, 64, 5, 1, 48, 3072, 13068, 4356, 0);
  conv_ad<4,1><<<dim3(256, 1, 2), TPB, 0, stream>>>(
      H0P, WE1, eb1, PC1, 64, 64, 32, 4, 1, 512, 65536, 73984, 1156, 65536);
  combine_cm_k<<<dim3(20736), TPB, 0, stream>>>(PC1, eb1, H1P);
  conv_ad<4,1><<<dim3(64, 2, 4), TPB, 0, stream>>>(
      H1P, WE2, eb2, PC23, 64, 128, 16, 3, 1, 256, 131072, 324, 82944, 16384);
  combine_pad_k<<<dim3(12800), TPB, 0, stream>>>(PC23, eb2, H2P);
  conv_ad<4,1><<<dim3(16, 4, 8), TPB, 0, stream>>>(
      H2P, WE3, eb3, PC23, 128, 256, 8, 2, 0, 256, 524288, 12800, 100, 4096);
  conv_combine<<<dim3(1024), TPB, 0, stream>>>(PC23, eb3, H3, 4096, 256, 8, 2, 0);

  // ---- encoder FC (MFMA NS=3, split-K + combine) ----
  gemm_mf<3,0><<<dim3(4, 16, 16), TPB, 0, stream>>>(H3, fw0, fb0, (void*)P, 256, 4096, 1024, 256);
  combine_k<<<dim3(256), TPB, 0, stream>>>(P, fb0, F0, 262144, 1024, 16, 1);
  gemm_mf<3,0><<<dim3(4, 16, 8), TPB, 0, stream>>>(F0, fw1, fb1, (void*)P, 256, 1024, 1024, 128);
  combine_k<<<dim3(256), TPB, 0, stream>>>(P, fb1, F1, 262144, 1024, 8, 1);
  gemm_mf<3,0><<<dim3(4, 24, 8), TPB, 0, stream>>>(F1, fw2, fb2, (void*)P, 256, 1024, 1536, 128);
  combine_k<<<dim3(384), TPB, 0, stream>>>(P, fb2, Z, 393216, 1536, 8, 0);

  // ---- VQ ----
  vq8_kernel<<<dim3(512), TPB, 0, stream>>>(Z, cb, E, RL);
  zs_copy_kernel<<<dim3(512), TPB, 0, stream>>>(Z, E);
  loss_reduce_kernel<<<dim3(1), TPB, 0, stream>>>(RL, out + (size_t)out_size - 1);

  // ---- decoder FC (MFMA NS=2 split-K + combine) ----
  gemm_mf<2,0><<<dim3(4, 8, 8), TPB, 0, stream>>>(E,  gw0, gb0, (void*)P, 256, 1536, 512, 192);
  combine_k<<<dim3(128), TPB, 0, stream>>>(P, gb0, G0, 131072, 512, 8, 1);
  gemm_mf<2,0><<<dim3(4, 16, 4), TPB, 0, stream>>>(G0, gw1, gb1, (void*)P, 256, 512, 1024, 128);
  combine_k<<<dim3(256), TPB, 0, stream>>>(P, gb1, G1, 262144, 1024, 4, 1);

  // ---- decoder weight prep ----
  wprep2_k<<<dim3(512), TPB, 0, stream>>>(tw0, WT0h, WT0l, 256, 128);
  wprep2_k<<<dim3(128), TPB, 0, stream>>>(tw1, WT1h, WT1l, 128, 64);
  wprep2_k<<<dim3(64),  TPB, 0, stream>>>(tw2, WT2h, WT2l, 64, 64);

  // g2: split-K z2 -> PG2; combine -> packed G2P
  gemm_mf<2,0><<<dim3(4, 64, 2), TPB, 0, stream>>>(G1, gw2, gb2, (void*)PG2, 256, 1024, 4096, 512);
  combine_pk_k<<<dim3(1024), TPB, 0, stream>>>(PG2, gb2, G2P);

  // ---- decoder transposed convs (MFMA NS=2, quadrant layouts) ----
  convt_mf2<64,1,0><<<dim3(64, 2, 4),   TPB, 0, stream>>>(G2P, WT0h, WT0l, tb0, T0S, 256, 128, 4,  2, 1);
  convt_mf2<128,1,1><<<dim3(128, 1, 4), TPB, 0, stream>>>(T0S, WT1h, WT1l, tb1, T1S, 128, 64,  8,  3, 1);
  convt_mf2<128,0,1><<<dim3(512, 1, 4), TPB, 0, stream>>>(T1S, WT2h, WT2l, tb2, (u32*)T2S, 64, 64, 16, 4, 1);
  convt3_kernel<<<dim3(256, 2), TPB, 0, stream>>>(T2S, tw3, PT3);
  c3_combine<<<dim3(3072), TPB, 0, stream>>>(PT3, tb3, out);
}